// Round 10
// baseline (2033.030 us; speedup 1.0000x reference)
//
#include <hip/hip_runtime.h>
#include <math.h>

#define B_ 4
#define C_ 128
#define HW_ 65536
#define H__ 256
#define KF_ 129
#define PLANEF_ 33024
#define PLD_ 257   // padded plane row stride (words)

typedef __attribute__((ext_vector_type(8))) short short8v;
typedef __attribute__((ext_vector_type(4))) float f32x4;
typedef __attribute__((ext_vector_type(4))) unsigned short ush4;
typedef __attribute__((ext_vector_type(8))) unsigned short ush8;

__device__ __forceinline__ unsigned short f2bf(float f) {
    union { float f; unsigned u; } v; v.f = f;
    return (unsigned short)((v.u + 0x7FFFu + ((v.u >> 16) & 1u)) >> 16);
}
__device__ __forceinline__ float bf2f(unsigned short s) {
    union { unsigned u; float f; } v; v.u = (unsigned)s << 16;
    return v.f;
}
__device__ __forceinline__ unsigned pack2bf(float2 v) {
    return (unsigned)f2bf(v.x) | ((unsigned)f2bf(v.y) << 16);
}
__device__ __forceinline__ float2 upk(unsigned u) {
    return make_float2(bf2f((unsigned short)(u & 0xffff)), bf2f((unsigned short)(u >> 16)));
}
// fast gelu: A&S 7.1.26 erf (|err|<=1.5e-7) with __expf
__device__ __forceinline__ float geluf(float x) {
    float z = 0.70710678118654752f * fabsf(x);
    float t = __fdividef(1.f, fmaf(0.3275911f, z, 1.f));
    float p = fmaf(1.061405429f, t, -1.453152027f);
    p = fmaf(p, t, 1.421413741f);
    p = fmaf(p, t, -0.284496736f);
    p = fmaf(p, t, 0.254829592f);
    p = p * t;
    float erfv = 1.f - p * __expf(-z * z);
    float cdf = (x >= 0.f) ? fmaf(0.5f, erfv, 0.5f) : fmaf(-0.5f, erfv, 0.5f);
    return x * cdf;
}
// fast atan2, poly err ~1e-5 rad
__device__ __forceinline__ float fatan2(float y, float x) {
    float ax = fabsf(x), ay = fabsf(y);
    float mx = fmaxf(ax, ay), mn = fminf(ax, ay);
    float a = __fdividef(mn, fmaxf(mx, 1e-38f));
    float s = a * a;
    float r = fmaf(0.0208351f, s, -0.0851330f);
    r = fmaf(r, s, 0.1801410f);
    r = fmaf(r, s, -0.3302995f);
    r = fmaf(r, s, 0.9998660f);
    r = r * a;
    if (ay > ax) r = 1.57079632679489662f - r;
    if (x < 0.f) r = 3.14159265358979324f - r;
    return copysignf(r, y);
}
// LDS XOR swizzle on byte-offset within row
template<int W>
__device__ __forceinline__ char* swz_ptr(unsigned short (*xs)[W], int px, int cb) {
    return (char*)xs + px * (W * 2) + (cb ^ (((px >> 2) & 7) << 4));
}

// ---------------------------------------------------------------- prep
__global__ __launch_bounds__(256) void tobf16_kernel(const float* __restrict__ src,
                                                     unsigned short* __restrict__ dst, int n)
{
    int i = blockIdx.x * 256 + threadIdx.x;
    if (i < n) dst[i] = f2bf(src[i]);
}

__global__ __launch_bounds__(128) void foldln_kernel(const float* __restrict__ W,
                                                     const float* __restrict__ lnw,
                                                     const float* __restrict__ lnb,
                                                     unsigned short* __restrict__ Wb,
                                                     float* __restrict__ wsum, float* __restrict__ bsum,
                                                     int Cc)
{
    int o = blockIdx.x, t = threadIdx.x;
    float sw = 0.f, sb = 0.f;
    for (int c = t; c < Cc; c += 128) {
        float w = W[(size_t)o * Cc + c];
        float fw = w * lnw[c];
        unsigned short us = f2bf(fw);
        Wb[(size_t)o * Cc + c] = us;
        sw += bf2f(us);
        sb += w * lnb[c];
    }
    __shared__ float r1[128], r2[128];
    r1[t] = sw; r2[t] = sb; __syncthreads();
    for (int st = 64; st; st >>= 1) {
        if (t < st) { r1[t] += r1[t + st]; r2[t] += r2[t + st]; }
        __syncthreads();
    }
    if (!t) { wsum[o] = r1[0]; bsum[o] = r2[0]; }
}

__global__ __launch_bounds__(256) void poutperm_kernel(const float* __restrict__ src,
                                                       unsigned short* __restrict__ dst)
{
    int i = blockIdx.x * 256 + threadIdx.x;   // 32768
    int half = i >> 14, rem = i & 16383, o = rem >> 7, kp = rem & 127;
    int h = (kp >> 5) * 64 + half * 32 + (kp & 31);
    dst[i] = f2bf(src[o * 256 + h]);
}

__global__ void pinc_kernel(const float* __restrict__ bb, const float* __restrict__ ws,
                            float4* __restrict__ pinC)
{
    int i = threadIdx.x;
    if (i < 256) pinC[i] = make_float4(bb[i], ws[i], bb[i + 256], ws[i + 256]);
}

__global__ void ksum_kernel(const float* __restrict__ dw, float* __restrict__ ks)
{
    int c = threadIdx.x;
    if (c < C_) {
        float s = 0.f;
        for (int k = 0; k < 9; ++k) s += dw[c * 9 + k];
        ks[c] = s;
    }
}

__global__ __launch_bounds__(256) void zero2_kernel(float* __restrict__ a, float* __restrict__ b, int n)
{
    int i = blockIdx.x * 256 + threadIdx.x;
    if (i < n) { a[i] = 0.f; b[i] = 0.f; }
}

// ---------------------------------------------------------------- MFMA conv1x1 (CIN=128)
// INBF: input dtype 0=f32 1=bf16. OUTBF: output dtype. PRO==1: leaky(0.1) on staged value.
// LNF: register LN stats + folded-affine epilogue (requires INBF=0). flags&1: +1e-8 after bias.
template<int INBF, int OUTBF, int PRO, bool LNF>
__global__ __launch_bounds__(256, 4) void mconv2(
    const void* __restrict__ Xv, size_t sx,
    const unsigned short* __restrict__ Wb, int wstride,
    const float* __restrict__ bias,
    const float* __restrict__ res, size_t sres,
    void* __restrict__ Yv, size_t sy, int plane, int flags,
    const float* __restrict__ wsum, const float* __restrict__ bsum)
{
    __shared__ unsigned short xs[128][136];
    __shared__ float2 lnred[LNF ? 8 : 1][LNF ? 128 : 1];
    __shared__ float2 lnmi[LNF ? 128 : 1];
    const int t = threadIdx.x;
    const int bz = blockIdx.z;
    const int p0 = blockIdx.x * 128;
    const int lane = t & 63;
    const int wr = t >> 7, wc = (t >> 6) & 1;
    const int lr = lane >> 4, lc = lane & 15;

    if constexpr (INBF == 0) {
        const float* Xb = (const float*)Xv + (size_t)bz * sx;
        const int px4 = t & 31;
        float s0 = 0.f, s1 = 0.f, s2v = 0.f, s3 = 0.f;
        float q0 = 0.f, q1 = 0.f, q2 = 0.f, q3 = 0.f;
#pragma unroll
        for (int g = 0; g < 2; ++g) {
            float4 st[8];
#pragma unroll
            for (int i = 0; i < 8; ++i) {
                int e = t + (g * 8 + i) * 256;           // 4096 items: 128c x 32 px4
                int c = e >> 5;
                st[i] = *(const float4*)(Xb + (size_t)c * plane + p0 + px4 * 4);
            }
#pragma unroll
            for (int i = 0; i < 8; ++i) {
                int e = t + (g * 8 + i) * 256;
                int c = e >> 5;
                float a0 = st[i].x, a1 = st[i].y, a2 = st[i].z, a3 = st[i].w;
                if constexpr (PRO == 1) {
                    a0 = a0 > 0.f ? a0 : 0.1f * a0;
                    a1 = a1 > 0.f ? a1 : 0.1f * a1;
                    a2 = a2 > 0.f ? a2 : 0.1f * a2;
                    a3 = a3 > 0.f ? a3 : 0.1f * a3;
                }
                if constexpr (LNF) {
                    s0 += a0; q0 += a0 * a0;
                    s1 += a1; q1 += a1 * a1;
                    s2v += a2; q2 += a2 * a2;
                    s3 += a3; q3 += a3 * a3;
                }
                *(unsigned short*)swz_ptr(xs, px4 * 4 + 0, 2 * c) = f2bf(a0);
                *(unsigned short*)swz_ptr(xs, px4 * 4 + 1, 2 * c) = f2bf(a1);
                *(unsigned short*)swz_ptr(xs, px4 * 4 + 2, 2 * c) = f2bf(a2);
                *(unsigned short*)swz_ptr(xs, px4 * 4 + 3, 2 * c) = f2bf(a3);
            }
        }
        if constexpr (LNF) {
            lnred[t >> 5][px4 * 4 + 0] = make_float2(s0, q0);
            lnred[t >> 5][px4 * 4 + 1] = make_float2(s1, q1);
            lnred[t >> 5][px4 * 4 + 2] = make_float2(s2v, q2);
            lnred[t >> 5][px4 * 4 + 3] = make_float2(s3, q3);
        }
    } else {
        const unsigned short* Xb = (const unsigned short*)Xv + (size_t)bz * sx;
        ush8 st[8];
#pragma unroll
        for (int i = 0; i < 8; ++i) {
            int e = t + i * 256;                         // 2048 items: 128c x 16 px8
            int c = e >> 4, px8 = e & 15;
            st[i] = *(const ush8*)(Xb + (size_t)c * plane + p0 + px8 * 8);
        }
#pragma unroll
        for (int i = 0; i < 8; ++i) {
            int e = t + i * 256;
            int c = e >> 4, px8 = e & 15;
#pragma unroll
            for (int j = 0; j < 8; ++j) {
                unsigned short us = (unsigned short)st[i][j];
                if constexpr (PRO == 1) {
                    float f = bf2f(us);
                    f = f > 0.f ? f : 0.1f * f;
                    us = f2bf(f);
                }
                *(unsigned short*)swz_ptr(xs, px8 * 8 + j, 2 * c) = us;
            }
        }
    }
    __syncthreads();
    if constexpr (LNF) {
        if (t < 128) {
            float ss = 0.f, qq = 0.f;
#pragma unroll
            for (int j = 0; j < 8; ++j) { float2 a = lnred[j][t]; ss += a.x; qq += a.y; }
            float m = ss * (1.f / 128.f);
            float inv = rsqrtf(qq * (1.f / 128.f) - m * m + 1e-5f);
            lnmi[t] = make_float2(m, inv);
        }
        __syncthreads();
    }

    f32x4 acc[4][4];
#pragma unroll
    for (int mi = 0; mi < 4; ++mi)
#pragma unroll
        for (int ni = 0; ni < 4; ++ni) acc[mi][ni] = (f32x4){0.f, 0.f, 0.f, 0.f};

#pragma unroll
    for (int kk = 0; kk < 128; kk += 32) {
        short8v bfr[4];
#pragma unroll
        for (int ni = 0; ni < 4; ++ni)
            bfr[ni] = *(const short8v*)swz_ptr(xs, wc * 64 + ni * 16 + lc, 2 * (kk + lr * 8));
#pragma unroll
        for (int mi = 0; mi < 4; ++mi) {
            int row = wr * 64 + mi * 16 + lc;
            short8v afr = *(const short8v*)(Wb + (size_t)row * wstride + kk + lr * 8);
#pragma unroll
            for (int ni = 0; ni < 4; ++ni)
                acc[mi][ni] = __builtin_amdgcn_mfma_f32_16x16x32_bf16(afr, bfr[ni], acc[mi][ni], 0, 0, 0);
        }
    }

    float2 mrow[4];
    if constexpr (LNF) {
#pragma unroll
        for (int ni = 0; ni < 4; ++ni) mrow[ni] = lnmi[wc * 64 + ni * 16 + lc];
    }

#pragma unroll
    for (int mi = 0; mi < 4; ++mi) {
        int ob = wr * 64 + mi * 16 + lr * 4;
#pragma unroll
        for (int r = 0; r < 4; ++r) {
            int o = ob + r;
            float bv = 0.f, wso = 0.f;
            if constexpr (LNF) { bv = bsum[o]; wso = wsum[o]; }
            else { if (bias) bv = bias[o]; if (flags & 1) bv += 1e-8f; }
#pragma unroll
            for (int ni = 0; ni < 4; ++ni) {
                int px = wc * 64 + ni * 16 + lc;
                float v;
                if constexpr (LNF) {
                    float m = mrow[ni].x, inv = mrow[ni].y;
                    v = acc[mi][ni][r] * inv + bv - m * inv * wso;
                } else {
                    v = acc[mi][ni][r] + bv;
                }
                if constexpr (OUTBF == 0) {
                    float* Y = (float*)Yv;
                    size_t yi = (size_t)bz * sy + (size_t)o * plane + p0 + px;
                    if (res) v += res[(size_t)bz * sres + (size_t)o * plane + p0 + px];
                    Y[yi] = v;
                } else {
                    unsigned short* Y = (unsigned short*)Yv;
                    Y[(size_t)bz * sy + (size_t)o * plane + p0 + px] = f2bf(v);
                }
            }
        }
    }
}

// ---------------------------------------------------------------- fused amp1+pha1+amp2+pha2 spectral block
__global__ __launch_bounds__(256, 2) void apconv2(
    const unsigned* __restrict__ T1, const unsigned* __restrict__ T2, size_t sT,
    const unsigned short* __restrict__ Wa1, const unsigned short* __restrict__ Wp1,  // [128][256]
    const unsigned short* __restrict__ Wa2, const unsigned short* __restrict__ Wp2,  // [128][128]
    const float* __restrict__ ba1, const float* __restrict__ bp1,
    const float* __restrict__ ba2, const float* __restrict__ bp2,
    unsigned short* __restrict__ AMP, unsigned short* __restrict__ PHA, size_t sO)
{
    __shared__ __align__(16) unsigned short buf[2][128][72];   // stage A: xa/xp ; stage B: [128][144]
    const int t = threadIdx.x;
    const int bz = blockIdx.z;
    const int p0 = blockIdx.x * 128;
    const int lane = t & 63;
    const int wr = t >> 7, wc = (t >> 6) & 1;
    const int lr = lane >> 4, lc = lane & 15;
    const int px2 = t & 63;

    typedef unsigned short (*row72)[72];
    typedef unsigned short (*row144)[144];
    row72 xa = (row72)buf[0];
    row72 xp = (row72)buf[1];
    row144 hb = (row144)&buf[0][0][0];

    f32x4 aa[4][4], ap[4][4];
#pragma unroll
    for (int mi = 0; mi < 4; ++mi)
#pragma unroll
        for (int ni = 0; ni < 4; ++ni) { aa[mi][ni] = (f32x4){0.f,0.f,0.f,0.f}; ap[mi][ni] = (f32x4){0.f,0.f,0.f,0.f}; }

    for (int ch = 0; ch < 256; ch += 64) {
        const unsigned* Ts = ((ch < 128) ? T1 : T2) + (size_t)bz * sT + (size_t)(ch & 127) * PLANEF_;
#pragma unroll
        for (int g = 0; g < 2; ++g) {
            uint2 st[8];
#pragma unroll
            for (int i = 0; i < 8; ++i) {
                int e = t + (g * 8 + i) * 256;       // 4096 items: 64c x 64 px2 (=128 px)
                int c = e >> 6;
                st[i] = *(const uint2*)(Ts + (size_t)c * PLANEF_ + p0 + px2 * 2);
            }
#pragma unroll
            for (int i = 0; i < 8; ++i) {
                int e = t + (g * 8 + i) * 256;
                int c = e >> 6;
                float2 z0 = upk(st[i].x), z1 = upk(st[i].y);
                float m0 = sqrtf(z0.x * z0.x + z0.y * z0.y);
                float m1 = sqrtf(z1.x * z1.x + z1.y * z1.y);
                float a0 = fatan2(z0.y, z0.x);
                float a1 = fatan2(z1.y, z1.x);
                *(unsigned short*)swz_ptr(xa, px2 * 2 + 0, 2 * c) = f2bf(m0);
                *(unsigned short*)swz_ptr(xa, px2 * 2 + 1, 2 * c) = f2bf(m1);
                *(unsigned short*)swz_ptr(xp, px2 * 2 + 0, 2 * c) = f2bf(a0);
                *(unsigned short*)swz_ptr(xp, px2 * 2 + 1, 2 * c) = f2bf(a1);
            }
        }
        __syncthreads();
#pragma unroll
        for (int kk = 0; kk < 64; kk += 32) {
            short8v bfa[4], bfp[4];
#pragma unroll
            for (int ni = 0; ni < 4; ++ni) {
                bfa[ni] = *(const short8v*)swz_ptr(xa, wc * 64 + ni * 16 + lc, 2 * (kk + lr * 8));
                bfp[ni] = *(const short8v*)swz_ptr(xp, wc * 64 + ni * 16 + lc, 2 * (kk + lr * 8));
            }
#pragma unroll
            for (int mi = 0; mi < 4; ++mi) {
                int row = wr * 64 + mi * 16 + lc;
                short8v afa = *(const short8v*)(Wa1 + (size_t)row * 256 + ch + kk + lr * 8);
                short8v afp = *(const short8v*)(Wp1 + (size_t)row * 256 + ch + kk + lr * 8);
#pragma unroll
                for (int ni = 0; ni < 4; ++ni) {
                    aa[mi][ni] = __builtin_amdgcn_mfma_f32_16x16x32_bf16(afa, bfa[ni], aa[mi][ni], 0, 0, 0);
                    ap[mi][ni] = __builtin_amdgcn_mfma_f32_16x16x32_bf16(afp, bfp[ni], ap[mi][ni], 0, 0, 0);
                }
            }
        }
        __syncthreads();
    }

    // ---- stage B (amp) ----
#pragma unroll
    for (int mi = 0; mi < 4; ++mi)
#pragma unroll
        for (int r = 0; r < 4; ++r) {
            int o = wr * 64 + mi * 16 + lr * 4 + r;
            float bva = ba1[o];
#pragma unroll
            for (int ni = 0; ni < 4; ++ni) {
                int px = wc * 64 + ni * 16 + lc;
                float v = aa[mi][ni][r] + bva;
                v = v > 0.f ? v : 0.1f * v;
                *(unsigned short*)swz_ptr(hb, px, 2 * o) = f2bf(v);
            }
        }
    __syncthreads();
    {
        f32x4 acc[4][4];
#pragma unroll
        for (int mi = 0; mi < 4; ++mi)
#pragma unroll
            for (int ni = 0; ni < 4; ++ni) acc[mi][ni] = (f32x4){0.f,0.f,0.f,0.f};
#pragma unroll
        for (int kk = 0; kk < 128; kk += 32) {
            short8v bfr[4];
#pragma unroll
            for (int ni = 0; ni < 4; ++ni)
                bfr[ni] = *(const short8v*)swz_ptr(hb, wc * 64 + ni * 16 + lc, 2 * (kk + lr * 8));
#pragma unroll
            for (int mi = 0; mi < 4; ++mi) {
                int row = wr * 64 + mi * 16 + lc;
                short8v afr = *(const short8v*)(Wa2 + (size_t)row * 128 + kk + lr * 8);
#pragma unroll
                for (int ni = 0; ni < 4; ++ni)
                    acc[mi][ni] = __builtin_amdgcn_mfma_f32_16x16x32_bf16(afr, bfr[ni], acc[mi][ni], 0, 0, 0);
            }
        }
#pragma unroll
        for (int mi = 0; mi < 4; ++mi)
#pragma unroll
            for (int r = 0; r < 4; ++r) {
                int o = wr * 64 + mi * 16 + lr * 4 + r;
                float bv = ba2[o];
#pragma unroll
                for (int ni = 0; ni < 4; ++ni) {
                    int px = wc * 64 + ni * 16 + lc;
                    AMP[(size_t)bz * sO + (size_t)o * PLANEF_ + p0 + px] = f2bf(acc[mi][ni][r] + bv);
                }
            }
    }
    __syncthreads();

    // ---- stage B (pha) ----
#pragma unroll
    for (int mi = 0; mi < 4; ++mi)
#pragma unroll
        for (int r = 0; r < 4; ++r) {
            int o = wr * 64 + mi * 16 + lr * 4 + r;
            float bvp = bp1[o];
#pragma unroll
            for (int ni = 0; ni < 4; ++ni) {
                int px = wc * 64 + ni * 16 + lc;
                float v = ap[mi][ni][r] + bvp;
                v = v > 0.f ? v : 0.1f * v;
                *(unsigned short*)swz_ptr(hb, px, 2 * o) = f2bf(v);
            }
        }
    __syncthreads();
    {
        f32x4 acc[4][4];
#pragma unroll
        for (int mi = 0; mi < 4; ++mi)
#pragma unroll
            for (int ni = 0; ni < 4; ++ni) acc[mi][ni] = (f32x4){0.f,0.f,0.f,0.f};
#pragma unroll
        for (int kk = 0; kk < 128; kk += 32) {
            short8v bfr[4];
#pragma unroll
            for (int ni = 0; ni < 4; ++ni)
                bfr[ni] = *(const short8v*)swz_ptr(hb, wc * 64 + ni * 16 + lc, 2 * (kk + lr * 8));
#pragma unroll
            for (int mi = 0; mi < 4; ++mi) {
                int row = wr * 64 + mi * 16 + lc;
                short8v afr = *(const short8v*)(Wp2 + (size_t)row * 128 + kk + lr * 8);
#pragma unroll
                for (int ni = 0; ni < 4; ++ni)
                    acc[mi][ni] = __builtin_amdgcn_mfma_f32_16x16x32_bf16(afr, bfr[ni], acc[mi][ni], 0, 0, 0);
            }
        }
#pragma unroll
        for (int mi = 0; mi < 4; ++mi)
#pragma unroll
            for (int r = 0; r < 4; ++r) {
                int o = wr * 64 + mi * 16 + lr * 4 + r;
                float bv = bp2[o];
#pragma unroll
                for (int ni = 0; ni < 4; ++ni) {
                    int px = wc * 64 + ni * 16 + lc;
                    PHA[(size_t)bz * sO + (size_t)o * PLANEF_ + p0 + px] = f2bf(acc[mi][ni][r] + bv);
                }
            }
    }
}

// ---------------------------------------------------------------- fused MFMA FFN (x f32, fre bf16)
__global__ __launch_bounds__(256, 3) void ffn_mfma5(
    const float* __restrict__ x, const unsigned short* __restrict__ fre,
    const unsigned short* __restrict__ pinb,    // [512][256] folded bf16
    const unsigned short* __restrict__ pout2,   // [2][128][128] permuted bf16
    const float4* __restrict__ pinC,            // [256] (bb1,ws1,bb2,ws2)
    float* __restrict__ out)
{
    __shared__ unsigned short xs[64][264];
    __shared__ unsigned short hs[64][136];
    __shared__ float2 muinv[64];
    float2* sred = (float2*)&hs[0][0];          // overlay: dead until GEMM1 epilogue
    const int b = blockIdx.y;
    const size_t p0 = (size_t)blockIdx.x * 64;
    const int t = threadIdx.x;
    const int wave = t >> 6, lane = t & 63;
    const int lr = lane >> 4, lc = lane & 15;
    const int px4 = t & 15;

    float s0 = 0.f, s1 = 0.f, s2v = 0.f, s3 = 0.f;
    float q0 = 0.f, q1 = 0.f, q2 = 0.f, q3 = 0.f;
    {
        float4 stx[8];
        ush4 stf[8];
#pragma unroll
        for (int i = 0; i < 8; ++i) {
            int e = t + i * 256;                 // 2048 items: 128c x 16 px4
            int c = e >> 4;
            stx[i] = *(const float4*)(x + ((size_t)b * 128 + c) * HW_ + p0 + px4 * 4);
        }
#pragma unroll
        for (int i = 0; i < 8; ++i) {
            int e = t + i * 256;
            int c = e >> 4;
            stf[i] = *(const ush4*)(fre + (size_t)b * 8388608 + (size_t)c * HW_ + p0 + px4 * 4);
        }
#pragma unroll
        for (int i = 0; i < 8; ++i) {
            int e = t + i * 256;
            int c = e >> 4;
            float a0 = stx[i].x, a1 = stx[i].y, a2 = stx[i].z, a3 = stx[i].w;
            s0 += a0; q0 += a0 * a0;
            s1 += a1; q1 += a1 * a1;
            s2v += a2; q2 += a2 * a2;
            s3 += a3; q3 += a3 * a3;
            *(unsigned short*)swz_ptr(xs, px4 * 4 + 0, 2 * c) = f2bf(a0);
            *(unsigned short*)swz_ptr(xs, px4 * 4 + 1, 2 * c) = f2bf(a1);
            *(unsigned short*)swz_ptr(xs, px4 * 4 + 2, 2 * c) = f2bf(a2);
            *(unsigned short*)swz_ptr(xs, px4 * 4 + 3, 2 * c) = f2bf(a3);
        }
#pragma unroll
        for (int i = 0; i < 8; ++i) {
            int e = t + i * 256;
            int c = e >> 4;
            float a0 = bf2f((unsigned short)stf[i][0]);
            float a1 = bf2f((unsigned short)stf[i][1]);
            float a2 = bf2f((unsigned short)stf[i][2]);
            float a3 = bf2f((unsigned short)stf[i][3]);
            s0 += a0; q0 += a0 * a0;
            s1 += a1; q1 += a1 * a1;
            s2v += a2; q2 += a2 * a2;
            s3 += a3; q3 += a3 * a3;
            *(unsigned short*)swz_ptr(xs, px4 * 4 + 0, 2 * (128 + c)) = (unsigned short)stf[i][0];
            *(unsigned short*)swz_ptr(xs, px4 * 4 + 1, 2 * (128 + c)) = (unsigned short)stf[i][1];
            *(unsigned short*)swz_ptr(xs, px4 * 4 + 2, 2 * (128 + c)) = (unsigned short)stf[i][2];
            *(unsigned short*)swz_ptr(xs, px4 * 4 + 3, 2 * (128 + c)) = (unsigned short)stf[i][3];
        }
    }
    sred[(t >> 4) * 64 + px4 * 4 + 0] = make_float2(s0, q0);
    sred[(t >> 4) * 64 + px4 * 4 + 1] = make_float2(s1, q1);
    sred[(t >> 4) * 64 + px4 * 4 + 2] = make_float2(s2v, q2);
    sred[(t >> 4) * 64 + px4 * 4 + 3] = make_float2(s3, q3);
    __syncthreads();
    if (t < 64) {
        float ss = 0.f, qq = 0.f;
#pragma unroll
        for (int j = 0; j < 16; ++j) { float2 a = sred[j * 64 + t]; ss += a.x; qq += a.y; }
        float m = ss * (1.f / 256.f);
        float inv = rsqrtf(qq * (1.f / 256.f) - m * m + 1e-5f);
        muinv[t] = make_float2(m, inv);
    }
    __syncthreads();

    float2 mrow[4];
#pragma unroll
    for (int ni = 0; ni < 4; ++ni) mrow[ni] = muinv[ni * 16 + lc];

    f32x4 oc[2][4];
#pragma unroll
    for (int mi = 0; mi < 2; ++mi)
#pragma unroll
        for (int ni = 0; ni < 4; ++ni) oc[mi][ni] = (f32x4){0.f, 0.f, 0.f, 0.f};

#pragma unroll
    for (int half = 0; half < 2; ++half) {
        f32x4 a1[2][4], a2[2][4];
#pragma unroll
        for (int mi = 0; mi < 2; ++mi)
#pragma unroll
            for (int ni = 0; ni < 4; ++ni) { a1[mi][ni] = (f32x4){0.f,0.f,0.f,0.f}; a2[mi][ni] = (f32x4){0.f,0.f,0.f,0.f}; }

#pragma unroll
        for (int k0 = 0; k0 < 256; k0 += 32) {
            short8v bfr[4];
#pragma unroll
            for (int ni = 0; ni < 4; ++ni)
                bfr[ni] = *(const short8v*)swz_ptr(xs, ni * 16 + lc, 2 * (k0 + lr * 8));
#pragma unroll
            for (int mi = 0; mi < 2; ++mi) {
                int hrow = wave * 64 + half * 32 + mi * 16 + lc;
                short8v af1 = *(const short8v*)(pinb + (size_t)hrow * 256 + k0 + lr * 8);
                short8v af2 = *(const short8v*)(pinb + (size_t)(hrow + 256) * 256 + k0 + lr * 8);
#pragma unroll
                for (int ni = 0; ni < 4; ++ni) {
                    a1[mi][ni] = __builtin_amdgcn_mfma_f32_16x16x32_bf16(af1, bfr[ni], a1[mi][ni], 0, 0, 0);
                    a2[mi][ni] = __builtin_amdgcn_mfma_f32_16x16x32_bf16(af2, bfr[ni], a2[mi][ni], 0, 0, 0);
                }
            }
        }
        __syncthreads();
#pragma unroll
        for (int mi = 0; mi < 2; ++mi)
#pragma unroll
            for (int r = 0; r < 4; ++r) {
                int ho = wave * 64 + half * 32 + mi * 16 + lr * 4 + r;
                float4 bwc = pinC[ho];
                int kp = wave * 32 + mi * 16 + lr * 4 + r;
#pragma unroll
                for (int ni = 0; ni < 4; ++ni) {
                    float m = mrow[ni].x, inv = mrow[ni].y;
                    float v1 = a1[mi][ni][r] * inv + bwc.x - m * inv * bwc.y;
                    float v2 = a2[mi][ni][r] * inv + bwc.z - m * inv * bwc.w;
                    hs[ni * 16 + lc][kp] = f2bf(geluf(v1) * v2);
                }
            }
        __syncthreads();
#pragma unroll
        for (int k0 = 0; k0 < 128; k0 += 32) {
            short8v bfr2[4];
#pragma unroll
            for (int ni = 0; ni < 4; ++ni)
                bfr2[ni] = *(const short8v*)&hs[ni * 16 + lc][k0 + lr * 8];
#pragma unroll
            for (int mi = 0; mi < 2; ++mi) {
                int orow = wave * 32 + mi * 16 + lc;
                short8v af = *(const short8v*)(pout2 + half * 16384 + orow * 128 + k0 + lr * 8);
#pragma unroll
                for (int ni = 0; ni < 4; ++ni)
                    oc[mi][ni] = __builtin_amdgcn_mfma_f32_16x16x32_bf16(af, bfr2[ni], oc[mi][ni], 0, 0, 0);
            }
        }
    }

#pragma unroll
    for (int mi = 0; mi < 2; ++mi)
#pragma unroll
        for (int r = 0; r < 4; ++r) {
            int o = wave * 32 + mi * 16 + lr * 4 + r;
#pragma unroll
            for (int ni = 0; ni < 4; ++ni) {
                size_t yi = ((size_t)b * 128 + o) * HW_ + p0 + ni * 16 + lc;
                out[yi] = oc[mi][ni][r] + x[yi];
            }
        }
}

// ---------------------------------------------------------------- depthwise 3x3 cd-conv (bf16 in/out) + fused sum-of-squares
__global__ __launch_bounds__(256) void dwconv2(const unsigned short* __restrict__ X, size_t sx,
                                               const float* __restrict__ w9,
                                               const float* __restrict__ ksum,
                                               unsigned short* __restrict__ Y, size_t sy,
                                               float* __restrict__ ssq)
{
    int bz = blockIdx.z;
    int c = blockIdx.y;
    int p4 = blockIdx.x * 256 + threadIdx.x;
    int p0 = p4 * 4;
    int i = p0 >> 8, j0 = p0 & 255;
    const unsigned short* xp = X + (size_t)bz * sx + (size_t)c * HW_;
    const float* wc = w9 + c * 9;
    float a[4] = {0.f, 0.f, 0.f, 0.f};
    float ctr[4];
#pragma unroll
    for (int di = -1; di <= 1; ++di) {
        int ii = i + di;
        if (ii < 0 || ii > 255) continue;
        const unsigned short* row = xp + ii * 256;
        ush4 m4 = *(const ush4*)(row + j0);
        float lft = (j0 > 0) ? bf2f(row[j0 - 1]) : 0.f;
        float rgt = (j0 < 252) ? bf2f(row[j0 + 4]) : 0.f;
        float v[6] = {lft, bf2f((unsigned short)m4[0]), bf2f((unsigned short)m4[1]),
                      bf2f((unsigned short)m4[2]), bf2f((unsigned short)m4[3]), rgt};
        if (di == 0) { ctr[0] = v[1]; ctr[1] = v[2]; ctr[2] = v[3]; ctr[3] = v[4]; }
        float w0 = wc[(di + 1) * 3], w1 = wc[(di + 1) * 3 + 1], w2 = wc[(di + 1) * 3 + 2];
#pragma unroll
        for (int k = 0; k < 4; ++k) a[k] += w0 * v[k] + w1 * v[k + 1] + w2 * v[k + 2];
    }
    float km = 0.7f * ksum[c];
    float o0 = a[0] - km * ctr[0], o1 = a[1] - km * ctr[1];
    float o2 = a[2] - km * ctr[2], o3 = a[3] - km * ctr[3];
    ush4 ov;
    ov[0] = f2bf(o0); ov[1] = f2bf(o1); ov[2] = f2bf(o2); ov[3] = f2bf(o3);
    *(ush4*)(Y + (size_t)bz * sy + (size_t)c * HW_ + p0) = ov;

    float q = o0 * o0 + o1 * o1 + o2 * o2 + o3 * o3;
    __shared__ float red[256];
    red[threadIdx.x] = q; __syncthreads();
    for (int st = 128; st; st >>= 1) {
        if (threadIdx.x < st) red[threadIdx.x] += red[threadIdx.x + st];
        __syncthreads();
    }
    if (!threadIdx.x) atomicAdd(&ssq[bz * C_ + c], red[0]);
}

// ---------------------------------------------------------------- attention helpers (bf16 q/k/v)
__global__ __launch_bounds__(256) void gram_kernel(const unsigned short* __restrict__ Q, size_t sq,
                                                   const unsigned short* __restrict__ K, size_t sk,
                                                   float* __restrict__ part)
{
    int sl = blockIdx.x, h = blockIdx.y, bz = blockIdx.z;
    const unsigned short* qb = Q + (size_t)bz * sq + (size_t)(h * 16) * HW_;
    const unsigned short* kb = K + (size_t)bz * sk + (size_t)(h * 16) * HW_;
    __shared__ __align__(16) float qs[16][68];
    __shared__ __align__(16) float ks[16][68];
    int c = threadIdx.x >> 4, d = threadIdx.x & 15;
    float acc = 0.f;
    for (int n0 = sl * 2048; n0 < (sl + 1) * 2048; n0 += 64) {
        {
            int cc = threadIdx.x >> 4, nn4 = threadIdx.x & 15;
            ush4 qv = *(const ush4*)(qb + (size_t)cc * HW_ + n0 + nn4 * 4);
            ush4 kv = *(const ush4*)(kb + (size_t)cc * HW_ + n0 + nn4 * 4);
#pragma unroll
            for (int j = 0; j < 4; ++j) {
                qs[cc][nn4 * 4 + j] = bf2f((unsigned short)qv[j]);
                ks[cc][nn4 * 4 + j] = bf2f((unsigned short)kv[j]);
            }
        }
        __syncthreads();
#pragma unroll
        for (int nn = 0; nn < 64; nn += 4) {
            float4 qv = *(const float4*)&qs[c][nn];
            float4 kv = *(const float4*)&ks[d][nn];
            acc += qv.x * kv.x + qv.y * kv.y + qv.z * kv.z + qv.w * kv.w;
        }
        __syncthreads();
    }
    part[((size_t)(bz * 8 + h) * 32 + sl) * 256 + threadIdx.x] = acc;
}

__global__ __launch_bounds__(256) void softmax_kernel(const float* __restrict__ part,
                                                      const float* __restrict__ nqsq,
                                                      const float* __restrict__ nksq,
                                                      const float* __restrict__ temp,
                                                      float* __restrict__ attn)
{
    int h = blockIdx.x, bz = blockIdx.y;
    int t = threadIdx.x;
    int c = t >> 4, d = t & 15;
    float g = 0.f;
    for (int sl = 0; sl < 32; ++sl) g += part[((size_t)(bz * 8 + h) * 32 + sl) * 256 + t];
    float nqv = fmaxf(sqrtf(nqsq[bz * C_ + h * 16 + c]), 1e-12f);
    float nkv = fmaxf(sqrtf(nksq[bz * C_ + h * 16 + d]), 1e-12f);
    g *= temp[h] / (nqv * nkv);
    float m = g;
#pragma unroll
    for (int off = 8; off; off >>= 1) m = fmaxf(m, __shfl_xor(m, off, 16));
    float e = __expf(g - m);
    float ssum = e;
#pragma unroll
    for (int off = 8; off; off >>= 1) ssum += __shfl_xor(ssum, off, 16);
    attn[(bz * 8 + h) * 256 + t] = e / ssum;
}

__global__ __launch_bounds__(256) void av_kernel(const float* __restrict__ attn,
                                                 const unsigned short* __restrict__ V, size_t sv,
                                                 unsigned short* __restrict__ Y, size_t sy)
{
    __shared__ __align__(16) float kv[16][260];
    __shared__ __align__(16) float at[16][16];
    int tile = blockIdx.x, h = blockIdx.y, bz = blockIdx.z;
    int n0 = tile * 256, t = threadIdx.x;
    const unsigned short* vb = V + (size_t)bz * sv + (size_t)(h * 16) * HW_;
    at[t >> 4][t & 15] = attn[(size_t)(bz * 8 + h) * 256 + (t & 15) * 16 + (t >> 4)];
#pragma unroll
    for (int i = 0; i < 4; ++i) {
        int e = t + i * 256;        // 1024 ush4 groups: 16 d x 64 nn4
        int d = e >> 6, nn4 = e & 63;
        ush4 v4 = *(const ush4*)(vb + (size_t)d * HW_ + n0 + nn4 * 4);
#pragma unroll
        for (int j = 0; j < 4; ++j) kv[d][nn4 * 4 + j] = bf2f((unsigned short)v4[j]);
    }
    __syncthreads();
    float acc[16];
#pragma unroll
    for (int cc = 0; cc < 16; ++cc) acc[cc] = 0.f;
#pragma unroll
    for (int d = 0; d < 16; ++d) {
        float kvv = kv[d][t];
        float4 a0 = *(const float4*)&at[d][0];
        float4 a1 = *(const float4*)&at[d][4];
        float4 a2 = *(const float4*)&at[d][8];
        float4 a3 = *(const float4*)&at[d][12];
        acc[0]  += a0.x * kvv; acc[1]  += a0.y * kvv; acc[2]  += a0.z * kvv; acc[3]  += a0.w * kvv;
        acc[4]  += a1.x * kvv; acc[5]  += a1.y * kvv; acc[6]  += a1.z * kvv; acc[7]  += a1.w * kvv;
        acc[8]  += a2.x * kvv; acc[9]  += a2.y * kvv; acc[10] += a2.z * kvv; acc[11] += a2.w * kvv;
        acc[12] += a3.x * kvv; acc[13] += a3.y * kvv; acc[14] += a3.z * kvv; acc[15] += a3.w * kvv;
    }
    unsigned short* yb = Y + (size_t)bz * sy + (size_t)(h * 16) * HW_ + n0 + t;
#pragma unroll
    for (int cc = 0; cc < 16; ++cc) yb[(size_t)cc * HW_] = f2bf(acc[cc]);
}

// ---------------------------------------------------------------- 256-pt radix-2 DIT FFT core (32 lanes/row)
__device__ __forceinline__ void fft_stages(float2* row, const float2* tw, int lane)
{
#pragma unroll
    for (int s = 1; s <= 8; ++s) {
        const int half = 1 << (s - 1);
#pragma unroll
        for (int r = 0; r < 4; ++r) {
            int jb = lane + r * 32;
            int j = jb & (half - 1);
            int g = jb >> (s - 1);
            int i1 = (g << s) + j;
            float2 w = tw[j << (8 - s)];
            float2 u = row[i1];
            float2 q = row[i1 + half];
            float2 v = make_float2(q.x * w.x - q.y * w.y, q.x * w.y + q.y * w.x);
            row[i1]        = make_float2(u.x + v.x, u.y + v.y);
            row[i1 + half] = make_float2(u.x - v.x, u.y - v.y);
        }
        __builtin_amdgcn_wave_barrier();   // rows are half-wave-private; in-wave DS ordering suffices
    }
    __syncthreads();
}

#define PI2_ 6.28318530717958647692f

// ---------------------------------------------------------------- fused 2D forward FFT (1 block = 1 channel)
// bf16 spatial [h][w] -> packed-bf16 spectrum T[c][k*256+h]; whole plane lives in LDS.
__global__ __launch_bounds__(256, 1) void fft2d_fwd(
    const unsigned short* __restrict__ X, size_t sx,
    unsigned* __restrict__ T, size_t st)
{
    __shared__ unsigned plane[129 * PLD_];
    __shared__ float2 sd[8][256];
    __shared__ float2 tw[128];
    const int t = threadIdx.x;
    const int c = blockIdx.x, bz = blockIdx.y;
    if (t < 128) { float sn, cs; __sincosf(-PI2_ * (float)t * (1.f / 256.f), &sn, &cs); tw[t] = make_float2(cs, sn); }
    const unsigned short* Xc = X + (size_t)bz * sx + (size_t)c * HW_;
    const int j = t >> 5;             // row within 8-row group
    const int i0 = (t & 31) * 8;      // col start (8 consecutive)

    // phase 1: row FFTs (32 groups of 8 rows), global loads software-pipelined
    ush8 pref = *(const ush8*)(Xc + (size_t)t * 8);
    for (int rg = 0; rg < 32; ++rg) {
        ush8 cur = pref;
        if (rg < 31) pref = *(const ush8*)(Xc + (size_t)(rg + 1) * 2048 + (size_t)t * 8);
        __syncthreads();              // prior pack-loop reads of sd complete
#pragma unroll
        for (int k2 = 0; k2 < 8; ++k2)
            sd[j][__brev((unsigned)(i0 + k2)) >> 24] = make_float2(bf2f((unsigned short)cur[k2]), 0.f);
        __syncthreads();
        fft_stages(sd[j], tw, t & 31);
        for (int e = t; e < 129 * 8; e += 256) {
            int j2 = e & 7, k = e >> 3;
            plane[k * PLD_ + rg * 8 + j2] = pack2bf(sd[j2][k]);
        }
    }
    __syncthreads();

    // phase 2: h FFTs per k-row (17 groups of 8)
    for (int kg = 0; kg < 17; ++kg) {
        for (int e = t; e < 2048; e += 256) {
            int j2 = e >> 8, i = e & 255;
            int k = kg * 8 + j2;
            float2 v = (k < KF_) ? upk(plane[k * PLD_ + i]) : make_float2(0.f, 0.f);
            sd[j2][__brev((unsigned)i) >> 24] = v;
        }
        __syncthreads();
        fft_stages(sd[j], tw, t & 31);
        for (int e = t; e < 2048; e += 256) {
            int j2 = e >> 8, i = e & 255;
            int k = kg * 8 + j2;
            if (k < KF_) plane[k * PLD_ + i] = pack2bf(sd[j2][i]);
        }
        __syncthreads();
    }

    // phase 3: stream plane to global (drop padding)
    unsigned* Tc = T + (size_t)bz * st + (size_t)c * PLANEF_;
    for (int e = t; e < 129 * 256; e += 256) {
        int k = e >> 8, h = e & 255;
        Tc[e] = plane[k * PLD_ + h];
    }
}

// ---------------------------------------------------------------- fused 2D inverse FFT + |.| (1 block = 1 channel)
// amp/pha bf16 [k*256+h] -> y bf16 [h][w]
__global__ __launch_bounds__(256, 1) void fft2d_inv_abs(
    const unsigned short* __restrict__ amp, const unsigned short* __restrict__ pha, size_t sa,
    unsigned short* __restrict__ Y, size_t sy)
{
    __shared__ unsigned plane[129 * PLD_];
    __shared__ float2 sd[8][256];
    __shared__ float2 tw[128];
    const int t = threadIdx.x;
    const int c = blockIdx.x, bz = blockIdx.y;
    if (t < 128) { float sn, cs; __sincosf(PI2_ * (float)t * (1.f / 256.f), &sn, &cs); tw[t] = make_float2(cs, sn); }
    const unsigned short* ac = amp + (size_t)bz * sa + (size_t)c * PLANEF_;
    const unsigned short* pc = pha + (size_t)bz * sa + (size_t)c * PLANEF_;
    const int j = t >> 5;

    // phase A+B: combine + inverse h-FFT per k-row (17 groups of 8)
    for (int kg = 0; kg < 17; ++kg) {
        for (int e = t; e < 512; e += 256) {
            int j2 = e >> 6, i4 = e & 63;
            int k = kg * 8 + j2;
            float2 v[4] = {{0.f,0.f},{0.f,0.f},{0.f,0.f},{0.f,0.f}};
            if (k < KF_) {
                ush4 a4 = *(const ush4*)(ac + (size_t)k * 256 + i4 * 4);
                ush4 p4 = *(const ush4*)(pc + (size_t)k * 256 + i4 * 4);
#pragma unroll
                for (int q = 0; q < 4; ++q) {
                    float a = bf2f((unsigned short)a4[q]);
                    float p = bf2f((unsigned short)p4[q]);
                    float sn, cs;
                    __sincosf(p, &sn, &cs);
                    v[q] = make_float2(a * cs + 2e-8f, a * sn + 1e-8f);
                }
            }
#pragma unroll
            for (int q = 0; q < 4; ++q)
                sd[j2][__brev((unsigned)(i4 * 4 + q)) >> 24] = v[q];
        }
        __syncthreads();
        fft_stages(sd[j], tw, t & 31);
        for (int e = t; e < 2048; e += 256) {
            int j2 = e >> 8, i = e & 255;
            int k = kg * 8 + j2;
            if (k < KF_) {
                float2 o = sd[j2][i];
                plane[k * PLD_ + i] = pack2bf(make_float2(o.x * (1.f / 256.f), o.y * (1.f / 256.f)));
            }
        }
        __syncthreads();
    }

    // phase C: Hermitian gather over k + inverse row-FFT + |.| (32 groups of 8 h-rows)
    unsigned short* Yc = Y + (size_t)bz * sy + (size_t)c * HW_;
    for (int hg = 0; hg < 32; ++hg) {
        for (int e = t; e < 2048; e += 256) {
            int j2 = e >> 8, i = e & 255;   // i = k index
            int h = hg * 8 + j2;
            float2 v;
            if (i < KF_) v = upk(plane[i * PLD_ + h]);
            else { float2 w2 = upk(plane[(256 - i) * PLD_ + h]); v = make_float2(w2.x, -w2.y); }
            sd[j2][__brev((unsigned)i) >> 24] = v;
        }
        __syncthreads();
        fft_stages(sd[j], tw, t & 31);
        for (int e = t; e < 2048; e += 256) {
            int j2 = e >> 8, i = e & 255;
            Yc[(size_t)(hg * 8 + j2) * 256 + i] = f2bf(fabsf(sd[j2][i].x * (1.f / 256.f)));
        }
        __syncthreads();
    }
}

// ---------------------------------------------------------------- host
extern "C" void kernel_launch(void* const* d_in, const int* in_sizes, int n_in,
                              void* d_out, int out_size, void* d_ws, size_t ws_size,
                              hipStream_t stream)
{
    (void)in_sizes; (void)n_in; (void)out_size;
    const float* ms    = (const float*)d_in[0];
    const float* pan   = (const float*)d_in[1];
    const float* ln1w  = (const float*)d_in[2];
    const float* ln1b  = (const float*)d_in[3];
    const float* ln2w  = (const float*)d_in[4];
    const float* ln2b  = (const float*)d_in[5];
    const float* qkvw  = (const float*)d_in[6];
    const float* dww   = (const float*)d_in[7];
    const float* temp  = (const float*)d_in[8];
    const float* projw = (const float*)d_in[9];
    const float* pre1w = (const float*)d_in[10];
    const float* pre1b = (const float*)d_in[11];
    const float* pre2w = (const float*)d_in[12];
    const float* pre2b = (const float*)d_in[13];
    const float* amp1w = (const float*)d_in[14];
    const float* amp1b = (const float*)d_in[15];
    const float* amp2w = (const float*)d_in[16];
    const float* amp2b = (const float*)d_in[17];
    const float* pha1w = (const float*)d_in[18];
    const float* pha1b = (const float*)d_in[19];
    const float* pha2w = (const float*)d_in[20];
    const float* pha2b = (const float*)d_in[21];
    const float* postw = (const float*)d_in[22];
    const float* postb = (const float*)d_in[23];
    const float* pinw  = (const float*)d_in[24];
    const float* poutw = (const float*)d_in[25];

    const size_t SLOT  = 8454144;    // ushorts per per-batch slot
    const size_t CHWu  = 8388608;    // C*HW ushorts
    const size_t CPFu  = 4227072;    // C*PLANEF ushorts
    const size_t SPECu = 4227072;    // C*PLANEF packed complex (unsigned)
    const size_t PARAMU = 344064;    // bf16 weight ushorts
    const size_t PARAMF = 273792;    // f32 param floats

    auto needB = [&](int nb) -> size_t {
        return 2ull * (33554432ull + (size_t)nb * 3ull * SLOT + PARAMU) + 4ull * PARAMF + 64;
    };
    int NB = (ws_size >= needB(4)) ? 4 : ((ws_size >= needB(2)) ? 2 : 1);

    unsigned short* F  = (unsigned short*)d_ws;      // 33554432 ushorts: frefuse bf16 (all batches)
    unsigned short* U0 = F + 33554432;
    unsigned short* U1 = U0 + (size_t)NB * SLOT;
    unsigned short* U2 = U1 + (size_t)NB * SLOT;
    unsigned short* w_qkv   = U2 + (size_t)NB * SLOT;
    unsigned short* w_proj  = w_qkv  + 16384;
    unsigned short* w_pre1  = w_proj + 16384;
    unsigned short* w_pre2  = w_pre1 + 16384;
    unsigned short* w_post  = w_pre2 + 16384;
    unsigned short* w_amp1  = w_post + 16384;   // [128][256]
    unsigned short* w_pha1  = w_amp1 + 32768;
    unsigned short* w_amp2  = w_pha1 + 32768;
    unsigned short* w_pha2  = w_amp2 + 16384;
    unsigned short* w_pin   = w_pha2 + 16384;   // [512][256] folded
    unsigned short* w_pout2 = w_pin  + 131072;  // [2][128][128]
    float* fpar   = (float*)(w_pout2 + 32768);
    float* ksumP  = fpar;
    float* nqsq   = ksumP + 128;     // 512
    float* nksq   = nqsq  + 512;     // 512
    float* attnP  = nksq  + 512;     // 8192
    float* partP  = attnP + 8192;    // 262144
    float* qkv_ws = partP + 262144;
    float* qkv_bb = qkv_ws + 128;
    float* pin_ws = qkv_bb + 128;    // 512
    float* pin_bb = pin_ws + 512;    // 512
    float* pinC   = pin_bb + 512;    // 1024 (float4[256])

    float* xout = (float*)d_out;

    auto CVT = [&](const float* src, unsigned short* dst, int n) {
        tobf16_kernel<<<(n + 255) / 256, 256, 0, stream>>>(src, dst, n);
    };
    foldln_kernel<<<128, 128, 0, stream>>>(qkvw, ln1w, ln1b, w_qkv, qkv_ws, qkv_bb, 128);
    foldln_kernel<<<512, 128, 0, stream>>>(pinw, ln2w, ln2b, w_pin, pin_ws, pin_bb, 256);
    CVT(projw, w_proj, 16384);
    CVT(pre1w, w_pre1, 16384); CVT(pre2w, w_pre2, 16384);
    CVT(postw, w_post, 16384);
    CVT(amp1w, w_amp1, 32768); CVT(pha1w, w_pha1, 32768);
    CVT(amp2w, w_amp2, 16384); CVT(pha2w, w_pha2, 16384);
    poutperm_kernel<<<128, 256, 0, stream>>>(poutw, w_pout2);
    pinc_kernel<<<1, 256, 0, stream>>>(pin_bb, pin_ws, (float4*)pinC);
    ksum_kernel<<<1, 128, 0, stream>>>(dww, ksumP);

    const size_t CHW = (size_t)C_ * HW_;   // floats
    const float* NUL = nullptr;

    for (int b0 = 0; b0 < B_; b0 += NB) {
        const float* msb  = ms  + (size_t)b0 * CHW;
        const float* panb = pan + (size_t)b0 * CHW;
        float* xb = xout + (size_t)b0 * CHW;
        unsigned short* freb = F + (size_t)b0 * CHWu;
        dim3 gz(512, 1, NB);
        dim3 gzf(258, 1, NB);

        // ---- attention ----
        zero2_kernel<<<(NB * 128 + 255) / 256, 256, 0, stream>>>(nqsq, nksq, NB * 128);
        mconv2<0, 1, 0, true><<<gz, 256, 0, stream>>>(
            msb, CHW, w_qkv, 128, nullptr, nullptr, 0, U0, SLOT, HW_, 0, qkv_ws, qkv_bb);
        dwconv2<<<dim3(64, 128, NB), 256, 0, stream>>>(U0, SLOT, dww, ksumP, U1, SLOT, nqsq);   // q
        mconv2<0, 1, 0, true><<<gz, 256, 0, stream>>>(
            panb, CHW, w_qkv, 128, nullptr, nullptr, 0, U0, SLOT, HW_, 0, qkv_ws, qkv_bb);
        dwconv2<<<dim3(64, 128, NB), 256, 0, stream>>>(U0, SLOT, dww, ksumP, U2, SLOT, nksq);   // kv
        gram_kernel<<<dim3(32, 8, NB), 256, 0, stream>>>(U1, SLOT, U2, SLOT, partP);
        softmax_kernel<<<dim3(8, NB), 256, 0, stream>>>(partP, nqsq, nksq, temp, attnP);
        av_kernel<<<dim3(256, 8, NB), 256, 0, stream>>>(attnP, U2, SLOT, U0, SLOT);
        mconv2<1, 0, 0, false><<<gz, 256, 0, stream>>>(
            U0, SLOT, w_proj, 128, nullptr, msb, CHW, xb, CHW, HW_, 0, NUL, NUL);

        // ---- freprocess ----
        mconv2<0, 1, 0, false><<<gz, 256, 0, stream>>>(
            msb, CHW, w_pre1, 128, pre1b, nullptr, 0, U0, SLOT, HW_, 1, NUL, NUL);
        fft2d_fwd<<<dim3(128, NB), 256, 0, stream>>>(U0, SLOT, (unsigned*)(void*)U1, SPECu);
        mconv2<0, 1, 0, false><<<gz, 256, 0, stream>>>(
            panb, CHW, w_pre2, 128, pre2b, nullptr, 0, U0, SLOT, HW_, 1, NUL, NUL);
        fft2d_fwd<<<dim3(128, NB), 256, 0, stream>>>(U0, SLOT, (unsigned*)(void*)U2, SPECu);
        // fused amp1+pha1 (stage A) + amp2/pha2 (stage B); amp/pha -> U0 slot (spatial dead)
        apconv2<<<gzf, 256, 0, stream>>>(
            (const unsigned*)(void*)U1, (const unsigned*)(void*)U2, SPECu,
            w_amp1, w_pha1, w_amp2, w_pha2, amp1b, pha1b, amp2b, pha2b,
            U0, U0 + CPFu, SLOT);
        // fused combine + inverse 2D FFT + |.| ; y -> U2 (spectra dead)
        fft2d_inv_abs<<<dim3(128, NB), 256, 0, stream>>>(U0, U0 + CPFu, SLOT, U2, SLOT);
        mconv2<1, 1, 0, false><<<gz, 256, 0, stream>>>(
            U2, SLOT, w_post, 128, postb, nullptr, 0, freb, CHWu, HW_, 0, NUL, NUL);
    }

    // ---- FFN (full batch, LN2 + gelu-gate fused) ----
    ffn_mfma5<<<dim3(HW_ / 64, B_), 256, 0, stream>>>(xout, F, w_pin, w_pout2, (const float4*)pinC, xout);
}

// Round 11
// 1746.557 us; speedup vs baseline: 1.1640x; 1.1640x over previous
//
#include <hip/hip_runtime.h>
#include <math.h>

#define B_ 4
#define C_ 128
#define HW_ 65536
#define H__ 256
#define KF_ 129
#define PLANEF_ 33024

typedef __attribute__((ext_vector_type(8))) short short8v;
typedef __attribute__((ext_vector_type(4))) float f32x4;
typedef __attribute__((ext_vector_type(4))) unsigned short ush4;
typedef __attribute__((ext_vector_type(8))) unsigned short ush8;

__device__ __forceinline__ unsigned short f2bf(float f) {
    union { float f; unsigned u; } v; v.f = f;
    return (unsigned short)((v.u + 0x7FFFu + ((v.u >> 16) & 1u)) >> 16);
}
__device__ __forceinline__ float bf2f(unsigned short s) {
    union { unsigned u; float f; } v; v.u = (unsigned)s << 16;
    return v.f;
}
__device__ __forceinline__ unsigned pack2bf(float2 v) {
    return (unsigned)f2bf(v.x) | ((unsigned)f2bf(v.y) << 16);
}
__device__ __forceinline__ float2 upk(unsigned u) {
    return make_float2(bf2f((unsigned short)(u & 0xffff)), bf2f((unsigned short)(u >> 16)));
}
// fast gelu: A&S 7.1.26 erf (|err|<=1.5e-7) with __expf
__device__ __forceinline__ float geluf(float x) {
    float z = 0.70710678118654752f * fabsf(x);
    float t = __fdividef(1.f, fmaf(0.3275911f, z, 1.f));
    float p = fmaf(1.061405429f, t, -1.453152027f);
    p = fmaf(p, t, 1.421413741f);
    p = fmaf(p, t, -0.284496736f);
    p = fmaf(p, t, 0.254829592f);
    p = p * t;
    float erfv = 1.f - p * __expf(-z * z);
    float cdf = (x >= 0.f) ? fmaf(0.5f, erfv, 0.5f) : fmaf(-0.5f, erfv, 0.5f);
    return x * cdf;
}
// fast atan2, poly err ~1e-5 rad
__device__ __forceinline__ float fatan2(float y, float x) {
    float ax = fabsf(x), ay = fabsf(y);
    float mx = fmaxf(ax, ay), mn = fminf(ax, ay);
    float a = __fdividef(mn, fmaxf(mx, 1e-38f));
    float s = a * a;
    float r = fmaf(0.0208351f, s, -0.0851330f);
    r = fmaf(r, s, 0.1801410f);
    r = fmaf(r, s, -0.3302995f);
    r = fmaf(r, s, 0.9998660f);
    r = r * a;
    if (ay > ax) r = 1.57079632679489662f - r;
    if (x < 0.f) r = 3.14159265358979324f - r;
    return copysignf(r, y);
}
// LDS XOR swizzle on byte-offset within row
template<int W>
__device__ __forceinline__ char* swz_ptr(unsigned short (*xs)[W], int px, int cb) {
    return (char*)xs + px * (W * 2) + (cb ^ (((px >> 2) & 7) << 4));
}

// ---------------------------------------------------------------- prep
__global__ __launch_bounds__(256) void tobf16_kernel(const float* __restrict__ src,
                                                     unsigned short* __restrict__ dst, int n)
{
    int i = blockIdx.x * 256 + threadIdx.x;
    if (i < n) dst[i] = f2bf(src[i]);
}

__global__ __launch_bounds__(128) void foldln_kernel(const float* __restrict__ W,
                                                     const float* __restrict__ lnw,
                                                     const float* __restrict__ lnb,
                                                     unsigned short* __restrict__ Wb,
                                                     float* __restrict__ wsum, float* __restrict__ bsum,
                                                     int Cc)
{
    int o = blockIdx.x, t = threadIdx.x;
    float sw = 0.f, sb = 0.f;
    for (int c = t; c < Cc; c += 128) {
        float w = W[(size_t)o * Cc + c];
        float fw = w * lnw[c];
        unsigned short us = f2bf(fw);
        Wb[(size_t)o * Cc + c] = us;
        sw += bf2f(us);
        sb += w * lnb[c];
    }
    __shared__ float r1[128], r2[128];
    r1[t] = sw; r2[t] = sb; __syncthreads();
    for (int st = 64; st; st >>= 1) {
        if (t < st) { r1[t] += r1[t + st]; r2[t] += r2[t + st]; }
        __syncthreads();
    }
    if (!t) { wsum[o] = r1[0]; bsum[o] = r2[0]; }
}

__global__ __launch_bounds__(256) void poutperm_kernel(const float* __restrict__ src,
                                                       unsigned short* __restrict__ dst)
{
    int i = blockIdx.x * 256 + threadIdx.x;   // 32768
    int half = i >> 14, rem = i & 16383, o = rem >> 7, kp = rem & 127;
    int h = (kp >> 5) * 64 + half * 32 + (kp & 31);
    dst[i] = f2bf(src[o * 256 + h]);
}

__global__ void pinc_kernel(const float* __restrict__ bb, const float* __restrict__ ws,
                            float4* __restrict__ pinC)
{
    int i = threadIdx.x;
    if (i < 256) pinC[i] = make_float4(bb[i], ws[i], bb[i + 256], ws[i + 256]);
}

__global__ void ksum_kernel(const float* __restrict__ dw, float* __restrict__ ks)
{
    int c = threadIdx.x;
    if (c < C_) {
        float s = 0.f;
        for (int k = 0; k < 9; ++k) s += dw[c * 9 + k];
        ks[c] = s;
    }
}

__global__ __launch_bounds__(256) void zero2_kernel(float* __restrict__ a, float* __restrict__ b, int n)
{
    int i = blockIdx.x * 256 + threadIdx.x;
    if (i < n) { a[i] = 0.f; b[i] = 0.f; }
}

// ---------------------------------------------------------------- MFMA conv1x1 (CIN=128)
// INBF: input dtype 0=f32 1=bf16. OUTBF: output dtype. PRO==1: leaky(0.1) on staged value.
// LNF: register LN stats + folded-affine epilogue (requires INBF=0). flags&1: +1e-8 after bias.
template<int INBF, int OUTBF, int PRO, bool LNF>
__global__ __launch_bounds__(256, 4) void mconv2(
    const void* __restrict__ Xv, size_t sx,
    const unsigned short* __restrict__ Wb, int wstride,
    const float* __restrict__ bias,
    const float* __restrict__ res, size_t sres,
    void* __restrict__ Yv, size_t sy, int plane, int flags,
    const float* __restrict__ wsum, const float* __restrict__ bsum)
{
    __shared__ unsigned short xs[128][136];
    __shared__ float2 lnred[LNF ? 8 : 1][LNF ? 128 : 1];
    __shared__ float2 lnmi[LNF ? 128 : 1];
    const int t = threadIdx.x;
    const int bz = blockIdx.z;
    const int p0 = blockIdx.x * 128;
    const int lane = t & 63;
    const int wr = t >> 7, wc = (t >> 6) & 1;
    const int lr = lane >> 4, lc = lane & 15;

    if constexpr (INBF == 0) {
        const float* Xb = (const float*)Xv + (size_t)bz * sx;
        const int px4 = t & 31;
        float s0 = 0.f, s1 = 0.f, s2v = 0.f, s3 = 0.f;
        float q0 = 0.f, q1 = 0.f, q2 = 0.f, q3 = 0.f;
#pragma unroll
        for (int g = 0; g < 2; ++g) {
            float4 st[8];
#pragma unroll
            for (int i = 0; i < 8; ++i) {
                int e = t + (g * 8 + i) * 256;           // 4096 items: 128c x 32 px4
                int c = e >> 5;
                st[i] = *(const float4*)(Xb + (size_t)c * plane + p0 + px4 * 4);
            }
#pragma unroll
            for (int i = 0; i < 8; ++i) {
                int e = t + (g * 8 + i) * 256;
                int c = e >> 5;
                float a0 = st[i].x, a1 = st[i].y, a2 = st[i].z, a3 = st[i].w;
                if constexpr (PRO == 1) {
                    a0 = a0 > 0.f ? a0 : 0.1f * a0;
                    a1 = a1 > 0.f ? a1 : 0.1f * a1;
                    a2 = a2 > 0.f ? a2 : 0.1f * a2;
                    a3 = a3 > 0.f ? a3 : 0.1f * a3;
                }
                if constexpr (LNF) {
                    s0 += a0; q0 += a0 * a0;
                    s1 += a1; q1 += a1 * a1;
                    s2v += a2; q2 += a2 * a2;
                    s3 += a3; q3 += a3 * a3;
                }
                *(unsigned short*)swz_ptr(xs, px4 * 4 + 0, 2 * c) = f2bf(a0);
                *(unsigned short*)swz_ptr(xs, px4 * 4 + 1, 2 * c) = f2bf(a1);
                *(unsigned short*)swz_ptr(xs, px4 * 4 + 2, 2 * c) = f2bf(a2);
                *(unsigned short*)swz_ptr(xs, px4 * 4 + 3, 2 * c) = f2bf(a3);
            }
        }
        if constexpr (LNF) {
            lnred[t >> 5][px4 * 4 + 0] = make_float2(s0, q0);
            lnred[t >> 5][px4 * 4 + 1] = make_float2(s1, q1);
            lnred[t >> 5][px4 * 4 + 2] = make_float2(s2v, q2);
            lnred[t >> 5][px4 * 4 + 3] = make_float2(s3, q3);
        }
    } else {
        const unsigned short* Xb = (const unsigned short*)Xv + (size_t)bz * sx;
        ush8 st[8];
#pragma unroll
        for (int i = 0; i < 8; ++i) {
            int e = t + i * 256;                         // 2048 items: 128c x 16 px8
            int c = e >> 4, px8 = e & 15;
            st[i] = *(const ush8*)(Xb + (size_t)c * plane + p0 + px8 * 8);
        }
#pragma unroll
        for (int i = 0; i < 8; ++i) {
            int e = t + i * 256;
            int c = e >> 4, px8 = e & 15;
#pragma unroll
            for (int j = 0; j < 8; ++j) {
                unsigned short us = (unsigned short)st[i][j];
                if constexpr (PRO == 1) {
                    float f = bf2f(us);
                    f = f > 0.f ? f : 0.1f * f;
                    us = f2bf(f);
                }
                *(unsigned short*)swz_ptr(xs, px8 * 8 + j, 2 * c) = us;
            }
        }
    }
    __syncthreads();
    if constexpr (LNF) {
        if (t < 128) {
            float ss = 0.f, qq = 0.f;
#pragma unroll
            for (int j = 0; j < 8; ++j) { float2 a = lnred[j][t]; ss += a.x; qq += a.y; }
            float m = ss * (1.f / 128.f);
            float inv = rsqrtf(qq * (1.f / 128.f) - m * m + 1e-5f);
            lnmi[t] = make_float2(m, inv);
        }
        __syncthreads();
    }

    f32x4 acc[4][4];
#pragma unroll
    for (int mi = 0; mi < 4; ++mi)
#pragma unroll
        for (int ni = 0; ni < 4; ++ni) acc[mi][ni] = (f32x4){0.f, 0.f, 0.f, 0.f};

#pragma unroll
    for (int kk = 0; kk < 128; kk += 32) {
        short8v bfr[4];
#pragma unroll
        for (int ni = 0; ni < 4; ++ni)
            bfr[ni] = *(const short8v*)swz_ptr(xs, wc * 64 + ni * 16 + lc, 2 * (kk + lr * 8));
#pragma unroll
        for (int mi = 0; mi < 4; ++mi) {
            int row = wr * 64 + mi * 16 + lc;
            short8v afr = *(const short8v*)(Wb + (size_t)row * wstride + kk + lr * 8);
#pragma unroll
            for (int ni = 0; ni < 4; ++ni)
                acc[mi][ni] = __builtin_amdgcn_mfma_f32_16x16x32_bf16(afr, bfr[ni], acc[mi][ni], 0, 0, 0);
        }
    }

    float2 mrow[4];
    if constexpr (LNF) {
#pragma unroll
        for (int ni = 0; ni < 4; ++ni) mrow[ni] = lnmi[wc * 64 + ni * 16 + lc];
    }

#pragma unroll
    for (int mi = 0; mi < 4; ++mi) {
        int ob = wr * 64 + mi * 16 + lr * 4;
#pragma unroll
        for (int r = 0; r < 4; ++r) {
            int o = ob + r;
            float bv = 0.f, wso = 0.f;
            if constexpr (LNF) { bv = bsum[o]; wso = wsum[o]; }
            else { if (bias) bv = bias[o]; if (flags & 1) bv += 1e-8f; }
#pragma unroll
            for (int ni = 0; ni < 4; ++ni) {
                int px = wc * 64 + ni * 16 + lc;
                float v;
                if constexpr (LNF) {
                    float m = mrow[ni].x, inv = mrow[ni].y;
                    v = acc[mi][ni][r] * inv + bv - m * inv * wso;
                } else {
                    v = acc[mi][ni][r] + bv;
                }
                if constexpr (OUTBF == 0) {
                    float* Y = (float*)Yv;
                    size_t yi = (size_t)bz * sy + (size_t)o * plane + p0 + px;
                    if (res) v += res[(size_t)bz * sres + (size_t)o * plane + p0 + px];
                    Y[yi] = v;
                } else {
                    unsigned short* Y = (unsigned short*)Yv;
                    Y[(size_t)bz * sy + (size_t)o * plane + p0 + px] = f2bf(v);
                }
            }
        }
    }
}

// ---------------------------------------------------------------- fused amp1+pha1+amp2+pha2 spectral block
__global__ __launch_bounds__(256, 2) void apconv2(
    const unsigned* __restrict__ T1, const unsigned* __restrict__ T2, size_t sT,
    const unsigned short* __restrict__ Wa1, const unsigned short* __restrict__ Wp1,  // [128][256]
    const unsigned short* __restrict__ Wa2, const unsigned short* __restrict__ Wp2,  // [128][128]
    const float* __restrict__ ba1, const float* __restrict__ bp1,
    const float* __restrict__ ba2, const float* __restrict__ bp2,
    unsigned short* __restrict__ AMP, unsigned short* __restrict__ PHA, size_t sO)
{
    __shared__ __align__(16) unsigned short buf[2][128][72];   // stage A: xa/xp ; stage B: [128][144]
    const int t = threadIdx.x;
    const int bz = blockIdx.z;
    const int p0 = blockIdx.x * 128;
    const int lane = t & 63;
    const int wr = t >> 7, wc = (t >> 6) & 1;
    const int lr = lane >> 4, lc = lane & 15;
    const int px2 = t & 63;

    typedef unsigned short (*row72)[72];
    typedef unsigned short (*row144)[144];
    row72 xa = (row72)buf[0];
    row72 xp = (row72)buf[1];
    row144 hb = (row144)&buf[0][0][0];

    f32x4 aa[4][4], ap[4][4];
#pragma unroll
    for (int mi = 0; mi < 4; ++mi)
#pragma unroll
        for (int ni = 0; ni < 4; ++ni) { aa[mi][ni] = (f32x4){0.f,0.f,0.f,0.f}; ap[mi][ni] = (f32x4){0.f,0.f,0.f,0.f}; }

    for (int ch = 0; ch < 256; ch += 64) {
        const unsigned* Ts = ((ch < 128) ? T1 : T2) + (size_t)bz * sT + (size_t)(ch & 127) * PLANEF_;
#pragma unroll
        for (int g = 0; g < 2; ++g) {
            uint2 st[8];
#pragma unroll
            for (int i = 0; i < 8; ++i) {
                int e = t + (g * 8 + i) * 256;       // 4096 items: 64c x 64 px2 (=128 px)
                int c = e >> 6;
                st[i] = *(const uint2*)(Ts + (size_t)c * PLANEF_ + p0 + px2 * 2);
            }
#pragma unroll
            for (int i = 0; i < 8; ++i) {
                int e = t + (g * 8 + i) * 256;
                int c = e >> 6;
                float2 z0 = upk(st[i].x), z1 = upk(st[i].y);
                float m0 = sqrtf(z0.x * z0.x + z0.y * z0.y);
                float m1 = sqrtf(z1.x * z1.x + z1.y * z1.y);
                float a0 = fatan2(z0.y, z0.x);
                float a1 = fatan2(z1.y, z1.x);
                *(unsigned short*)swz_ptr(xa, px2 * 2 + 0, 2 * c) = f2bf(m0);
                *(unsigned short*)swz_ptr(xa, px2 * 2 + 1, 2 * c) = f2bf(m1);
                *(unsigned short*)swz_ptr(xp, px2 * 2 + 0, 2 * c) = f2bf(a0);
                *(unsigned short*)swz_ptr(xp, px2 * 2 + 1, 2 * c) = f2bf(a1);
            }
        }
        __syncthreads();
#pragma unroll
        for (int kk = 0; kk < 64; kk += 32) {
            short8v bfa[4], bfp[4];
#pragma unroll
            for (int ni = 0; ni < 4; ++ni) {
                bfa[ni] = *(const short8v*)swz_ptr(xa, wc * 64 + ni * 16 + lc, 2 * (kk + lr * 8));
                bfp[ni] = *(const short8v*)swz_ptr(xp, wc * 64 + ni * 16 + lc, 2 * (kk + lr * 8));
            }
#pragma unroll
            for (int mi = 0; mi < 4; ++mi) {
                int row = wr * 64 + mi * 16 + lc;
                short8v afa = *(const short8v*)(Wa1 + (size_t)row * 256 + ch + kk + lr * 8);
                short8v afp = *(const short8v*)(Wp1 + (size_t)row * 256 + ch + kk + lr * 8);
#pragma unroll
                for (int ni = 0; ni < 4; ++ni) {
                    aa[mi][ni] = __builtin_amdgcn_mfma_f32_16x16x32_bf16(afa, bfa[ni], aa[mi][ni], 0, 0, 0);
                    ap[mi][ni] = __builtin_amdgcn_mfma_f32_16x16x32_bf16(afp, bfp[ni], ap[mi][ni], 0, 0, 0);
                }
            }
        }
        __syncthreads();
    }

    // ---- stage B (amp) ----
#pragma unroll
    for (int mi = 0; mi < 4; ++mi)
#pragma unroll
        for (int r = 0; r < 4; ++r) {
            int o = wr * 64 + mi * 16 + lr * 4 + r;
            float bva = ba1[o];
#pragma unroll
            for (int ni = 0; ni < 4; ++ni) {
                int px = wc * 64 + ni * 16 + lc;
                float v = aa[mi][ni][r] + bva;
                v = v > 0.f ? v : 0.1f * v;
                *(unsigned short*)swz_ptr(hb, px, 2 * o) = f2bf(v);
            }
        }
    __syncthreads();
    {
        f32x4 acc[4][4];
#pragma unroll
        for (int mi = 0; mi < 4; ++mi)
#pragma unroll
            for (int ni = 0; ni < 4; ++ni) acc[mi][ni] = (f32x4){0.f,0.f,0.f,0.f};
#pragma unroll
        for (int kk = 0; kk < 128; kk += 32) {
            short8v bfr[4];
#pragma unroll
            for (int ni = 0; ni < 4; ++ni)
                bfr[ni] = *(const short8v*)swz_ptr(hb, wc * 64 + ni * 16 + lc, 2 * (kk + lr * 8));
#pragma unroll
            for (int mi = 0; mi < 4; ++mi) {
                int row = wr * 64 + mi * 16 + lc;
                short8v afr = *(const short8v*)(Wa2 + (size_t)row * 128 + kk + lr * 8);
#pragma unroll
                for (int ni = 0; ni < 4; ++ni)
                    acc[mi][ni] = __builtin_amdgcn_mfma_f32_16x16x32_bf16(afr, bfr[ni], acc[mi][ni], 0, 0, 0);
            }
        }
#pragma unroll
        for (int mi = 0; mi < 4; ++mi)
#pragma unroll
            for (int r = 0; r < 4; ++r) {
                int o = wr * 64 + mi * 16 + lr * 4 + r;
                float bv = ba2[o];
#pragma unroll
                for (int ni = 0; ni < 4; ++ni) {
                    int px = wc * 64 + ni * 16 + lc;
                    AMP[(size_t)bz * sO + (size_t)o * PLANEF_ + p0 + px] = f2bf(acc[mi][ni][r] + bv);
                }
            }
    }
    __syncthreads();

    // ---- stage B (pha) ----
#pragma unroll
    for (int mi = 0; mi < 4; ++mi)
#pragma unroll
        for (int r = 0; r < 4; ++r) {
            int o = wr * 64 + mi * 16 + lr * 4 + r;
            float bvp = bp1[o];
#pragma unroll
            for (int ni = 0; ni < 4; ++ni) {
                int px = wc * 64 + ni * 16 + lc;
                float v = ap[mi][ni][r] + bvp;
                v = v > 0.f ? v : 0.1f * v;
                *(unsigned short*)swz_ptr(hb, px, 2 * o) = f2bf(v);
            }
        }
    __syncthreads();
    {
        f32x4 acc[4][4];
#pragma unroll
        for (int mi = 0; mi < 4; ++mi)
#pragma unroll
            for (int ni = 0; ni < 4; ++ni) acc[mi][ni] = (f32x4){0.f,0.f,0.f,0.f};
#pragma unroll
        for (int kk = 0; kk < 128; kk += 32) {
            short8v bfr[4];
#pragma unroll
            for (int ni = 0; ni < 4; ++ni)
                bfr[ni] = *(const short8v*)swz_ptr(hb, wc * 64 + ni * 16 + lc, 2 * (kk + lr * 8));
#pragma unroll
            for (int mi = 0; mi < 4; ++mi) {
                int row = wr * 64 + mi * 16 + lc;
                short8v afr = *(const short8v*)(Wp2 + (size_t)row * 128 + kk + lr * 8);
#pragma unroll
                for (int ni = 0; ni < 4; ++ni)
                    acc[mi][ni] = __builtin_amdgcn_mfma_f32_16x16x32_bf16(afr, bfr[ni], acc[mi][ni], 0, 0, 0);
            }
        }
#pragma unroll
        for (int mi = 0; mi < 4; ++mi)
#pragma unroll
            for (int r = 0; r < 4; ++r) {
                int o = wr * 64 + mi * 16 + lr * 4 + r;
                float bv = bp2[o];
#pragma unroll
                for (int ni = 0; ni < 4; ++ni) {
                    int px = wc * 64 + ni * 16 + lc;
                    PHA[(size_t)bz * sO + (size_t)o * PLANEF_ + p0 + px] = f2bf(acc[mi][ni][r] + bv);
                }
            }
    }
}

// ---------------------------------------------------------------- fused MFMA FFN (x f32, fre bf16; residual from LDS)
__global__ __launch_bounds__(256, 3) void ffn_mfma6(
    const float* __restrict__ x, const unsigned short* __restrict__ fre,
    const unsigned short* __restrict__ pinb,    // [512][256] folded bf16
    const unsigned short* __restrict__ pout2,   // [2][128][128] permuted bf16
    const float4* __restrict__ pinC,            // [256] (bb1,ws1,bb2,ws2)
    float* __restrict__ out)
{
    __shared__ unsigned short xs[64][264];
    __shared__ unsigned short hs[64][136];
    __shared__ float2 muinv[64];
    float2* sred = (float2*)&hs[0][0];          // overlay: dead until GEMM1 epilogue
    const int b = blockIdx.y;
    const size_t p0 = (size_t)blockIdx.x * 64;
    const int t = threadIdx.x;
    const int wave = t >> 6, lane = t & 63;
    const int lr = lane >> 4, lc = lane & 15;
    const int px4 = t & 15;

    float s0 = 0.f, s1 = 0.f, s2v = 0.f, s3 = 0.f;
    float q0 = 0.f, q1 = 0.f, q2 = 0.f, q3 = 0.f;
    {
        float4 stx[8];
        ush4 stf[8];
#pragma unroll
        for (int i = 0; i < 8; ++i) {
            int e = t + i * 256;                 // 2048 items: 128c x 16 px4
            int c = e >> 4;
            stx[i] = *(const float4*)(x + ((size_t)b * 128 + c) * HW_ + p0 + px4 * 4);
        }
#pragma unroll
        for (int i = 0; i < 8; ++i) {
            int e = t + i * 256;
            int c = e >> 4;
            stf[i] = *(const ush4*)(fre + (size_t)b * 8388608 + (size_t)c * HW_ + p0 + px4 * 4);
        }
#pragma unroll
        for (int i = 0; i < 8; ++i) {
            int e = t + i * 256;
            int c = e >> 4;
            float a0 = stx[i].x, a1 = stx[i].y, a2 = stx[i].z, a3 = stx[i].w;
            s0 += a0; q0 += a0 * a0;
            s1 += a1; q1 += a1 * a1;
            s2v += a2; q2 += a2 * a2;
            s3 += a3; q3 += a3 * a3;
            *(unsigned short*)swz_ptr(xs, px4 * 4 + 0, 2 * c) = f2bf(a0);
            *(unsigned short*)swz_ptr(xs, px4 * 4 + 1, 2 * c) = f2bf(a1);
            *(unsigned short*)swz_ptr(xs, px4 * 4 + 2, 2 * c) = f2bf(a2);
            *(unsigned short*)swz_ptr(xs, px4 * 4 + 3, 2 * c) = f2bf(a3);
        }
#pragma unroll
        for (int i = 0; i < 8; ++i) {
            int e = t + i * 256;
            int c = e >> 4;
            float a0 = bf2f((unsigned short)stf[i][0]);
            float a1 = bf2f((unsigned short)stf[i][1]);
            float a2 = bf2f((unsigned short)stf[i][2]);
            float a3 = bf2f((unsigned short)stf[i][3]);
            s0 += a0; q0 += a0 * a0;
            s1 += a1; q1 += a1 * a1;
            s2v += a2; q2 += a2 * a2;
            s3 += a3; q3 += a3 * a3;
            *(unsigned short*)swz_ptr(xs, px4 * 4 + 0, 2 * (128 + c)) = (unsigned short)stf[i][0];
            *(unsigned short*)swz_ptr(xs, px4 * 4 + 1, 2 * (128 + c)) = (unsigned short)stf[i][1];
            *(unsigned short*)swz_ptr(xs, px4 * 4 + 2, 2 * (128 + c)) = (unsigned short)stf[i][2];
            *(unsigned short*)swz_ptr(xs, px4 * 4 + 3, 2 * (128 + c)) = (unsigned short)stf[i][3];
        }
    }
    sred[(t >> 4) * 64 + px4 * 4 + 0] = make_float2(s0, q0);
    sred[(t >> 4) * 64 + px4 * 4 + 1] = make_float2(s1, q1);
    sred[(t >> 4) * 64 + px4 * 4 + 2] = make_float2(s2v, q2);
    sred[(t >> 4) * 64 + px4 * 4 + 3] = make_float2(s3, q3);
    __syncthreads();
    if (t < 64) {
        float ss = 0.f, qq = 0.f;
#pragma unroll
        for (int j = 0; j < 16; ++j) { float2 a = sred[j * 64 + t]; ss += a.x; qq += a.y; }
        float m = ss * (1.f / 256.f);
        float inv = rsqrtf(qq * (1.f / 256.f) - m * m + 1e-5f);
        muinv[t] = make_float2(m, inv);
    }
    __syncthreads();

    float2 mrow[4];
#pragma unroll
    for (int ni = 0; ni < 4; ++ni) mrow[ni] = muinv[ni * 16 + lc];

    f32x4 oc[2][4];
#pragma unroll
    for (int mi = 0; mi < 2; ++mi)
#pragma unroll
        for (int ni = 0; ni < 4; ++ni) oc[mi][ni] = (f32x4){0.f, 0.f, 0.f, 0.f};

#pragma unroll
    for (int half = 0; half < 2; ++half) {
        f32x4 a1[2][4], a2[2][4];
#pragma unroll
        for (int mi = 0; mi < 2; ++mi)
#pragma unroll
            for (int ni = 0; ni < 4; ++ni) { a1[mi][ni] = (f32x4){0.f,0.f,0.f,0.f}; a2[mi][ni] = (f32x4){0.f,0.f,0.f,0.f}; }

#pragma unroll
        for (int k0 = 0; k0 < 256; k0 += 32) {
            short8v bfr[4];
#pragma unroll
            for (int ni = 0; ni < 4; ++ni)
                bfr[ni] = *(const short8v*)swz_ptr(xs, ni * 16 + lc, 2 * (k0 + lr * 8));
#pragma unroll
            for (int mi = 0; mi < 2; ++mi) {
                int hrow = wave * 64 + half * 32 + mi * 16 + lc;
                short8v af1 = *(const short8v*)(pinb + (size_t)hrow * 256 + k0 + lr * 8);
                short8v af2 = *(const short8v*)(pinb + (size_t)(hrow + 256) * 256 + k0 + lr * 8);
#pragma unroll
                for (int ni = 0; ni < 4; ++ni) {
                    a1[mi][ni] = __builtin_amdgcn_mfma_f32_16x16x32_bf16(af1, bfr[ni], a1[mi][ni], 0, 0, 0);
                    a2[mi][ni] = __builtin_amdgcn_mfma_f32_16x16x32_bf16(af2, bfr[ni], a2[mi][ni], 0, 0, 0);
                }
            }
        }
        __syncthreads();
#pragma unroll
        for (int mi = 0; mi < 2; ++mi)
#pragma unroll
            for (int r = 0; r < 4; ++r) {
                int ho = wave * 64 + half * 32 + mi * 16 + lr * 4 + r;
                float4 bwc = pinC[ho];
                int kp = wave * 32 + mi * 16 + lr * 4 + r;
#pragma unroll
                for (int ni = 0; ni < 4; ++ni) {
                    float m = mrow[ni].x, inv = mrow[ni].y;
                    float v1 = a1[mi][ni][r] * inv + bwc.x - m * inv * bwc.y;
                    float v2 = a2[mi][ni][r] * inv + bwc.z - m * inv * bwc.w;
                    hs[ni * 16 + lc][kp] = f2bf(geluf(v1) * v2);
                }
            }
        __syncthreads();
#pragma unroll
        for (int k0 = 0; k0 < 128; k0 += 32) {
            short8v bfr2[4];
#pragma unroll
            for (int ni = 0; ni < 4; ++ni)
                bfr2[ni] = *(const short8v*)&hs[ni * 16 + lc][k0 + lr * 8];
#pragma unroll
            for (int mi = 0; mi < 2; ++mi) {
                int orow = wave * 32 + mi * 16 + lc;
                short8v af = *(const short8v*)(pout2 + half * 16384 + orow * 128 + k0 + lr * 8);
#pragma unroll
                for (int ni = 0; ni < 4; ++ni)
                    oc[mi][ni] = __builtin_amdgcn_mfma_f32_16x16x32_bf16(af, bfr2[ni], oc[mi][ni], 0, 0, 0);
            }
        }
    }

#pragma unroll
    for (int mi = 0; mi < 2; ++mi)
#pragma unroll
        for (int r = 0; r < 4; ++r) {
            int o = wave * 32 + mi * 16 + lr * 4 + r;
#pragma unroll
            for (int ni = 0; ni < 4; ++ni) {
                int px = ni * 16 + lc;
                float rx = bf2f(*(const unsigned short*)swz_ptr(xs, px, 2 * o));  // bf16(x) residual from LDS
                size_t yi = ((size_t)b * 128 + o) * HW_ + p0 + px;
                out[yi] = oc[mi][ni][r] + rx;
            }
        }
}

// ---------------------------------------------------------------- depthwise 3x3 cd-conv (bf16 in/out) + fused sum-of-squares
__global__ __launch_bounds__(256) void dwconv2(const unsigned short* __restrict__ X, size_t sx,
                                               const float* __restrict__ w9,
                                               const float* __restrict__ ksum,
                                               unsigned short* __restrict__ Y, size_t sy,
                                               float* __restrict__ ssq)
{
    int bz = blockIdx.z;
    int c = blockIdx.y;
    int p4 = blockIdx.x * 256 + threadIdx.x;
    int p0 = p4 * 4;
    int i = p0 >> 8, j0 = p0 & 255;
    const unsigned short* xp = X + (size_t)bz * sx + (size_t)c * HW_;
    const float* wc = w9 + c * 9;
    float a[4] = {0.f, 0.f, 0.f, 0.f};
    float ctr[4];
#pragma unroll
    for (int di = -1; di <= 1; ++di) {
        int ii = i + di;
        if (ii < 0 || ii > 255) continue;
        const unsigned short* row = xp + ii * 256;
        ush4 m4 = *(const ush4*)(row + j0);
        float lft = (j0 > 0) ? bf2f(row[j0 - 1]) : 0.f;
        float rgt = (j0 < 252) ? bf2f(row[j0 + 4]) : 0.f;
        float v[6] = {lft, bf2f((unsigned short)m4[0]), bf2f((unsigned short)m4[1]),
                      bf2f((unsigned short)m4[2]), bf2f((unsigned short)m4[3]), rgt};
        if (di == 0) { ctr[0] = v[1]; ctr[1] = v[2]; ctr[2] = v[3]; ctr[3] = v[4]; }
        float w0 = wc[(di + 1) * 3], w1 = wc[(di + 1) * 3 + 1], w2 = wc[(di + 1) * 3 + 2];
#pragma unroll
        for (int k = 0; k < 4; ++k) a[k] += w0 * v[k] + w1 * v[k + 1] + w2 * v[k + 2];
    }
    float km = 0.7f * ksum[c];
    float o0 = a[0] - km * ctr[0], o1 = a[1] - km * ctr[1];
    float o2 = a[2] - km * ctr[2], o3 = a[3] - km * ctr[3];
    ush4 ov;
    ov[0] = f2bf(o0); ov[1] = f2bf(o1); ov[2] = f2bf(o2); ov[3] = f2bf(o3);
    *(ush4*)(Y + (size_t)bz * sy + (size_t)c * HW_ + p0) = ov;

    float q = o0 * o0 + o1 * o1 + o2 * o2 + o3 * o3;
    __shared__ float red[256];
    red[threadIdx.x] = q; __syncthreads();
    for (int st = 128; st; st >>= 1) {
        if (threadIdx.x < st) red[threadIdx.x] += red[threadIdx.x + st];
        __syncthreads();
    }
    if (!threadIdx.x) atomicAdd(&ssq[bz * C_ + c], red[0]);
}

// ---------------------------------------------------------------- attention helpers (bf16 q/k/v)
__global__ __launch_bounds__(256) void gram_kernel(const unsigned short* __restrict__ Q, size_t sq,
                                                   const unsigned short* __restrict__ K, size_t sk,
                                                   float* __restrict__ part)
{
    int sl = blockIdx.x, h = blockIdx.y, bz = blockIdx.z;
    const unsigned short* qb = Q + (size_t)bz * sq + (size_t)(h * 16) * HW_;
    const unsigned short* kb = K + (size_t)bz * sk + (size_t)(h * 16) * HW_;
    __shared__ __align__(16) float qs[16][68];
    __shared__ __align__(16) float ks[16][68];
    int c = threadIdx.x >> 4, d = threadIdx.x & 15;
    float acc = 0.f;
    for (int n0 = sl * 2048; n0 < (sl + 1) * 2048; n0 += 64) {
        {
            int cc = threadIdx.x >> 4, nn4 = threadIdx.x & 15;
            ush4 qv = *(const ush4*)(qb + (size_t)cc * HW_ + n0 + nn4 * 4);
            ush4 kv = *(const ush4*)(kb + (size_t)cc * HW_ + n0 + nn4 * 4);
#pragma unroll
            for (int j = 0; j < 4; ++j) {
                qs[cc][nn4 * 4 + j] = bf2f((unsigned short)qv[j]);
                ks[cc][nn4 * 4 + j] = bf2f((unsigned short)kv[j]);
            }
        }
        __syncthreads();
#pragma unroll
        for (int nn = 0; nn < 64; nn += 4) {
            float4 qv = *(const float4*)&qs[c][nn];
            float4 kv = *(const float4*)&ks[d][nn];
            acc += qv.x * kv.x + qv.y * kv.y + qv.z * kv.z + qv.w * kv.w;
        }
        __syncthreads();
    }
    part[((size_t)(bz * 8 + h) * 32 + sl) * 256 + threadIdx.x] = acc;
}

__global__ __launch_bounds__(256) void softmax_kernel(const float* __restrict__ part,
                                                      const float* __restrict__ nqsq,
                                                      const float* __restrict__ nksq,
                                                      const float* __restrict__ temp,
                                                      float* __restrict__ attn)
{
    int h = blockIdx.x, bz = blockIdx.y;
    int t = threadIdx.x;
    int c = t >> 4, d = t & 15;
    float g = 0.f;
    for (int sl = 0; sl < 32; ++sl) g += part[((size_t)(bz * 8 + h) * 32 + sl) * 256 + t];
    float nqv = fmaxf(sqrtf(nqsq[bz * C_ + h * 16 + c]), 1e-12f);
    float nkv = fmaxf(sqrtf(nksq[bz * C_ + h * 16 + d]), 1e-12f);
    g *= temp[h] / (nqv * nkv);
    float m = g;
#pragma unroll
    for (int off = 8; off; off >>= 1) m = fmaxf(m, __shfl_xor(m, off, 16));
    float e = __expf(g - m);
    float ssum = e;
#pragma unroll
    for (int off = 8; off; off >>= 1) ssum += __shfl_xor(ssum, off, 16);
    attn[(bz * 8 + h) * 256 + t] = e / ssum;
}

__global__ __launch_bounds__(256) void av_kernel(const float* __restrict__ attn,
                                                 const unsigned short* __restrict__ V, size_t sv,
                                                 unsigned short* __restrict__ Y, size_t sy)
{
    __shared__ __align__(16) float kv[16][260];
    __shared__ __align__(16) float at[16][16];
    int tile = blockIdx.x, h = blockIdx.y, bz = blockIdx.z;
    int n0 = tile * 256, t = threadIdx.x;
    const unsigned short* vb = V + (size_t)bz * sv + (size_t)(h * 16) * HW_;
    at[t >> 4][t & 15] = attn[(size_t)(bz * 8 + h) * 256 + (t & 15) * 16 + (t >> 4)];
#pragma unroll
    for (int i = 0; i < 4; ++i) {
        int e = t + i * 256;        // 1024 ush4 groups: 16 d x 64 nn4
        int d = e >> 6, nn4 = e & 63;
        ush4 v4 = *(const ush4*)(vb + (size_t)d * HW_ + n0 + nn4 * 4);
#pragma unroll
        for (int j = 0; j < 4; ++j) kv[d][nn4 * 4 + j] = bf2f((unsigned short)v4[j]);
    }
    __syncthreads();
    float acc[16];
#pragma unroll
    for (int cc = 0; cc < 16; ++cc) acc[cc] = 0.f;
#pragma unroll
    for (int d = 0; d < 16; ++d) {
        float kvv = kv[d][t];
        float4 a0 = *(const float4*)&at[d][0];
        float4 a1 = *(const float4*)&at[d][4];
        float4 a2 = *(const float4*)&at[d][8];
        float4 a3 = *(const float4*)&at[d][12];
        acc[0]  += a0.x * kvv; acc[1]  += a0.y * kvv; acc[2]  += a0.z * kvv; acc[3]  += a0.w * kvv;
        acc[4]  += a1.x * kvv; acc[5]  += a1.y * kvv; acc[6]  += a1.z * kvv; acc[7]  += a1.w * kvv;
        acc[8]  += a2.x * kvv; acc[9]  += a2.y * kvv; acc[10] += a2.z * kvv; acc[11] += a2.w * kvv;
        acc[12] += a3.x * kvv; acc[13] += a3.y * kvv; acc[14] += a3.z * kvv; acc[15] += a3.w * kvv;
    }
    unsigned short* yb = Y + (size_t)bz * sy + (size_t)(h * 16) * HW_ + n0 + t;
#pragma unroll
    for (int cc = 0; cc < 16; ++cc) yb[(size_t)cc * HW_] = f2bf(acc[cc]);
}

// ---------------------------------------------------------------- 256-pt radix-2 DIT FFT core (32 lanes/row)
__device__ __forceinline__ void fft_stages(float2* row, const float2* tw, int lane)
{
#pragma unroll
    for (int s = 1; s <= 8; ++s) {
        const int half = 1 << (s - 1);
#pragma unroll
        for (int r = 0; r < 4; ++r) {
            int jb = lane + r * 32;
            int j = jb & (half - 1);
            int g = jb >> (s - 1);
            int i1 = (g << s) + j;
            float2 w = tw[j << (8 - s)];
            float2 u = row[i1];
            float2 q = row[i1 + half];
            float2 v = make_float2(q.x * w.x - q.y * w.y, q.x * w.y + q.y * w.x);
            row[i1]        = make_float2(u.x + v.x, u.y + v.y);
            row[i1 + half] = make_float2(u.x - v.x, u.y - v.y);
        }
        __builtin_amdgcn_wave_barrier();   // rows are half-wave-private; in-wave DS ordering suffices
    }
    __syncthreads();
}

#define PI2_ 6.28318530717958647692f

// bf16 real rows -> transposed packed-bf16 spectrum T[c][k][h]
__global__ __launch_bounds__(256) void rfft_rowsT(const unsigned short* __restrict__ X, size_t sx,
                                                  unsigned* __restrict__ T, size_t st)
{
    __shared__ float2 sd[8][256];
    __shared__ float2 tw[128];
    int t = threadIdx.x;
    int bz = blockIdx.y;
    if (t < 128) { float sn, cs; __sincosf(-PI2_ * (float)t * (1.f / 256.f), &sn, &cs); tw[t] = make_float2(cs, sn); }
    size_t r0 = (size_t)blockIdx.x * 8;
    int c = (int)(r0 >> 8), h0 = (int)(r0 & 255);
    const unsigned short* Xb = X + (size_t)bz * sx;
#pragma unroll
    for (int ii = 0; ii < 2; ++ii) {
        int e = t + ii * 256;            // 512 ush4 groups: 8 rows x 64
        int j = e >> 6, i4 = e & 63;
        ush4 v4 = *(const ush4*)(Xb + (r0 + j) * 256 + i4 * 4);
#pragma unroll
        for (int k2 = 0; k2 < 4; ++k2)
            sd[j][__brev((unsigned)(i4 * 4 + k2)) >> 24] = make_float2(bf2f((unsigned short)v4[k2]), 0.f);
    }
    __syncthreads();
    fft_stages(sd[t >> 5], tw, t & 31);
    unsigned* base = T + (size_t)bz * st + (size_t)c * PLANEF_;
    for (int e = t; e < 8 * 129; e += 256) {
        int j = e & 7, k = e >> 3;
        base[(size_t)k * 256 + h0 + j] = pack2bf(sd[j][k]);
    }
}

// forward complex FFT along h, in-place on packed-bf16 transposed layout
__global__ __launch_bounds__(256) void cfftT_fwd(unsigned* __restrict__ T, size_t st)
{
    __shared__ float2 sd[8][256];
    __shared__ float2 tw[128];
    int t = threadIdx.x;
    int bz = blockIdx.z;
    if (t < 128) { float sn, cs; __sincosf(-PI2_ * (float)t * (1.f / 256.f), &sn, &cs); tw[t] = make_float2(cs, sn); }
    int k0 = blockIdx.x * 8;
    int c = blockIdx.y;
    unsigned* base = T + (size_t)bz * st + (size_t)c * PLANEF_;
    for (int e = t; e < 2048; e += 256) {
        int j = e >> 8, i = e & 255;
        int k = k0 + j;
        float2 v = (k < KF_) ? upk(base[(size_t)k * 256 + i]) : make_float2(0.f, 0.f);
        sd[j][__brev((unsigned)i) >> 24] = v;
    }
    __syncthreads();
    fft_stages(sd[t >> 5], tw, t & 31);
    for (int e = t; e < 2048; e += 256) {
        int j = e >> 8, i = e & 255;
        int k = k0 + j;
        if (k < KF_) base[(size_t)k * 256 + i] = pack2bf(sd[j][i]);
    }
}

// combine(amp,pha bf16) + inverse h-FFT; writes row-major packed-bf16 spectrum S[c][h][k]
__global__ __launch_bounds__(256) void cifft_combine(const unsigned short* __restrict__ amp, size_t sa,
                                                     const unsigned short* __restrict__ pha, size_t sp,
                                                     unsigned* __restrict__ S, size_t ss)
{
    __shared__ float2 sd[8][256];
    __shared__ float2 tw[128];
    int t = threadIdx.x;
    int bz = blockIdx.z;
    if (t < 128) { float sn, cs; __sincosf(PI2_ * (float)t * (1.f / 256.f), &sn, &cs); tw[t] = make_float2(cs, sn); }
    int k0 = blockIdx.x * 8;
    int c = blockIdx.y;
    const unsigned short* ab = amp + (size_t)bz * sa + (size_t)c * PLANEF_;
    const unsigned short* pb = pha + (size_t)bz * sp + (size_t)c * PLANEF_;
    for (int e = t; e < 2048; e += 256) {
        int j = e >> 8, i = e & 255;
        int k = k0 + j;
        float2 v = make_float2(0.f, 0.f);
        if (k < KF_) {
            float a = bf2f(ab[(size_t)k * 256 + i]);
            float p = bf2f(pb[(size_t)k * 256 + i]);
            float sn, cs;
            __sincosf(p, &sn, &cs);
            v = make_float2(a * cs + 2e-8f, a * sn + 1e-8f);
        }
        sd[j][__brev((unsigned)i) >> 24] = v;
    }
    __syncthreads();
    fft_stages(sd[t >> 5], tw, t & 31);
    unsigned* base = S + (size_t)bz * ss + (size_t)c * PLANEF_;
    for (int e = t; e < 2048; e += 256) {
        int j = e & 7, h = e >> 3;
        int k = k0 + j;
        if (k < KF_) {
            float2 o = sd[j][h];
            base[(size_t)h * KF_ + k] = pack2bf(make_float2(o.x * (1.f / 256.f), o.y * (1.f / 256.f)));
        }
    }
}

// row-major packed-bf16 spectrum -> 256 real (Hermitian) -> |.| -> bf16
__global__ __launch_bounds__(256) void irfft_rows8_abs(const unsigned* __restrict__ S, size_t ss,
                                                       unsigned short* __restrict__ Y, size_t sy)
{
    __shared__ float2 sd[8][256];
    __shared__ float2 tw[128];
    int t = threadIdx.x;
    int bz = blockIdx.y;
    if (t < 128) { float sn, cs; __sincosf(PI2_ * (float)t * (1.f / 256.f), &sn, &cs); tw[t] = make_float2(cs, sn); }
    size_t r0 = (size_t)blockIdx.x * 8;
    const unsigned* Sb = S + (size_t)bz * ss;
    for (int e = t; e < 2048; e += 256) {
        int j = e >> 8, i = e & 255;
        const unsigned* row = Sb + (r0 + j) * 129;
        float2 v;
        if (i < 129) v = upk(row[i]);
        else { float2 w2 = upk(row[256 - i]); v = make_float2(w2.x, -w2.y); }
        sd[j][__brev((unsigned)i) >> 24] = v;
    }
    __syncthreads();
    fft_stages(sd[t >> 5], tw, t & 31);
    unsigned short* Yb = Y + (size_t)bz * sy;
    for (int e = t; e < 2048; e += 256) {
        int j = e >> 8, i = e & 255;
        Yb[(r0 + j) * 256 + i] = f2bf(fabsf(sd[j][i].x * (1.f / 256.f)));
    }
}

// ---------------------------------------------------------------- host
extern "C" void kernel_launch(void* const* d_in, const int* in_sizes, int n_in,
                              void* d_out, int out_size, void* d_ws, size_t ws_size,
                              hipStream_t stream)
{
    (void)in_sizes; (void)n_in; (void)out_size;
    const float* ms    = (const float*)d_in[0];
    const float* pan   = (const float*)d_in[1];
    const float* ln1w  = (const float*)d_in[2];
    const float* ln1b  = (const float*)d_in[3];
    const float* ln2w  = (const float*)d_in[4];
    const float* ln2b  = (const float*)d_in[5];
    const float* qkvw  = (const float*)d_in[6];
    const float* dww   = (const float*)d_in[7];
    const float* temp  = (const float*)d_in[8];
    const float* projw = (const float*)d_in[9];
    const float* pre1w = (const float*)d_in[10];
    const float* pre1b = (const float*)d_in[11];
    const float* pre2w = (const float*)d_in[12];
    const float* pre2b = (const float*)d_in[13];
    const float* amp1w = (const float*)d_in[14];
    const float* amp1b = (const float*)d_in[15];
    const float* amp2w = (const float*)d_in[16];
    const float* amp2b = (const float*)d_in[17];
    const float* pha1w = (const float*)d_in[18];
    const float* pha1b = (const float*)d_in[19];
    const float* pha2w = (const float*)d_in[20];
    const float* pha2b = (const float*)d_in[21];
    const float* postw = (const float*)d_in[22];
    const float* postb = (const float*)d_in[23];
    const float* pinw  = (const float*)d_in[24];
    const float* poutw = (const float*)d_in[25];

    const size_t SLOT  = 8454144;    // ushorts per per-batch slot
    const size_t CHWu  = 8388608;    // C*HW ushorts
    const size_t CPFu  = 4227072;    // C*PLANEF ushorts
    const size_t SPECu = 4227072;    // C*PLANEF packed complex (unsigned)
    const size_t PARAMU = 344064;    // bf16 weight ushorts
    const size_t PARAMF = 273792;    // f32 param floats

    auto needB = [&](int nb) -> size_t {
        return 2ull * (33554432ull + (size_t)nb * 3ull * SLOT + PARAMU) + 4ull * PARAMF + 64;
    };
    int NB = (ws_size >= needB(4)) ? 4 : ((ws_size >= needB(2)) ? 2 : 1);

    unsigned short* F  = (unsigned short*)d_ws;      // 33554432 ushorts: frefuse bf16 (all batches)
    unsigned short* U0 = F + 33554432;
    unsigned short* U1 = U0 + (size_t)NB * SLOT;
    unsigned short* U2 = U1 + (size_t)NB * SLOT;
    unsigned short* w_qkv   = U2 + (size_t)NB * SLOT;
    unsigned short* w_proj  = w_qkv  + 16384;
    unsigned short* w_pre1  = w_proj + 16384;
    unsigned short* w_pre2  = w_pre1 + 16384;
    unsigned short* w_post  = w_pre2 + 16384;
    unsigned short* w_amp1  = w_post + 16384;   // [128][256]
    unsigned short* w_pha1  = w_amp1 + 32768;
    unsigned short* w_amp2  = w_pha1 + 32768;
    unsigned short* w_pha2  = w_amp2 + 16384;
    unsigned short* w_pin   = w_pha2 + 16384;   // [512][256] folded
    unsigned short* w_pout2 = w_pin  + 131072;  // [2][128][128]
    float* fpar   = (float*)(w_pout2 + 32768);
    float* ksumP  = fpar;
    float* nqsq   = ksumP + 128;     // 512
    float* nksq   = nqsq  + 512;     // 512
    float* attnP  = nksq  + 512;     // 8192
    float* partP  = attnP + 8192;    // 262144
    float* qkv_ws = partP + 262144;
    float* qkv_bb = qkv_ws + 128;
    float* pin_ws = qkv_bb + 128;    // 512
    float* pin_bb = pin_ws + 512;    // 512
    float* pinC   = pin_bb + 512;    // 1024 (float4[256])

    float* xout = (float*)d_out;

    auto CVT = [&](const float* src, unsigned short* dst, int n) {
        tobf16_kernel<<<(n + 255) / 256, 256, 0, stream>>>(src, dst, n);
    };
    foldln_kernel<<<128, 128, 0, stream>>>(qkvw, ln1w, ln1b, w_qkv, qkv_ws, qkv_bb, 128);
    foldln_kernel<<<512, 128, 0, stream>>>(pinw, ln2w, ln2b, w_pin, pin_ws, pin_bb, 256);
    CVT(projw, w_proj, 16384);
    CVT(pre1w, w_pre1, 16384); CVT(pre2w, w_pre2, 16384);
    CVT(postw, w_post, 16384);
    CVT(amp1w, w_amp1, 32768); CVT(pha1w, w_pha1, 32768);
    CVT(amp2w, w_amp2, 16384); CVT(pha2w, w_pha2, 16384);
    poutperm_kernel<<<128, 256, 0, stream>>>(poutw, w_pout2);
    pinc_kernel<<<1, 256, 0, stream>>>(pin_bb, pin_ws, (float4*)pinC);
    ksum_kernel<<<1, 128, 0, stream>>>(dww, ksumP);

    const size_t CHW = (size_t)C_ * HW_;   // floats
    const float* NUL = nullptr;

    for (int b0 = 0; b0 < B_; b0 += NB) {
        const float* msb  = ms  + (size_t)b0 * CHW;
        const float* panb = pan + (size_t)b0 * CHW;
        float* xb = xout + (size_t)b0 * CHW;
        unsigned short* freb = F + (size_t)b0 * CHWu;
        dim3 gz(512, 1, NB);
        dim3 gzf(258, 1, NB);

        // ---- attention ----
        zero2_kernel<<<(NB * 128 + 255) / 256, 256, 0, stream>>>(nqsq, nksq, NB * 128);
        mconv2<0, 1, 0, true><<<gz, 256, 0, stream>>>(
            msb, CHW, w_qkv, 128, nullptr, nullptr, 0, U0, SLOT, HW_, 0, qkv_ws, qkv_bb);
        dwconv2<<<dim3(64, 128, NB), 256, 0, stream>>>(U0, SLOT, dww, ksumP, U1, SLOT, nqsq);   // q
        mconv2<0, 1, 0, true><<<gz, 256, 0, stream>>>(
            panb, CHW, w_qkv, 128, nullptr, nullptr, 0, U0, SLOT, HW_, 0, qkv_ws, qkv_bb);
        dwconv2<<<dim3(64, 128, NB), 256, 0, stream>>>(U0, SLOT, dww, ksumP, U2, SLOT, nksq);   // kv
        gram_kernel<<<dim3(32, 8, NB), 256, 0, stream>>>(U1, SLOT, U2, SLOT, partP);
        softmax_kernel<<<dim3(8, NB), 256, 0, stream>>>(partP, nqsq, nksq, temp, attnP);
        av_kernel<<<dim3(256, 8, NB), 256, 0, stream>>>(attnP, U2, SLOT, U0, SLOT);
        mconv2<1, 0, 0, false><<<gz, 256, 0, stream>>>(
            U0, SLOT, w_proj, 128, nullptr, msb, CHW, xb, CHW, HW_, 0, NUL, NUL);

        // ---- freprocess ----
        mconv2<0, 1, 0, false><<<gz, 256, 0, stream>>>(
            msb, CHW, w_pre1, 128, pre1b, nullptr, 0, U0, SLOT, HW_, 1, NUL, NUL);
        rfft_rowsT<<<dim3(4096, NB), 256, 0, stream>>>(U0, SLOT, (unsigned*)(void*)U1, SPECu);
        cfftT_fwd<<<dim3(17, 128, NB), 256, 0, stream>>>((unsigned*)(void*)U1, SPECu);
        mconv2<0, 1, 0, false><<<gz, 256, 0, stream>>>(
            panb, CHW, w_pre2, 128, pre2b, nullptr, 0, U0, SLOT, HW_, 1, NUL, NUL);
        rfft_rowsT<<<dim3(4096, NB), 256, 0, stream>>>(U0, SLOT, (unsigned*)(void*)U2, SPECu);
        cfftT_fwd<<<dim3(17, 128, NB), 256, 0, stream>>>((unsigned*)(void*)U2, SPECu);
        // fused amp1+pha1 (stage A) + amp2/pha2 (stage B); amp/pha -> U0 slot (spatial dead)
        apconv2<<<gzf, 256, 0, stream>>>(
            (const unsigned*)(void*)U1, (const unsigned*)(void*)U2, SPECu,
            w_amp1, w_pha1, w_amp2, w_pha2, amp1b, pha1b, amp2b, pha2b,
            U0, U0 + CPFu, SLOT);
        cifft_combine<<<dim3(17, 128, NB), 256, 0, stream>>>(
            U0, SLOT, U0 + CPFu, SLOT, (unsigned*)(void*)U2, SPECu);
        irfft_rows8_abs<<<dim3(4096, NB), 256, 0, stream>>>((unsigned*)(void*)U2, SPECu, U0, SLOT);
        mconv2<1, 1, 0, false><<<gz, 256, 0, stream>>>(
            U0, SLOT, w_post, 128, postb, nullptr, 0, freb, CHWu, HW_, 0, NUL, NUL);
    }

    // ---- FFN (full batch, LN2 + gelu-gate fused, residual from LDS) ----
    ffn_mfma6<<<dim3(HW_ / 64, B_), 256, 0, stream>>>(xout, F, w_pin, w_pout2, (const float4*)pinC, xout);
}

// Round 12
// 1640.404 us; speedup vs baseline: 1.2393x; 1.0647x over previous
//
#include <hip/hip_runtime.h>
#include <math.h>

#define B_ 4
#define C_ 128
#define HW_ 65536
#define H__ 256
#define KF_ 129
#define PLANEF_ 33024

typedef __attribute__((ext_vector_type(8))) short short8v;
typedef __attribute__((ext_vector_type(4))) float f32x4;
typedef __attribute__((ext_vector_type(4))) unsigned short ush4;
typedef __attribute__((ext_vector_type(8))) unsigned short ush8;
typedef __attribute__((ext_vector_type(4))) unsigned uint4v;

__device__ __forceinline__ unsigned short f2bf(float f) {
    union { float f; unsigned u; } v; v.f = f;
    return (unsigned short)((v.u + 0x7FFFu + ((v.u >> 16) & 1u)) >> 16);
}
__device__ __forceinline__ float bf2f(unsigned short s) {
    union { unsigned u; float f; } v; v.u = (unsigned)s << 16;
    return v.f;
}
__device__ __forceinline__ unsigned pack2bf(float2 v) {
    return (unsigned)f2bf(v.x) | ((unsigned)f2bf(v.y) << 16);
}
__device__ __forceinline__ float2 upk(unsigned u) {
    return make_float2(bf2f((unsigned short)(u & 0xffff)), bf2f((unsigned short)(u >> 16)));
}
// fast gelu: A&S 7.1.26 erf (|err|<=1.5e-7) with __expf
__device__ __forceinline__ float geluf(float x) {
    float z = 0.70710678118654752f * fabsf(x);
    float t = __fdividef(1.f, fmaf(0.3275911f, z, 1.f));
    float p = fmaf(1.061405429f, t, -1.453152027f);
    p = fmaf(p, t, 1.421413741f);
    p = fmaf(p, t, -0.284496736f);
    p = fmaf(p, t, 0.254829592f);
    p = p * t;
    float erfv = 1.f - p * __expf(-z * z);
    float cdf = (x >= 0.f) ? fmaf(0.5f, erfv, 0.5f) : fmaf(-0.5f, erfv, 0.5f);
    return x * cdf;
}
// fast atan2, poly err ~1e-5 rad
__device__ __forceinline__ float fatan2(float y, float x) {
    float ax = fabsf(x), ay = fabsf(y);
    float mx = fmaxf(ax, ay), mn = fminf(ax, ay);
    float a = __fdividef(mn, fmaxf(mx, 1e-38f));
    float s = a * a;
    float r = fmaf(0.0208351f, s, -0.0851330f);
    r = fmaf(r, s, 0.1801410f);
    r = fmaf(r, s, -0.3302995f);
    r = fmaf(r, s, 0.9998660f);
    r = r * a;
    if (ay > ax) r = 1.57079632679489662f - r;
    if (x < 0.f) r = 3.14159265358979324f - r;
    return copysignf(r, y);
}
// LDS XOR swizzle on byte-offset within row
template<int W>
__device__ __forceinline__ char* swz_ptr(unsigned short (*xs)[W], int px, int cb) {
    return (char*)xs + px * (W * 2) + (cb ^ (((px >> 2) & 7) << 4));
}

// ---------------------------------------------------------------- prep
__global__ __launch_bounds__(256) void tobf16_kernel(const float* __restrict__ src,
                                                     unsigned short* __restrict__ dst, int n)
{
    int i = blockIdx.x * 256 + threadIdx.x;
    if (i < n) dst[i] = f2bf(src[i]);
}

__global__ __launch_bounds__(128) void foldln_kernel(const float* __restrict__ W,
                                                     const float* __restrict__ lnw,
                                                     const float* __restrict__ lnb,
                                                     unsigned short* __restrict__ Wb,
                                                     float* __restrict__ wsum, float* __restrict__ bsum,
                                                     int Cc)
{
    int o = blockIdx.x, t = threadIdx.x;
    float sw = 0.f, sb = 0.f;
    for (int c = t; c < Cc; c += 128) {
        float w = W[(size_t)o * Cc + c];
        float fw = w * lnw[c];
        unsigned short us = f2bf(fw);
        Wb[(size_t)o * Cc + c] = us;
        sw += bf2f(us);
        sb += w * lnb[c];
    }
    __shared__ float r1[128], r2[128];
    r1[t] = sw; r2[t] = sb; __syncthreads();
    for (int st = 64; st; st >>= 1) {
        if (t < st) { r1[t] += r1[t + st]; r2[t] += r2[t + st]; }
        __syncthreads();
    }
    if (!t) { wsum[o] = r1[0]; bsum[o] = r2[0]; }
}

__global__ __launch_bounds__(256) void poutperm_kernel(const float* __restrict__ src,
                                                       unsigned short* __restrict__ dst)
{
    int i = blockIdx.x * 256 + threadIdx.x;   // 32768
    int half = i >> 14, rem = i & 16383, o = rem >> 7, kp = rem & 127;
    int h = (kp >> 5) * 64 + half * 32 + (kp & 31);
    dst[i] = f2bf(src[o * 256 + h]);
}

__global__ void pinc_kernel(const float* __restrict__ bb, const float* __restrict__ ws,
                            float4* __restrict__ pinC)
{
    int i = threadIdx.x;
    if (i < 256) pinC[i] = make_float4(bb[i], ws[i], bb[i + 256], ws[i + 256]);
}

__global__ void ksum_kernel(const float* __restrict__ dw, float* __restrict__ ks)
{
    int c = threadIdx.x;
    if (c < C_) {
        float s = 0.f;
        for (int k = 0; k < 9; ++k) s += dw[c * 9 + k];
        ks[c] = s;
    }
}

__global__ __launch_bounds__(256) void zero2_kernel(float* __restrict__ a, float* __restrict__ b, int n)
{
    int i = blockIdx.x * 256 + threadIdx.x;
    if (i < n) { a[i] = 0.f; b[i] = 0.f; }
}

// ---------------------------------------------------------------- MFMA conv1x1 (CIN=128)
template<int INBF, int OUTBF, int PRO, bool LNF>
__global__ __launch_bounds__(256, 4) void mconv2(
    const void* __restrict__ Xv, size_t sx,
    const unsigned short* __restrict__ Wb, int wstride,
    const float* __restrict__ bias,
    const float* __restrict__ res, size_t sres,
    void* __restrict__ Yv, size_t sy, int plane, int flags,
    const float* __restrict__ wsum, const float* __restrict__ bsum)
{
    __shared__ unsigned short xs[128][136];
    __shared__ float2 lnred[LNF ? 8 : 1][LNF ? 128 : 1];
    __shared__ float2 lnmi[LNF ? 128 : 1];
    const int t = threadIdx.x;
    const int bz = blockIdx.z;
    const int p0 = blockIdx.x * 128;
    const int lane = t & 63;
    const int wr = t >> 7, wc = (t >> 6) & 1;
    const int lr = lane >> 4, lc = lane & 15;

    if constexpr (INBF == 0) {
        const float* Xb = (const float*)Xv + (size_t)bz * sx;
        const int px4 = t & 31;
        float s0 = 0.f, s1 = 0.f, s2v = 0.f, s3 = 0.f;
        float q0 = 0.f, q1 = 0.f, q2 = 0.f, q3 = 0.f;
#pragma unroll
        for (int g = 0; g < 2; ++g) {
            float4 st[8];
#pragma unroll
            for (int i = 0; i < 8; ++i) {
                int e = t + (g * 8 + i) * 256;
                int c = e >> 5;
                st[i] = *(const float4*)(Xb + (size_t)c * plane + p0 + px4 * 4);
            }
#pragma unroll
            for (int i = 0; i < 8; ++i) {
                int e = t + (g * 8 + i) * 256;
                int c = e >> 5;
                float a0 = st[i].x, a1 = st[i].y, a2 = st[i].z, a3 = st[i].w;
                if constexpr (PRO == 1) {
                    a0 = a0 > 0.f ? a0 : 0.1f * a0;
                    a1 = a1 > 0.f ? a1 : 0.1f * a1;
                    a2 = a2 > 0.f ? a2 : 0.1f * a2;
                    a3 = a3 > 0.f ? a3 : 0.1f * a3;
                }
                if constexpr (LNF) {
                    s0 += a0; q0 += a0 * a0;
                    s1 += a1; q1 += a1 * a1;
                    s2v += a2; q2 += a2 * a2;
                    s3 += a3; q3 += a3 * a3;
                }
                *(unsigned short*)swz_ptr(xs, px4 * 4 + 0, 2 * c) = f2bf(a0);
                *(unsigned short*)swz_ptr(xs, px4 * 4 + 1, 2 * c) = f2bf(a1);
                *(unsigned short*)swz_ptr(xs, px4 * 4 + 2, 2 * c) = f2bf(a2);
                *(unsigned short*)swz_ptr(xs, px4 * 4 + 3, 2 * c) = f2bf(a3);
            }
        }
        if constexpr (LNF) {
            lnred[t >> 5][px4 * 4 + 0] = make_float2(s0, q0);
            lnred[t >> 5][px4 * 4 + 1] = make_float2(s1, q1);
            lnred[t >> 5][px4 * 4 + 2] = make_float2(s2v, q2);
            lnred[t >> 5][px4 * 4 + 3] = make_float2(s3, q3);
        }
    } else {
        const unsigned short* Xb = (const unsigned short*)Xv + (size_t)bz * sx;
        ush8 st[8];
#pragma unroll
        for (int i = 0; i < 8; ++i) {
            int e = t + i * 256;
            int c = e >> 4, px8 = e & 15;
            st[i] = *(const ush8*)(Xb + (size_t)c * plane + p0 + px8 * 8);
        }
#pragma unroll
        for (int i = 0; i < 8; ++i) {
            int e = t + i * 256;
            int c = e >> 4, px8 = e & 15;
#pragma unroll
            for (int j = 0; j < 8; ++j) {
                unsigned short us = (unsigned short)st[i][j];
                if constexpr (PRO == 1) {
                    float f = bf2f(us);
                    f = f > 0.f ? f : 0.1f * f;
                    us = f2bf(f);
                }
                *(unsigned short*)swz_ptr(xs, px8 * 8 + j, 2 * c) = us;
            }
        }
    }
    __syncthreads();
    if constexpr (LNF) {
        if (t < 128) {
            float ss = 0.f, qq = 0.f;
#pragma unroll
            for (int j = 0; j < 8; ++j) { float2 a = lnred[j][t]; ss += a.x; qq += a.y; }
            float m = ss * (1.f / 128.f);
            float inv = rsqrtf(qq * (1.f / 128.f) - m * m + 1e-5f);
            lnmi[t] = make_float2(m, inv);
        }
        __syncthreads();
    }

    f32x4 acc[4][4];
#pragma unroll
    for (int mi = 0; mi < 4; ++mi)
#pragma unroll
        for (int ni = 0; ni < 4; ++ni) acc[mi][ni] = (f32x4){0.f, 0.f, 0.f, 0.f};

#pragma unroll
    for (int kk = 0; kk < 128; kk += 32) {
        short8v bfr[4];
#pragma unroll
        for (int ni = 0; ni < 4; ++ni)
            bfr[ni] = *(const short8v*)swz_ptr(xs, wc * 64 + ni * 16 + lc, 2 * (kk + lr * 8));
#pragma unroll
        for (int mi = 0; mi < 4; ++mi) {
            int row = wr * 64 + mi * 16 + lc;
            short8v afr = *(const short8v*)(Wb + (size_t)row * wstride + kk + lr * 8);
#pragma unroll
            for (int ni = 0; ni < 4; ++ni)
                acc[mi][ni] = __builtin_amdgcn_mfma_f32_16x16x32_bf16(afr, bfr[ni], acc[mi][ni], 0, 0, 0);
        }
    }

    float2 mrow[4];
    if constexpr (LNF) {
#pragma unroll
        for (int ni = 0; ni < 4; ++ni) mrow[ni] = lnmi[wc * 64 + ni * 16 + lc];
    }

#pragma unroll
    for (int mi = 0; mi < 4; ++mi) {
        int ob = wr * 64 + mi * 16 + lr * 4;
#pragma unroll
        for (int r = 0; r < 4; ++r) {
            int o = ob + r;
            float bv = 0.f, wso = 0.f;
            if constexpr (LNF) { bv = bsum[o]; wso = wsum[o]; }
            else { if (bias) bv = bias[o]; if (flags & 1) bv += 1e-8f; }
#pragma unroll
            for (int ni = 0; ni < 4; ++ni) {
                int px = wc * 64 + ni * 16 + lc;
                float v;
                if constexpr (LNF) {
                    float m = mrow[ni].x, inv = mrow[ni].y;
                    v = acc[mi][ni][r] * inv + bv - m * inv * wso;
                } else {
                    v = acc[mi][ni][r] + bv;
                }
                if constexpr (OUTBF == 0) {
                    float* Y = (float*)Yv;
                    size_t yi = (size_t)bz * sy + (size_t)o * plane + p0 + px;
                    if (res) v += res[(size_t)bz * sres + (size_t)o * plane + p0 + px];
                    Y[yi] = v;
                } else {
                    unsigned short* Y = (unsigned short*)Yv;
                    Y[(size_t)bz * sy + (size_t)o * plane + p0 + px] = f2bf(v);
                }
            }
        }
    }
}

// ---------------------------------------------------------------- fused amp1+pha1+amp2+pha2 spectral block
__global__ __launch_bounds__(256, 2) void apconv2(
    const unsigned* __restrict__ T1, const unsigned* __restrict__ T2, size_t sT,
    const unsigned short* __restrict__ Wa1, const unsigned short* __restrict__ Wp1,  // [128][256]
    const unsigned short* __restrict__ Wa2, const unsigned short* __restrict__ Wp2,  // [128][128]
    const float* __restrict__ ba1, const float* __restrict__ bp1,
    const float* __restrict__ ba2, const float* __restrict__ bp2,
    unsigned short* __restrict__ AMP, unsigned short* __restrict__ PHA, size_t sO)
{
    __shared__ __align__(16) unsigned short buf[2][128][72];
    const int t = threadIdx.x;
    const int bz = blockIdx.z;
    const int p0 = blockIdx.x * 128;
    const int lane = t & 63;
    const int wr = t >> 7, wc = (t >> 6) & 1;
    const int lr = lane >> 4, lc = lane & 15;
    const int px2 = t & 63;

    typedef unsigned short (*row72)[72];
    typedef unsigned short (*row144)[144];
    row72 xa = (row72)buf[0];
    row72 xp = (row72)buf[1];
    row144 hb = (row144)&buf[0][0][0];

    f32x4 aa[4][4], ap[4][4];
#pragma unroll
    for (int mi = 0; mi < 4; ++mi)
#pragma unroll
        for (int ni = 0; ni < 4; ++ni) { aa[mi][ni] = (f32x4){0.f,0.f,0.f,0.f}; ap[mi][ni] = (f32x4){0.f,0.f,0.f,0.f}; }

    for (int ch = 0; ch < 256; ch += 64) {
        const unsigned* Ts = ((ch < 128) ? T1 : T2) + (size_t)bz * sT + (size_t)(ch & 127) * PLANEF_;
#pragma unroll
        for (int g = 0; g < 2; ++g) {
            uint2 st[8];
#pragma unroll
            for (int i = 0; i < 8; ++i) {
                int e = t + (g * 8 + i) * 256;
                int c = e >> 6;
                st[i] = *(const uint2*)(Ts + (size_t)c * PLANEF_ + p0 + px2 * 2);
            }
#pragma unroll
            for (int i = 0; i < 8; ++i) {
                int e = t + (g * 8 + i) * 256;
                int c = e >> 6;
                float2 z0 = upk(st[i].x), z1 = upk(st[i].y);
                float m0 = sqrtf(z0.x * z0.x + z0.y * z0.y);
                float m1 = sqrtf(z1.x * z1.x + z1.y * z1.y);
                float a0 = fatan2(z0.y, z0.x);
                float a1 = fatan2(z1.y, z1.x);
                *(unsigned short*)swz_ptr(xa, px2 * 2 + 0, 2 * c) = f2bf(m0);
                *(unsigned short*)swz_ptr(xa, px2 * 2 + 1, 2 * c) = f2bf(m1);
                *(unsigned short*)swz_ptr(xp, px2 * 2 + 0, 2 * c) = f2bf(a0);
                *(unsigned short*)swz_ptr(xp, px2 * 2 + 1, 2 * c) = f2bf(a1);
            }
        }
        __syncthreads();
#pragma unroll
        for (int kk = 0; kk < 64; kk += 32) {
            short8v bfa[4], bfp[4];
#pragma unroll
            for (int ni = 0; ni < 4; ++ni) {
                bfa[ni] = *(const short8v*)swz_ptr(xa, wc * 64 + ni * 16 + lc, 2 * (kk + lr * 8));
                bfp[ni] = *(const short8v*)swz_ptr(xp, wc * 64 + ni * 16 + lc, 2 * (kk + lr * 8));
            }
#pragma unroll
            for (int mi = 0; mi < 4; ++mi) {
                int row = wr * 64 + mi * 16 + lc;
                short8v afa = *(const short8v*)(Wa1 + (size_t)row * 256 + ch + kk + lr * 8);
                short8v afp = *(const short8v*)(Wp1 + (size_t)row * 256 + ch + kk + lr * 8);
#pragma unroll
                for (int ni = 0; ni < 4; ++ni) {
                    aa[mi][ni] = __builtin_amdgcn_mfma_f32_16x16x32_bf16(afa, bfa[ni], aa[mi][ni], 0, 0, 0);
                    ap[mi][ni] = __builtin_amdgcn_mfma_f32_16x16x32_bf16(afp, bfp[ni], ap[mi][ni], 0, 0, 0);
                }
            }
        }
        __syncthreads();
    }

    // ---- stage B (amp) ----
#pragma unroll
    for (int mi = 0; mi < 4; ++mi)
#pragma unroll
        for (int r = 0; r < 4; ++r) {
            int o = wr * 64 + mi * 16 + lr * 4 + r;
            float bva = ba1[o];
#pragma unroll
            for (int ni = 0; ni < 4; ++ni) {
                int px = wc * 64 + ni * 16 + lc;
                float v = aa[mi][ni][r] + bva;
                v = v > 0.f ? v : 0.1f * v;
                *(unsigned short*)swz_ptr(hb, px, 2 * o) = f2bf(v);
            }
        }
    __syncthreads();
    {
        f32x4 acc[4][4];
#pragma unroll
        for (int mi = 0; mi < 4; ++mi)
#pragma unroll
            for (int ni = 0; ni < 4; ++ni) acc[mi][ni] = (f32x4){0.f,0.f,0.f,0.f};
#pragma unroll
        for (int kk = 0; kk < 128; kk += 32) {
            short8v bfr[4];
#pragma unroll
            for (int ni = 0; ni < 4; ++ni)
                bfr[ni] = *(const short8v*)swz_ptr(hb, wc * 64 + ni * 16 + lc, 2 * (kk + lr * 8));
#pragma unroll
            for (int mi = 0; mi < 4; ++mi) {
                int row = wr * 64 + mi * 16 + lc;
                short8v afr = *(const short8v*)(Wa2 + (size_t)row * 128 + kk + lr * 8);
#pragma unroll
                for (int ni = 0; ni < 4; ++ni)
                    acc[mi][ni] = __builtin_amdgcn_mfma_f32_16x16x32_bf16(afr, bfr[ni], acc[mi][ni], 0, 0, 0);
            }
        }
#pragma unroll
        for (int mi = 0; mi < 4; ++mi)
#pragma unroll
            for (int r = 0; r < 4; ++r) {
                int o = wr * 64 + mi * 16 + lr * 4 + r;
                float bv = ba2[o];
#pragma unroll
                for (int ni = 0; ni < 4; ++ni) {
                    int px = wc * 64 + ni * 16 + lc;
                    AMP[(size_t)bz * sO + (size_t)o * PLANEF_ + p0 + px] = f2bf(acc[mi][ni][r] + bv);
                }
            }
    }
    __syncthreads();

    // ---- stage B (pha) ----
#pragma unroll
    for (int mi = 0; mi < 4; ++mi)
#pragma unroll
        for (int r = 0; r < 4; ++r) {
            int o = wr * 64 + mi * 16 + lr * 4 + r;
            float bvp = bp1[o];
#pragma unroll
            for (int ni = 0; ni < 4; ++ni) {
                int px = wc * 64 + ni * 16 + lc;
                float v = ap[mi][ni][r] + bvp;
                v = v > 0.f ? v : 0.1f * v;
                *(unsigned short*)swz_ptr(hb, px, 2 * o) = f2bf(v);
            }
        }
    __syncthreads();
    {
        f32x4 acc[4][4];
#pragma unroll
        for (int mi = 0; mi < 4; ++mi)
#pragma unroll
            for (int ni = 0; ni < 4; ++ni) acc[mi][ni] = (f32x4){0.f,0.f,0.f,0.f};
#pragma unroll
        for (int kk = 0; kk < 128; kk += 32) {
            short8v bfr[4];
#pragma unroll
            for (int ni = 0; ni < 4; ++ni)
                bfr[ni] = *(const short8v*)swz_ptr(hb, wc * 64 + ni * 16 + lc, 2 * (kk + lr * 8));
#pragma unroll
            for (int mi = 0; mi < 4; ++mi) {
                int row = wr * 64 + mi * 16 + lc;
                short8v afr = *(const short8v*)(Wp2 + (size_t)row * 128 + kk + lr * 8);
#pragma unroll
                for (int ni = 0; ni < 4; ++ni)
                    acc[mi][ni] = __builtin_amdgcn_mfma_f32_16x16x32_bf16(afr, bfr[ni], acc[mi][ni], 0, 0, 0);
            }
        }
#pragma unroll
        for (int mi = 0; mi < 4; ++mi)
#pragma unroll
            for (int r = 0; r < 4; ++r) {
                int o = wr * 64 + mi * 16 + lr * 4 + r;
                float bv = bp2[o];
#pragma unroll
                for (int ni = 0; ni < 4; ++ni) {
                    int px = wc * 64 + ni * 16 + lc;
                    PHA[(size_t)bz * sO + (size_t)o * PLANEF_ + p0 + px] = f2bf(acc[mi][ni][r] + bv);
                }
            }
    }
}

// ---------------------------------------------------------------- fused MFMA FFN (x f32, fre bf16; residual from LDS)
__global__ __launch_bounds__(256, 3) void ffn_mfma6(
    const float* __restrict__ x, const unsigned short* __restrict__ fre,
    const unsigned short* __restrict__ pinb,
    const unsigned short* __restrict__ pout2,
    const float4* __restrict__ pinC,
    float* __restrict__ out)
{
    __shared__ unsigned short xs[64][264];
    __shared__ unsigned short hs[64][136];
    __shared__ float2 muinv[64];
    float2* sred = (float2*)&hs[0][0];
    const int b = blockIdx.y;
    const size_t p0 = (size_t)blockIdx.x * 64;
    const int t = threadIdx.x;
    const int wave = t >> 6, lane = t & 63;
    const int lr = lane >> 4, lc = lane & 15;
    const int px4 = t & 15;

    float s0 = 0.f, s1 = 0.f, s2v = 0.f, s3 = 0.f;
    float q0 = 0.f, q1 = 0.f, q2 = 0.f, q3 = 0.f;
    {
        float4 stx[8];
        ush4 stf[8];
#pragma unroll
        for (int i = 0; i < 8; ++i) {
            int e = t + i * 256;
            int c = e >> 4;
            stx[i] = *(const float4*)(x + ((size_t)b * 128 + c) * HW_ + p0 + px4 * 4);
        }
#pragma unroll
        for (int i = 0; i < 8; ++i) {
            int e = t + i * 256;
            int c = e >> 4;
            stf[i] = *(const ush4*)(fre + (size_t)b * 8388608 + (size_t)c * HW_ + p0 + px4 * 4);
        }
#pragma unroll
        for (int i = 0; i < 8; ++i) {
            int e = t + i * 256;
            int c = e >> 4;
            float a0 = stx[i].x, a1 = stx[i].y, a2 = stx[i].z, a3 = stx[i].w;
            s0 += a0; q0 += a0 * a0;
            s1 += a1; q1 += a1 * a1;
            s2v += a2; q2 += a2 * a2;
            s3 += a3; q3 += a3 * a3;
            *(unsigned short*)swz_ptr(xs, px4 * 4 + 0, 2 * c) = f2bf(a0);
            *(unsigned short*)swz_ptr(xs, px4 * 4 + 1, 2 * c) = f2bf(a1);
            *(unsigned short*)swz_ptr(xs, px4 * 4 + 2, 2 * c) = f2bf(a2);
            *(unsigned short*)swz_ptr(xs, px4 * 4 + 3, 2 * c) = f2bf(a3);
        }
#pragma unroll
        for (int i = 0; i < 8; ++i) {
            int e = t + i * 256;
            int c = e >> 4;
            float a0 = bf2f((unsigned short)stf[i][0]);
            float a1 = bf2f((unsigned short)stf[i][1]);
            float a2 = bf2f((unsigned short)stf[i][2]);
            float a3 = bf2f((unsigned short)stf[i][3]);
            s0 += a0; q0 += a0 * a0;
            s1 += a1; q1 += a1 * a1;
            s2v += a2; q2 += a2 * a2;
            s3 += a3; q3 += a3 * a3;
            *(unsigned short*)swz_ptr(xs, px4 * 4 + 0, 2 * (128 + c)) = (unsigned short)stf[i][0];
            *(unsigned short*)swz_ptr(xs, px4 * 4 + 1, 2 * (128 + c)) = (unsigned short)stf[i][1];
            *(unsigned short*)swz_ptr(xs, px4 * 4 + 2, 2 * (128 + c)) = (unsigned short)stf[i][2];
            *(unsigned short*)swz_ptr(xs, px4 * 4 + 3, 2 * (128 + c)) = (unsigned short)stf[i][3];
        }
    }
    sred[(t >> 4) * 64 + px4 * 4 + 0] = make_float2(s0, q0);
    sred[(t >> 4) * 64 + px4 * 4 + 1] = make_float2(s1, q1);
    sred[(t >> 4) * 64 + px4 * 4 + 2] = make_float2(s2v, q2);
    sred[(t >> 4) * 64 + px4 * 4 + 3] = make_float2(s3, q3);
    __syncthreads();
    if (t < 64) {
        float ss = 0.f, qq = 0.f;
#pragma unroll
        for (int j = 0; j < 16; ++j) { float2 a = sred[j * 64 + t]; ss += a.x; qq += a.y; }
        float m = ss * (1.f / 256.f);
        float inv = rsqrtf(qq * (1.f / 256.f) - m * m + 1e-5f);
        muinv[t] = make_float2(m, inv);
    }
    __syncthreads();

    float2 mrow[4];
#pragma unroll
    for (int ni = 0; ni < 4; ++ni) mrow[ni] = muinv[ni * 16 + lc];

    f32x4 oc[2][4];
#pragma unroll
    for (int mi = 0; mi < 2; ++mi)
#pragma unroll
        for (int ni = 0; ni < 4; ++ni) oc[mi][ni] = (f32x4){0.f, 0.f, 0.f, 0.f};

#pragma unroll
    for (int half = 0; half < 2; ++half) {
        f32x4 a1[2][4], a2[2][4];
#pragma unroll
        for (int mi = 0; mi < 2; ++mi)
#pragma unroll
            for (int ni = 0; ni < 4; ++ni) { a1[mi][ni] = (f32x4){0.f,0.f,0.f,0.f}; a2[mi][ni] = (f32x4){0.f,0.f,0.f,0.f}; }

#pragma unroll
        for (int k0 = 0; k0 < 256; k0 += 32) {
            short8v bfr[4];
#pragma unroll
            for (int ni = 0; ni < 4; ++ni)
                bfr[ni] = *(const short8v*)swz_ptr(xs, ni * 16 + lc, 2 * (k0 + lr * 8));
#pragma unroll
            for (int mi = 0; mi < 2; ++mi) {
                int hrow = wave * 64 + half * 32 + mi * 16 + lc;
                short8v af1 = *(const short8v*)(pinb + (size_t)hrow * 256 + k0 + lr * 8);
                short8v af2 = *(const short8v*)(pinb + (size_t)(hrow + 256) * 256 + k0 + lr * 8);
#pragma unroll
                for (int ni = 0; ni < 4; ++ni) {
                    a1[mi][ni] = __builtin_amdgcn_mfma_f32_16x16x32_bf16(af1, bfr[ni], a1[mi][ni], 0, 0, 0);
                    a2[mi][ni] = __builtin_amdgcn_mfma_f32_16x16x32_bf16(af2, bfr[ni], a2[mi][ni], 0, 0, 0);
                }
            }
        }
        __syncthreads();
#pragma unroll
        for (int mi = 0; mi < 2; ++mi)
#pragma unroll
            for (int r = 0; r < 4; ++r) {
                int ho = wave * 64 + half * 32 + mi * 16 + lr * 4 + r;
                float4 bwc = pinC[ho];
                int kp = wave * 32 + mi * 16 + lr * 4 + r;
#pragma unroll
                for (int ni = 0; ni < 4; ++ni) {
                    float m = mrow[ni].x, inv = mrow[ni].y;
                    float v1 = a1[mi][ni][r] * inv + bwc.x - m * inv * bwc.y;
                    float v2 = a2[mi][ni][r] * inv + bwc.z - m * inv * bwc.w;
                    hs[ni * 16 + lc][kp] = f2bf(geluf(v1) * v2);
                }
            }
        __syncthreads();
#pragma unroll
        for (int k0 = 0; k0 < 128; k0 += 32) {
            short8v bfr2[4];
#pragma unroll
            for (int ni = 0; ni < 4; ++ni)
                bfr2[ni] = *(const short8v*)&hs[ni * 16 + lc][k0 + lr * 8];
#pragma unroll
            for (int mi = 0; mi < 2; ++mi) {
                int orow = wave * 32 + mi * 16 + lc;
                short8v af = *(const short8v*)(pout2 + half * 16384 + orow * 128 + k0 + lr * 8);
#pragma unroll
                for (int ni = 0; ni < 4; ++ni)
                    oc[mi][ni] = __builtin_amdgcn_mfma_f32_16x16x32_bf16(af, bfr2[ni], oc[mi][ni], 0, 0, 0);
            }
        }
    }

#pragma unroll
    for (int mi = 0; mi < 2; ++mi)
#pragma unroll
        for (int r = 0; r < 4; ++r) {
            int o = wave * 32 + mi * 16 + lr * 4 + r;
#pragma unroll
            for (int ni = 0; ni < 4; ++ni) {
                int px = ni * 16 + lc;
                float rx = bf2f(*(const unsigned short*)swz_ptr(xs, px, 2 * o));
                size_t yi = ((size_t)b * 128 + o) * HW_ + p0 + px;
                out[yi] = oc[mi][ni][r] + rx;
            }
        }
}

// ---------------------------------------------------------------- depthwise 3x3 cd-conv (bf16), 8 px/thread, fused ssq
__global__ __launch_bounds__(256) void dwconv2(const unsigned short* __restrict__ X, size_t sx,
                                               const float* __restrict__ w9,
                                               const float* __restrict__ ksum,
                                               unsigned short* __restrict__ Y, size_t sy,
                                               float* __restrict__ ssq)
{
    int bz = blockIdx.z;
    int c = blockIdx.y;
    int p8 = blockIdx.x * 256 + threadIdx.x;   // grid x = 32
    int p0 = p8 * 8;
    int i = p0 >> 8, j0 = p0 & 255;
    const unsigned short* xp = X + (size_t)bz * sx + (size_t)c * HW_;
    const float* wc = w9 + c * 9;
    float a[8] = {0.f,0.f,0.f,0.f,0.f,0.f,0.f,0.f};
    float ctr[8];
#pragma unroll
    for (int di = -1; di <= 1; ++di) {
        int ii = i + di;
        if (ii < 0 || ii > 255) continue;
        const unsigned short* row = xp + ii * 256;
        ush8 m8 = *(const ush8*)(row + j0);
        float lft = (j0 > 0) ? bf2f(row[j0 - 1]) : 0.f;
        float rgt = (j0 < 248) ? bf2f(row[j0 + 8]) : 0.f;
        float v[10];
        v[0] = lft;
#pragma unroll
        for (int k = 0; k < 8; ++k) v[k + 1] = bf2f((unsigned short)m8[k]);
        v[9] = rgt;
        if (di == 0) {
#pragma unroll
            for (int k = 0; k < 8; ++k) ctr[k] = v[k + 1];
        }
        float w0 = wc[(di + 1) * 3], w1 = wc[(di + 1) * 3 + 1], w2 = wc[(di + 1) * 3 + 2];
#pragma unroll
        for (int k = 0; k < 8; ++k) a[k] += w0 * v[k] + w1 * v[k + 1] + w2 * v[k + 2];
    }
    float km = 0.7f * ksum[c];
    ush8 ov;
    float q = 0.f;
#pragma unroll
    for (int k = 0; k < 8; ++k) {
        float o = a[k] - km * ctr[k];
        ov[k] = f2bf(o);
        q += o * o;
    }
    *(ush8*)(Y + (size_t)bz * sy + (size_t)c * HW_ + p0) = ov;

    __shared__ float red[256];
    red[threadIdx.x] = q; __syncthreads();
    for (int st = 128; st; st >>= 1) {
        if (threadIdx.x < st) red[threadIdx.x] += red[threadIdx.x + st];
        __syncthreads();
    }
    if (!threadIdx.x) atomicAdd(&ssq[bz * C_ + c], red[0]);
}

// ---------------------------------------------------------------- attention helpers (bf16 q/k/v)
__global__ __launch_bounds__(256) void gram_kernel(const unsigned short* __restrict__ Q, size_t sq,
                                                   const unsigned short* __restrict__ K, size_t sk,
                                                   float* __restrict__ part)
{
    int sl = blockIdx.x, h = blockIdx.y, bz = blockIdx.z;
    const unsigned short* qb = Q + (size_t)bz * sq + (size_t)(h * 16) * HW_;
    const unsigned short* kb = K + (size_t)bz * sk + (size_t)(h * 16) * HW_;
    __shared__ __align__(16) float qs[16][264];
    __shared__ __align__(16) float ks[16][264];
    int c = threadIdx.x >> 4, d = threadIdx.x & 15;
    int t = threadIdx.x;
    float acc = 0.f;
    for (int n0 = sl * 2048; n0 < (sl + 1) * 2048; n0 += 256) {
        ush4 qv[4], kv[4];
#pragma unroll
        for (int ii = 0; ii < 4; ++ii) {
            int e = t + ii * 256;       // 1024: 16 c x 64 n4
            int cc = e >> 6, n4 = e & 63;
            qv[ii] = *(const ush4*)(qb + (size_t)cc * HW_ + n0 + n4 * 4);
            kv[ii] = *(const ush4*)(kb + (size_t)cc * HW_ + n0 + n4 * 4);
        }
#pragma unroll
        for (int ii = 0; ii < 4; ++ii) {
            int e = t + ii * 256;
            int cc = e >> 6, n4 = e & 63;
#pragma unroll
            for (int j = 0; j < 4; ++j) {
                qs[cc][n4 * 4 + j] = bf2f((unsigned short)qv[ii][j]);
                ks[cc][n4 * 4 + j] = bf2f((unsigned short)kv[ii][j]);
            }
        }
        __syncthreads();
#pragma unroll 16
        for (int nn = 0; nn < 256; nn += 4) {
            float4 a4 = *(const float4*)&qs[c][nn];
            float4 b4 = *(const float4*)&ks[d][nn];
            acc += a4.x * b4.x + a4.y * b4.y + a4.z * b4.z + a4.w * b4.w;
        }
        __syncthreads();
    }
    part[((size_t)(bz * 8 + h) * 32 + sl) * 256 + threadIdx.x] = acc;
}

__global__ __launch_bounds__(256) void softmax_kernel(const float* __restrict__ part,
                                                      const float* __restrict__ nqsq,
                                                      const float* __restrict__ nksq,
                                                      const float* __restrict__ temp,
                                                      float* __restrict__ attn)
{
    int h = blockIdx.x, bz = blockIdx.y;
    int t = threadIdx.x;
    int c = t >> 4, d = t & 15;
    float g = 0.f;
    for (int sl = 0; sl < 32; ++sl) g += part[((size_t)(bz * 8 + h) * 32 + sl) * 256 + t];
    float nqv = fmaxf(sqrtf(nqsq[bz * C_ + h * 16 + c]), 1e-12f);
    float nkv = fmaxf(sqrtf(nksq[bz * C_ + h * 16 + d]), 1e-12f);
    g *= temp[h] / (nqv * nkv);
    float m = g;
#pragma unroll
    for (int off = 8; off; off >>= 1) m = fmaxf(m, __shfl_xor(m, off, 16));
    float e = __expf(g - m);
    float ssum = e;
#pragma unroll
    for (int off = 8; off; off >>= 1) ssum += __shfl_xor(ssum, off, 16);
    attn[(bz * 8 + h) * 256 + t] = e / ssum;
}

__global__ __launch_bounds__(256) void av_kernel(const float* __restrict__ attn,
                                                 const unsigned short* __restrict__ V, size_t sv,
                                                 unsigned short* __restrict__ Y, size_t sy)
{
    __shared__ __align__(16) float kv[16][260];
    __shared__ __align__(16) float at[16][16];
    int tile = blockIdx.x, h = blockIdx.y, bz = blockIdx.z;
    int n0 = tile * 256, t = threadIdx.x;
    const unsigned short* vb = V + (size_t)bz * sv + (size_t)(h * 16) * HW_;
    at[t >> 4][t & 15] = attn[(size_t)(bz * 8 + h) * 256 + (t & 15) * 16 + (t >> 4)];
#pragma unroll
    for (int i = 0; i < 4; ++i) {
        int e = t + i * 256;
        int d = e >> 6, nn4 = e & 63;
        ush4 v4 = *(const ush4*)(vb + (size_t)d * HW_ + n0 + nn4 * 4);
#pragma unroll
        for (int j = 0; j < 4; ++j) kv[d][nn4 * 4 + j] = bf2f((unsigned short)v4[j]);
    }
    __syncthreads();
    float acc[16];
#pragma unroll
    for (int cc = 0; cc < 16; ++cc) acc[cc] = 0.f;
#pragma unroll
    for (int d = 0; d < 16; ++d) {
        float kvv = kv[d][t];
        float4 a0 = *(const float4*)&at[d][0];
        float4 a1 = *(const float4*)&at[d][4];
        float4 a2 = *(const float4*)&at[d][8];
        float4 a3 = *(const float4*)&at[d][12];
        acc[0]  += a0.x * kvv; acc[1]  += a0.y * kvv; acc[2]  += a0.z * kvv; acc[3]  += a0.w * kvv;
        acc[4]  += a1.x * kvv; acc[5]  += a1.y * kvv; acc[6]  += a1.z * kvv; acc[7]  += a1.w * kvv;
        acc[8]  += a2.x * kvv; acc[9]  += a2.y * kvv; acc[10] += a2.z * kvv; acc[11] += a2.w * kvv;
        acc[12] += a3.x * kvv; acc[13] += a3.y * kvv; acc[14] += a3.z * kvv; acc[15] += a3.w * kvv;
    }
    unsigned short* yb = Y + (size_t)bz * sy + (size_t)(h * 16) * HW_ + n0 + t;
#pragma unroll
    for (int cc = 0; cc < 16; ++cc) yb[(size_t)cc * HW_] = f2bf(acc[cc]);
}

// ---------------------------------------------------------------- 256-pt radix-2 DIT FFT, 2 rows per 32-lane group
__device__ __forceinline__ void fft_stages2(float2* rowA, float2* rowB, const float2* tw, int lane)
{
#pragma unroll
    for (int s = 1; s <= 8; ++s) {
        const int half = 1 << (s - 1);
#pragma unroll
        for (int r = 0; r < 4; ++r) {
            int jb = lane + r * 32;
            int j = jb & (half - 1);
            int g = jb >> (s - 1);
            int i1 = (g << s) + j;
            float2 w = tw[j << (8 - s)];
            float2 u = rowA[i1];
            float2 q = rowA[i1 + half];
            float2 v = make_float2(q.x * w.x - q.y * w.y, q.x * w.y + q.y * w.x);
            rowA[i1]        = make_float2(u.x + v.x, u.y + v.y);
            rowA[i1 + half] = make_float2(u.x - v.x, u.y - v.y);
            float2 u2 = rowB[i1];
            float2 q2 = rowB[i1 + half];
            float2 v2 = make_float2(q2.x * w.x - q2.y * w.y, q2.x * w.y + q2.y * w.x);
            rowB[i1]        = make_float2(u2.x + v2.x, u2.y + v2.y);
            rowB[i1 + half] = make_float2(u2.x - v2.x, u2.y - v2.y);
        }
        __builtin_amdgcn_wave_barrier();   // rows half-wave-private; in-wave DS ordering suffices
    }
    __syncthreads();
}

#define PI2_ 6.28318530717958647692f

// bf16 real rows -> transposed packed-bf16 spectrum T[c][k][h]; 16 rows/block (64B-chunk writes)
__global__ __launch_bounds__(256) void rfft_rowsT(const unsigned short* __restrict__ X, size_t sx,
                                                  unsigned* __restrict__ T, size_t st)
{
    __shared__ float2 sd[16][256];
    __shared__ float2 tw[128];
    int t = threadIdx.x;
    int bz = blockIdx.y;
    if (t < 128) { float sn, cs; __sincosf(-PI2_ * (float)t * (1.f / 256.f), &sn, &cs); tw[t] = make_float2(cs, sn); }
    size_t r0 = (size_t)blockIdx.x * 16;
    int c = (int)(r0 >> 8), h0 = (int)(r0 & 255);
    const unsigned short* Xb = X + (size_t)bz * sx;
    ush4 v4[4];
#pragma unroll
    for (int ii = 0; ii < 4; ++ii) {
        int e = t + ii * 256;            // 1024: 16 rows x 64 ush4
        int j = e >> 6, i4 = e & 63;
        v4[ii] = *(const ush4*)(Xb + (r0 + j) * 256 + i4 * 4);
    }
#pragma unroll
    for (int ii = 0; ii < 4; ++ii) {
        int e = t + ii * 256;
        int j = e >> 6, i4 = e & 63;
#pragma unroll
        for (int k2 = 0; k2 < 4; ++k2)
            sd[j][__brev((unsigned)(i4 * 4 + k2)) >> 24] = make_float2(bf2f((unsigned short)v4[ii][k2]), 0.f);
    }
    __syncthreads();
    fft_stages2(sd[t >> 5], sd[(t >> 5) + 8], tw, t & 31);
    unsigned* base = T + (size_t)bz * st + (size_t)c * PLANEF_;
    for (int e = t; e < 129 * 16; e += 256) {
        int j = e & 15, k = e >> 4;
        base[(size_t)k * 256 + h0 + j] = pack2bf(sd[j][k]);
    }
}

// forward complex FFT along h; 16 k-rows/block; uint4 I/O
__global__ __launch_bounds__(256) void cfftT_fwd(unsigned* __restrict__ T, size_t st)
{
    __shared__ float2 sd[16][256];
    __shared__ float2 tw[128];
    int t = threadIdx.x;
    int bz = blockIdx.z;
    if (t < 128) { float sn, cs; __sincosf(-PI2_ * (float)t * (1.f / 256.f), &sn, &cs); tw[t] = make_float2(cs, sn); }
    int k0 = blockIdx.x * 16;          // grid.x = 9 (144 >= 129)
    int c = blockIdx.y;
    unsigned* base = T + (size_t)bz * st + (size_t)c * PLANEF_;
    uint4v v4[4];
#pragma unroll
    for (int ii = 0; ii < 4; ++ii) {
        int e = t + ii * 256;            // 1024: 16 rows x 64 uint4
        int j = e >> 6, i4 = e & 63;
        int k = k0 + j;
        if (k < KF_) v4[ii] = *(const uint4v*)(base + (size_t)k * 256 + i4 * 4);
        else v4[ii] = (uint4v){0u, 0u, 0u, 0u};
    }
#pragma unroll
    for (int ii = 0; ii < 4; ++ii) {
        int e = t + ii * 256;
        int j = e >> 6, i4 = e & 63;
#pragma unroll
        for (int q = 0; q < 4; ++q)
            sd[j][__brev((unsigned)(i4 * 4 + q)) >> 24] = upk(v4[ii][q]);
    }
    __syncthreads();
    fft_stages2(sd[t >> 5], sd[(t >> 5) + 8], tw, t & 31);
#pragma unroll
    for (int ii = 0; ii < 4; ++ii) {
        int e = t + ii * 256;
        int j = e >> 6, i4 = e & 63;
        int k = k0 + j;
        if (k < KF_) {
            uint4v o;
#pragma unroll
            for (int q = 0; q < 4; ++q) o[q] = pack2bf(sd[j][i4 * 4 + q]);
            *(uint4v*)(base + (size_t)k * 256 + i4 * 4) = o;
        }
    }
}

// combine(amp,pha bf16) + inverse h-FFT; 16 k-rows/block; writes row-major S[c][h][k] in 64B chunks
__global__ __launch_bounds__(256) void cifft_combine(const unsigned short* __restrict__ amp, size_t sa,
                                                     const unsigned short* __restrict__ pha, size_t sp,
                                                     unsigned* __restrict__ S, size_t ss)
{
    __shared__ float2 sd[16][256];
    __shared__ float2 tw[128];
    int t = threadIdx.x;
    int bz = blockIdx.z;
    if (t < 128) { float sn, cs; __sincosf(PI2_ * (float)t * (1.f / 256.f), &sn, &cs); tw[t] = make_float2(cs, sn); }
    int k0 = blockIdx.x * 16;          // grid.x = 9
    int c = blockIdx.y;
    const unsigned short* ab = amp + (size_t)bz * sa + (size_t)c * PLANEF_;
    const unsigned short* pb = pha + (size_t)bz * sp + (size_t)c * PLANEF_;
    ush4 a4[4], p4[4];
#pragma unroll
    for (int ii = 0; ii < 4; ++ii) {
        int e = t + ii * 256;            // 1024: 16 rows x 64 ush4
        int j = e >> 6, i4 = e & 63;
        int k = k0 + j;
        if (k < KF_) {
            a4[ii] = *(const ush4*)(ab + (size_t)k * 256 + i4 * 4);
            p4[ii] = *(const ush4*)(pb + (size_t)k * 256 + i4 * 4);
        } else {
            a4[ii] = (ush4){0,0,0,0}; p4[ii] = (ush4){0,0,0,0};
        }
    }
#pragma unroll
    for (int ii = 0; ii < 4; ++ii) {
        int e = t + ii * 256;
        int j = e >> 6, i4 = e & 63;
        int k = k0 + j;
#pragma unroll
        for (int q = 0; q < 4; ++q) {
            float2 v = make_float2(0.f, 0.f);
            if (k < KF_) {
                float a = bf2f((unsigned short)a4[ii][q]);
                float p = bf2f((unsigned short)p4[ii][q]);
                float sn, cs;
                __sincosf(p, &sn, &cs);
                v = make_float2(a * cs + 2e-8f, a * sn + 1e-8f);
            }
            sd[j][__brev((unsigned)(i4 * 4 + q)) >> 24] = v;
        }
    }
    __syncthreads();
    fft_stages2(sd[t >> 5], sd[(t >> 5) + 8], tw, t & 31);
    unsigned* base = S + (size_t)bz * ss + (size_t)c * PLANEF_;
    for (int e = t; e < 4096; e += 256) {
        int j = e & 15, h = e >> 4;
        int k = k0 + j;
        if (k < KF_) {
            float2 o = sd[j][h];
            base[(size_t)h * KF_ + k] = pack2bf(make_float2(o.x * (1.f / 256.f), o.y * (1.f / 256.f)));
        }
    }
}

// row-major packed-bf16 spectrum -> 256 real (Hermitian) -> |.| -> bf16; 16 rows/block
__global__ __launch_bounds__(256) void irfft_rows16_abs(const unsigned* __restrict__ S, size_t ss,
                                                        unsigned short* __restrict__ Y, size_t sy)
{
    __shared__ float2 sd[16][256];
    __shared__ float2 tw[128];
    int t = threadIdx.x;
    int bz = blockIdx.y;
    if (t < 128) { float sn, cs; __sincosf(PI2_ * (float)t * (1.f / 256.f), &sn, &cs); tw[t] = make_float2(cs, sn); }
    size_t r0 = (size_t)blockIdx.x * 16;
    const unsigned* Sb = S + (size_t)bz * ss;
    for (int e = t; e < 4096; e += 256) {
        int j = e >> 8, i = e & 255;
        const unsigned* row = Sb + (r0 + j) * 129;
        float2 v;
        if (i < 129) v = upk(row[i]);
        else { float2 w2 = upk(row[256 - i]); v = make_float2(w2.x, -w2.y); }
        sd[j][__brev((unsigned)i) >> 24] = v;
    }
    __syncthreads();
    fft_stages2(sd[t >> 5], sd[(t >> 5) + 8], tw, t & 31);
    unsigned short* Yb = Y + (size_t)bz * sy;
#pragma unroll
    for (int ii = 0; ii < 2; ++ii) {
        int e = t + ii * 256;            // 512: 16 rows x 32 ush8
        int j = e >> 5, i8 = e & 31;
        ush8 ov;
#pragma unroll
        for (int q = 0; q < 8; ++q) ov[q] = f2bf(fabsf(sd[j][i8 * 8 + q].x * (1.f / 256.f)));
        *(ush8*)(Yb + (r0 + j) * 256 + i8 * 8) = ov;
    }
}

// ---------------------------------------------------------------- host
extern "C" void kernel_launch(void* const* d_in, const int* in_sizes, int n_in,
                              void* d_out, int out_size, void* d_ws, size_t ws_size,
                              hipStream_t stream)
{
    (void)in_sizes; (void)n_in; (void)out_size;
    const float* ms    = (const float*)d_in[0];
    const float* pan   = (const float*)d_in[1];
    const float* ln1w  = (const float*)d_in[2];
    const float* ln1b  = (const float*)d_in[3];
    const float* ln2w  = (const float*)d_in[4];
    const float* ln2b  = (const float*)d_in[5];
    const float* qkvw  = (const float*)d_in[6];
    const float* dww   = (const float*)d_in[7];
    const float* temp  = (const float*)d_in[8];
    const float* projw = (const float*)d_in[9];
    const float* pre1w = (const float*)d_in[10];
    const float* pre1b = (const float*)d_in[11];
    const float* pre2w = (const float*)d_in[12];
    const float* pre2b = (const float*)d_in[13];
    const float* amp1w = (const float*)d_in[14];
    const float* amp1b = (const float*)d_in[15];
    const float* amp2w = (const float*)d_in[16];
    const float* amp2b = (const float*)d_in[17];
    const float* pha1w = (const float*)d_in[18];
    const float* pha1b = (const float*)d_in[19];
    const float* pha2w = (const float*)d_in[20];
    const float* pha2b = (const float*)d_in[21];
    const float* postw = (const float*)d_in[22];
    const float* postb = (const float*)d_in[23];
    const float* pinw  = (const float*)d_in[24];
    const float* poutw = (const float*)d_in[25];

    const size_t SLOT  = 8454144;
    const size_t CHWu  = 8388608;
    const size_t CPFu  = 4227072;
    const size_t SPECu = 4227072;
    const size_t PARAMU = 344064;
    const size_t PARAMF = 273792;

    auto needB = [&](int nb) -> size_t {
        return 2ull * (33554432ull + (size_t)nb * 3ull * SLOT + PARAMU) + 4ull * PARAMF + 64;
    };
    int NB = (ws_size >= needB(4)) ? 4 : ((ws_size >= needB(2)) ? 2 : 1);

    unsigned short* F  = (unsigned short*)d_ws;
    unsigned short* U0 = F + 33554432;
    unsigned short* U1 = U0 + (size_t)NB * SLOT;
    unsigned short* U2 = U1 + (size_t)NB * SLOT;
    unsigned short* w_qkv   = U2 + (size_t)NB * SLOT;
    unsigned short* w_proj  = w_qkv  + 16384;
    unsigned short* w_pre1  = w_proj + 16384;
    unsigned short* w_pre2  = w_pre1 + 16384;
    unsigned short* w_post  = w_pre2 + 16384;
    unsigned short* w_amp1  = w_post + 16384;
    unsigned short* w_pha1  = w_amp1 + 32768;
    unsigned short* w_amp2  = w_pha1 + 32768;
    unsigned short* w_pha2  = w_amp2 + 16384;
    unsigned short* w_pin   = w_pha2 + 16384;
    unsigned short* w_pout2 = w_pin  + 131072;
    float* fpar   = (float*)(w_pout2 + 32768);
    float* ksumP  = fpar;
    float* nqsq   = ksumP + 128;
    float* nksq   = nqsq  + 512;
    float* attnP  = nksq  + 512;
    float* partP  = attnP + 8192;
    float* qkv_ws = partP + 262144;
    float* qkv_bb = qkv_ws + 128;
    float* pin_ws = qkv_bb + 128;
    float* pin_bb = pin_ws + 512;
    float* pinC   = pin_bb + 512;

    float* xout = (float*)d_out;

    auto CVT = [&](const float* src, unsigned short* dst, int n) {
        tobf16_kernel<<<(n + 255) / 256, 256, 0, stream>>>(src, dst, n);
    };
    foldln_kernel<<<128, 128, 0, stream>>>(qkvw, ln1w, ln1b, w_qkv, qkv_ws, qkv_bb, 128);
    foldln_kernel<<<512, 128, 0, stream>>>(pinw, ln2w, ln2b, w_pin, pin_ws, pin_bb, 256);
    CVT(projw, w_proj, 16384);
    CVT(pre1w, w_pre1, 16384); CVT(pre2w, w_pre2, 16384);
    CVT(postw, w_post, 16384);
    CVT(amp1w, w_amp1, 32768); CVT(pha1w, w_pha1, 32768);
    CVT(amp2w, w_amp2, 16384); CVT(pha2w, w_pha2, 16384);
    poutperm_kernel<<<128, 256, 0, stream>>>(poutw, w_pout2);
    pinc_kernel<<<1, 256, 0, stream>>>(pin_bb, pin_ws, (float4*)pinC);
    ksum_kernel<<<1, 128, 0, stream>>>(dww, ksumP);

    const size_t CHW = (size_t)C_ * HW_;
    const float* NUL = nullptr;

    for (int b0 = 0; b0 < B_; b0 += NB) {
        const float* msb  = ms  + (size_t)b0 * CHW;
        const float* panb = pan + (size_t)b0 * CHW;
        float* xb = xout + (size_t)b0 * CHW;
        unsigned short* freb = F + (size_t)b0 * CHWu;
        dim3 gz(512, 1, NB);
        dim3 gzf(258, 1, NB);

        // ---- attention ----
        zero2_kernel<<<(NB * 128 + 255) / 256, 256, 0, stream>>>(nqsq, nksq, NB * 128);
        mconv2<0, 1, 0, true><<<gz, 256, 0, stream>>>(
            msb, CHW, w_qkv, 128, nullptr, nullptr, 0, U0, SLOT, HW_, 0, qkv_ws, qkv_bb);
        dwconv2<<<dim3(32, 128, NB), 256, 0, stream>>>(U0, SLOT, dww, ksumP, U1, SLOT, nqsq);   // q
        mconv2<0, 1, 0, true><<<gz, 256, 0, stream>>>(
            panb, CHW, w_qkv, 128, nullptr, nullptr, 0, U0, SLOT, HW_, 0, qkv_ws, qkv_bb);
        dwconv2<<<dim3(32, 128, NB), 256, 0, stream>>>(U0, SLOT, dww, ksumP, U2, SLOT, nksq);   // kv
        gram_kernel<<<dim3(32, 8, NB), 256, 0, stream>>>(U1, SLOT, U2, SLOT, partP);
        softmax_kernel<<<dim3(8, NB), 256, 0, stream>>>(partP, nqsq, nksq, temp, attnP);
        av_kernel<<<dim3(256, 8, NB), 256, 0, stream>>>(attnP, U2, SLOT, U0, SLOT);
        mconv2<1, 0, 0, false><<<gz, 256, 0, stream>>>(
            U0, SLOT, w_proj, 128, nullptr, msb, CHW, xb, CHW, HW_, 0, NUL, NUL);

        // ---- freprocess ----
        mconv2<0, 1, 0, false><<<gz, 256, 0, stream>>>(
            msb, CHW, w_pre1, 128, pre1b, nullptr, 0, U0, SLOT, HW_, 1, NUL, NUL);
        rfft_rowsT<<<dim3(2048, NB), 256, 0, stream>>>(U0, SLOT, (unsigned*)(void*)U1, SPECu);
        cfftT_fwd<<<dim3(9, 128, NB), 256, 0, stream>>>((unsigned*)(void*)U1, SPECu);
        mconv2<0, 1, 0, false><<<gz, 256, 0, stream>>>(
            panb, CHW, w_pre2, 128, pre2b, nullptr, 0, U0, SLOT, HW_, 1, NUL, NUL);
        rfft_rowsT<<<dim3(2048, NB), 256, 0, stream>>>(U0, SLOT, (unsigned*)(void*)U2, SPECu);
        cfftT_fwd<<<dim3(9, 128, NB), 256, 0, stream>>>((unsigned*)(void*)U2, SPECu);
        apconv2<<<gzf, 256, 0, stream>>>(
            (const unsigned*)(void*)U1, (const unsigned*)(void*)U2, SPECu,
            w_amp1, w_pha1, w_amp2, w_pha2, amp1b, pha1b, amp2b, pha2b,
            U0, U0 + CPFu, SLOT);
        cifft_combine<<<dim3(9, 128, NB), 256, 0, stream>>>(
            U0, SLOT, U0 + CPFu, SLOT, (unsigned*)(void*)U2, SPECu);
        irfft_rows16_abs<<<dim3(2048, NB), 256, 0, stream>>>((unsigned*)(void*)U2, SPECu, U0, SLOT);
        mconv2<1, 1, 0, false><<<gz, 256, 0, stream>>>(
            U0, SLOT, w_post, 128, postb, nullptr, 0, freb, CHWu, HW_, 0, NUL, NUL);
    }

    // ---- FFN (full batch, LN2 + gelu-gate fused, residual from LDS) ----
    ffn_mfma6<<<dim3(HW_ / 64, B_), 256, 0, stream>>>(xout, F, w_pin, w_pout2, (const float4*)pinC, xout);
}

// Round 13
// 1607.928 us; speedup vs baseline: 1.2644x; 1.0202x over previous
//
#include <hip/hip_runtime.h>
#include <math.h>

#define B_ 4
#define C_ 128
#define HW_ 65536
#define H__ 256
#define KF_ 129
#define PLANEF_ 33024

typedef __attribute__((ext_vector_type(8))) short short8v;
typedef __attribute__((ext_vector_type(4))) float f32x4;
typedef __attribute__((ext_vector_type(4))) unsigned short ush4;
typedef __attribute__((ext_vector_type(8))) unsigned short ush8;
typedef __attribute__((ext_vector_type(4))) unsigned uint4v;

__device__ __forceinline__ unsigned short f2bf(float f) {
    union { float f; unsigned u; } v; v.f = f;
    return (unsigned short)((v.u + 0x7FFFu + ((v.u >> 16) & 1u)) >> 16);
}
__device__ __forceinline__ float bf2f(unsigned short s) {
    union { unsigned u; float f; } v; v.u = (unsigned)s << 16;
    return v.f;
}
__device__ __forceinline__ unsigned pack2bf(float2 v) {
    return (unsigned)f2bf(v.x) | ((unsigned)f2bf(v.y) << 16);
}
__device__ __forceinline__ float2 upk(unsigned u) {
    return make_float2(bf2f((unsigned short)(u & 0xffff)), bf2f((unsigned short)(u >> 16)));
}
// fast gelu: A&S 7.1.26 erf (|err|<=1.5e-7) with __expf
__device__ __forceinline__ float geluf(float x) {
    float z = 0.70710678118654752f * fabsf(x);
    float t = __fdividef(1.f, fmaf(0.3275911f, z, 1.f));
    float p = fmaf(1.061405429f, t, -1.453152027f);
    p = fmaf(p, t, 1.421413741f);
    p = fmaf(p, t, -0.284496736f);
    p = fmaf(p, t, 0.254829592f);
    p = p * t;
    float erfv = 1.f - p * __expf(-z * z);
    float cdf = (x >= 0.f) ? fmaf(0.5f, erfv, 0.5f) : fmaf(-0.5f, erfv, 0.5f);
    return x * cdf;
}
// fast atan2, poly err ~1e-5 rad
__device__ __forceinline__ float fatan2(float y, float x) {
    float ax = fabsf(x), ay = fabsf(y);
    float mx = fmaxf(ax, ay), mn = fminf(ax, ay);
    float a = __fdividef(mn, fmaxf(mx, 1e-38f));
    float s = a * a;
    float r = fmaf(0.0208351f, s, -0.0851330f);
    r = fmaf(r, s, 0.1801410f);
    r = fmaf(r, s, -0.3302995f);
    r = fmaf(r, s, 0.9998660f);
    r = r * a;
    if (ay > ax) r = 1.57079632679489662f - r;
    if (x < 0.f) r = 3.14159265358979324f - r;
    return copysignf(r, y);
}
// LDS XOR swizzle on byte-offset within row
template<int W>
__device__ __forceinline__ char* swz_ptr(unsigned short (*xs)[W], int px, int cb) {
    return (char*)xs + px * (W * 2) + (cb ^ (((px >> 2) & 7) << 4));
}

// ---------------------------------------------------------------- prep
__global__ __launch_bounds__(256) void tobf16_kernel(const float* __restrict__ src,
                                                     unsigned short* __restrict__ dst, int n)
{
    int i = blockIdx.x * 256 + threadIdx.x;
    if (i < n) dst[i] = f2bf(src[i]);
}

__global__ __launch_bounds__(128) void foldln_kernel(const float* __restrict__ W,
                                                     const float* __restrict__ lnw,
                                                     const float* __restrict__ lnb,
                                                     unsigned short* __restrict__ Wb,
                                                     float* __restrict__ wsum, float* __restrict__ bsum,
                                                     int Cc)
{
    int o = blockIdx.x, t = threadIdx.x;
    float sw = 0.f, sb = 0.f;
    for (int c = t; c < Cc; c += 128) {
        float w = W[(size_t)o * Cc + c];
        float fw = w * lnw[c];
        unsigned short us = f2bf(fw);
        Wb[(size_t)o * Cc + c] = us;
        sw += bf2f(us);
        sb += w * lnb[c];
    }
    __shared__ float r1[128], r2[128];
    r1[t] = sw; r2[t] = sb; __syncthreads();
    for (int st = 64; st; st >>= 1) {
        if (t < st) { r1[t] += r1[t + st]; r2[t] += r2[t + st]; }
        __syncthreads();
    }
    if (!t) { wsum[o] = r1[0]; bsum[o] = r2[0]; }
}

__global__ __launch_bounds__(256) void poutperm_kernel(const float* __restrict__ src,
                                                       unsigned short* __restrict__ dst)
{
    int i = blockIdx.x * 256 + threadIdx.x;   // 32768
    int half = i >> 14, rem = i & 16383, o = rem >> 7, kp = rem & 127;
    int h = (kp >> 5) * 64 + half * 32 + (kp & 31);
    dst[i] = f2bf(src[o * 256 + h]);
}

__global__ void pinc_kernel(const float* __restrict__ bb, const float* __restrict__ ws,
                            float4* __restrict__ pinC)
{
    int i = threadIdx.x;
    if (i < 256) pinC[i] = make_float4(bb[i], ws[i], bb[i + 256], ws[i + 256]);
}

__global__ void ksum_kernel(const float* __restrict__ dw, float* __restrict__ ks)
{
    int c = threadIdx.x;
    if (c < C_) {
        float s = 0.f;
        for (int k = 0; k < 9; ++k) s += dw[c * 9 + k];
        ks[c] = s;
    }
}

__global__ __launch_bounds__(256) void zero2_kernel(float* __restrict__ a, float* __restrict__ b, int n)
{
    int i = blockIdx.x * 256 + threadIdx.x;
    if (i < n) { a[i] = 0.f; b[i] = 0.f; }
}

// ---------------------------------------------------------------- MFMA conv1x1 (CIN=128)
template<int INBF, int OUTBF, int PRO, bool LNF>
__global__ __launch_bounds__(256, 4) void mconv2(
    const void* __restrict__ Xv, size_t sx,
    const unsigned short* __restrict__ Wb, int wstride,
    const float* __restrict__ bias,
    const float* __restrict__ res, size_t sres,
    void* __restrict__ Yv, size_t sy, int plane, int flags,
    const float* __restrict__ wsum, const float* __restrict__ bsum)
{
    __shared__ unsigned short xs[128][136];
    __shared__ float2 lnred[LNF ? 8 : 1][LNF ? 128 : 1];
    __shared__ float2 lnmi[LNF ? 128 : 1];
    const int t = threadIdx.x;
    const int bz = blockIdx.z;
    const int p0 = blockIdx.x * 128;
    const int lane = t & 63;
    const int wr = t >> 7, wc = (t >> 6) & 1;
    const int lr = lane >> 4, lc = lane & 15;

    if constexpr (INBF == 0) {
        const float* Xb = (const float*)Xv + (size_t)bz * sx;
        const int px4 = t & 31;
        float s0 = 0.f, s1 = 0.f, s2v = 0.f, s3 = 0.f;
        float q0 = 0.f, q1 = 0.f, q2 = 0.f, q3 = 0.f;
#pragma unroll
        for (int g = 0; g < 2; ++g) {
            float4 st[8];
#pragma unroll
            for (int i = 0; i < 8; ++i) {
                int e = t + (g * 8 + i) * 256;
                int c = e >> 5;
                st[i] = *(const float4*)(Xb + (size_t)c * plane + p0 + px4 * 4);
            }
#pragma unroll
            for (int i = 0; i < 8; ++i) {
                int e = t + (g * 8 + i) * 256;
                int c = e >> 5;
                float a0 = st[i].x, a1 = st[i].y, a2 = st[i].z, a3 = st[i].w;
                if constexpr (PRO == 1) {
                    a0 = a0 > 0.f ? a0 : 0.1f * a0;
                    a1 = a1 > 0.f ? a1 : 0.1f * a1;
                    a2 = a2 > 0.f ? a2 : 0.1f * a2;
                    a3 = a3 > 0.f ? a3 : 0.1f * a3;
                }
                if constexpr (LNF) {
                    s0 += a0; q0 += a0 * a0;
                    s1 += a1; q1 += a1 * a1;
                    s2v += a2; q2 += a2 * a2;
                    s3 += a3; q3 += a3 * a3;
                }
                *(unsigned short*)swz_ptr(xs, px4 * 4 + 0, 2 * c) = f2bf(a0);
                *(unsigned short*)swz_ptr(xs, px4 * 4 + 1, 2 * c) = f2bf(a1);
                *(unsigned short*)swz_ptr(xs, px4 * 4 + 2, 2 * c) = f2bf(a2);
                *(unsigned short*)swz_ptr(xs, px4 * 4 + 3, 2 * c) = f2bf(a3);
            }
        }
        if constexpr (LNF) {
            lnred[t >> 5][px4 * 4 + 0] = make_float2(s0, q0);
            lnred[t >> 5][px4 * 4 + 1] = make_float2(s1, q1);
            lnred[t >> 5][px4 * 4 + 2] = make_float2(s2v, q2);
            lnred[t >> 5][px4 * 4 + 3] = make_float2(s3, q3);
        }
    } else {
        const unsigned short* Xb = (const unsigned short*)Xv + (size_t)bz * sx;
        ush8 st[8];
#pragma unroll
        for (int i = 0; i < 8; ++i) {
            int e = t + i * 256;
            int c = e >> 4, px8 = e & 15;
            st[i] = *(const ush8*)(Xb + (size_t)c * plane + p0 + px8 * 8);
        }
#pragma unroll
        for (int i = 0; i < 8; ++i) {
            int e = t + i * 256;
            int c = e >> 4, px8 = e & 15;
#pragma unroll
            for (int j = 0; j < 8; ++j) {
                unsigned short us = (unsigned short)st[i][j];
                if constexpr (PRO == 1) {
                    float f = bf2f(us);
                    f = f > 0.f ? f : 0.1f * f;
                    us = f2bf(f);
                }
                *(unsigned short*)swz_ptr(xs, px8 * 8 + j, 2 * c) = us;
            }
        }
    }
    __syncthreads();
    if constexpr (LNF) {
        if (t < 128) {
            float ss = 0.f, qq = 0.f;
#pragma unroll
            for (int j = 0; j < 8; ++j) { float2 a = lnred[j][t]; ss += a.x; qq += a.y; }
            float m = ss * (1.f / 128.f);
            float inv = rsqrtf(qq * (1.f / 128.f) - m * m + 1e-5f);
            lnmi[t] = make_float2(m, inv);
        }
        __syncthreads();
    }

    f32x4 acc[4][4];
#pragma unroll
    for (int mi = 0; mi < 4; ++mi)
#pragma unroll
        for (int ni = 0; ni < 4; ++ni) acc[mi][ni] = (f32x4){0.f, 0.f, 0.f, 0.f};

#pragma unroll
    for (int kk = 0; kk < 128; kk += 32) {
        short8v bfr[4];
#pragma unroll
        for (int ni = 0; ni < 4; ++ni)
            bfr[ni] = *(const short8v*)swz_ptr(xs, wc * 64 + ni * 16 + lc, 2 * (kk + lr * 8));
#pragma unroll
        for (int mi = 0; mi < 4; ++mi) {
            int row = wr * 64 + mi * 16 + lc;
            short8v afr = *(const short8v*)(Wb + (size_t)row * wstride + kk + lr * 8);
#pragma unroll
            for (int ni = 0; ni < 4; ++ni)
                acc[mi][ni] = __builtin_amdgcn_mfma_f32_16x16x32_bf16(afr, bfr[ni], acc[mi][ni], 0, 0, 0);
        }
    }

    float2 mrow[4];
    if constexpr (LNF) {
#pragma unroll
        for (int ni = 0; ni < 4; ++ni) mrow[ni] = lnmi[wc * 64 + ni * 16 + lc];
    }

#pragma unroll
    for (int mi = 0; mi < 4; ++mi) {
        int ob = wr * 64 + mi * 16 + lr * 4;
#pragma unroll
        for (int r = 0; r < 4; ++r) {
            int o = ob + r;
            float bv = 0.f, wso = 0.f;
            if constexpr (LNF) { bv = bsum[o]; wso = wsum[o]; }
            else { if (bias) bv = bias[o]; if (flags & 1) bv += 1e-8f; }
#pragma unroll
            for (int ni = 0; ni < 4; ++ni) {
                int px = wc * 64 + ni * 16 + lc;
                float v;
                if constexpr (LNF) {
                    float m = mrow[ni].x, inv = mrow[ni].y;
                    v = acc[mi][ni][r] * inv + bv - m * inv * wso;
                } else {
                    v = acc[mi][ni][r] + bv;
                }
                if constexpr (OUTBF == 0) {
                    float* Y = (float*)Yv;
                    size_t yi = (size_t)bz * sy + (size_t)o * plane + p0 + px;
                    if (res) v += res[(size_t)bz * sres + (size_t)o * plane + p0 + px];
                    Y[yi] = v;
                } else {
                    unsigned short* Y = (unsigned short*)Yv;
                    Y[(size_t)bz * sy + (size_t)o * plane + p0 + px] = f2bf(v);
                }
            }
        }
    }
}

// ---------------------------------------------------------------- fused dual conv1x1: qkv (folded-LN) + pre (bias+1e-8)
// Stages f32 input once as bf16; two sequential GEMMs over the same tile.
__global__ __launch_bounds__(256, 3) void mconv_dual(
    const float* __restrict__ X, size_t sx,
    const unsigned short* __restrict__ Wq,   // [128][128] folded-LN
    const float* __restrict__ q_ws, const float* __restrict__ q_bb,
    const unsigned short* __restrict__ Wp,   // [128][128]
    const float* __restrict__ pre_b,
    unsigned short* __restrict__ Y1, unsigned short* __restrict__ Y2, size_t sy)
{
    __shared__ unsigned short xs[128][136];
    __shared__ float2 lnred[8][128];
    __shared__ float2 lnmi[128];
    const int t = threadIdx.x;
    const int bz = blockIdx.z;
    const int p0 = blockIdx.x * 128;
    const int lane = t & 63;
    const int wr = t >> 7, wc = (t >> 6) & 1;
    const int lr = lane >> 4, lc = lane & 15;

    const float* Xb = X + (size_t)bz * sx;
    const int px4 = t & 31;
    float s0 = 0.f, s1 = 0.f, s2v = 0.f, s3 = 0.f;
    float q0 = 0.f, q1 = 0.f, q2 = 0.f, q3 = 0.f;
#pragma unroll
    for (int g = 0; g < 2; ++g) {
        float4 st[8];
#pragma unroll
        for (int i = 0; i < 8; ++i) {
            int e = t + (g * 8 + i) * 256;
            int c = e >> 5;
            st[i] = *(const float4*)(Xb + (size_t)c * HW_ + p0 + px4 * 4);
        }
#pragma unroll
        for (int i = 0; i < 8; ++i) {
            int e = t + (g * 8 + i) * 256;
            int c = e >> 5;
            float a0 = st[i].x, a1 = st[i].y, a2 = st[i].z, a3 = st[i].w;
            s0 += a0; q0 += a0 * a0;
            s1 += a1; q1 += a1 * a1;
            s2v += a2; q2 += a2 * a2;
            s3 += a3; q3 += a3 * a3;
            *(unsigned short*)swz_ptr(xs, px4 * 4 + 0, 2 * c) = f2bf(a0);
            *(unsigned short*)swz_ptr(xs, px4 * 4 + 1, 2 * c) = f2bf(a1);
            *(unsigned short*)swz_ptr(xs, px4 * 4 + 2, 2 * c) = f2bf(a2);
            *(unsigned short*)swz_ptr(xs, px4 * 4 + 3, 2 * c) = f2bf(a3);
        }
    }
    lnred[t >> 5][px4 * 4 + 0] = make_float2(s0, q0);
    lnred[t >> 5][px4 * 4 + 1] = make_float2(s1, q1);
    lnred[t >> 5][px4 * 4 + 2] = make_float2(s2v, q2);
    lnred[t >> 5][px4 * 4 + 3] = make_float2(s3, q3);
    __syncthreads();
    if (t < 128) {
        float ss = 0.f, qq = 0.f;
#pragma unroll
        for (int j = 0; j < 8; ++j) { float2 a = lnred[j][t]; ss += a.x; qq += a.y; }
        float m = ss * (1.f / 128.f);
        float inv = rsqrtf(qq * (1.f / 128.f) - m * m + 1e-5f);
        lnmi[t] = make_float2(m, inv);
    }
    __syncthreads();

    float2 mrow[4];
#pragma unroll
    for (int ni = 0; ni < 4; ++ni) mrow[ni] = lnmi[wc * 64 + ni * 16 + lc];

    // ---- GEMM 1: qkv (folded-LN epilogue) ----
    {
        f32x4 acc[4][4];
#pragma unroll
        for (int mi = 0; mi < 4; ++mi)
#pragma unroll
            for (int ni = 0; ni < 4; ++ni) acc[mi][ni] = (f32x4){0.f, 0.f, 0.f, 0.f};
#pragma unroll
        for (int kk = 0; kk < 128; kk += 32) {
            short8v bfr[4];
#pragma unroll
            for (int ni = 0; ni < 4; ++ni)
                bfr[ni] = *(const short8v*)swz_ptr(xs, wc * 64 + ni * 16 + lc, 2 * (kk + lr * 8));
#pragma unroll
            for (int mi = 0; mi < 4; ++mi) {
                int row = wr * 64 + mi * 16 + lc;
                short8v afr = *(const short8v*)(Wq + (size_t)row * 128 + kk + lr * 8);
#pragma unroll
                for (int ni = 0; ni < 4; ++ni)
                    acc[mi][ni] = __builtin_amdgcn_mfma_f32_16x16x32_bf16(afr, bfr[ni], acc[mi][ni], 0, 0, 0);
            }
        }
#pragma unroll
        for (int mi = 0; mi < 4; ++mi)
#pragma unroll
            for (int r = 0; r < 4; ++r) {
                int o = wr * 64 + mi * 16 + lr * 4 + r;
                float bv = q_bb[o], wso = q_ws[o];
#pragma unroll
                for (int ni = 0; ni < 4; ++ni) {
                    int px = wc * 64 + ni * 16 + lc;
                    float m = mrow[ni].x, inv = mrow[ni].y;
                    float v = acc[mi][ni][r] * inv + bv - m * inv * wso;
                    Y1[(size_t)bz * sy + (size_t)o * HW_ + p0 + px] = f2bf(v);
                }
            }
    }

    // ---- GEMM 2: pre (bias + 1e-8 epilogue) ----
    {
        f32x4 acc[4][4];
#pragma unroll
        for (int mi = 0; mi < 4; ++mi)
#pragma unroll
            for (int ni = 0; ni < 4; ++ni) acc[mi][ni] = (f32x4){0.f, 0.f, 0.f, 0.f};
#pragma unroll
        for (int kk = 0; kk < 128; kk += 32) {
            short8v bfr[4];
#pragma unroll
            for (int ni = 0; ni < 4; ++ni)
                bfr[ni] = *(const short8v*)swz_ptr(xs, wc * 64 + ni * 16 + lc, 2 * (kk + lr * 8));
#pragma unroll
            for (int mi = 0; mi < 4; ++mi) {
                int row = wr * 64 + mi * 16 + lc;
                short8v afr = *(const short8v*)(Wp + (size_t)row * 128 + kk + lr * 8);
#pragma unroll
                for (int ni = 0; ni < 4; ++ni)
                    acc[mi][ni] = __builtin_amdgcn_mfma_f32_16x16x32_bf16(afr, bfr[ni], acc[mi][ni], 0, 0, 0);
            }
        }
#pragma unroll
        for (int mi = 0; mi < 4; ++mi)
#pragma unroll
            for (int r = 0; r < 4; ++r) {
                int o = wr * 64 + mi * 16 + lr * 4 + r;
                float bv = pre_b[o] + 1e-8f;
#pragma unroll
                for (int ni = 0; ni < 4; ++ni) {
                    int px = wc * 64 + ni * 16 + lc;
                    Y2[(size_t)bz * sy + (size_t)o * HW_ + p0 + px] = f2bf(acc[mi][ni][r] + bv);
                }
            }
    }
}

// ---------------------------------------------------------------- fused amp1+pha1+amp2+pha2 spectral block
__global__ __launch_bounds__(256, 2) void apconv2(
    const unsigned* __restrict__ T1, const unsigned* __restrict__ T2, size_t sT,
    const unsigned short* __restrict__ Wa1, const unsigned short* __restrict__ Wp1,
    const unsigned short* __restrict__ Wa2, const unsigned short* __restrict__ Wp2,
    const float* __restrict__ ba1, const float* __restrict__ bp1,
    const float* __restrict__ ba2, const float* __restrict__ bp2,
    unsigned short* __restrict__ AMP, unsigned short* __restrict__ PHA, size_t sO)
{
    __shared__ __align__(16) unsigned short buf[2][128][72];
    const int t = threadIdx.x;
    const int bz = blockIdx.z;
    const int p0 = blockIdx.x * 128;
    const int lane = t & 63;
    const int wr = t >> 7, wc = (t >> 6) & 1;
    const int lr = lane >> 4, lc = lane & 15;
    const int px2 = t & 63;

    typedef unsigned short (*row72)[72];
    typedef unsigned short (*row144)[144];
    row72 xa = (row72)buf[0];
    row72 xp = (row72)buf[1];
    row144 hb = (row144)&buf[0][0][0];

    f32x4 aa[4][4], ap[4][4];
#pragma unroll
    for (int mi = 0; mi < 4; ++mi)
#pragma unroll
        for (int ni = 0; ni < 4; ++ni) { aa[mi][ni] = (f32x4){0.f,0.f,0.f,0.f}; ap[mi][ni] = (f32x4){0.f,0.f,0.f,0.f}; }

    for (int ch = 0; ch < 256; ch += 64) {
        const unsigned* Ts = ((ch < 128) ? T1 : T2) + (size_t)bz * sT + (size_t)(ch & 127) * PLANEF_;
#pragma unroll
        for (int g = 0; g < 2; ++g) {
            uint2 st[8];
#pragma unroll
            for (int i = 0; i < 8; ++i) {
                int e = t + (g * 8 + i) * 256;
                int c = e >> 6;
                st[i] = *(const uint2*)(Ts + (size_t)c * PLANEF_ + p0 + px2 * 2);
            }
#pragma unroll
            for (int i = 0; i < 8; ++i) {
                int e = t + (g * 8 + i) * 256;
                int c = e >> 6;
                float2 z0 = upk(st[i].x), z1 = upk(st[i].y);
                float m0 = sqrtf(z0.x * z0.x + z0.y * z0.y);
                float m1 = sqrtf(z1.x * z1.x + z1.y * z1.y);
                float a0 = fatan2(z0.y, z0.x);
                float a1 = fatan2(z1.y, z1.x);
                *(unsigned short*)swz_ptr(xa, px2 * 2 + 0, 2 * c) = f2bf(m0);
                *(unsigned short*)swz_ptr(xa, px2 * 2 + 1, 2 * c) = f2bf(m1);
                *(unsigned short*)swz_ptr(xp, px2 * 2 + 0, 2 * c) = f2bf(a0);
                *(unsigned short*)swz_ptr(xp, px2 * 2 + 1, 2 * c) = f2bf(a1);
            }
        }
        __syncthreads();
#pragma unroll
        for (int kk = 0; kk < 64; kk += 32) {
            short8v bfa[4], bfp[4];
#pragma unroll
            for (int ni = 0; ni < 4; ++ni) {
                bfa[ni] = *(const short8v*)swz_ptr(xa, wc * 64 + ni * 16 + lc, 2 * (kk + lr * 8));
                bfp[ni] = *(const short8v*)swz_ptr(xp, wc * 64 + ni * 16 + lc, 2 * (kk + lr * 8));
            }
#pragma unroll
            for (int mi = 0; mi < 4; ++mi) {
                int row = wr * 64 + mi * 16 + lc;
                short8v afa = *(const short8v*)(Wa1 + (size_t)row * 256 + ch + kk + lr * 8);
                short8v afp = *(const short8v*)(Wp1 + (size_t)row * 256 + ch + kk + lr * 8);
#pragma unroll
                for (int ni = 0; ni < 4; ++ni) {
                    aa[mi][ni] = __builtin_amdgcn_mfma_f32_16x16x32_bf16(afa, bfa[ni], aa[mi][ni], 0, 0, 0);
                    ap[mi][ni] = __builtin_amdgcn_mfma_f32_16x16x32_bf16(afp, bfp[ni], ap[mi][ni], 0, 0, 0);
                }
            }
        }
        __syncthreads();
    }

    // ---- stage B (amp) ----
#pragma unroll
    for (int mi = 0; mi < 4; ++mi)
#pragma unroll
        for (int r = 0; r < 4; ++r) {
            int o = wr * 64 + mi * 16 + lr * 4 + r;
            float bva = ba1[o];
#pragma unroll
            for (int ni = 0; ni < 4; ++ni) {
                int px = wc * 64 + ni * 16 + lc;
                float v = aa[mi][ni][r] + bva;
                v = v > 0.f ? v : 0.1f * v;
                *(unsigned short*)swz_ptr(hb, px, 2 * o) = f2bf(v);
            }
        }
    __syncthreads();
    {
        f32x4 acc[4][4];
#pragma unroll
        for (int mi = 0; mi < 4; ++mi)
#pragma unroll
            for (int ni = 0; ni < 4; ++ni) acc[mi][ni] = (f32x4){0.f,0.f,0.f,0.f};
#pragma unroll
        for (int kk = 0; kk < 128; kk += 32) {
            short8v bfr[4];
#pragma unroll
            for (int ni = 0; ni < 4; ++ni)
                bfr[ni] = *(const short8v*)swz_ptr(hb, wc * 64 + ni * 16 + lc, 2 * (kk + lr * 8));
#pragma unroll
            for (int mi = 0; mi < 4; ++mi) {
                int row = wr * 64 + mi * 16 + lc;
                short8v afr = *(const short8v*)(Wa2 + (size_t)row * 128 + kk + lr * 8);
#pragma unroll
                for (int ni = 0; ni < 4; ++ni)
                    acc[mi][ni] = __builtin_amdgcn_mfma_f32_16x16x32_bf16(afr, bfr[ni], acc[mi][ni], 0, 0, 0);
            }
        }
#pragma unroll
        for (int mi = 0; mi < 4; ++mi)
#pragma unroll
            for (int r = 0; r < 4; ++r) {
                int o = wr * 64 + mi * 16 + lr * 4 + r;
                float bv = ba2[o];
#pragma unroll
                for (int ni = 0; ni < 4; ++ni) {
                    int px = wc * 64 + ni * 16 + lc;
                    AMP[(size_t)bz * sO + (size_t)o * PLANEF_ + p0 + px] = f2bf(acc[mi][ni][r] + bv);
                }
            }
    }
    __syncthreads();

    // ---- stage B (pha) ----
#pragma unroll
    for (int mi = 0; mi < 4; ++mi)
#pragma unroll
        for (int r = 0; r < 4; ++r) {
            int o = wr * 64 + mi * 16 + lr * 4 + r;
            float bvp = bp1[o];
#pragma unroll
            for (int ni = 0; ni < 4; ++ni) {
                int px = wc * 64 + ni * 16 + lc;
                float v = ap[mi][ni][r] + bvp;
                v = v > 0.f ? v : 0.1f * v;
                *(unsigned short*)swz_ptr(hb, px, 2 * o) = f2bf(v);
            }
        }
    __syncthreads();
    {
        f32x4 acc[4][4];
#pragma unroll
        for (int mi = 0; mi < 4; ++mi)
#pragma unroll
            for (int ni = 0; ni < 4; ++ni) acc[mi][ni] = (f32x4){0.f,0.f,0.f,0.f};
#pragma unroll
        for (int kk = 0; kk < 128; kk += 32) {
            short8v bfr[4];
#pragma unroll
            for (int ni = 0; ni < 4; ++ni)
                bfr[ni] = *(const short8v*)swz_ptr(hb, wc * 64 + ni * 16 + lc, 2 * (kk + lr * 8));
#pragma unroll
            for (int mi = 0; mi < 4; ++mi) {
                int row = wr * 64 + mi * 16 + lc;
                short8v afr = *(const short8v*)(Wp2 + (size_t)row * 128 + kk + lr * 8);
#pragma unroll
                for (int ni = 0; ni < 4; ++ni)
                    acc[mi][ni] = __builtin_amdgcn_mfma_f32_16x16x32_bf16(afr, bfr[ni], acc[mi][ni], 0, 0, 0);
            }
        }
#pragma unroll
        for (int mi = 0; mi < 4; ++mi)
#pragma unroll
            for (int r = 0; r < 4; ++r) {
                int o = wr * 64 + mi * 16 + lr * 4 + r;
                float bv = bp2[o];
#pragma unroll
                for (int ni = 0; ni < 4; ++ni) {
                    int px = wc * 64 + ni * 16 + lc;
                    PHA[(size_t)bz * sO + (size_t)o * PLANEF_ + p0 + px] = f2bf(acc[mi][ni][r] + bv);
                }
            }
    }
}

// ---------------------------------------------------------------- fused MFMA FFN (x f32, fre bf16; residual from LDS; float4 out)
__global__ __launch_bounds__(256, 3) void ffn_mfma7(
    const float* __restrict__ x, const unsigned short* __restrict__ fre,
    const unsigned short* __restrict__ pinb,
    const unsigned short* __restrict__ pout2,
    const float4* __restrict__ pinC,
    float* __restrict__ out)
{
    __shared__ __align__(16) unsigned short xs[64][264];
    __shared__ unsigned short hs[64][136];
    __shared__ float2 muinv[64];
    float2* sred = (float2*)&hs[0][0];
    const int b = blockIdx.y;
    const size_t p0 = (size_t)blockIdx.x * 64;
    const int t = threadIdx.x;
    const int wave = t >> 6, lane = t & 63;
    const int lr = lane >> 4, lc = lane & 15;
    const int px4 = t & 15;

    float s0 = 0.f, s1 = 0.f, s2v = 0.f, s3 = 0.f;
    float q0 = 0.f, q1 = 0.f, q2 = 0.f, q3 = 0.f;
    {
        float4 stx[8];
        ush4 stf[8];
#pragma unroll
        for (int i = 0; i < 8; ++i) {
            int e = t + i * 256;
            int c = e >> 4;
            stx[i] = *(const float4*)(x + ((size_t)b * 128 + c) * HW_ + p0 + px4 * 4);
        }
#pragma unroll
        for (int i = 0; i < 8; ++i) {
            int e = t + i * 256;
            int c = e >> 4;
            stf[i] = *(const ush4*)(fre + (size_t)b * 8388608 + (size_t)c * HW_ + p0 + px4 * 4);
        }
#pragma unroll
        for (int i = 0; i < 8; ++i) {
            int e = t + i * 256;
            int c = e >> 4;
            float a0 = stx[i].x, a1 = stx[i].y, a2 = stx[i].z, a3 = stx[i].w;
            s0 += a0; q0 += a0 * a0;
            s1 += a1; q1 += a1 * a1;
            s2v += a2; q2 += a2 * a2;
            s3 += a3; q3 += a3 * a3;
            *(unsigned short*)swz_ptr(xs, px4 * 4 + 0, 2 * c) = f2bf(a0);
            *(unsigned short*)swz_ptr(xs, px4 * 4 + 1, 2 * c) = f2bf(a1);
            *(unsigned short*)swz_ptr(xs, px4 * 4 + 2, 2 * c) = f2bf(a2);
            *(unsigned short*)swz_ptr(xs, px4 * 4 + 3, 2 * c) = f2bf(a3);
        }
#pragma unroll
        for (int i = 0; i < 8; ++i) {
            int e = t + i * 256;
            int c = e >> 4;
            float a0 = bf2f((unsigned short)stf[i][0]);
            float a1 = bf2f((unsigned short)stf[i][1]);
            float a2 = bf2f((unsigned short)stf[i][2]);
            float a3 = bf2f((unsigned short)stf[i][3]);
            s0 += a0; q0 += a0 * a0;
            s1 += a1; q1 += a1 * a1;
            s2v += a2; q2 += a2 * a2;
            s3 += a3; q3 += a3 * a3;
            *(unsigned short*)swz_ptr(xs, px4 * 4 + 0, 2 * (128 + c)) = (unsigned short)stf[i][0];
            *(unsigned short*)swz_ptr(xs, px4 * 4 + 1, 2 * (128 + c)) = (unsigned short)stf[i][1];
            *(unsigned short*)swz_ptr(xs, px4 * 4 + 2, 2 * (128 + c)) = (unsigned short)stf[i][2];
            *(unsigned short*)swz_ptr(xs, px4 * 4 + 3, 2 * (128 + c)) = (unsigned short)stf[i][3];
        }
    }
    sred[(t >> 4) * 64 + px4 * 4 + 0] = make_float2(s0, q0);
    sred[(t >> 4) * 64 + px4 * 4 + 1] = make_float2(s1, q1);
    sred[(t >> 4) * 64 + px4 * 4 + 2] = make_float2(s2v, q2);
    sred[(t >> 4) * 64 + px4 * 4 + 3] = make_float2(s3, q3);
    __syncthreads();
    if (t < 64) {
        float ss = 0.f, qq = 0.f;
#pragma unroll
        for (int j = 0; j < 16; ++j) { float2 a = sred[j * 64 + t]; ss += a.x; qq += a.y; }
        float m = ss * (1.f / 256.f);
        float inv = rsqrtf(qq * (1.f / 256.f) - m * m + 1e-5f);
        muinv[t] = make_float2(m, inv);
    }
    __syncthreads();

    float2 mrow[4];
#pragma unroll
    for (int ni = 0; ni < 4; ++ni) mrow[ni] = muinv[ni * 16 + lc];

    f32x4 oc[2][4];
#pragma unroll
    for (int mi = 0; mi < 2; ++mi)
#pragma unroll
        for (int ni = 0; ni < 4; ++ni) oc[mi][ni] = (f32x4){0.f, 0.f, 0.f, 0.f};

#pragma unroll
    for (int half = 0; half < 2; ++half) {
        f32x4 a1[2][4], a2[2][4];
#pragma unroll
        for (int mi = 0; mi < 2; ++mi)
#pragma unroll
            for (int ni = 0; ni < 4; ++ni) { a1[mi][ni] = (f32x4){0.f,0.f,0.f,0.f}; a2[mi][ni] = (f32x4){0.f,0.f,0.f,0.f}; }

#pragma unroll
        for (int k0 = 0; k0 < 256; k0 += 32) {
            short8v bfr[4];
#pragma unroll
            for (int ni = 0; ni < 4; ++ni)
                bfr[ni] = *(const short8v*)swz_ptr(xs, ni * 16 + lc, 2 * (k0 + lr * 8));
#pragma unroll
            for (int mi = 0; mi < 2; ++mi) {
                int hrow = wave * 64 + half * 32 + mi * 16 + lc;
                short8v af1 = *(const short8v*)(pinb + (size_t)hrow * 256 + k0 + lr * 8);
                short8v af2 = *(const short8v*)(pinb + (size_t)(hrow + 256) * 256 + k0 + lr * 8);
#pragma unroll
                for (int ni = 0; ni < 4; ++ni) {
                    a1[mi][ni] = __builtin_amdgcn_mfma_f32_16x16x32_bf16(af1, bfr[ni], a1[mi][ni], 0, 0, 0);
                    a2[mi][ni] = __builtin_amdgcn_mfma_f32_16x16x32_bf16(af2, bfr[ni], a2[mi][ni], 0, 0, 0);
                }
            }
        }
        __syncthreads();
#pragma unroll
        for (int mi = 0; mi < 2; ++mi)
#pragma unroll
            for (int r = 0; r < 4; ++r) {
                int ho = wave * 64 + half * 32 + mi * 16 + lr * 4 + r;
                float4 bwc = pinC[ho];
                int kp = wave * 32 + mi * 16 + lr * 4 + r;
#pragma unroll
                for (int ni = 0; ni < 4; ++ni) {
                    float m = mrow[ni].x, inv = mrow[ni].y;
                    float v1 = a1[mi][ni][r] * inv + bwc.x - m * inv * bwc.y;
                    float v2 = a2[mi][ni][r] * inv + bwc.z - m * inv * bwc.w;
                    hs[ni * 16 + lc][kp] = f2bf(geluf(v1) * v2);
                }
            }
        __syncthreads();
#pragma unroll
        for (int k0 = 0; k0 < 128; k0 += 32) {
            short8v bfr2[4];
#pragma unroll
            for (int ni = 0; ni < 4; ++ni)
                bfr2[ni] = *(const short8v*)&hs[ni * 16 + lc][k0 + lr * 8];
#pragma unroll
            for (int mi = 0; mi < 2; ++mi) {
                int orow = wave * 32 + mi * 16 + lc;
                short8v af = *(const short8v*)(pout2 + half * 16384 + orow * 128 + k0 + lr * 8);
#pragma unroll
                for (int ni = 0; ni < 4; ++ni)
                    oc[mi][ni] = __builtin_amdgcn_mfma_f32_16x16x32_bf16(af, bfr2[ni], oc[mi][ni], 0, 0, 0);
            }
        }
    }

    // residual add from LDS (bf16 x), then coalesced float4 store via LDS transpose
    float vout[2][4][4];
#pragma unroll
    for (int mi = 0; mi < 2; ++mi)
#pragma unroll
        for (int r = 0; r < 4; ++r) {
            int o = wave * 32 + mi * 16 + lr * 4 + r;
#pragma unroll
            for (int ni = 0; ni < 4; ++ni) {
                int px = ni * 16 + lc;
                float rx = bf2f(*(const unsigned short*)swz_ptr(xs, px, 2 * o));
                vout[mi][r][ni] = oc[mi][ni][r] + rx;
            }
        }
    __syncthreads();                                   // all residual reads done
    float* fb = (float*)&xs[0][0];                     // [128][65] floats = 33280 B <= 33792 B
#pragma unroll
    for (int mi = 0; mi < 2; ++mi)
#pragma unroll
        for (int r = 0; r < 4; ++r) {
            int o = wave * 32 + mi * 16 + lr * 4 + r;
#pragma unroll
            for (int ni = 0; ni < 4; ++ni)
                fb[o * 65 + ni * 16 + lc] = vout[mi][r][ni];
        }
    __syncthreads();
    float* outb = out + ((size_t)b * 128) * HW_ + p0;
#pragma unroll
    for (int ii = 0; ii < 8; ++ii) {
        int e = t + ii * 256;                          // 2048: 128 o x 16 px4
        int o = e >> 4, q4 = e & 15;
        float4 w4 = make_float4(fb[o * 65 + q4 * 4 + 0], fb[o * 65 + q4 * 4 + 1],
                                fb[o * 65 + q4 * 4 + 2], fb[o * 65 + q4 * 4 + 3]);
        *(float4*)(outb + (size_t)o * HW_ + q4 * 4) = w4;
    }
}

// ---------------------------------------------------------------- depthwise 3x3 cd-conv (bf16), 8 px/thread, fused ssq
__global__ __launch_bounds__(256) void dwconv2(const unsigned short* __restrict__ X, size_t sx,
                                               const float* __restrict__ w9,
                                               const float* __restrict__ ksum,
                                               unsigned short* __restrict__ Y, size_t sy,
                                               float* __restrict__ ssq)
{
    int bz = blockIdx.z;
    int c = blockIdx.y;
    int p8 = blockIdx.x * 256 + threadIdx.x;
    int p0 = p8 * 8;
    int i = p0 >> 8, j0 = p0 & 255;
    const unsigned short* xp = X + (size_t)bz * sx + (size_t)c * HW_;
    const float* wc = w9 + c * 9;
    float a[8] = {0.f,0.f,0.f,0.f,0.f,0.f,0.f,0.f};
    float ctr[8];
#pragma unroll
    for (int di = -1; di <= 1; ++di) {
        int ii = i + di;
        if (ii < 0 || ii > 255) continue;
        const unsigned short* row = xp + ii * 256;
        ush8 m8 = *(const ush8*)(row + j0);
        float lft = (j0 > 0) ? bf2f(row[j0 - 1]) : 0.f;
        float rgt = (j0 < 248) ? bf2f(row[j0 + 8]) : 0.f;
        float v[10];
        v[0] = lft;
#pragma unroll
        for (int k = 0; k < 8; ++k) v[k + 1] = bf2f((unsigned short)m8[k]);
        v[9] = rgt;
        if (di == 0) {
#pragma unroll
            for (int k = 0; k < 8; ++k) ctr[k] = v[k + 1];
        }
        float w0 = wc[(di + 1) * 3], w1 = wc[(di + 1) * 3 + 1], w2 = wc[(di + 1) * 3 + 2];
#pragma unroll
        for (int k = 0; k < 8; ++k) a[k] += w0 * v[k] + w1 * v[k + 1] + w2 * v[k + 2];
    }
    float km = 0.7f * ksum[c];
    ush8 ov;
    float q = 0.f;
#pragma unroll
    for (int k = 0; k < 8; ++k) {
        float o = a[k] - km * ctr[k];
        ov[k] = f2bf(o);
        q += o * o;
    }
    *(ush8*)(Y + (size_t)bz * sy + (size_t)c * HW_ + p0) = ov;

    __shared__ float red[256];
    red[threadIdx.x] = q; __syncthreads();
    for (int st = 128; st; st >>= 1) {
        if (threadIdx.x < st) red[threadIdx.x] += red[threadIdx.x + st];
        __syncthreads();
    }
    if (!threadIdx.x) atomicAdd(&ssq[bz * C_ + c], red[0]);
}

// ---------------------------------------------------------------- attention helpers (bf16 q/k/v)
__global__ __launch_bounds__(256) void gram_kernel(const unsigned short* __restrict__ Q, size_t sq,
                                                   const unsigned short* __restrict__ K, size_t sk,
                                                   float* __restrict__ part)
{
    int sl = blockIdx.x, h = blockIdx.y, bz = blockIdx.z;
    const unsigned short* qb = Q + (size_t)bz * sq + (size_t)(h * 16) * HW_;
    const unsigned short* kb = K + (size_t)bz * sk + (size_t)(h * 16) * HW_;
    __shared__ __align__(16) float qs[16][264];
    __shared__ __align__(16) float ks[16][264];
    int c = threadIdx.x >> 4, d = threadIdx.x & 15;
    int t = threadIdx.x;
    float acc = 0.f;
    for (int n0 = sl * 2048; n0 < (sl + 1) * 2048; n0 += 256) {
        ush4 qv[4], kv[4];
#pragma unroll
        for (int ii = 0; ii < 4; ++ii) {
            int e = t + ii * 256;
            int cc = e >> 6, n4 = e & 63;
            qv[ii] = *(const ush4*)(qb + (size_t)cc * HW_ + n0 + n4 * 4);
            kv[ii] = *(const ush4*)(kb + (size_t)cc * HW_ + n0 + n4 * 4);
        }
#pragma unroll
        for (int ii = 0; ii < 4; ++ii) {
            int e = t + ii * 256;
            int cc = e >> 6, n4 = e & 63;
#pragma unroll
            for (int j = 0; j < 4; ++j) {
                qs[cc][n4 * 4 + j] = bf2f((unsigned short)qv[ii][j]);
                ks[cc][n4 * 4 + j] = bf2f((unsigned short)kv[ii][j]);
            }
        }
        __syncthreads();
#pragma unroll 16
        for (int nn = 0; nn < 256; nn += 4) {
            float4 a4 = *(const float4*)&qs[c][nn];
            float4 b4 = *(const float4*)&ks[d][nn];
            acc += a4.x * b4.x + a4.y * b4.y + a4.z * b4.z + a4.w * b4.w;
        }
        __syncthreads();
    }
    part[((size_t)(bz * 8 + h) * 32 + sl) * 256 + threadIdx.x] = acc;
}

__global__ __launch_bounds__(256) void softmax_kernel(const float* __restrict__ part,
                                                      const float* __restrict__ nqsq,
                                                      const float* __restrict__ nksq,
                                                      const float* __restrict__ temp,
                                                      float* __restrict__ attn)
{
    int h = blockIdx.x, bz = blockIdx.y;
    int t = threadIdx.x;
    int c = t >> 4, d = t & 15;
    float g = 0.f;
    for (int sl = 0; sl < 32; ++sl) g += part[((size_t)(bz * 8 + h) * 32 + sl) * 256 + t];
    float nqv = fmaxf(sqrtf(nqsq[bz * C_ + h * 16 + c]), 1e-12f);
    float nkv = fmaxf(sqrtf(nksq[bz * C_ + h * 16 + d]), 1e-12f);
    g *= temp[h] / (nqv * nkv);
    float m = g;
#pragma unroll
    for (int off = 8; off; off >>= 1) m = fmaxf(m, __shfl_xor(m, off, 16));
    float e = __expf(g - m);
    float ssum = e;
#pragma unroll
    for (int off = 8; off; off >>= 1) ssum += __shfl_xor(ssum, off, 16);
    attn[(bz * 8 + h) * 256 + t] = e / ssum;
}

__global__ __launch_bounds__(256) void av_kernel(const float* __restrict__ attn,
                                                 const unsigned short* __restrict__ V, size_t sv,
                                                 unsigned short* __restrict__ Y, size_t sy)
{
    __shared__ __align__(16) float kv[16][260];
    __shared__ __align__(16) float at[16][16];
    int tile = blockIdx.x, h = blockIdx.y, bz = blockIdx.z;
    int n0 = tile * 256, t = threadIdx.x;
    const unsigned short* vb = V + (size_t)bz * sv + (size_t)(h * 16) * HW_;
    at[t >> 4][t & 15] = attn[(size_t)(bz * 8 + h) * 256 + (t & 15) * 16 + (t >> 4)];
#pragma unroll
    for (int i = 0; i < 4; ++i) {
        int e = t + i * 256;
        int d = e >> 6, nn4 = e & 63;
        ush4 v4 = *(const ush4*)(vb + (size_t)d * HW_ + n0 + nn4 * 4);
#pragma unroll
        for (int j = 0; j < 4; ++j) kv[d][nn4 * 4 + j] = bf2f((unsigned short)v4[j]);
    }
    __syncthreads();
    float acc[16];
#pragma unroll
    for (int cc = 0; cc < 16; ++cc) acc[cc] = 0.f;
#pragma unroll
    for (int d = 0; d < 16; ++d) {
        float kvv = kv[d][t];
        float4 a0 = *(const float4*)&at[d][0];
        float4 a1 = *(const float4*)&at[d][4];
        float4 a2 = *(const float4*)&at[d][8];
        float4 a3 = *(const float4*)&at[d][12];
        acc[0]  += a0.x * kvv; acc[1]  += a0.y * kvv; acc[2]  += a0.z * kvv; acc[3]  += a0.w * kvv;
        acc[4]  += a1.x * kvv; acc[5]  += a1.y * kvv; acc[6]  += a1.z * kvv; acc[7]  += a1.w * kvv;
        acc[8]  += a2.x * kvv; acc[9]  += a2.y * kvv; acc[10] += a2.z * kvv; acc[11] += a2.w * kvv;
        acc[12] += a3.x * kvv; acc[13] += a3.y * kvv; acc[14] += a3.z * kvv; acc[15] += a3.w * kvv;
    }
    unsigned short* yb = Y + (size_t)bz * sy + (size_t)(h * 16) * HW_ + n0 + t;
#pragma unroll
    for (int cc = 0; cc < 16; ++cc) yb[(size_t)cc * HW_] = f2bf(acc[cc]);
}

// ---------------------------------------------------------------- 256-pt radix-2 DIT FFT, 2 rows per 32-lane group
__device__ __forceinline__ void fft_stages2(float2* rowA, float2* rowB, const float2* tw, int lane)
{
#pragma unroll
    for (int s = 1; s <= 8; ++s) {
        const int half = 1 << (s - 1);
#pragma unroll
        for (int r = 0; r < 4; ++r) {
            int jb = lane + r * 32;
            int j = jb & (half - 1);
            int g = jb >> (s - 1);
            int i1 = (g << s) + j;
            float2 w = tw[j << (8 - s)];
            float2 u = rowA[i1];
            float2 q = rowA[i1 + half];
            float2 v = make_float2(q.x * w.x - q.y * w.y, q.x * w.y + q.y * w.x);
            rowA[i1]        = make_float2(u.x + v.x, u.y + v.y);
            rowA[i1 + half] = make_float2(u.x - v.x, u.y - v.y);
            float2 u2 = rowB[i1];
            float2 q2 = rowB[i1 + half];
            float2 v2 = make_float2(q2.x * w.x - q2.y * w.y, q2.x * w.y + q2.y * w.x);
            rowB[i1]        = make_float2(u2.x + v2.x, u2.y + v2.y);
            rowB[i1 + half] = make_float2(u2.x - v2.x, u2.y - v2.y);
        }
        __builtin_amdgcn_wave_barrier();
    }
    __syncthreads();
}

#define PI2_ 6.28318530717958647692f

// bf16 real rows -> transposed packed-bf16 spectrum T[c][k][h]; 16 rows/block
__global__ __launch_bounds__(256) void rfft_rowsT(const unsigned short* __restrict__ X, size_t sx,
                                                  unsigned* __restrict__ T, size_t st)
{
    __shared__ float2 sd[16][256];
    __shared__ float2 tw[128];
    int t = threadIdx.x;
    int bz = blockIdx.y;
    if (t < 128) { float sn, cs; __sincosf(-PI2_ * (float)t * (1.f / 256.f), &sn, &cs); tw[t] = make_float2(cs, sn); }
    size_t r0 = (size_t)blockIdx.x * 16;
    int c = (int)(r0 >> 8), h0 = (int)(r0 & 255);
    const unsigned short* Xb = X + (size_t)bz * sx;
    ush4 v4[4];
#pragma unroll
    for (int ii = 0; ii < 4; ++ii) {
        int e = t + ii * 256;
        int j = e >> 6, i4 = e & 63;
        v4[ii] = *(const ush4*)(Xb + (r0 + j) * 256 + i4 * 4);
    }
#pragma unroll
    for (int ii = 0; ii < 4; ++ii) {
        int e = t + ii * 256;
        int j = e >> 6, i4 = e & 63;
#pragma unroll
        for (int k2 = 0; k2 < 4; ++k2)
            sd[j][__brev((unsigned)(i4 * 4 + k2)) >> 24] = make_float2(bf2f((unsigned short)v4[ii][k2]), 0.f);
    }
    __syncthreads();
    fft_stages2(sd[t >> 5], sd[(t >> 5) + 8], tw, t & 31);
    unsigned* base = T + (size_t)bz * st + (size_t)c * PLANEF_;
    for (int e = t; e < 129 * 16; e += 256) {
        int j = e & 15, k = e >> 4;
        base[(size_t)k * 256 + h0 + j] = pack2bf(sd[j][k]);
    }
}

// forward complex FFT along h; 16 k-rows/block; uint4 I/O
__global__ __launch_bounds__(256) void cfftT_fwd(unsigned* __restrict__ T, size_t st)
{
    __shared__ float2 sd[16][256];
    __shared__ float2 tw[128];
    int t = threadIdx.x;
    int bz = blockIdx.z;
    if (t < 128) { float sn, cs; __sincosf(-PI2_ * (float)t * (1.f / 256.f), &sn, &cs); tw[t] = make_float2(cs, sn); }
    int k0 = blockIdx.x * 16;
    int c = blockIdx.y;
    unsigned* base = T + (size_t)bz * st + (size_t)c * PLANEF_;
    uint4v v4[4];
#pragma unroll
    for (int ii = 0; ii < 4; ++ii) {
        int e = t + ii * 256;
        int j = e >> 6, i4 = e & 63;
        int k = k0 + j;
        if (k < KF_) v4[ii] = *(const uint4v*)(base + (size_t)k * 256 + i4 * 4);
        else v4[ii] = (uint4v){0u, 0u, 0u, 0u};
    }
#pragma unroll
    for (int ii = 0; ii < 4; ++ii) {
        int e = t + ii * 256;
        int j = e >> 6, i4 = e & 63;
#pragma unroll
        for (int q = 0; q < 4; ++q)
            sd[j][__brev((unsigned)(i4 * 4 + q)) >> 24] = upk(v4[ii][q]);
    }
    __syncthreads();
    fft_stages2(sd[t >> 5], sd[(t >> 5) + 8], tw, t & 31);
#pragma unroll
    for (int ii = 0; ii < 4; ++ii) {
        int e = t + ii * 256;
        int j = e >> 6, i4 = e & 63;
        int k = k0 + j;
        if (k < KF_) {
            uint4v o;
#pragma unroll
            for (int q = 0; q < 4; ++q) o[q] = pack2bf(sd[j][i4 * 4 + q]);
            *(uint4v*)(base + (size_t)k * 256 + i4 * 4) = o;
        }
    }
}

// combine(amp,pha bf16) + inverse h-FFT; 16 k-rows/block
__global__ __launch_bounds__(256) void cifft_combine(const unsigned short* __restrict__ amp, size_t sa,
                                                     const unsigned short* __restrict__ pha, size_t sp,
                                                     unsigned* __restrict__ S, size_t ss)
{
    __shared__ float2 sd[16][256];
    __shared__ float2 tw[128];
    int t = threadIdx.x;
    int bz = blockIdx.z;
    if (t < 128) { float sn, cs; __sincosf(PI2_ * (float)t * (1.f / 256.f), &sn, &cs); tw[t] = make_float2(cs, sn); }
    int k0 = blockIdx.x * 16;
    int c = blockIdx.y;
    const unsigned short* ab = amp + (size_t)bz * sa + (size_t)c * PLANEF_;
    const unsigned short* pb = pha + (size_t)bz * sp + (size_t)c * PLANEF_;
    ush4 a4[4], p4[4];
#pragma unroll
    for (int ii = 0; ii < 4; ++ii) {
        int e = t + ii * 256;
        int j = e >> 6, i4 = e & 63;
        int k = k0 + j;
        if (k < KF_) {
            a4[ii] = *(const ush4*)(ab + (size_t)k * 256 + i4 * 4);
            p4[ii] = *(const ush4*)(pb + (size_t)k * 256 + i4 * 4);
        } else {
            a4[ii] = (ush4){0,0,0,0}; p4[ii] = (ush4){0,0,0,0};
        }
    }
#pragma unroll
    for (int ii = 0; ii < 4; ++ii) {
        int e = t + ii * 256;
        int j = e >> 6, i4 = e & 63;
        int k = k0 + j;
#pragma unroll
        for (int q = 0; q < 4; ++q) {
            float2 v = make_float2(0.f, 0.f);
            if (k < KF_) {
                float a = bf2f((unsigned short)a4[ii][q]);
                float p = bf2f((unsigned short)p4[ii][q]);
                float sn, cs;
                __sincosf(p, &sn, &cs);
                v = make_float2(a * cs + 2e-8f, a * sn + 1e-8f);
            }
            sd[j][__brev((unsigned)(i4 * 4 + q)) >> 24] = v;
        }
    }
    __syncthreads();
    fft_stages2(sd[t >> 5], sd[(t >> 5) + 8], tw, t & 31);
    unsigned* base = S + (size_t)bz * ss + (size_t)c * PLANEF_;
    for (int e = t; e < 4096; e += 256) {
        int j = e & 15, h = e >> 4;
        int k = k0 + j;
        if (k < KF_) {
            float2 o = sd[j][h];
            base[(size_t)h * KF_ + k] = pack2bf(make_float2(o.x * (1.f / 256.f), o.y * (1.f / 256.f)));
        }
    }
}

// row-major packed-bf16 spectrum -> 256 real (Hermitian) -> |.| -> bf16; 16 rows/block
__global__ __launch_bounds__(256) void irfft_rows16_abs(const unsigned* __restrict__ S, size_t ss,
                                                        unsigned short* __restrict__ Y, size_t sy)
{
    __shared__ float2 sd[16][256];
    __shared__ float2 tw[128];
    int t = threadIdx.x;
    int bz = blockIdx.y;
    if (t < 128) { float sn, cs; __sincosf(PI2_ * (float)t * (1.f / 256.f), &sn, &cs); tw[t] = make_float2(cs, sn); }
    size_t r0 = (size_t)blockIdx.x * 16;
    const unsigned* Sb = S + (size_t)bz * ss;
    for (int e = t; e < 4096; e += 256) {
        int j = e >> 8, i = e & 255;
        const unsigned* row = Sb + (r0 + j) * 129;
        float2 v;
        if (i < 129) v = upk(row[i]);
        else { float2 w2 = upk(row[256 - i]); v = make_float2(w2.x, -w2.y); }
        sd[j][__brev((unsigned)i) >> 24] = v;
    }
    __syncthreads();
    fft_stages2(sd[t >> 5], sd[(t >> 5) + 8], tw, t & 31);
    unsigned short* Yb = Y + (size_t)bz * sy;
#pragma unroll
    for (int ii = 0; ii < 2; ++ii) {
        int e = t + ii * 256;
        int j = e >> 5, i8 = e & 31;
        ush8 ov;
#pragma unroll
        for (int q = 0; q < 8; ++q) ov[q] = f2bf(fabsf(sd[j][i8 * 8 + q].x * (1.f / 256.f)));
        *(ush8*)(Yb + (r0 + j) * 256 + i8 * 8) = ov;
    }
}

// ---------------------------------------------------------------- host
extern "C" void kernel_launch(void* const* d_in, const int* in_sizes, int n_in,
                              void* d_out, int out_size, void* d_ws, size_t ws_size,
                              hipStream_t stream)
{
    (void)in_sizes; (void)n_in; (void)out_size;
    const float* ms    = (const float*)d_in[0];
    const float* pan   = (const float*)d_in[1];
    const float* ln1w  = (const float*)d_in[2];
    const float* ln1b  = (const float*)d_in[3];
    const float* ln2w  = (const float*)d_in[4];
    const float* ln2b  = (const float*)d_in[5];
    const float* qkvw  = (const float*)d_in[6];
    const float* dww   = (const float*)d_in[7];
    const float* temp  = (const float*)d_in[8];
    const float* projw = (const float*)d_in[9];
    const float* pre1w = (const float*)d_in[10];
    const float* pre1b = (const float*)d_in[11];
    const float* pre2w = (const float*)d_in[12];
    const float* pre2b = (const float*)d_in[13];
    const float* amp1w = (const float*)d_in[14];
    const float* amp1b = (const float*)d_in[15];
    const float* amp2w = (const float*)d_in[16];
    const float* amp2b = (const float*)d_in[17];
    const float* pha1w = (const float*)d_in[18];
    const float* pha1b = (const float*)d_in[19];
    const float* pha2w = (const float*)d_in[20];
    const float* pha2b = (const float*)d_in[21];
    const float* postw = (const float*)d_in[22];
    const float* postb = (const float*)d_in[23];
    const float* pinw  = (const float*)d_in[24];
    const float* poutw = (const float*)d_in[25];

    const size_t SLOT  = 8454144;
    const size_t CHWu  = 8388608;
    const size_t CPFu  = 4227072;
    const size_t SPECu = 4227072;
    const size_t PARAMU = 344064;
    const size_t PARAMF = 273792;

    auto need = [&](int nb, int nslot) -> size_t {
        return 2ull * (33554432ull + (size_t)nb * (size_t)nslot * SLOT + PARAMU) + 4ull * PARAMF + 64;
    };
    int NB; bool FUSED;
    if      (ws_size >= need(4, 5)) { NB = 4; FUSED = true;  }
    else if (ws_size >= need(4, 3)) { NB = 4; FUSED = false; }
    else if (ws_size >= need(2, 5)) { NB = 2; FUSED = true;  }
    else if (ws_size >= need(2, 3)) { NB = 2; FUSED = false; }
    else if (ws_size >= need(1, 5)) { NB = 1; FUSED = true;  }
    else                            { NB = 1; FUSED = false; }
    const int NSLOT = FUSED ? 5 : 3;

    unsigned short* F  = (unsigned short*)d_ws;
    unsigned short* U0 = F + 33554432;
    unsigned short* U1 = U0 + (size_t)NB * SLOT;
    unsigned short* U2 = U1 + (size_t)NB * SLOT;
    unsigned short* U3 = U2 + (size_t)NB * SLOT;   // valid only if FUSED
    unsigned short* U4 = U3 + (size_t)NB * SLOT;   // valid only if FUSED
    unsigned short* parU = U0 + (size_t)NB * (size_t)NSLOT * SLOT;
    unsigned short* w_qkv   = parU;
    unsigned short* w_proj  = w_qkv  + 16384;
    unsigned short* w_pre1  = w_proj + 16384;
    unsigned short* w_pre2  = w_pre1 + 16384;
    unsigned short* w_post  = w_pre2 + 16384;
    unsigned short* w_amp1  = w_post + 16384;
    unsigned short* w_pha1  = w_amp1 + 32768;
    unsigned short* w_amp2  = w_pha1 + 32768;
    unsigned short* w_pha2  = w_amp2 + 16384;
    unsigned short* w_pin   = w_pha2 + 16384;
    unsigned short* w_pout2 = w_pin  + 131072;
    float* fpar   = (float*)(w_pout2 + 32768);
    float* ksumP  = fpar;
    float* nqsq   = ksumP + 128;
    float* nksq   = nqsq  + 512;
    float* attnP  = nksq  + 512;
    float* partP  = attnP + 8192;
    float* qkv_ws = partP + 262144;
    float* qkv_bb = qkv_ws + 128;
    float* pin_ws = qkv_bb + 128;
    float* pin_bb = pin_ws + 512;
    float* pinC   = pin_bb + 512;

    float* xout = (float*)d_out;

    auto CVT = [&](const float* src, unsigned short* dst, int n) {
        tobf16_kernel<<<(n + 255) / 256, 256, 0, stream>>>(src, dst, n);
    };
    foldln_kernel<<<128, 128, 0, stream>>>(qkvw, ln1w, ln1b, w_qkv, qkv_ws, qkv_bb, 128);
    foldln_kernel<<<512, 128, 0, stream>>>(pinw, ln2w, ln2b, w_pin, pin_ws, pin_bb, 256);
    CVT(projw, w_proj, 16384);
    CVT(pre1w, w_pre1, 16384); CVT(pre2w, w_pre2, 16384);
    CVT(postw, w_post, 16384);
    CVT(amp1w, w_amp1, 32768); CVT(pha1w, w_pha1, 32768);
    CVT(amp2w, w_amp2, 16384); CVT(pha2w, w_pha2, 16384);
    poutperm_kernel<<<128, 256, 0, stream>>>(poutw, w_pout2);
    pinc_kernel<<<1, 256, 0, stream>>>(pin_bb, pin_ws, (float4*)pinC);
    ksum_kernel<<<1, 128, 0, stream>>>(dww, ksumP);

    const size_t CHW = (size_t)C_ * HW_;
    const float* NUL = nullptr;

    for (int b0 = 0; b0 < B_; b0 += NB) {
        const float* msb  = ms  + (size_t)b0 * CHW;
        const float* panb = pan + (size_t)b0 * CHW;
        float* xb = xout + (size_t)b0 * CHW;
        unsigned short* freb = F + (size_t)b0 * CHWu;
        dim3 gz(512, 1, NB);
        dim3 gzf(258, 1, NB);

        zero2_kernel<<<(NB * 128 + 255) / 256, 256, 0, stream>>>(nqsq, nksq, NB * 128);

        if (FUSED) {
            // ---- fused qkv+pre staging (ms, pan read once each) ----
            mconv_dual<<<gz, 256, 0, stream>>>(
                msb, CHW, w_qkv, qkv_ws, qkv_bb, w_pre1, pre1b, U0, U1, SLOT);     // qkv_ms->U0, pre_ms->U1
            dwconv2<<<dim3(32, 128, NB), 256, 0, stream>>>(U0, SLOT, dww, ksumP, U2, SLOT, nqsq);  // q->U2
            mconv_dual<<<gz, 256, 0, stream>>>(
                panb, CHW, w_qkv, qkv_ws, qkv_bb, w_pre2, pre2b, U0, U3, SLOT);    // qkv_pan->U0, pre_pan->U3
            dwconv2<<<dim3(32, 128, NB), 256, 0, stream>>>(U0, SLOT, dww, ksumP, U4, SLOT, nksq);  // kv->U4
            gram_kernel<<<dim3(32, 8, NB), 256, 0, stream>>>(U2, SLOT, U4, SLOT, partP);
            softmax_kernel<<<dim3(8, NB), 256, 0, stream>>>(partP, nqsq, nksq, temp, attnP);
            av_kernel<<<dim3(256, 8, NB), 256, 0, stream>>>(attnP, U4, SLOT, U0, SLOT);            // attnout->U0
            mconv2<1, 0, 0, false><<<gz, 256, 0, stream>>>(
                U0, SLOT, w_proj, 128, nullptr, msb, CHW, xb, CHW, HW_, 0, NUL, NUL);

            // ---- freprocess ----
            rfft_rowsT<<<dim3(2048, NB), 256, 0, stream>>>(U1, SLOT, (unsigned*)(void*)U0, SPECu); // spec1->U0
            cfftT_fwd<<<dim3(9, 128, NB), 256, 0, stream>>>((unsigned*)(void*)U0, SPECu);
            rfft_rowsT<<<dim3(2048, NB), 256, 0, stream>>>(U3, SLOT, (unsigned*)(void*)U2, SPECu); // spec2->U2
            cfftT_fwd<<<dim3(9, 128, NB), 256, 0, stream>>>((unsigned*)(void*)U2, SPECu);
            apconv2<<<gzf, 256, 0, stream>>>(
                (const unsigned*)(void*)U0, (const unsigned*)(void*)U2, SPECu,
                w_amp1, w_pha1, w_amp2, w_pha2, amp1b, pha1b, amp2b, pha2b,
                U1, U1 + CPFu, SLOT);                                                              // amp/pha->U1
            cifft_combine<<<dim3(9, 128, NB), 256, 0, stream>>>(
                U1, SLOT, U1 + CPFu, SLOT, (unsigned*)(void*)U3, SPECu);                           // S->U3
            irfft_rows16_abs<<<dim3(2048, NB), 256, 0, stream>>>((unsigned*)(void*)U3, SPECu, U0, SLOT); // y->U0
            mconv2<1, 1, 0, false><<<gz, 256, 0, stream>>>(
                U0, SLOT, w_post, 128, postb, nullptr, 0, freb, CHWu, HW_, 0, NUL, NUL);
        } else {
            // ---- unfused 3-slot flow (round-12 behavior) ----
            mconv2<0, 1, 0, true><<<gz, 256, 0, stream>>>(
                msb, CHW, w_qkv, 128, nullptr, nullptr, 0, U0, SLOT, HW_, 0, qkv_ws, qkv_bb);
            dwconv2<<<dim3(32, 128, NB), 256, 0, stream>>>(U0, SLOT, dww, ksumP, U1, SLOT, nqsq);
            mconv2<0, 1, 0, true><<<gz, 256, 0, stream>>>(
                panb, CHW, w_qkv, 128, nullptr, nullptr, 0, U0, SLOT, HW_, 0, qkv_ws, qkv_bb);
            dwconv2<<<dim3(32, 128, NB), 256, 0, stream>>>(U0, SLOT, dww, ksumP, U2, SLOT, nksq);
            gram_kernel<<<dim3(32, 8, NB), 256, 0, stream>>>(U1, SLOT, U2, SLOT, partP);
            softmax_kernel<<<dim3(8, NB), 256, 0, stream>>>(partP, nqsq, nksq, temp, attnP);
            av_kernel<<<dim3(256, 8, NB), 256, 0, stream>>>(attnP, U2, SLOT, U0, SLOT);
            mconv2<1, 0, 0, false><<<gz, 256, 0, stream>>>(
                U0, SLOT, w_proj, 128, nullptr, msb, CHW, xb, CHW, HW_, 0, NUL, NUL);

            mconv2<0, 1, 0, false><<<gz, 256, 0, stream>>>(
                msb, CHW, w_pre1, 128, pre1b, nullptr, 0, U0, SLOT, HW_, 1, NUL, NUL);
            rfft_rowsT<<<dim3(2048, NB), 256, 0, stream>>>(U0, SLOT, (unsigned*)(void*)U1, SPECu);
            cfftT_fwd<<<dim3(9, 128, NB), 256, 0, stream>>>((unsigned*)(void*)U1, SPECu);
            mconv2<0, 1, 0, false><<<gz, 256, 0, stream>>>(
                panb, CHW, w_pre2, 128, pre2b, nullptr, 0, U0, SLOT, HW_, 1, NUL, NUL);
            rfft_rowsT<<<dim3(2048, NB), 256, 0, stream>>>(U0, SLOT, (unsigned*)(void*)U2, SPECu);
            cfftT_fwd<<<dim3(9, 128, NB), 256, 0, stream>>>((unsigned*)(void*)U2, SPECu);
            apconv2<<<gzf, 256, 0, stream>>>(
                (const unsigned*)(void*)U1, (const unsigned*)(void*)U2, SPECu,
                w_amp1, w_pha1, w_amp2, w_pha2, amp1b, pha1b, amp2b, pha2b,
                U0, U0 + CPFu, SLOT);
            cifft_combine<<<dim3(9, 128, NB), 256, 0, stream>>>(
                U0, SLOT, U0 + CPFu, SLOT, (unsigned*)(void*)U2, SPECu);
            irfft_rows16_abs<<<dim3(2048, NB), 256, 0, stream>>>((unsigned*)(void*)U2, SPECu, U0, SLOT);
            mconv2<1, 1, 0, false><<<gz, 256, 0, stream>>>(
                U0, SLOT, w_post, 128, postb, nullptr, 0, freb, CHWu, HW_, 0, NUL, NUL);
        }
    }

    // ---- FFN (full batch, LN2 + gelu-gate fused, residual from LDS, float4 out) ----
    ffn_mfma7<<<dim3(HW_ / 64, B_), 256, 0, stream>>>(xout, F, w_pin, w_pout2, (const float4*)pinC, xout);
}

// Round 14
// 1577.383 us; speedup vs baseline: 1.2889x; 1.0194x over previous
//
#include <hip/hip_runtime.h>
#include <math.h>

#define B_ 4
#define C_ 128
#define HW_ 65536
#define H__ 256
#define KF_ 129
#define PLANEF_ 33024

typedef __attribute__((ext_vector_type(8))) short short8v;
typedef __attribute__((ext_vector_type(4))) float f32x4;
typedef __attribute__((ext_vector_type(4))) unsigned short ush4;
typedef __attribute__((ext_vector_type(8))) unsigned short ush8;
typedef __attribute__((ext_vector_type(4))) unsigned uint4v;

__device__ __forceinline__ unsigned short f2bf(float f) {
    union { float f; unsigned u; } v; v.f = f;
    return (unsigned short)((v.u + 0x7FFFu + ((v.u >> 16) & 1u)) >> 16);
}
__device__ __forceinline__ float bf2f(unsigned short s) {
    union { unsigned u; float f; } v; v.u = (unsigned)s << 16;
    return v.f;
}
__device__ __forceinline__ unsigned pack2bf(float2 v) {
    return (unsigned)f2bf(v.x) | ((unsigned)f2bf(v.y) << 16);
}
__device__ __forceinline__ float2 upk(unsigned u) {
    return make_float2(bf2f((unsigned short)(u & 0xffff)), bf2f((unsigned short)(u >> 16)));
}
// fast gelu: A&S 7.1.26 erf (|err|<=1.5e-7) with __expf
__device__ __forceinline__ float geluf(float x) {
    float z = 0.70710678118654752f * fabsf(x);
    float t = __fdividef(1.f, fmaf(0.3275911f, z, 1.f));
    float p = fmaf(1.061405429f, t, -1.453152027f);
    p = fmaf(p, t, 1.421413741f);
    p = fmaf(p, t, -0.284496736f);
    p = fmaf(p, t, 0.254829592f);
    p = p * t;
    float erfv = 1.f - p * __expf(-z * z);
    float cdf = (x >= 0.f) ? fmaf(0.5f, erfv, 0.5f) : fmaf(-0.5f, erfv, 0.5f);
    return x * cdf;
}
// fast atan2, poly err ~1e-5 rad
__device__ __forceinline__ float fatan2(float y, float x) {
    float ax = fabsf(x), ay = fabsf(y);
    float mx = fmaxf(ax, ay), mn = fminf(ax, ay);
    float a = __fdividef(mn, fmaxf(mx, 1e-38f));
    float s = a * a;
    float r = fmaf(0.0208351f, s, -0.0851330f);
    r = fmaf(r, s, 0.1801410f);
    r = fmaf(r, s, -0.3302995f);
    r = fmaf(r, s, 0.9998660f);
    r = r * a;
    if (ay > ax) r = 1.57079632679489662f - r;
    if (x < 0.f) r = 3.14159265358979324f - r;
    return copysignf(r, y);
}
// LDS XOR swizzle on byte-offset within row
template<int W>
__device__ __forceinline__ char* swz_ptr(unsigned short (*xs)[W], int px, int cb) {
    return (char*)xs + px * (W * 2) + (cb ^ (((px >> 2) & 7) << 4));
}

// ---------------------------------------------------------------- prep
__global__ __launch_bounds__(256) void tobf16_kernel(const float* __restrict__ src,
                                                     unsigned short* __restrict__ dst, int n)
{
    int i = blockIdx.x * 256 + threadIdx.x;
    if (i < n) dst[i] = f2bf(src[i]);
}

__global__ __launch_bounds__(128) void foldln_kernel(const float* __restrict__ W,
                                                     const float* __restrict__ lnw,
                                                     const float* __restrict__ lnb,
                                                     unsigned short* __restrict__ Wb,
                                                     float* __restrict__ wsum, float* __restrict__ bsum,
                                                     int Cc)
{
    int o = blockIdx.x, t = threadIdx.x;
    float sw = 0.f, sb = 0.f;
    for (int c = t; c < Cc; c += 128) {
        float w = W[(size_t)o * Cc + c];
        float fw = w * lnw[c];
        unsigned short us = f2bf(fw);
        Wb[(size_t)o * Cc + c] = us;
        sw += bf2f(us);
        sb += w * lnb[c];
    }
    __shared__ float r1[128], r2[128];
    r1[t] = sw; r2[t] = sb; __syncthreads();
    for (int st = 64; st; st >>= 1) {
        if (t < st) { r1[t] += r1[t + st]; r2[t] += r2[t + st]; }
        __syncthreads();
    }
    if (!t) { wsum[o] = r1[0]; bsum[o] = r2[0]; }
}

__global__ __launch_bounds__(256) void poutperm_kernel(const float* __restrict__ src,
                                                       unsigned short* __restrict__ dst)
{
    int i = blockIdx.x * 256 + threadIdx.x;   // 32768
    int half = i >> 14, rem = i & 16383, o = rem >> 7, kp = rem & 127;
    int h = (kp >> 5) * 64 + half * 32 + (kp & 31);
    dst[i] = f2bf(src[o * 256 + h]);
}

__global__ void pinc_kernel(const float* __restrict__ bb, const float* __restrict__ ws,
                            float4* __restrict__ pinC)
{
    int i = threadIdx.x;
    if (i < 256) pinC[i] = make_float4(bb[i], ws[i], bb[i + 256], ws[i + 256]);
}

__global__ void ksum_kernel(const float* __restrict__ dw, float* __restrict__ ks)
{
    int c = threadIdx.x;
    if (c < C_) {
        float s = 0.f;
        for (int k = 0; k < 9; ++k) s += dw[c * 9 + k];
        ks[c] = s;
    }
}

__global__ __launch_bounds__(256) void zero2_kernel(float* __restrict__ a, float* __restrict__ b, int n)
{
    int i = blockIdx.x * 256 + threadIdx.x;
    if (i < n) { a[i] = 0.f; b[i] = 0.f; }
}

// ---------------------------------------------------------------- MFMA conv1x1 (CIN=128)
// INBF: input dtype 0=f32 1=bf16. OUTBF: output dtype. PRO==1: leaky(0.1) on staged value.
// LNF: register LN stats + folded-affine epilogue. flags&1: +1e-8 after bias. res: f32 residual (any OUTBF).
template<int INBF, int OUTBF, int PRO, bool LNF>
__global__ __launch_bounds__(256, 4) void mconv2(
    const void* __restrict__ Xv, size_t sx,
    const unsigned short* __restrict__ Wb, int wstride,
    const float* __restrict__ bias,
    const float* __restrict__ res, size_t sres,
    void* __restrict__ Yv, size_t sy, int plane, int flags,
    const float* __restrict__ wsum, const float* __restrict__ bsum)
{
    __shared__ unsigned short xs[128][136];
    __shared__ float2 lnred[LNF ? 8 : 1][LNF ? 128 : 1];
    __shared__ float2 lnmi[LNF ? 128 : 1];
    const int t = threadIdx.x;
    const int bz = blockIdx.z;
    const int p0 = blockIdx.x * 128;
    const int lane = t & 63;
    const int wr = t >> 7, wc = (t >> 6) & 1;
    const int lr = lane >> 4, lc = lane & 15;

    if constexpr (INBF == 0) {
        const float* Xb = (const float*)Xv + (size_t)bz * sx;
        const int px4 = t & 31;
        float s0 = 0.f, s1 = 0.f, s2v = 0.f, s3 = 0.f;
        float q0 = 0.f, q1 = 0.f, q2 = 0.f, q3 = 0.f;
#pragma unroll
        for (int g = 0; g < 2; ++g) {
            float4 st[8];
#pragma unroll
            for (int i = 0; i < 8; ++i) {
                int e = t + (g * 8 + i) * 256;
                int c = e >> 5;
                st[i] = *(const float4*)(Xb + (size_t)c * plane + p0 + px4 * 4);
            }
#pragma unroll
            for (int i = 0; i < 8; ++i) {
                int e = t + (g * 8 + i) * 256;
                int c = e >> 5;
                float a0 = st[i].x, a1 = st[i].y, a2 = st[i].z, a3 = st[i].w;
                if constexpr (PRO == 1) {
                    a0 = a0 > 0.f ? a0 : 0.1f * a0;
                    a1 = a1 > 0.f ? a1 : 0.1f * a1;
                    a2 = a2 > 0.f ? a2 : 0.1f * a2;
                    a3 = a3 > 0.f ? a3 : 0.1f * a3;
                }
                if constexpr (LNF) {
                    s0 += a0; q0 += a0 * a0;
                    s1 += a1; q1 += a1 * a1;
                    s2v += a2; q2 += a2 * a2;
                    s3 += a3; q3 += a3 * a3;
                }
                *(unsigned short*)swz_ptr(xs, px4 * 4 + 0, 2 * c) = f2bf(a0);
                *(unsigned short*)swz_ptr(xs, px4 * 4 + 1, 2 * c) = f2bf(a1);
                *(unsigned short*)swz_ptr(xs, px4 * 4 + 2, 2 * c) = f2bf(a2);
                *(unsigned short*)swz_ptr(xs, px4 * 4 + 3, 2 * c) = f2bf(a3);
            }
        }
        if constexpr (LNF) {
            lnred[t >> 5][px4 * 4 + 0] = make_float2(s0, q0);
            lnred[t >> 5][px4 * 4 + 1] = make_float2(s1, q1);
            lnred[t >> 5][px4 * 4 + 2] = make_float2(s2v, q2);
            lnred[t >> 5][px4 * 4 + 3] = make_float2(s3, q3);
        }
    } else {
        const unsigned short* Xb = (const unsigned short*)Xv + (size_t)bz * sx;
        ush8 st[8];
#pragma unroll
        for (int i = 0; i < 8; ++i) {
            int e = t + i * 256;
            int c = e >> 4, px8 = e & 15;
            st[i] = *(const ush8*)(Xb + (size_t)c * plane + p0 + px8 * 8);
        }
#pragma unroll
        for (int i = 0; i < 8; ++i) {
            int e = t + i * 256;
            int c = e >> 4, px8 = e & 15;
#pragma unroll
            for (int j = 0; j < 8; ++j) {
                unsigned short us = (unsigned short)st[i][j];
                if constexpr (PRO == 1) {
                    float f = bf2f(us);
                    f = f > 0.f ? f : 0.1f * f;
                    us = f2bf(f);
                }
                *(unsigned short*)swz_ptr(xs, px8 * 8 + j, 2 * c) = us;
            }
        }
    }
    __syncthreads();
    if constexpr (LNF) {
        if (t < 128) {
            float ss = 0.f, qq = 0.f;
#pragma unroll
            for (int j = 0; j < 8; ++j) { float2 a = lnred[j][t]; ss += a.x; qq += a.y; }
            float m = ss * (1.f / 128.f);
            float inv = rsqrtf(qq * (1.f / 128.f) - m * m + 1e-5f);
            lnmi[t] = make_float2(m, inv);
        }
        __syncthreads();
    }

    f32x4 acc[4][4];
#pragma unroll
    for (int mi = 0; mi < 4; ++mi)
#pragma unroll
        for (int ni = 0; ni < 4; ++ni) acc[mi][ni] = (f32x4){0.f, 0.f, 0.f, 0.f};

#pragma unroll
    for (int kk = 0; kk < 128; kk += 32) {
        short8v bfr[4];
#pragma unroll
        for (int ni = 0; ni < 4; ++ni)
            bfr[ni] = *(const short8v*)swz_ptr(xs, wc * 64 + ni * 16 + lc, 2 * (kk + lr * 8));
#pragma unroll
        for (int mi = 0; mi < 4; ++mi) {
            int row = wr * 64 + mi * 16 + lc;
            short8v afr = *(const short8v*)(Wb + (size_t)row * wstride + kk + lr * 8);
#pragma unroll
            for (int ni = 0; ni < 4; ++ni)
                acc[mi][ni] = __builtin_amdgcn_mfma_f32_16x16x32_bf16(afr, bfr[ni], acc[mi][ni], 0, 0, 0);
        }
    }

    float2 mrow[4];
    if constexpr (LNF) {
#pragma unroll
        for (int ni = 0; ni < 4; ++ni) mrow[ni] = lnmi[wc * 64 + ni * 16 + lc];
    }

#pragma unroll
    for (int mi = 0; mi < 4; ++mi) {
        int ob = wr * 64 + mi * 16 + lr * 4;
#pragma unroll
        for (int r = 0; r < 4; ++r) {
            int o = ob + r;
            float bv = 0.f, wso = 0.f;
            if constexpr (LNF) { bv = bsum[o]; wso = wsum[o]; }
            else { if (bias) bv = bias[o]; if (flags & 1) bv += 1e-8f; }
#pragma unroll
            for (int ni = 0; ni < 4; ++ni) {
                int px = wc * 64 + ni * 16 + lc;
                float v;
                if constexpr (LNF) {
                    float m = mrow[ni].x, inv = mrow[ni].y;
                    v = acc[mi][ni][r] * inv + bv - m * inv * wso;
                } else {
                    v = acc[mi][ni][r] + bv;
                }
                if (res) v += res[(size_t)bz * sres + (size_t)o * plane + p0 + px];
                if constexpr (OUTBF == 0) {
                    float* Y = (float*)Yv;
                    Y[(size_t)bz * sy + (size_t)o * plane + p0 + px] = v;
                } else {
                    unsigned short* Y = (unsigned short*)Yv;
                    Y[(size_t)bz * sy + (size_t)o * plane + p0 + px] = f2bf(v);
                }
            }
        }
    }
}

// ---------------------------------------------------------------- fused dual conv1x1: qkv (folded-LN) + pre (bias+1e-8)
__global__ __launch_bounds__(256, 3) void mconv_dual(
    const float* __restrict__ X, size_t sx,
    const unsigned short* __restrict__ Wq,
    const float* __restrict__ q_ws, const float* __restrict__ q_bb,
    const unsigned short* __restrict__ Wp,
    const float* __restrict__ pre_b,
    unsigned short* __restrict__ Y1, unsigned short* __restrict__ Y2, size_t sy)
{
    __shared__ unsigned short xs[128][136];
    __shared__ float2 lnred[8][128];
    __shared__ float2 lnmi[128];
    const int t = threadIdx.x;
    const int bz = blockIdx.z;
    const int p0 = blockIdx.x * 128;
    const int lane = t & 63;
    const int wr = t >> 7, wc = (t >> 6) & 1;
    const int lr = lane >> 4, lc = lane & 15;

    const float* Xb = X + (size_t)bz * sx;
    const int px4 = t & 31;
    float s0 = 0.f, s1 = 0.f, s2v = 0.f, s3 = 0.f;
    float q0 = 0.f, q1 = 0.f, q2 = 0.f, q3 = 0.f;
#pragma unroll
    for (int g = 0; g < 2; ++g) {
        float4 st[8];
#pragma unroll
        for (int i = 0; i < 8; ++i) {
            int e = t + (g * 8 + i) * 256;
            int c = e >> 5;
            st[i] = *(const float4*)(Xb + (size_t)c * HW_ + p0 + px4 * 4);
        }
#pragma unroll
        for (int i = 0; i < 8; ++i) {
            int e = t + (g * 8 + i) * 256;
            int c = e >> 5;
            float a0 = st[i].x, a1 = st[i].y, a2 = st[i].z, a3 = st[i].w;
            s0 += a0; q0 += a0 * a0;
            s1 += a1; q1 += a1 * a1;
            s2v += a2; q2 += a2 * a2;
            s3 += a3; q3 += a3 * a3;
            *(unsigned short*)swz_ptr(xs, px4 * 4 + 0, 2 * c) = f2bf(a0);
            *(unsigned short*)swz_ptr(xs, px4 * 4 + 1, 2 * c) = f2bf(a1);
            *(unsigned short*)swz_ptr(xs, px4 * 4 + 2, 2 * c) = f2bf(a2);
            *(unsigned short*)swz_ptr(xs, px4 * 4 + 3, 2 * c) = f2bf(a3);
        }
    }
    lnred[t >> 5][px4 * 4 + 0] = make_float2(s0, q0);
    lnred[t >> 5][px4 * 4 + 1] = make_float2(s1, q1);
    lnred[t >> 5][px4 * 4 + 2] = make_float2(s2v, q2);
    lnred[t >> 5][px4 * 4 + 3] = make_float2(s3, q3);
    __syncthreads();
    if (t < 128) {
        float ss = 0.f, qq = 0.f;
#pragma unroll
        for (int j = 0; j < 8; ++j) { float2 a = lnred[j][t]; ss += a.x; qq += a.y; }
        float m = ss * (1.f / 128.f);
        float inv = rsqrtf(qq * (1.f / 128.f) - m * m + 1e-5f);
        lnmi[t] = make_float2(m, inv);
    }
    __syncthreads();

    float2 mrow[4];
#pragma unroll
    for (int ni = 0; ni < 4; ++ni) mrow[ni] = lnmi[wc * 64 + ni * 16 + lc];

    {
        f32x4 acc[4][4];
#pragma unroll
        for (int mi = 0; mi < 4; ++mi)
#pragma unroll
            for (int ni = 0; ni < 4; ++ni) acc[mi][ni] = (f32x4){0.f, 0.f, 0.f, 0.f};
#pragma unroll
        for (int kk = 0; kk < 128; kk += 32) {
            short8v bfr[4];
#pragma unroll
            for (int ni = 0; ni < 4; ++ni)
                bfr[ni] = *(const short8v*)swz_ptr(xs, wc * 64 + ni * 16 + lc, 2 * (kk + lr * 8));
#pragma unroll
            for (int mi = 0; mi < 4; ++mi) {
                int row = wr * 64 + mi * 16 + lc;
                short8v afr = *(const short8v*)(Wq + (size_t)row * 128 + kk + lr * 8);
#pragma unroll
                for (int ni = 0; ni < 4; ++ni)
                    acc[mi][ni] = __builtin_amdgcn_mfma_f32_16x16x32_bf16(afr, bfr[ni], acc[mi][ni], 0, 0, 0);
            }
        }
#pragma unroll
        for (int mi = 0; mi < 4; ++mi)
#pragma unroll
            for (int r = 0; r < 4; ++r) {
                int o = wr * 64 + mi * 16 + lr * 4 + r;
                float bv = q_bb[o], wso = q_ws[o];
#pragma unroll
                for (int ni = 0; ni < 4; ++ni) {
                    int px = wc * 64 + ni * 16 + lc;
                    float m = mrow[ni].x, inv = mrow[ni].y;
                    float v = acc[mi][ni][r] * inv + bv - m * inv * wso;
                    Y1[(size_t)bz * sy + (size_t)o * HW_ + p0 + px] = f2bf(v);
                }
            }
    }

    {
        f32x4 acc[4][4];
#pragma unroll
        for (int mi = 0; mi < 4; ++mi)
#pragma unroll
            for (int ni = 0; ni < 4; ++ni) acc[mi][ni] = (f32x4){0.f, 0.f, 0.f, 0.f};
#pragma unroll
        for (int kk = 0; kk < 128; kk += 32) {
            short8v bfr[4];
#pragma unroll
            for (int ni = 0; ni < 4; ++ni)
                bfr[ni] = *(const short8v*)swz_ptr(xs, wc * 64 + ni * 16 + lc, 2 * (kk + lr * 8));
#pragma unroll
            for (int mi = 0; mi < 4; ++mi) {
                int row = wr * 64 + mi * 16 + lc;
                short8v afr = *(const short8v*)(Wp + (size_t)row * 128 + kk + lr * 8);
#pragma unroll
                for (int ni = 0; ni < 4; ++ni)
                    acc[mi][ni] = __builtin_amdgcn_mfma_f32_16x16x32_bf16(afr, bfr[ni], acc[mi][ni], 0, 0, 0);
            }
        }
#pragma unroll
        for (int mi = 0; mi < 4; ++mi)
#pragma unroll
            for (int r = 0; r < 4; ++r) {
                int o = wr * 64 + mi * 16 + lr * 4 + r;
                float bv = pre_b[o] + 1e-8f;
#pragma unroll
                for (int ni = 0; ni < 4; ++ni) {
                    int px = wc * 64 + ni * 16 + lc;
                    Y2[(size_t)bz * sy + (size_t)o * HW_ + p0 + px] = f2bf(acc[mi][ni][r] + bv);
                }
            }
    }
}

// ---------------------------------------------------------------- fused amp1+pha1+amp2+pha2 spectral block
__global__ __launch_bounds__(256, 2) void apconv2(
    const unsigned* __restrict__ T1, const unsigned* __restrict__ T2, size_t sT,
    const unsigned short* __restrict__ Wa1, const unsigned short* __restrict__ Wp1,
    const unsigned short* __restrict__ Wa2, const unsigned short* __restrict__ Wp2,
    const float* __restrict__ ba1, const float* __restrict__ bp1,
    const float* __restrict__ ba2, const float* __restrict__ bp2,
    unsigned short* __restrict__ AMP, unsigned short* __restrict__ PHA, size_t sO)
{
    __shared__ __align__(16) unsigned short buf[2][128][72];
    const int t = threadIdx.x;
    const int bz = blockIdx.z;
    const int p0 = blockIdx.x * 128;
    const int lane = t & 63;
    const int wr = t >> 7, wc = (t >> 6) & 1;
    const int lr = lane >> 4, lc = lane & 15;
    const int px2 = t & 63;

    typedef unsigned short (*row72)[72];
    typedef unsigned short (*row144)[144];
    row72 xa = (row72)buf[0];
    row72 xp = (row72)buf[1];
    row144 hb = (row144)&buf[0][0][0];

    f32x4 aa[4][4], ap[4][4];
#pragma unroll
    for (int mi = 0; mi < 4; ++mi)
#pragma unroll
        for (int ni = 0; ni < 4; ++ni) { aa[mi][ni] = (f32x4){0.f,0.f,0.f,0.f}; ap[mi][ni] = (f32x4){0.f,0.f,0.f,0.f}; }

    for (int ch = 0; ch < 256; ch += 64) {
        const unsigned* Ts = ((ch < 128) ? T1 : T2) + (size_t)bz * sT + (size_t)(ch & 127) * PLANEF_;
#pragma unroll
        for (int g = 0; g < 2; ++g) {
            uint2 st[8];
#pragma unroll
            for (int i = 0; i < 8; ++i) {
                int e = t + (g * 8 + i) * 256;
                int c = e >> 6;
                st[i] = *(const uint2*)(Ts + (size_t)c * PLANEF_ + p0 + px2 * 2);
            }
#pragma unroll
            for (int i = 0; i < 8; ++i) {
                int e = t + (g * 8 + i) * 256;
                int c = e >> 6;
                float2 z0 = upk(st[i].x), z1 = upk(st[i].y);
                float m0 = sqrtf(z0.x * z0.x + z0.y * z0.y);
                float m1 = sqrtf(z1.x * z1.x + z1.y * z1.y);
                float a0 = fatan2(z0.y, z0.x);
                float a1 = fatan2(z1.y, z1.x);
                *(unsigned short*)swz_ptr(xa, px2 * 2 + 0, 2 * c) = f2bf(m0);
                *(unsigned short*)swz_ptr(xa, px2 * 2 + 1, 2 * c) = f2bf(m1);
                *(unsigned short*)swz_ptr(xp, px2 * 2 + 0, 2 * c) = f2bf(a0);
                *(unsigned short*)swz_ptr(xp, px2 * 2 + 1, 2 * c) = f2bf(a1);
            }
        }
        __syncthreads();
#pragma unroll
        for (int kk = 0; kk < 64; kk += 32) {
            short8v bfa[4], bfp[4];
#pragma unroll
            for (int ni = 0; ni < 4; ++ni) {
                bfa[ni] = *(const short8v*)swz_ptr(xa, wc * 64 + ni * 16 + lc, 2 * (kk + lr * 8));
                bfp[ni] = *(const short8v*)swz_ptr(xp, wc * 64 + ni * 16 + lc, 2 * (kk + lr * 8));
            }
#pragma unroll
            for (int mi = 0; mi < 4; ++mi) {
                int row = wr * 64 + mi * 16 + lc;
                short8v afa = *(const short8v*)(Wa1 + (size_t)row * 256 + ch + kk + lr * 8);
                short8v afp = *(const short8v*)(Wp1 + (size_t)row * 256 + ch + kk + lr * 8);
#pragma unroll
                for (int ni = 0; ni < 4; ++ni) {
                    aa[mi][ni] = __builtin_amdgcn_mfma_f32_16x16x32_bf16(afa, bfa[ni], aa[mi][ni], 0, 0, 0);
                    ap[mi][ni] = __builtin_amdgcn_mfma_f32_16x16x32_bf16(afp, bfp[ni], ap[mi][ni], 0, 0, 0);
                }
            }
        }
        __syncthreads();
    }

    // ---- stage B (amp) ----
#pragma unroll
    for (int mi = 0; mi < 4; ++mi)
#pragma unroll
        for (int r = 0; r < 4; ++r) {
            int o = wr * 64 + mi * 16 + lr * 4 + r;
            float bva = ba1[o];
#pragma unroll
            for (int ni = 0; ni < 4; ++ni) {
                int px = wc * 64 + ni * 16 + lc;
                float v = aa[mi][ni][r] + bva;
                v = v > 0.f ? v : 0.1f * v;
                *(unsigned short*)swz_ptr(hb, px, 2 * o) = f2bf(v);
            }
        }
    __syncthreads();
    {
        f32x4 acc[4][4];
#pragma unroll
        for (int mi = 0; mi < 4; ++mi)
#pragma unroll
            for (int ni = 0; ni < 4; ++ni) acc[mi][ni] = (f32x4){0.f,0.f,0.f,0.f};
#pragma unroll
        for (int kk = 0; kk < 128; kk += 32) {
            short8v bfr[4];
#pragma unroll
            for (int ni = 0; ni < 4; ++ni)
                bfr[ni] = *(const short8v*)swz_ptr(hb, wc * 64 + ni * 16 + lc, 2 * (kk + lr * 8));
#pragma unroll
            for (int mi = 0; mi < 4; ++mi) {
                int row = wr * 64 + mi * 16 + lc;
                short8v afr = *(const short8v*)(Wa2 + (size_t)row * 128 + kk + lr * 8);
#pragma unroll
                for (int ni = 0; ni < 4; ++ni)
                    acc[mi][ni] = __builtin_amdgcn_mfma_f32_16x16x32_bf16(afr, bfr[ni], acc[mi][ni], 0, 0, 0);
            }
        }
#pragma unroll
        for (int mi = 0; mi < 4; ++mi)
#pragma unroll
            for (int r = 0; r < 4; ++r) {
                int o = wr * 64 + mi * 16 + lr * 4 + r;
                float bv = ba2[o];
#pragma unroll
                for (int ni = 0; ni < 4; ++ni) {
                    int px = wc * 64 + ni * 16 + lc;
                    AMP[(size_t)bz * sO + (size_t)o * PLANEF_ + p0 + px] = f2bf(acc[mi][ni][r] + bv);
                }
            }
    }
    __syncthreads();

    // ---- stage B (pha) ----
#pragma unroll
    for (int mi = 0; mi < 4; ++mi)
#pragma unroll
        for (int r = 0; r < 4; ++r) {
            int o = wr * 64 + mi * 16 + lr * 4 + r;
            float bvp = bp1[o];
#pragma unroll
            for (int ni = 0; ni < 4; ++ni) {
                int px = wc * 64 + ni * 16 + lc;
                float v = ap[mi][ni][r] + bvp;
                v = v > 0.f ? v : 0.1f * v;
                *(unsigned short*)swz_ptr(hb, px, 2 * o) = f2bf(v);
            }
        }
    __syncthreads();
    {
        f32x4 acc[4][4];
#pragma unroll
        for (int mi = 0; mi < 4; ++mi)
#pragma unroll
            for (int ni = 0; ni < 4; ++ni) acc[mi][ni] = (f32x4){0.f,0.f,0.f,0.f};
#pragma unroll
        for (int kk = 0; kk < 128; kk += 32) {
            short8v bfr[4];
#pragma unroll
            for (int ni = 0; ni < 4; ++ni)
                bfr[ni] = *(const short8v*)swz_ptr(hb, wc * 64 + ni * 16 + lc, 2 * (kk + lr * 8));
#pragma unroll
            for (int mi = 0; mi < 4; ++mi) {
                int row = wr * 64 + mi * 16 + lc;
                short8v afr = *(const short8v*)(Wp2 + (size_t)row * 128 + kk + lr * 8);
#pragma unroll
                for (int ni = 0; ni < 4; ++ni)
                    acc[mi][ni] = __builtin_amdgcn_mfma_f32_16x16x32_bf16(afr, bfr[ni], acc[mi][ni], 0, 0, 0);
            }
        }
#pragma unroll
        for (int mi = 0; mi < 4; ++mi)
#pragma unroll
            for (int r = 0; r < 4; ++r) {
                int o = wr * 64 + mi * 16 + lr * 4 + r;
                float bv = bp2[o];
#pragma unroll
                for (int ni = 0; ni < 4; ++ni) {
                    int px = wc * 64 + ni * 16 + lc;
                    PHA[(size_t)bz * sO + (size_t)o * PLANEF_ + p0 + px] = f2bf(acc[mi][ni][r] + bv);
                }
            }
    }
}

// ---------------------------------------------------------------- fused MFMA FFN (x bf16, fre bf16; residual from LDS; direct f32 stores)
__global__ __launch_bounds__(256, 3) void ffn_mfma8(
    const unsigned short* __restrict__ x, const unsigned short* __restrict__ fre,
    const unsigned short* __restrict__ pinb,
    const unsigned short* __restrict__ pout2,
    const float4* __restrict__ pinC,
    float* __restrict__ out)
{
    __shared__ unsigned short xs[64][264];
    __shared__ unsigned short hs[64][136];
    __shared__ float2 muinv[64];
    float2* sred = (float2*)&hs[0][0];
    const int b = blockIdx.y;
    const size_t p0 = (size_t)blockIdx.x * 64;
    const int t = threadIdx.x;
    const int wave = t >> 6, lane = t & 63;
    const int lr = lane >> 4, lc = lane & 15;
    const int px4 = t & 15;

    float s0 = 0.f, s1 = 0.f, s2v = 0.f, s3 = 0.f;
    float q0 = 0.f, q1 = 0.f, q2 = 0.f, q3 = 0.f;
    {
        ush4 stx[8], stf[8];
#pragma unroll
        for (int i = 0; i < 8; ++i) {
            int e = t + i * 256;
            int c = e >> 4;
            stx[i] = *(const ush4*)(x + (size_t)b * 8388608 + (size_t)c * HW_ + p0 + px4 * 4);
        }
#pragma unroll
        for (int i = 0; i < 8; ++i) {
            int e = t + i * 256;
            int c = e >> 4;
            stf[i] = *(const ush4*)(fre + (size_t)b * 8388608 + (size_t)c * HW_ + p0 + px4 * 4);
        }
#pragma unroll
        for (int i = 0; i < 8; ++i) {
            int e = t + i * 256;
            int c = e >> 4;
#pragma unroll
            for (int j = 0; j < 4; ++j) {
                unsigned short us = (unsigned short)stx[i][j];
                float a = bf2f(us);
                s0 += (j == 0) ? a : 0.f; s1 += (j == 1) ? a : 0.f;
                s2v += (j == 2) ? a : 0.f; s3 += (j == 3) ? a : 0.f;
                q0 += (j == 0) ? a * a : 0.f; q1 += (j == 1) ? a * a : 0.f;
                q2 += (j == 2) ? a * a : 0.f; q3 += (j == 3) ? a * a : 0.f;
                *(unsigned short*)swz_ptr(xs, px4 * 4 + j, 2 * c) = us;
            }
        }
#pragma unroll
        for (int i = 0; i < 8; ++i) {
            int e = t + i * 256;
            int c = e >> 4;
#pragma unroll
            for (int j = 0; j < 4; ++j) {
                unsigned short us = (unsigned short)stf[i][j];
                float a = bf2f(us);
                s0 += (j == 0) ? a : 0.f; s1 += (j == 1) ? a : 0.f;
                s2v += (j == 2) ? a : 0.f; s3 += (j == 3) ? a : 0.f;
                q0 += (j == 0) ? a * a : 0.f; q1 += (j == 1) ? a * a : 0.f;
                q2 += (j == 2) ? a * a : 0.f; q3 += (j == 3) ? a * a : 0.f;
                *(unsigned short*)swz_ptr(xs, px4 * 4 + j, 2 * (128 + c)) = us;
            }
        }
    }
    sred[(t >> 4) * 64 + px4 * 4 + 0] = make_float2(s0, q0);
    sred[(t >> 4) * 64 + px4 * 4 + 1] = make_float2(s1, q1);
    sred[(t >> 4) * 64 + px4 * 4 + 2] = make_float2(s2v, q2);
    sred[(t >> 4) * 64 + px4 * 4 + 3] = make_float2(s3, q3);
    __syncthreads();
    if (t < 64) {
        float ss = 0.f, qq = 0.f;
#pragma unroll
        for (int j = 0; j < 16; ++j) { float2 a = sred[j * 64 + t]; ss += a.x; qq += a.y; }
        float m = ss * (1.f / 256.f);
        float inv = rsqrtf(qq * (1.f / 256.f) - m * m + 1e-5f);
        muinv[t] = make_float2(m, inv);
    }
    __syncthreads();

    float2 mrow[4];
#pragma unroll
    for (int ni = 0; ni < 4; ++ni) mrow[ni] = muinv[ni * 16 + lc];

    f32x4 oc[2][4];
#pragma unroll
    for (int mi = 0; mi < 2; ++mi)
#pragma unroll
        for (int ni = 0; ni < 4; ++ni) oc[mi][ni] = (f32x4){0.f, 0.f, 0.f, 0.f};

#pragma unroll
    for (int half = 0; half < 2; ++half) {
        f32x4 a1[2][4], a2[2][4];
#pragma unroll
        for (int mi = 0; mi < 2; ++mi)
#pragma unroll
            for (int ni = 0; ni < 4; ++ni) { a1[mi][ni] = (f32x4){0.f,0.f,0.f,0.f}; a2[mi][ni] = (f32x4){0.f,0.f,0.f,0.f}; }

#pragma unroll
        for (int k0 = 0; k0 < 256; k0 += 32) {
            short8v bfr[4];
#pragma unroll
            for (int ni = 0; ni < 4; ++ni)
                bfr[ni] = *(const short8v*)swz_ptr(xs, ni * 16 + lc, 2 * (k0 + lr * 8));
#pragma unroll
            for (int mi = 0; mi < 2; ++mi) {
                int hrow = wave * 64 + half * 32 + mi * 16 + lc;
                short8v af1 = *(const short8v*)(pinb + (size_t)hrow * 256 + k0 + lr * 8);
                short8v af2 = *(const short8v*)(pinb + (size_t)(hrow + 256) * 256 + k0 + lr * 8);
#pragma unroll
                for (int ni = 0; ni < 4; ++ni) {
                    a1[mi][ni] = __builtin_amdgcn_mfma_f32_16x16x32_bf16(af1, bfr[ni], a1[mi][ni], 0, 0, 0);
                    a2[mi][ni] = __builtin_amdgcn_mfma_f32_16x16x32_bf16(af2, bfr[ni], a2[mi][ni], 0, 0, 0);
                }
            }
        }
        __syncthreads();
#pragma unroll
        for (int mi = 0; mi < 2; ++mi)
#pragma unroll
            for (int r = 0; r < 4; ++r) {
                int ho = wave * 64 + half * 32 + mi * 16 + lr * 4 + r;
                float4 bwc = pinC[ho];
                int kp = wave * 32 + mi * 16 + lr * 4 + r;
#pragma unroll
                for (int ni = 0; ni < 4; ++ni) {
                    float m = mrow[ni].x, inv = mrow[ni].y;
                    float v1 = a1[mi][ni][r] * inv + bwc.x - m * inv * bwc.y;
                    float v2 = a2[mi][ni][r] * inv + bwc.z - m * inv * bwc.w;
                    hs[ni * 16 + lc][kp] = f2bf(geluf(v1) * v2);
                }
            }
        __syncthreads();
#pragma unroll
        for (int k0 = 0; k0 < 128; k0 += 32) {
            short8v bfr2[4];
#pragma unroll
            for (int ni = 0; ni < 4; ++ni)
                bfr2[ni] = *(const short8v*)&hs[ni * 16 + lc][k0 + lr * 8];
#pragma unroll
            for (int mi = 0; mi < 2; ++mi) {
                int orow = wave * 32 + mi * 16 + lc;
                short8v af = *(const short8v*)(pout2 + half * 16384 + orow * 128 + k0 + lr * 8);
#pragma unroll
                for (int ni = 0; ni < 4; ++ni)
                    oc[mi][ni] = __builtin_amdgcn_mfma_f32_16x16x32_bf16(af, bfr2[ni], oc[mi][ni], 0, 0, 0);
            }
        }
    }

#pragma unroll
    for (int mi = 0; mi < 2; ++mi)
#pragma unroll
        for (int r = 0; r < 4; ++r) {
            int o = wave * 32 + mi * 16 + lr * 4 + r;
#pragma unroll
            for (int ni = 0; ni < 4; ++ni) {
                int px = ni * 16 + lc;
                float rx = bf2f(*(const unsigned short*)swz_ptr(xs, px, 2 * o));
                size_t yi = ((size_t)b * 128 + o) * HW_ + p0 + px;
                out[yi] = oc[mi][ni][r] + rx;
            }
        }
}

// ---------------------------------------------------------------- depthwise 3x3 cd-conv (bf16), 8 px/thread, fused ssq
__global__ __launch_bounds__(256) void dwconv2(const unsigned short* __restrict__ X, size_t sx,
                                               const float* __restrict__ w9,
                                               const float* __restrict__ ksum,
                                               unsigned short* __restrict__ Y, size_t sy,
                                               float* __restrict__ ssq)
{
    int bz = blockIdx.z;
    int c = blockIdx.y;
    int p8 = blockIdx.x * 256 + threadIdx.x;
    int p0 = p8 * 8;
    int i = p0 >> 8, j0 = p0 & 255;
    const unsigned short* xp = X + (size_t)bz * sx + (size_t)c * HW_;
    const float* wc = w9 + c * 9;
    float a[8] = {0.f,0.f,0.f,0.f,0.f,0.f,0.f,0.f};
    float ctr[8];
#pragma unroll
    for (int di = -1; di <= 1; ++di) {
        int ii = i + di;
        if (ii < 0 || ii > 255) continue;
        const unsigned short* row = xp + ii * 256;
        ush8 m8 = *(const ush8*)(row + j0);
        float lft = (j0 > 0) ? bf2f(row[j0 - 1]) : 0.f;
        float rgt = (j0 < 248) ? bf2f(row[j0 + 8]) : 0.f;
        float v[10];
        v[0] = lft;
#pragma unroll
        for (int k = 0; k < 8; ++k) v[k + 1] = bf2f((unsigned short)m8[k]);
        v[9] = rgt;
        if (di == 0) {
#pragma unroll
            for (int k = 0; k < 8; ++k) ctr[k] = v[k + 1];
        }
        float w0 = wc[(di + 1) * 3], w1 = wc[(di + 1) * 3 + 1], w2 = wc[(di + 1) * 3 + 2];
#pragma unroll
        for (int k = 0; k < 8; ++k) a[k] += w0 * v[k] + w1 * v[k + 1] + w2 * v[k + 2];
    }
    float km = 0.7f * ksum[c];
    ush8 ov;
    float q = 0.f;
#pragma unroll
    for (int k = 0; k < 8; ++k) {
        float o = a[k] - km * ctr[k];
        ov[k] = f2bf(o);
        q += o * o;
    }
    *(ush8*)(Y + (size_t)bz * sy + (size_t)c * HW_ + p0) = ov;

    __shared__ float red[256];
    red[threadIdx.x] = q; __syncthreads();
    for (int st = 128; st; st >>= 1) {
        if (threadIdx.x < st) red[threadIdx.x] += red[threadIdx.x + st];
        __syncthreads();
    }
    if (!threadIdx.x) atomicAdd(&ssq[bz * C_ + c], red[0]);
}

// ---------------------------------------------------------------- attention helpers (bf16 q/k/v)
__global__ __launch_bounds__(256) void gram_kernel(const unsigned short* __restrict__ Q, size_t sq,
                                                   const unsigned short* __restrict__ K, size_t sk,
                                                   float* __restrict__ part)
{
    int sl = blockIdx.x, h = blockIdx.y, bz = blockIdx.z;
    const unsigned short* qb = Q + (size_t)bz * sq + (size_t)(h * 16) * HW_;
    const unsigned short* kb = K + (size_t)bz * sk + (size_t)(h * 16) * HW_;
    __shared__ __align__(16) float qs[16][264];
    __shared__ __align__(16) float ks[16][264];
    int c = threadIdx.x >> 4, d = threadIdx.x & 15;
    int t = threadIdx.x;
    float acc = 0.f;
    for (int n0 = sl * 2048; n0 < (sl + 1) * 2048; n0 += 256) {
        ush4 qv[4], kv[4];
#pragma unroll
        for (int ii = 0; ii < 4; ++ii) {
            int e = t + ii * 256;
            int cc = e >> 6, n4 = e & 63;
            qv[ii] = *(const ush4*)(qb + (size_t)cc * HW_ + n0 + n4 * 4);
            kv[ii] = *(const ush4*)(kb + (size_t)cc * HW_ + n0 + n4 * 4);
        }
#pragma unroll
        for (int ii = 0; ii < 4; ++ii) {
            int e = t + ii * 256;
            int cc = e >> 6, n4 = e & 63;
#pragma unroll
            for (int j = 0; j < 4; ++j) {
                qs[cc][n4 * 4 + j] = bf2f((unsigned short)qv[ii][j]);
                ks[cc][n4 * 4 + j] = bf2f((unsigned short)kv[ii][j]);
            }
        }
        __syncthreads();
#pragma unroll 16
        for (int nn = 0; nn < 256; nn += 4) {
            float4 a4 = *(const float4*)&qs[c][nn];
            float4 b4 = *(const float4*)&ks[d][nn];
            acc += a4.x * b4.x + a4.y * b4.y + a4.z * b4.z + a4.w * b4.w;
        }
        __syncthreads();
    }
    part[((size_t)(bz * 8 + h) * 32 + sl) * 256 + threadIdx.x] = acc;
}

__global__ __launch_bounds__(256) void softmax_kernel(const float* __restrict__ part,
                                                      const float* __restrict__ nqsq,
                                                      const float* __restrict__ nksq,
                                                      const float* __restrict__ temp,
                                                      float* __restrict__ attn)
{
    int h = blockIdx.x, bz = blockIdx.y;
    int t = threadIdx.x;
    int c = t >> 4, d = t & 15;
    float g = 0.f;
    for (int sl = 0; sl < 32; ++sl) g += part[((size_t)(bz * 8 + h) * 32 + sl) * 256 + t];
    float nqv = fmaxf(sqrtf(nqsq[bz * C_ + h * 16 + c]), 1e-12f);
    float nkv = fmaxf(sqrtf(nksq[bz * C_ + h * 16 + d]), 1e-12f);
    g *= temp[h] / (nqv * nkv);
    float m = g;
#pragma unroll
    for (int off = 8; off; off >>= 1) m = fmaxf(m, __shfl_xor(m, off, 16));
    float e = __expf(g - m);
    float ssum = e;
#pragma unroll
    for (int off = 8; off; off >>= 1) ssum += __shfl_xor(ssum, off, 16);
    attn[(bz * 8 + h) * 256 + t] = e / ssum;
}

__global__ __launch_bounds__(256) void av_kernel(const float* __restrict__ attn,
                                                 const unsigned short* __restrict__ V, size_t sv,
                                                 unsigned short* __restrict__ Y, size_t sy)
{
    __shared__ __align__(16) float kv[16][260];
    __shared__ __align__(16) float at[16][16];
    int tile = blockIdx.x, h = blockIdx.y, bz = blockIdx.z;
    int n0 = tile * 256, t = threadIdx.x;
    const unsigned short* vb = V + (size_t)bz * sv + (size_t)(h * 16) * HW_;
    at[t >> 4][t & 15] = attn[(size_t)(bz * 8 + h) * 256 + (t & 15) * 16 + (t >> 4)];
#pragma unroll
    for (int i = 0; i < 4; ++i) {
        int e = t + i * 256;
        int d = e >> 6, nn4 = e & 63;
        ush4 v4 = *(const ush4*)(vb + (size_t)d * HW_ + n0 + nn4 * 4);
#pragma unroll
        for (int j = 0; j < 4; ++j) kv[d][nn4 * 4 + j] = bf2f((unsigned short)v4[j]);
    }
    __syncthreads();
    float acc[16];
#pragma unroll
    for (int cc = 0; cc < 16; ++cc) acc[cc] = 0.f;
#pragma unroll
    for (int d = 0; d < 16; ++d) {
        float kvv = kv[d][t];
        float4 a0 = *(const float4*)&at[d][0];
        float4 a1 = *(const float4*)&at[d][4];
        float4 a2 = *(const float4*)&at[d][8];
        float4 a3 = *(const float4*)&at[d][12];
        acc[0]  += a0.x * kvv; acc[1]  += a0.y * kvv; acc[2]  += a0.z * kvv; acc[3]  += a0.w * kvv;
        acc[4]  += a1.x * kvv; acc[5]  += a1.y * kvv; acc[6]  += a1.z * kvv; acc[7]  += a1.w * kvv;
        acc[8]  += a2.x * kvv; acc[9]  += a2.y * kvv; acc[10] += a2.z * kvv; acc[11] += a2.w * kvv;
        acc[12] += a3.x * kvv; acc[13] += a3.y * kvv; acc[14] += a3.z * kvv; acc[15] += a3.w * kvv;
    }
    unsigned short* yb = Y + (size_t)bz * sy + (size_t)(h * 16) * HW_ + n0 + t;
#pragma unroll
    for (int cc = 0; cc < 16; ++cc) yb[(size_t)cc * HW_] = f2bf(acc[cc]);
}

// ---------------------------------------------------------------- 256-pt radix-2 DIT FFT, 2 rows per 32-lane group
__device__ __forceinline__ void fft_stages2(float2* rowA, float2* rowB, const float2* tw, int lane)
{
#pragma unroll
    for (int s = 1; s <= 8; ++s) {
        const int half = 1 << (s - 1);
#pragma unroll
        for (int r = 0; r < 4; ++r) {
            int jb = lane + r * 32;
            int j = jb & (half - 1);
            int g = jb >> (s - 1);
            int i1 = (g << s) + j;
            float2 w = tw[j << (8 - s)];
            float2 u = rowA[i1];
            float2 q = rowA[i1 + half];
            float2 v = make_float2(q.x * w.x - q.y * w.y, q.x * w.y + q.y * w.x);
            rowA[i1]        = make_float2(u.x + v.x, u.y + v.y);
            rowA[i1 + half] = make_float2(u.x - v.x, u.y - v.y);
            float2 u2 = rowB[i1];
            float2 q2 = rowB[i1 + half];
            float2 v2 = make_float2(q2.x * w.x - q2.y * w.y, q2.x * w.y + q2.y * w.x);
            rowB[i1]        = make_float2(u2.x + v2.x, u2.y + v2.y);
            rowB[i1 + half] = make_float2(u2.x - v2.x, u2.y - v2.y);
        }
        __builtin_amdgcn_wave_barrier();
    }
    __syncthreads();
}

#define PI2_ 6.28318530717958647692f

// bf16 real rows -> transposed packed-bf16 spectrum T[c][k][h]; 16 rows/block
__global__ __launch_bounds__(256) void rfft_rowsT(const unsigned short* __restrict__ X, size_t sx,
                                                  unsigned* __restrict__ T, size_t st)
{
    __shared__ float2 sd[16][256];
    __shared__ float2 tw[128];
    int t = threadIdx.x;
    int bz = blockIdx.y;
    if (t < 128) { float sn, cs; __sincosf(-PI2_ * (float)t * (1.f / 256.f), &sn, &cs); tw[t] = make_float2(cs, sn); }
    size_t r0 = (size_t)blockIdx.x * 16;
    int c = (int)(r0 >> 8), h0 = (int)(r0 & 255);
    const unsigned short* Xb = X + (size_t)bz * sx;
    ush4 v4[4];
#pragma unroll
    for (int ii = 0; ii < 4; ++ii) {
        int e = t + ii * 256;
        int j = e >> 6, i4 = e & 63;
        v4[ii] = *(const ush4*)(Xb + (r0 + j) * 256 + i4 * 4);
    }
#pragma unroll
    for (int ii = 0; ii < 4; ++ii) {
        int e = t + ii * 256;
        int j = e >> 6, i4 = e & 63;
#pragma unroll
        for (int k2 = 0; k2 < 4; ++k2)
            sd[j][__brev((unsigned)(i4 * 4 + k2)) >> 24] = make_float2(bf2f((unsigned short)v4[ii][k2]), 0.f);
    }
    __syncthreads();
    fft_stages2(sd[t >> 5], sd[(t >> 5) + 8], tw, t & 31);
    unsigned* base = T + (size_t)bz * st + (size_t)c * PLANEF_;
    for (int e = t; e < 129 * 16; e += 256) {
        int j = e & 15, k = e >> 4;
        base[(size_t)k * 256 + h0 + j] = pack2bf(sd[j][k]);
    }
}

// forward complex FFT along h; 16 k-rows/block; uint4 I/O
__global__ __launch_bounds__(256) void cfftT_fwd(unsigned* __restrict__ T, size_t st)
{
    __shared__ float2 sd[16][256];
    __shared__ float2 tw[128];
    int t = threadIdx.x;
    int bz = blockIdx.z;
    if (t < 128) { float sn, cs; __sincosf(-PI2_ * (float)t * (1.f / 256.f), &sn, &cs); tw[t] = make_float2(cs, sn); }
    int k0 = blockIdx.x * 16;
    int c = blockIdx.y;
    unsigned* base = T + (size_t)bz * st + (size_t)c * PLANEF_;
    uint4v v4[4];
#pragma unroll
    for (int ii = 0; ii < 4; ++ii) {
        int e = t + ii * 256;
        int j = e >> 6, i4 = e & 63;
        int k = k0 + j;
        if (k < KF_) v4[ii] = *(const uint4v*)(base + (size_t)k * 256 + i4 * 4);
        else v4[ii] = (uint4v){0u, 0u, 0u, 0u};
    }
#pragma unroll
    for (int ii = 0; ii < 4; ++ii) {
        int e = t + ii * 256;
        int j = e >> 6, i4 = e & 63;
#pragma unroll
        for (int q = 0; q < 4; ++q)
            sd[j][__brev((unsigned)(i4 * 4 + q)) >> 24] = upk(v4[ii][q]);
    }
    __syncthreads();
    fft_stages2(sd[t >> 5], sd[(t >> 5) + 8], tw, t & 31);
#pragma unroll
    for (int ii = 0; ii < 4; ++ii) {
        int e = t + ii * 256;
        int j = e >> 6, i4 = e & 63;
        int k = k0 + j;
        if (k < KF_) {
            uint4v o;
#pragma unroll
            for (int q = 0; q < 4; ++q) o[q] = pack2bf(sd[j][i4 * 4 + q]);
            *(uint4v*)(base + (size_t)k * 256 + i4 * 4) = o;
        }
    }
}

// combine(amp,pha bf16) + inverse h-FFT; 16 k-rows/block
__global__ __launch_bounds__(256) void cifft_combine(const unsigned short* __restrict__ amp, size_t sa,
                                                     const unsigned short* __restrict__ pha, size_t sp,
                                                     unsigned* __restrict__ S, size_t ss)
{
    __shared__ float2 sd[16][256];
    __shared__ float2 tw[128];
    int t = threadIdx.x;
    int bz = blockIdx.z;
    if (t < 128) { float sn, cs; __sincosf(PI2_ * (float)t * (1.f / 256.f), &sn, &cs); tw[t] = make_float2(cs, sn); }
    int k0 = blockIdx.x * 16;
    int c = blockIdx.y;
    const unsigned short* ab = amp + (size_t)bz * sa + (size_t)c * PLANEF_;
    const unsigned short* pb = pha + (size_t)bz * sp + (size_t)c * PLANEF_;
    ush4 a4[4], p4[4];
#pragma unroll
    for (int ii = 0; ii < 4; ++ii) {
        int e = t + ii * 256;
        int j = e >> 6, i4 = e & 63;
        int k = k0 + j;
        if (k < KF_) {
            a4[ii] = *(const ush4*)(ab + (size_t)k * 256 + i4 * 4);
            p4[ii] = *(const ush4*)(pb + (size_t)k * 256 + i4 * 4);
        } else {
            a4[ii] = (ush4){0,0,0,0}; p4[ii] = (ush4){0,0,0,0};
        }
    }
#pragma unroll
    for (int ii = 0; ii < 4; ++ii) {
        int e = t + ii * 256;
        int j = e >> 6, i4 = e & 63;
        int k = k0 + j;
#pragma unroll
        for (int q = 0; q < 4; ++q) {
            float2 v = make_float2(0.f, 0.f);
            if (k < KF_) {
                float a = bf2f((unsigned short)a4[ii][q]);
                float p = bf2f((unsigned short)p4[ii][q]);
                float sn, cs;
                __sincosf(p, &sn, &cs);
                v = make_float2(a * cs + 2e-8f, a * sn + 1e-8f);
            }
            sd[j][__brev((unsigned)(i4 * 4 + q)) >> 24] = v;
        }
    }
    __syncthreads();
    fft_stages2(sd[t >> 5], sd[(t >> 5) + 8], tw, t & 31);
    unsigned* base = S + (size_t)bz * ss + (size_t)c * PLANEF_;
    for (int e = t; e < 4096; e += 256) {
        int j = e & 15, h = e >> 4;
        int k = k0 + j;
        if (k < KF_) {
            float2 o = sd[j][h];
            base[(size_t)h * KF_ + k] = pack2bf(make_float2(o.x * (1.f / 256.f), o.y * (1.f / 256.f)));
        }
    }
}

// row-major packed-bf16 spectrum -> 256 real (Hermitian) -> |.| -> bf16; 16 rows/block
__global__ __launch_bounds__(256) void irfft_rows16_abs(const unsigned* __restrict__ S, size_t ss,
                                                        unsigned short* __restrict__ Y, size_t sy)
{
    __shared__ float2 sd[16][256];
    __shared__ float2 tw[128];
    int t = threadIdx.x;
    int bz = blockIdx.y;
    if (t < 128) { float sn, cs; __sincosf(PI2_ * (float)t * (1.f / 256.f), &sn, &cs); tw[t] = make_float2(cs, sn); }
    size_t r0 = (size_t)blockIdx.x * 16;
    const unsigned* Sb = S + (size_t)bz * ss;
    for (int e = t; e < 4096; e += 256) {
        int j = e >> 8, i = e & 255;
        const unsigned* row = Sb + (r0 + j) * 129;
        float2 v;
        if (i < 129) v = upk(row[i]);
        else { float2 w2 = upk(row[256 - i]); v = make_float2(w2.x, -w2.y); }
        sd[j][__brev((unsigned)i) >> 24] = v;
    }
    __syncthreads();
    fft_stages2(sd[t >> 5], sd[(t >> 5) + 8], tw, t & 31);
    unsigned short* Yb = Y + (size_t)bz * sy;
#pragma unroll
    for (int ii = 0; ii < 2; ++ii) {
        int e = t + ii * 256;
        int j = e >> 5, i8 = e & 31;
        ush8 ov;
#pragma unroll
        for (int q = 0; q < 8; ++q) ov[q] = f2bf(fabsf(sd[j][i8 * 8 + q].x * (1.f / 256.f)));
        *(ush8*)(Yb + (r0 + j) * 256 + i8 * 8) = ov;
    }
}

// ---------------------------------------------------------------- host
extern "C" void kernel_launch(void* const* d_in, const int* in_sizes, int n_in,
                              void* d_out, int out_size, void* d_ws, size_t ws_size,
                              hipStream_t stream)
{
    (void)in_sizes; (void)n_in; (void)out_size;
    const float* ms    = (const float*)d_in[0];
    const float* pan   = (const float*)d_in[1];
    const float* ln1w  = (const float*)d_in[2];
    const float* ln1b  = (const float*)d_in[3];
    const float* ln2w  = (const float*)d_in[4];
    const float* ln2b  = (const float*)d_in[5];
    const float* qkvw  = (const float*)d_in[6];
    const float* dww   = (const float*)d_in[7];
    const float* temp  = (const float*)d_in[8];
    const float* projw = (const float*)d_in[9];
    const float* pre1w = (const float*)d_in[10];
    const float* pre1b = (const float*)d_in[11];
    const float* pre2w = (const float*)d_in[12];
    const float* pre2b = (const float*)d_in[13];
    const float* amp1w = (const float*)d_in[14];
    const float* amp1b = (const float*)d_in[15];
    const float* amp2w = (const float*)d_in[16];
    const float* amp2b = (const float*)d_in[17];
    const float* pha1w = (const float*)d_in[18];
    const float* pha1b = (const float*)d_in[19];
    const float* pha2w = (const float*)d_in[20];
    const float* pha2b = (const float*)d_in[21];
    const float* postw = (const float*)d_in[22];
    const float* postb = (const float*)d_in[23];
    const float* pinw  = (const float*)d_in[24];
    const float* poutw = (const float*)d_in[25];

    const size_t SLOT  = 8454144;
    const size_t CHWu  = 8388608;
    const size_t CPFu  = 4227072;
    const size_t SPECu = 4227072;
    const size_t PARAMU = 344064;
    const size_t PARAMF = 273792;

    // F (frefuse bf16, full batch) + XB (x bf16, full batch) + NB*NSLOT slots + params
    auto need = [&](int nb, int nslot) -> size_t {
        return 2ull * (67108864ull + (size_t)nb * (size_t)nslot * SLOT + PARAMU) + 4ull * PARAMF + 64;
    };
    int NB; bool FUSED;
    if      (ws_size >= need(4, 5)) { NB = 4; FUSED = true;  }
    else if (ws_size >= need(4, 3)) { NB = 4; FUSED = false; }
    else if (ws_size >= need(2, 5)) { NB = 2; FUSED = true;  }
    else if (ws_size >= need(2, 3)) { NB = 2; FUSED = false; }
    else if (ws_size >= need(1, 5)) { NB = 1; FUSED = true;  }
    else                            { NB = 1; FUSED = false; }
    const int NSLOT = FUSED ? 5 : 3;

    unsigned short* F  = (unsigned short*)d_ws;          // frefuse bf16 (full batch)
    unsigned short* XB = F + 33554432;                   // x bf16 (full batch)
    unsigned short* U0 = XB + 33554432;
    unsigned short* U1 = U0 + (size_t)NB * SLOT;
    unsigned short* U2 = U1 + (size_t)NB * SLOT;
    unsigned short* U3 = U2 + (size_t)NB * SLOT;   // valid only if FUSED
    unsigned short* U4 = U3 + (size_t)NB * SLOT;   // valid only if FUSED
    unsigned short* parU = U0 + (size_t)NB * (size_t)NSLOT * SLOT;
    unsigned short* w_qkv   = parU;
    unsigned short* w_proj  = w_qkv  + 16384;
    unsigned short* w_pre1  = w_proj + 16384;
    unsigned short* w_pre2  = w_pre1 + 16384;
    unsigned short* w_post  = w_pre2 + 16384;
    unsigned short* w_amp1  = w_post + 16384;
    unsigned short* w_pha1  = w_amp1 + 32768;
    unsigned short* w_amp2  = w_pha1 + 32768;
    unsigned short* w_pha2  = w_amp2 + 16384;
    unsigned short* w_pin   = w_pha2 + 16384;
    unsigned short* w_pout2 = w_pin  + 131072;
    float* fpar   = (float*)(w_pout2 + 32768);
    float* ksumP  = fpar;
    float* nqsq   = ksumP + 128;
    float* nksq   = nqsq  + 512;
    float* attnP  = nksq  + 512;
    float* partP  = attnP + 8192;
    float* qkv_ws = partP + 262144;
    float* qkv_bb = qkv_ws + 128;
    float* pin_ws = qkv_bb + 128;
    float* pin_bb = pin_ws + 512;
    float* pinC   = pin_bb + 512;

    float* xout = (float*)d_out;

    auto CVT = [&](const float* src, unsigned short* dst, int n) {
        tobf16_kernel<<<(n + 255) / 256, 256, 0, stream>>>(src, dst, n);
    };
    foldln_kernel<<<128, 128, 0, stream>>>(qkvw, ln1w, ln1b, w_qkv, qkv_ws, qkv_bb, 128);
    foldln_kernel<<<512, 128, 0, stream>>>(pinw, ln2w, ln2b, w_pin, pin_ws, pin_bb, 256);
    CVT(projw, w_proj, 16384);
    CVT(pre1w, w_pre1, 16384); CVT(pre2w, w_pre2, 16384);
    CVT(postw, w_post, 16384);
    CVT(amp1w, w_amp1, 32768); CVT(pha1w, w_pha1, 32768);
    CVT(amp2w, w_amp2, 16384); CVT(pha2w, w_pha2, 16384);
    poutperm_kernel<<<128, 256, 0, stream>>>(poutw, w_pout2);
    pinc_kernel<<<1, 256, 0, stream>>>(pin_bb, pin_ws, (float4*)pinC);
    ksum_kernel<<<1, 128, 0, stream>>>(dww, ksumP);

    const size_t CHW = (size_t)C_ * HW_;
    const float* NUL = nullptr;

    for (int b0 = 0; b0 < B_; b0 += NB) {
        const float* msb  = ms  + (size_t)b0 * CHW;
        const float* panb = pan + (size_t)b0 * CHW;
        unsigned short* xbf  = XB + (size_t)b0 * CHWu;
        unsigned short* freb = F  + (size_t)b0 * CHWu;
        dim3 gz(512, 1, NB);
        dim3 gzf(258, 1, NB);

        zero2_kernel<<<(NB * 128 + 255) / 256, 256, 0, stream>>>(nqsq, nksq, NB * 128);

        if (FUSED) {
            mconv_dual<<<gz, 256, 0, stream>>>(
                msb, CHW, w_qkv, qkv_ws, qkv_bb, w_pre1, pre1b, U0, U1, SLOT);
            dwconv2<<<dim3(32, 128, NB), 256, 0, stream>>>(U0, SLOT, dww, ksumP, U2, SLOT, nqsq);
            mconv_dual<<<gz, 256, 0, stream>>>(
                panb, CHW, w_qkv, qkv_ws, qkv_bb, w_pre2, pre2b, U0, U3, SLOT);
            dwconv2<<<dim3(32, 128, NB), 256, 0, stream>>>(U0, SLOT, dww, ksumP, U4, SLOT, nksq);
            gram_kernel<<<dim3(32, 8, NB), 256, 0, stream>>>(U2, SLOT, U4, SLOT, partP);
            softmax_kernel<<<dim3(8, NB), 256, 0, stream>>>(partP, nqsq, nksq, temp, attnP);
            av_kernel<<<dim3(256, 8, NB), 256, 0, stream>>>(attnP, U4, SLOT, U0, SLOT);
            mconv2<1, 1, 0, false><<<gz, 256, 0, stream>>>(
                U0, SLOT, w_proj, 128, nullptr, msb, CHW, xbf, CHWu, HW_, 0, NUL, NUL);  // x bf16

            rfft_rowsT<<<dim3(2048, NB), 256, 0, stream>>>(U1, SLOT, (unsigned*)(void*)U0, SPECu);
            cfftT_fwd<<<dim3(9, 128, NB), 256, 0, stream>>>((unsigned*)(void*)U0, SPECu);
            rfft_rowsT<<<dim3(2048, NB), 256, 0, stream>>>(U3, SLOT, (unsigned*)(void*)U2, SPECu);
            cfftT_fwd<<<dim3(9, 128, NB), 256, 0, stream>>>((unsigned*)(void*)U2, SPECu);
            apconv2<<<gzf, 256, 0, stream>>>(
                (const unsigned*)(void*)U0, (const unsigned*)(void*)U2, SPECu,
                w_amp1, w_pha1, w_amp2, w_pha2, amp1b, pha1b, amp2b, pha2b,
                U1, U1 + CPFu, SLOT);
            cifft_combine<<<dim3(9, 128, NB), 256, 0, stream>>>(
                U1, SLOT, U1 + CPFu, SLOT, (unsigned*)(void*)U3, SPECu);
            irfft_rows16_abs<<<dim3(2048, NB), 256, 0, stream>>>((unsigned*)(void*)U3, SPECu, U0, SLOT);
            mconv2<1, 1, 0, false><<<gz, 256, 0, stream>>>(
                U0, SLOT, w_post, 128, postb, nullptr, 0, freb, CHWu, HW_, 0, NUL, NUL);
        } else {
            mconv2<0, 1, 0, true><<<gz, 256, 0, stream>>>(
                msb, CHW, w_qkv, 128, nullptr, nullptr, 0, U0, SLOT, HW_, 0, qkv_ws, qkv_bb);
            dwconv2<<<dim3(32, 128, NB), 256, 0, stream>>>(U0, SLOT, dww, ksumP, U1, SLOT, nqsq);
            mconv2<0, 1, 0, true><<<gz, 256, 0, stream>>>(
                panb, CHW, w_qkv, 128, nullptr, nullptr, 0, U0, SLOT, HW_, 0, qkv_ws, qkv_bb);
            dwconv2<<<dim3(32, 128, NB), 256, 0, stream>>>(U0, SLOT, dww, ksumP, U2, SLOT, nksq);
            gram_kernel<<<dim3(32, 8, NB), 256, 0, stream>>>(U1, SLOT, U2, SLOT, partP);
            softmax_kernel<<<dim3(8, NB), 256, 0, stream>>>(partP, nqsq, nksq, temp, attnP);
            av_kernel<<<dim3(256, 8, NB), 256, 0, stream>>>(attnP, U2, SLOT, U0, SLOT);
            mconv2<1, 1, 0, false><<<gz, 256, 0, stream>>>(
                U0, SLOT, w_proj, 128, nullptr, msb, CHW, xbf, CHWu, HW_, 0, NUL, NUL);  // x bf16

            mconv2<0, 1, 0, false><<<gz, 256, 0, stream>>>(
                msb, CHW, w_pre1, 128, pre1b, nullptr, 0, U0, SLOT, HW_, 1, NUL, NUL);
            rfft_rowsT<<<dim3(2048, NB), 256, 0, stream>>>(U0, SLOT, (unsigned*)(void*)U1, SPECu);
            cfftT_fwd<<<dim3(9, 128, NB), 256, 0, stream>>>((unsigned*)(void*)U1, SPECu);
            mconv2<0, 1, 0, false><<<gz, 256, 0, stream>>>(
                panb, CHW, w_pre2, 128, pre2b, nullptr, 0, U0, SLOT, HW_, 1, NUL, NUL);
            rfft_rowsT<<<dim3(2048, NB), 256, 0, stream>>>(U0, SLOT, (unsigned*)(void*)U2, SPECu);
            cfftT_fwd<<<dim3(9, 128, NB), 256, 0, stream>>>((unsigned*)(void*)U2, SPECu);
            apconv2<<<gzf, 256, 0, stream>>>(
                (const unsigned*)(void*)U1, (const unsigned*)(void*)U2, SPECu,
                w_amp1, w_pha1, w_amp2, w_pha2, amp1b, pha1b, amp2b, pha2b,
                U0, U0 + CPFu, SLOT);
            cifft_combine<<<dim3(9, 128, NB), 256, 0, stream>>>(
                U0, SLOT, U0 + CPFu, SLOT, (unsigned*)(void*)U2, SPECu);
            irfft_rows16_abs<<<dim3(2048, NB), 256, 0, stream>>>((unsigned*)(void*)U2, SPECu, U0, SLOT);
            mconv2<1, 1, 0, false><<<gz, 256, 0, stream>>>(
                U0, SLOT, w_post, 128, postb, nullptr, 0, freb, CHWu, HW_, 0, NUL, NUL);
        }
    }

    // ---- FFN (full batch, LN2 + gelu-gate fused, x bf16, direct f32 out) ----
    ffn_mfma8<<<dim3(HW_ / 64, B_), 256, 0, stream>>>(XB, F, w_pin, w_pout2, (const float4*)pinC, xout);
}

// Round 15
// 1553.218 us; speedup vs baseline: 1.3089x; 1.0156x over previous
//
#include <hip/hip_runtime.h>
#include <math.h>

#define B_ 4
#define C_ 128
#define HW_ 65536
#define H__ 256
#define KF_ 129
#define PLANEF_ 33024

typedef __attribute__((ext_vector_type(8))) short short8v;
typedef __attribute__((ext_vector_type(4))) float f32x4;
typedef __attribute__((ext_vector_type(4))) unsigned short ush4;
typedef __attribute__((ext_vector_type(8))) unsigned short ush8;
typedef __attribute__((ext_vector_type(4))) unsigned uint4v;

__device__ __forceinline__ unsigned short f2bf(float f) {
    union { float f; unsigned u; } v; v.f = f;
    return (unsigned short)((v.u + 0x7FFFu + ((v.u >> 16) & 1u)) >> 16);
}
__device__ __forceinline__ float bf2f(unsigned short s) {
    union { unsigned u; float f; } v; v.u = (unsigned)s << 16;
    return v.f;
}
__device__ __forceinline__ unsigned pack2bf(float2 v) {
    return (unsigned)f2bf(v.x) | ((unsigned)f2bf(v.y) << 16);
}
__device__ __forceinline__ float2 upk(unsigned u) {
    return make_float2(bf2f((unsigned short)(u & 0xffff)), bf2f((unsigned short)(u >> 16)));
}
// fast gelu: A&S 7.1.26 erf (|err|<=1.5e-7) with __expf
__device__ __forceinline__ float geluf(float x) {
    float z = 0.70710678118654752f * fabsf(x);
    float t = __fdividef(1.f, fmaf(0.3275911f, z, 1.f));
    float p = fmaf(1.061405429f, t, -1.453152027f);
    p = fmaf(p, t, 1.421413741f);
    p = fmaf(p, t, -0.284496736f);
    p = fmaf(p, t, 0.254829592f);
    p = p * t;
    float erfv = 1.f - p * __expf(-z * z);
    float cdf = (x >= 0.f) ? fmaf(0.5f, erfv, 0.5f) : fmaf(-0.5f, erfv, 0.5f);
    return x * cdf;
}
// fast atan2, poly err ~1e-5 rad
__device__ __forceinline__ float fatan2(float y, float x) {
    float ax = fabsf(x), ay = fabsf(y);
    float mx = fmaxf(ax, ay), mn = fminf(ax, ay);
    float a = __fdividef(mn, fmaxf(mx, 1e-38f));
    float s = a * a;
    float r = fmaf(0.0208351f, s, -0.0851330f);
    r = fmaf(r, s, 0.1801410f);
    r = fmaf(r, s, -0.3302995f);
    r = fmaf(r, s, 0.9998660f);
    r = r * a;
    if (ay > ax) r = 1.57079632679489662f - r;
    if (x < 0.f) r = 3.14159265358979324f - r;
    return copysignf(r, y);
}
// LDS XOR swizzle on byte-offset within row
template<int W>
__device__ __forceinline__ char* swz_ptr(unsigned short (*xs)[W], int px, int cb) {
    return (char*)xs + px * (W * 2) + (cb ^ (((px >> 2) & 7) << 4));
}

// ---------------------------------------------------------------- prep
__global__ __launch_bounds__(256) void tobf16_kernel(const float* __restrict__ src,
                                                     unsigned short* __restrict__ dst, int n)
{
    int i = blockIdx.x * 256 + threadIdx.x;
    if (i < n) dst[i] = f2bf(src[i]);
}

__global__ __launch_bounds__(128) void foldln_kernel(const float* __restrict__ W,
                                                     const float* __restrict__ lnw,
                                                     const float* __restrict__ lnb,
                                                     unsigned short* __restrict__ Wb,
                                                     float* __restrict__ wsum, float* __restrict__ bsum,
                                                     int Cc)
{
    int o = blockIdx.x, t = threadIdx.x;
    float sw = 0.f, sb = 0.f;
    for (int c = t; c < Cc; c += 128) {
        float w = W[(size_t)o * Cc + c];
        float fw = w * lnw[c];
        unsigned short us = f2bf(fw);
        Wb[(size_t)o * Cc + c] = us;
        sw += bf2f(us);
        sb += w * lnb[c];
    }
    __shared__ float r1[128], r2[128];
    r1[t] = sw; r2[t] = sb; __syncthreads();
    for (int st = 64; st; st >>= 1) {
        if (t < st) { r1[t] += r1[t + st]; r2[t] += r2[t + st]; }
        __syncthreads();
    }
    if (!t) { wsum[o] = r1[0]; bsum[o] = r2[0]; }
}

__global__ __launch_bounds__(256) void poutperm_kernel(const float* __restrict__ src,
                                                       unsigned short* __restrict__ dst)
{
    int i = blockIdx.x * 256 + threadIdx.x;   // 32768
    int half = i >> 14, rem = i & 16383, o = rem >> 7, kp = rem & 127;
    int h = (kp >> 5) * 64 + half * 32 + (kp & 31);
    dst[i] = f2bf(src[o * 256 + h]);
}

__global__ void pinc_kernel(const float* __restrict__ bb, const float* __restrict__ ws,
                            float4* __restrict__ pinC)
{
    int i = threadIdx.x;
    if (i < 256) pinC[i] = make_float4(bb[i], ws[i], bb[i + 256], ws[i + 256]);
}

__global__ void ksum_kernel(const float* __restrict__ dw, float* __restrict__ ks)
{
    int c = threadIdx.x;
    if (c < C_) {
        float s = 0.f;
        for (int k = 0; k < 9; ++k) s += dw[c * 9 + k];
        ks[c] = s;
    }
}

__global__ __launch_bounds__(256) void zero2_kernel(float* __restrict__ a, float* __restrict__ b, int n)
{
    int i = blockIdx.x * 256 + threadIdx.x;
    if (i < n) { a[i] = 0.f; b[i] = 0.f; }
}

// ---------------------------------------------------------------- MFMA conv1x1 (CIN=128)
template<int INBF, int OUTBF, int PRO, bool LNF>
__global__ __launch_bounds__(256, 4) void mconv2(
    const void* __restrict__ Xv, size_t sx,
    const unsigned short* __restrict__ Wb, int wstride,
    const float* __restrict__ bias,
    const float* __restrict__ res, size_t sres,
    void* __restrict__ Yv, size_t sy, int plane, int flags,
    const float* __restrict__ wsum, const float* __restrict__ bsum)
{
    __shared__ unsigned short xs[128][136];
    __shared__ float2 lnred[LNF ? 8 : 1][LNF ? 128 : 1];
    __shared__ float2 lnmi[LNF ? 128 : 1];
    const int t = threadIdx.x;
    const int bz = blockIdx.z;
    const int p0 = blockIdx.x * 128;
    const int lane = t & 63;
    const int wr = t >> 7, wc = (t >> 6) & 1;
    const int lr = lane >> 4, lc = lane & 15;

    if constexpr (INBF == 0) {
        const float* Xb = (const float*)Xv + (size_t)bz * sx;
        const int px4 = t & 31;
        float s0 = 0.f, s1 = 0.f, s2v = 0.f, s3 = 0.f;
        float q0 = 0.f, q1 = 0.f, q2 = 0.f, q3 = 0.f;
#pragma unroll
        for (int g = 0; g < 2; ++g) {
            float4 st[8];
#pragma unroll
            for (int i = 0; i < 8; ++i) {
                int e = t + (g * 8 + i) * 256;
                int c = e >> 5;
                st[i] = *(const float4*)(Xb + (size_t)c * plane + p0 + px4 * 4);
            }
#pragma unroll
            for (int i = 0; i < 8; ++i) {
                int e = t + (g * 8 + i) * 256;
                int c = e >> 5;
                float a0 = st[i].x, a1 = st[i].y, a2 = st[i].z, a3 = st[i].w;
                if constexpr (PRO == 1) {
                    a0 = a0 > 0.f ? a0 : 0.1f * a0;
                    a1 = a1 > 0.f ? a1 : 0.1f * a1;
                    a2 = a2 > 0.f ? a2 : 0.1f * a2;
                    a3 = a3 > 0.f ? a3 : 0.1f * a3;
                }
                if constexpr (LNF) {
                    s0 += a0; q0 += a0 * a0;
                    s1 += a1; q1 += a1 * a1;
                    s2v += a2; q2 += a2 * a2;
                    s3 += a3; q3 += a3 * a3;
                }
                *(unsigned short*)swz_ptr(xs, px4 * 4 + 0, 2 * c) = f2bf(a0);
                *(unsigned short*)swz_ptr(xs, px4 * 4 + 1, 2 * c) = f2bf(a1);
                *(unsigned short*)swz_ptr(xs, px4 * 4 + 2, 2 * c) = f2bf(a2);
                *(unsigned short*)swz_ptr(xs, px4 * 4 + 3, 2 * c) = f2bf(a3);
            }
        }
        if constexpr (LNF) {
            lnred[t >> 5][px4 * 4 + 0] = make_float2(s0, q0);
            lnred[t >> 5][px4 * 4 + 1] = make_float2(s1, q1);
            lnred[t >> 5][px4 * 4 + 2] = make_float2(s2v, q2);
            lnred[t >> 5][px4 * 4 + 3] = make_float2(s3, q3);
        }
    } else {
        const unsigned short* Xb = (const unsigned short*)Xv + (size_t)bz * sx;
        ush8 st[8];
#pragma unroll
        for (int i = 0; i < 8; ++i) {
            int e = t + i * 256;
            int c = e >> 4, px8 = e & 15;
            st[i] = *(const ush8*)(Xb + (size_t)c * plane + p0 + px8 * 8);
        }
#pragma unroll
        for (int i = 0; i < 8; ++i) {
            int e = t + i * 256;
            int c = e >> 4, px8 = e & 15;
#pragma unroll
            for (int j = 0; j < 8; ++j) {
                unsigned short us = (unsigned short)st[i][j];
                if constexpr (PRO == 1) {
                    float f = bf2f(us);
                    f = f > 0.f ? f : 0.1f * f;
                    us = f2bf(f);
                }
                *(unsigned short*)swz_ptr(xs, px8 * 8 + j, 2 * c) = us;
            }
        }
    }
    __syncthreads();
    if constexpr (LNF) {
        if (t < 128) {
            float ss = 0.f, qq = 0.f;
#pragma unroll
            for (int j = 0; j < 8; ++j) { float2 a = lnred[j][t]; ss += a.x; qq += a.y; }
            float m = ss * (1.f / 128.f);
            float inv = rsqrtf(qq * (1.f / 128.f) - m * m + 1e-5f);
            lnmi[t] = make_float2(m, inv);
        }
        __syncthreads();
    }

    f32x4 acc[4][4];
#pragma unroll
    for (int mi = 0; mi < 4; ++mi)
#pragma unroll
        for (int ni = 0; ni < 4; ++ni) acc[mi][ni] = (f32x4){0.f, 0.f, 0.f, 0.f};

#pragma unroll
    for (int kk = 0; kk < 128; kk += 32) {
        short8v bfr[4];
#pragma unroll
        for (int ni = 0; ni < 4; ++ni)
            bfr[ni] = *(const short8v*)swz_ptr(xs, wc * 64 + ni * 16 + lc, 2 * (kk + lr * 8));
#pragma unroll
        for (int mi = 0; mi < 4; ++mi) {
            int row = wr * 64 + mi * 16 + lc;
            short8v afr = *(const short8v*)(Wb + (size_t)row * wstride + kk + lr * 8);
#pragma unroll
            for (int ni = 0; ni < 4; ++ni)
                acc[mi][ni] = __builtin_amdgcn_mfma_f32_16x16x32_bf16(afr, bfr[ni], acc[mi][ni], 0, 0, 0);
        }
    }

    float2 mrow[4];
    if constexpr (LNF) {
#pragma unroll
        for (int ni = 0; ni < 4; ++ni) mrow[ni] = lnmi[wc * 64 + ni * 16 + lc];
    }

#pragma unroll
    for (int mi = 0; mi < 4; ++mi) {
        int ob = wr * 64 + mi * 16 + lr * 4;
#pragma unroll
        for (int r = 0; r < 4; ++r) {
            int o = ob + r;
            float bv = 0.f, wso = 0.f;
            if constexpr (LNF) { bv = bsum[o]; wso = wsum[o]; }
            else { if (bias) bv = bias[o]; if (flags & 1) bv += 1e-8f; }
#pragma unroll
            for (int ni = 0; ni < 4; ++ni) {
                int px = wc * 64 + ni * 16 + lc;
                float v;
                if constexpr (LNF) {
                    float m = mrow[ni].x, inv = mrow[ni].y;
                    v = acc[mi][ni][r] * inv + bv - m * inv * wso;
                } else {
                    v = acc[mi][ni][r] + bv;
                }
                if (res) v += res[(size_t)bz * sres + (size_t)o * plane + p0 + px];
                if constexpr (OUTBF == 0) {
                    float* Y = (float*)Yv;
                    Y[(size_t)bz * sy + (size_t)o * plane + p0 + px] = v;
                } else {
                    unsigned short* Y = (unsigned short*)Yv;
                    Y[(size_t)bz * sy + (size_t)o * plane + p0 + px] = f2bf(v);
                }
            }
        }
    }
}

// ---------------------------------------------------------------- fused dual conv1x1: qkv (folded-LN) + pre (bias+1e-8)
__global__ __launch_bounds__(256, 3) void mconv_dual(
    const float* __restrict__ X, size_t sx,
    const unsigned short* __restrict__ Wq,
    const float* __restrict__ q_ws, const float* __restrict__ q_bb,
    const unsigned short* __restrict__ Wp,
    const float* __restrict__ pre_b,
    unsigned short* __restrict__ Y1, unsigned short* __restrict__ Y2, size_t sy)
{
    __shared__ unsigned short xs[128][136];
    __shared__ float2 lnred[8][128];
    __shared__ float2 lnmi[128];
    const int t = threadIdx.x;
    const int bz = blockIdx.z;
    const int p0 = blockIdx.x * 128;
    const int lane = t & 63;
    const int wr = t >> 7, wc = (t >> 6) & 1;
    const int lr = lane >> 4, lc = lane & 15;

    const float* Xb = X + (size_t)bz * sx;
    const int px4 = t & 31;
    float s0 = 0.f, s1 = 0.f, s2v = 0.f, s3 = 0.f;
    float q0 = 0.f, q1 = 0.f, q2 = 0.f, q3 = 0.f;
#pragma unroll
    for (int g = 0; g < 2; ++g) {
        float4 st[8];
#pragma unroll
        for (int i = 0; i < 8; ++i) {
            int e = t + (g * 8 + i) * 256;
            int c = e >> 5;
            st[i] = *(const float4*)(Xb + (size_t)c * HW_ + p0 + px4 * 4);
        }
#pragma unroll
        for (int i = 0; i < 8; ++i) {
            int e = t + (g * 8 + i) * 256;
            int c = e >> 5;
            float a0 = st[i].x, a1 = st[i].y, a2 = st[i].z, a3 = st[i].w;
            s0 += a0; q0 += a0 * a0;
            s1 += a1; q1 += a1 * a1;
            s2v += a2; q2 += a2 * a2;
            s3 += a3; q3 += a3 * a3;
            *(unsigned short*)swz_ptr(xs, px4 * 4 + 0, 2 * c) = f2bf(a0);
            *(unsigned short*)swz_ptr(xs, px4 * 4 + 1, 2 * c) = f2bf(a1);
            *(unsigned short*)swz_ptr(xs, px4 * 4 + 2, 2 * c) = f2bf(a2);
            *(unsigned short*)swz_ptr(xs, px4 * 4 + 3, 2 * c) = f2bf(a3);
        }
    }
    lnred[t >> 5][px4 * 4 + 0] = make_float2(s0, q0);
    lnred[t >> 5][px4 * 4 + 1] = make_float2(s1, q1);
    lnred[t >> 5][px4 * 4 + 2] = make_float2(s2v, q2);
    lnred[t >> 5][px4 * 4 + 3] = make_float2(s3, q3);
    __syncthreads();
    if (t < 128) {
        float ss = 0.f, qq = 0.f;
#pragma unroll
        for (int j = 0; j < 8; ++j) { float2 a = lnred[j][t]; ss += a.x; qq += a.y; }
        float m = ss * (1.f / 128.f);
        float inv = rsqrtf(qq * (1.f / 128.f) - m * m + 1e-5f);
        lnmi[t] = make_float2(m, inv);
    }
    __syncthreads();

    float2 mrow[4];
#pragma unroll
    for (int ni = 0; ni < 4; ++ni) mrow[ni] = lnmi[wc * 64 + ni * 16 + lc];

    {
        f32x4 acc[4][4];
#pragma unroll
        for (int mi = 0; mi < 4; ++mi)
#pragma unroll
            for (int ni = 0; ni < 4; ++ni) acc[mi][ni] = (f32x4){0.f, 0.f, 0.f, 0.f};
#pragma unroll
        for (int kk = 0; kk < 128; kk += 32) {
            short8v bfr[4];
#pragma unroll
            for (int ni = 0; ni < 4; ++ni)
                bfr[ni] = *(const short8v*)swz_ptr(xs, wc * 64 + ni * 16 + lc, 2 * (kk + lr * 8));
#pragma unroll
            for (int mi = 0; mi < 4; ++mi) {
                int row = wr * 64 + mi * 16 + lc;
                short8v afr = *(const short8v*)(Wq + (size_t)row * 128 + kk + lr * 8);
#pragma unroll
                for (int ni = 0; ni < 4; ++ni)
                    acc[mi][ni] = __builtin_amdgcn_mfma_f32_16x16x32_bf16(afr, bfr[ni], acc[mi][ni], 0, 0, 0);
            }
        }
#pragma unroll
        for (int mi = 0; mi < 4; ++mi)
#pragma unroll
            for (int r = 0; r < 4; ++r) {
                int o = wr * 64 + mi * 16 + lr * 4 + r;
                float bv = q_bb[o], wso = q_ws[o];
#pragma unroll
                for (int ni = 0; ni < 4; ++ni) {
                    int px = wc * 64 + ni * 16 + lc;
                    float m = mrow[ni].x, inv = mrow[ni].y;
                    float v = acc[mi][ni][r] * inv + bv - m * inv * wso;
                    Y1[(size_t)bz * sy + (size_t)o * HW_ + p0 + px] = f2bf(v);
                }
            }
    }

    {
        f32x4 acc[4][4];
#pragma unroll
        for (int mi = 0; mi < 4; ++mi)
#pragma unroll
            for (int ni = 0; ni < 4; ++ni) acc[mi][ni] = (f32x4){0.f, 0.f, 0.f, 0.f};
#pragma unroll
        for (int kk = 0; kk < 128; kk += 32) {
            short8v bfr[4];
#pragma unroll
            for (int ni = 0; ni < 4; ++ni)
                bfr[ni] = *(const short8v*)swz_ptr(xs, wc * 64 + ni * 16 + lc, 2 * (kk + lr * 8));
#pragma unroll
            for (int mi = 0; mi < 4; ++mi) {
                int row = wr * 64 + mi * 16 + lc;
                short8v afr = *(const short8v*)(Wp + (size_t)row * 128 + kk + lr * 8);
#pragma unroll
                for (int ni = 0; ni < 4; ++ni)
                    acc[mi][ni] = __builtin_amdgcn_mfma_f32_16x16x32_bf16(afr, bfr[ni], acc[mi][ni], 0, 0, 0);
            }
        }
#pragma unroll
        for (int mi = 0; mi < 4; ++mi)
#pragma unroll
            for (int r = 0; r < 4; ++r) {
                int o = wr * 64 + mi * 16 + lr * 4 + r;
                float bv = pre_b[o] + 1e-8f;
#pragma unroll
                for (int ni = 0; ni < 4; ++ni) {
                    int px = wc * 64 + ni * 16 + lc;
                    Y2[(size_t)bz * sy + (size_t)o * HW_ + p0 + px] = f2bf(acc[mi][ni][r] + bv);
                }
            }
    }
}

// ---------------------------------------------------------------- fused amp1+pha1+amp2+pha2 spectral block
__global__ __launch_bounds__(256, 2) void apconv2(
    const unsigned* __restrict__ T1, const unsigned* __restrict__ T2, size_t sT,
    const unsigned short* __restrict__ Wa1, const unsigned short* __restrict__ Wp1,
    const unsigned short* __restrict__ Wa2, const unsigned short* __restrict__ Wp2,
    const float* __restrict__ ba1, const float* __restrict__ bp1,
    const float* __restrict__ ba2, const float* __restrict__ bp2,
    unsigned short* __restrict__ AMP, unsigned short* __restrict__ PHA, size_t sO)
{
    __shared__ __align__(16) unsigned short buf[2][128][72];
    const int t = threadIdx.x;
    const int bz = blockIdx.z;
    const int p0 = blockIdx.x * 128;
    const int lane = t & 63;
    const int wr = t >> 7, wc = (t >> 6) & 1;
    const int lr = lane >> 4, lc = lane & 15;
    const int px2 = t & 63;

    typedef unsigned short (*row72)[72];
    typedef unsigned short (*row144)[144];
    row72 xa = (row72)buf[0];
    row72 xp = (row72)buf[1];
    row144 hb = (row144)&buf[0][0][0];

    f32x4 aa[4][4], ap[4][4];
#pragma unroll
    for (int mi = 0; mi < 4; ++mi)
#pragma unroll
        for (int ni = 0; ni < 4; ++ni) { aa[mi][ni] = (f32x4){0.f,0.f,0.f,0.f}; ap[mi][ni] = (f32x4){0.f,0.f,0.f,0.f}; }

    for (int ch = 0; ch < 256; ch += 64) {
        const unsigned* Ts = ((ch < 128) ? T1 : T2) + (size_t)bz * sT + (size_t)(ch & 127) * PLANEF_;
#pragma unroll
        for (int g = 0; g < 2; ++g) {
            uint2 st[8];
#pragma unroll
            for (int i = 0; i < 8; ++i) {
                int e = t + (g * 8 + i) * 256;
                int c = e >> 6;
                st[i] = *(const uint2*)(Ts + (size_t)c * PLANEF_ + p0 + px2 * 2);
            }
#pragma unroll
            for (int i = 0; i < 8; ++i) {
                int e = t + (g * 8 + i) * 256;
                int c = e >> 6;
                float2 z0 = upk(st[i].x), z1 = upk(st[i].y);
                float m0 = sqrtf(z0.x * z0.x + z0.y * z0.y);
                float m1 = sqrtf(z1.x * z1.x + z1.y * z1.y);
                float a0 = fatan2(z0.y, z0.x);
                float a1 = fatan2(z1.y, z1.x);
                *(unsigned short*)swz_ptr(xa, px2 * 2 + 0, 2 * c) = f2bf(m0);
                *(unsigned short*)swz_ptr(xa, px2 * 2 + 1, 2 * c) = f2bf(m1);
                *(unsigned short*)swz_ptr(xp, px2 * 2 + 0, 2 * c) = f2bf(a0);
                *(unsigned short*)swz_ptr(xp, px2 * 2 + 1, 2 * c) = f2bf(a1);
            }
        }
        __syncthreads();
#pragma unroll
        for (int kk = 0; kk < 64; kk += 32) {
            short8v bfa[4], bfp[4];
#pragma unroll
            for (int ni = 0; ni < 4; ++ni) {
                bfa[ni] = *(const short8v*)swz_ptr(xa, wc * 64 + ni * 16 + lc, 2 * (kk + lr * 8));
                bfp[ni] = *(const short8v*)swz_ptr(xp, wc * 64 + ni * 16 + lc, 2 * (kk + lr * 8));
            }
#pragma unroll
            for (int mi = 0; mi < 4; ++mi) {
                int row = wr * 64 + mi * 16 + lc;
                short8v afa = *(const short8v*)(Wa1 + (size_t)row * 256 + ch + kk + lr * 8);
                short8v afp = *(const short8v*)(Wp1 + (size_t)row * 256 + ch + kk + lr * 8);
#pragma unroll
                for (int ni = 0; ni < 4; ++ni) {
                    aa[mi][ni] = __builtin_amdgcn_mfma_f32_16x16x32_bf16(afa, bfa[ni], aa[mi][ni], 0, 0, 0);
                    ap[mi][ni] = __builtin_amdgcn_mfma_f32_16x16x32_bf16(afp, bfp[ni], ap[mi][ni], 0, 0, 0);
                }
            }
        }
        __syncthreads();
    }

    // ---- stage B (amp) ----
#pragma unroll
    for (int mi = 0; mi < 4; ++mi)
#pragma unroll
        for (int r = 0; r < 4; ++r) {
            int o = wr * 64 + mi * 16 + lr * 4 + r;
            float bva = ba1[o];
#pragma unroll
            for (int ni = 0; ni < 4; ++ni) {
                int px = wc * 64 + ni * 16 + lc;
                float v = aa[mi][ni][r] + bva;
                v = v > 0.f ? v : 0.1f * v;
                *(unsigned short*)swz_ptr(hb, px, 2 * o) = f2bf(v);
            }
        }
    __syncthreads();
    {
        f32x4 acc[4][4];
#pragma unroll
        for (int mi = 0; mi < 4; ++mi)
#pragma unroll
            for (int ni = 0; ni < 4; ++ni) acc[mi][ni] = (f32x4){0.f,0.f,0.f,0.f};
#pragma unroll
        for (int kk = 0; kk < 128; kk += 32) {
            short8v bfr[4];
#pragma unroll
            for (int ni = 0; ni < 4; ++ni)
                bfr[ni] = *(const short8v*)swz_ptr(hb, wc * 64 + ni * 16 + lc, 2 * (kk + lr * 8));
#pragma unroll
            for (int mi = 0; mi < 4; ++mi) {
                int row = wr * 64 + mi * 16 + lc;
                short8v afr = *(const short8v*)(Wa2 + (size_t)row * 128 + kk + lr * 8);
#pragma unroll
                for (int ni = 0; ni < 4; ++ni)
                    acc[mi][ni] = __builtin_amdgcn_mfma_f32_16x16x32_bf16(afr, bfr[ni], acc[mi][ni], 0, 0, 0);
            }
        }
#pragma unroll
        for (int mi = 0; mi < 4; ++mi)
#pragma unroll
            for (int r = 0; r < 4; ++r) {
                int o = wr * 64 + mi * 16 + lr * 4 + r;
                float bv = ba2[o];
#pragma unroll
                for (int ni = 0; ni < 4; ++ni) {
                    int px = wc * 64 + ni * 16 + lc;
                    AMP[(size_t)bz * sO + (size_t)o * PLANEF_ + p0 + px] = f2bf(acc[mi][ni][r] + bv);
                }
            }
    }
    __syncthreads();

    // ---- stage B (pha) ----
#pragma unroll
    for (int mi = 0; mi < 4; ++mi)
#pragma unroll
        for (int r = 0; r < 4; ++r) {
            int o = wr * 64 + mi * 16 + lr * 4 + r;
            float bvp = bp1[o];
#pragma unroll
            for (int ni = 0; ni < 4; ++ni) {
                int px = wc * 64 + ni * 16 + lc;
                float v = ap[mi][ni][r] + bvp;
                v = v > 0.f ? v : 0.1f * v;
                *(unsigned short*)swz_ptr(hb, px, 2 * o) = f2bf(v);
            }
        }
    __syncthreads();
    {
        f32x4 acc[4][4];
#pragma unroll
        for (int mi = 0; mi < 4; ++mi)
#pragma unroll
            for (int ni = 0; ni < 4; ++ni) acc[mi][ni] = (f32x4){0.f,0.f,0.f,0.f};
#pragma unroll
        for (int kk = 0; kk < 128; kk += 32) {
            short8v bfr[4];
#pragma unroll
            for (int ni = 0; ni < 4; ++ni)
                bfr[ni] = *(const short8v*)swz_ptr(hb, wc * 64 + ni * 16 + lc, 2 * (kk + lr * 8));
#pragma unroll
            for (int mi = 0; mi < 4; ++mi) {
                int row = wr * 64 + mi * 16 + lc;
                short8v afr = *(const short8v*)(Wp2 + (size_t)row * 128 + kk + lr * 8);
#pragma unroll
                for (int ni = 0; ni < 4; ++ni)
                    acc[mi][ni] = __builtin_amdgcn_mfma_f32_16x16x32_bf16(afr, bfr[ni], acc[mi][ni], 0, 0, 0);
            }
        }
#pragma unroll
        for (int mi = 0; mi < 4; ++mi)
#pragma unroll
            for (int r = 0; r < 4; ++r) {
                int o = wr * 64 + mi * 16 + lr * 4 + r;
                float bv = bp2[o];
#pragma unroll
                for (int ni = 0; ni < 4; ++ni) {
                    int px = wc * 64 + ni * 16 + lc;
                    PHA[(size_t)bz * sO + (size_t)o * PLANEF_ + p0 + px] = f2bf(acc[mi][ni][r] + bv);
                }
            }
    }
}

// ---------------------------------------------------------------- fused MFMA FFN (x bf16, fre bf16; residual from LDS; nontemporal f32 out)
__global__ __launch_bounds__(256, 3) void ffn_mfma8(
    const unsigned short* __restrict__ x, const unsigned short* __restrict__ fre,
    const unsigned short* __restrict__ pinb,
    const unsigned short* __restrict__ pout2,
    const float4* __restrict__ pinC,
    float* __restrict__ out)
{
    __shared__ unsigned short xs[64][264];
    __shared__ unsigned short hs[64][136];
    __shared__ float2 muinv[64];
    float2* sred = (float2*)&hs[0][0];
    const int b = blockIdx.y;
    const size_t p0 = (size_t)blockIdx.x * 64;
    const int t = threadIdx.x;
    const int wave = t >> 6, lane = t & 63;
    const int lr = lane >> 4, lc = lane & 15;
    const int px4 = t & 15;

    float s0 = 0.f, s1 = 0.f, s2v = 0.f, s3 = 0.f;
    float q0 = 0.f, q1 = 0.f, q2 = 0.f, q3 = 0.f;
    {
        ush4 stx[8], stf[8];
#pragma unroll
        for (int i = 0; i < 8; ++i) {
            int e = t + i * 256;
            int c = e >> 4;
            stx[i] = *(const ush4*)(x + (size_t)b * 8388608 + (size_t)c * HW_ + p0 + px4 * 4);
        }
#pragma unroll
        for (int i = 0; i < 8; ++i) {
            int e = t + i * 256;
            int c = e >> 4;
            stf[i] = *(const ush4*)(fre + (size_t)b * 8388608 + (size_t)c * HW_ + p0 + px4 * 4);
        }
#pragma unroll
        for (int i = 0; i < 8; ++i) {
            int e = t + i * 256;
            int c = e >> 4;
#pragma unroll
            for (int j = 0; j < 4; ++j) {
                unsigned short us = (unsigned short)stx[i][j];
                float a = bf2f(us);
                s0 += (j == 0) ? a : 0.f; s1 += (j == 1) ? a : 0.f;
                s2v += (j == 2) ? a : 0.f; s3 += (j == 3) ? a : 0.f;
                q0 += (j == 0) ? a * a : 0.f; q1 += (j == 1) ? a * a : 0.f;
                q2 += (j == 2) ? a * a : 0.f; q3 += (j == 3) ? a * a : 0.f;
                *(unsigned short*)swz_ptr(xs, px4 * 4 + j, 2 * c) = us;
            }
        }
#pragma unroll
        for (int i = 0; i < 8; ++i) {
            int e = t + i * 256;
            int c = e >> 4;
#pragma unroll
            for (int j = 0; j < 4; ++j) {
                unsigned short us = (unsigned short)stf[i][j];
                float a = bf2f(us);
                s0 += (j == 0) ? a : 0.f; s1 += (j == 1) ? a : 0.f;
                s2v += (j == 2) ? a : 0.f; s3 += (j == 3) ? a : 0.f;
                q0 += (j == 0) ? a * a : 0.f; q1 += (j == 1) ? a * a : 0.f;
                q2 += (j == 2) ? a * a : 0.f; q3 += (j == 3) ? a * a : 0.f;
                *(unsigned short*)swz_ptr(xs, px4 * 4 + j, 2 * (128 + c)) = us;
            }
        }
    }
    sred[(t >> 4) * 64 + px4 * 4 + 0] = make_float2(s0, q0);
    sred[(t >> 4) * 64 + px4 * 4 + 1] = make_float2(s1, q1);
    sred[(t >> 4) * 64 + px4 * 4 + 2] = make_float2(s2v, q2);
    sred[(t >> 4) * 64 + px4 * 4 + 3] = make_float2(s3, q3);
    __syncthreads();
    if (t < 64) {
        float ss = 0.f, qq = 0.f;
#pragma unroll
        for (int j = 0; j < 16; ++j) { float2 a = sred[j * 64 + t]; ss += a.x; qq += a.y; }
        float m = ss * (1.f / 256.f);
        float inv = rsqrtf(qq * (1.f / 256.f) - m * m + 1e-5f);
        muinv[t] = make_float2(m, inv);
    }
    __syncthreads();

    float2 mrow[4];
#pragma unroll
    for (int ni = 0; ni < 4; ++ni) mrow[ni] = muinv[ni * 16 + lc];

    f32x4 oc[2][4];
#pragma unroll
    for (int mi = 0; mi < 2; ++mi)
#pragma unroll
        for (int ni = 0; ni < 4; ++ni) oc[mi][ni] = (f32x4){0.f, 0.f, 0.f, 0.f};

#pragma unroll
    for (int half = 0; half < 2; ++half) {
        f32x4 a1[2][4], a2[2][4];
#pragma unroll
        for (int mi = 0; mi < 2; ++mi)
#pragma unroll
            for (int ni = 0; ni < 4; ++ni) { a1[mi][ni] = (f32x4){0.f,0.f,0.f,0.f}; a2[mi][ni] = (f32x4){0.f,0.f,0.f,0.f}; }

#pragma unroll
        for (int k0 = 0; k0 < 256; k0 += 32) {
            short8v bfr[4];
#pragma unroll
            for (int ni = 0; ni < 4; ++ni)
                bfr[ni] = *(const short8v*)swz_ptr(xs, ni * 16 + lc, 2 * (k0 + lr * 8));
#pragma unroll
            for (int mi = 0; mi < 2; ++mi) {
                int hrow = wave * 64 + half * 32 + mi * 16 + lc;
                short8v af1 = *(const short8v*)(pinb + (size_t)hrow * 256 + k0 + lr * 8);
                short8v af2 = *(const short8v*)(pinb + (size_t)(hrow + 256) * 256 + k0 + lr * 8);
#pragma unroll
                for (int ni = 0; ni < 4; ++ni) {
                    a1[mi][ni] = __builtin_amdgcn_mfma_f32_16x16x32_bf16(af1, bfr[ni], a1[mi][ni], 0, 0, 0);
                    a2[mi][ni] = __builtin_amdgcn_mfma_f32_16x16x32_bf16(af2, bfr[ni], a2[mi][ni], 0, 0, 0);
                }
            }
        }
        __syncthreads();
#pragma unroll
        for (int mi = 0; mi < 2; ++mi)
#pragma unroll
            for (int r = 0; r < 4; ++r) {
                int ho = wave * 64 + half * 32 + mi * 16 + lr * 4 + r;
                float4 bwc = pinC[ho];
                int kp = wave * 32 + mi * 16 + lr * 4 + r;
#pragma unroll
                for (int ni = 0; ni < 4; ++ni) {
                    float m = mrow[ni].x, inv = mrow[ni].y;
                    float v1 = a1[mi][ni][r] * inv + bwc.x - m * inv * bwc.y;
                    float v2 = a2[mi][ni][r] * inv + bwc.z - m * inv * bwc.w;
                    hs[ni * 16 + lc][kp] = f2bf(geluf(v1) * v2);
                }
            }
        __syncthreads();
#pragma unroll
        for (int k0 = 0; k0 < 128; k0 += 32) {
            short8v bfr2[4];
#pragma unroll
            for (int ni = 0; ni < 4; ++ni)
                bfr2[ni] = *(const short8v*)&hs[ni * 16 + lc][k0 + lr * 8];
#pragma unroll
            for (int mi = 0; mi < 2; ++mi) {
                int orow = wave * 32 + mi * 16 + lc;
                short8v af = *(const short8v*)(pout2 + half * 16384 + orow * 128 + k0 + lr * 8);
#pragma unroll
                for (int ni = 0; ni < 4; ++ni)
                    oc[mi][ni] = __builtin_amdgcn_mfma_f32_16x16x32_bf16(af, bfr2[ni], oc[mi][ni], 0, 0, 0);
            }
        }
    }

#pragma unroll
    for (int mi = 0; mi < 2; ++mi)
#pragma unroll
        for (int r = 0; r < 4; ++r) {
            int o = wave * 32 + mi * 16 + lr * 4 + r;
#pragma unroll
            for (int ni = 0; ni < 4; ++ni) {
                int px = ni * 16 + lc;
                float rx = bf2f(*(const unsigned short*)swz_ptr(xs, px, 2 * o));
                size_t yi = ((size_t)b * 128 + o) * HW_ + p0 + px;
                __builtin_nontemporal_store(oc[mi][ni][r] + rx, &out[yi]);
            }
        }
}

// ---------------------------------------------------------------- depthwise 3x3 cd-conv (bf16), 8 px/thread, fused ssq
__global__ __launch_bounds__(256) void dwconv2(const unsigned short* __restrict__ X, size_t sx,
                                               const float* __restrict__ w9,
                                               const float* __restrict__ ksum,
                                               unsigned short* __restrict__ Y, size_t sy,
                                               float* __restrict__ ssq)
{
    int bz = blockIdx.z;
    int c = blockIdx.y;
    int p8 = blockIdx.x * 256 + threadIdx.x;
    int p0 = p8 * 8;
    int i = p0 >> 8, j0 = p0 & 255;
    const unsigned short* xp = X + (size_t)bz * sx + (size_t)c * HW_;
    const float* wc = w9 + c * 9;
    float a[8] = {0.f,0.f,0.f,0.f,0.f,0.f,0.f,0.f};
    float ctr[8];
#pragma unroll
    for (int di = -1; di <= 1; ++di) {
        int ii = i + di;
        if (ii < 0 || ii > 255) continue;
        const unsigned short* row = xp + ii * 256;
        ush8 m8 = *(const ush8*)(row + j0);
        float lft = (j0 > 0) ? bf2f(row[j0 - 1]) : 0.f;
        float rgt = (j0 < 248) ? bf2f(row[j0 + 8]) : 0.f;
        float v[10];
        v[0] = lft;
#pragma unroll
        for (int k = 0; k < 8; ++k) v[k + 1] = bf2f((unsigned short)m8[k]);
        v[9] = rgt;
        if (di == 0) {
#pragma unroll
            for (int k = 0; k < 8; ++k) ctr[k] = v[k + 1];
        }
        float w0 = wc[(di + 1) * 3], w1 = wc[(di + 1) * 3 + 1], w2 = wc[(di + 1) * 3 + 2];
#pragma unroll
        for (int k = 0; k < 8; ++k) a[k] += w0 * v[k] + w1 * v[k + 1] + w2 * v[k + 2];
    }
    float km = 0.7f * ksum[c];
    ush8 ov;
    float q = 0.f;
#pragma unroll
    for (int k = 0; k < 8; ++k) {
        float o = a[k] - km * ctr[k];
        ov[k] = f2bf(o);
        q += o * o;
    }
    *(ush8*)(Y + (size_t)bz * sy + (size_t)c * HW_ + p0) = ov;

    __shared__ float red[256];
    red[threadIdx.x] = q; __syncthreads();
    for (int st = 128; st; st >>= 1) {
        if (threadIdx.x < st) red[threadIdx.x] += red[threadIdx.x + st];
        __syncthreads();
    }
    if (!threadIdx.x) atomicAdd(&ssq[bz * C_ + c], red[0]);
}

// ---------------------------------------------------------------- MFMA Gram: part[sl] = Q_h K_h^T over n-slice (direct global frags)
__global__ __launch_bounds__(256) void gram_mfma(const unsigned short* __restrict__ Q, size_t sq,
                                                 const unsigned short* __restrict__ K, size_t sk,
                                                 float* __restrict__ part)
{
    int sl = blockIdx.x, h = blockIdx.y, bz = blockIdx.z;
    const unsigned short* qb = Q + (size_t)bz * sq + (size_t)(h * 16) * HW_;
    const unsigned short* kb = K + (size_t)bz * sk + (size_t)(h * 16) * HW_;
    const int t = threadIdx.x;
    const int w = t >> 6, lane = t & 63;
    const int cr = lane & 15;             // A row (c) / B col (d)
    const int kg = lane >> 4;             // k-group: 8 consecutive n

    f32x4 acc = (f32x4){0.f, 0.f, 0.f, 0.f};
    const int nbase0 = sl * 2048 + w * 512;
#pragma unroll 4
    for (int step = 0; step < 16; ++step) {
        int nb = nbase0 + step * 32 + kg * 8;
        short8v aq = *(const short8v*)(qb + (size_t)cr * HW_ + nb);
        short8v bk = *(const short8v*)(kb + (size_t)cr * HW_ + nb);
        acc = __builtin_amdgcn_mfma_f32_16x16x32_bf16(aq, bk, acc, 0, 0, 0);
    }

    __shared__ float red[4][256];
#pragma unroll
    for (int r = 0; r < 4; ++r)
        red[w][((lane >> 4) * 4 + r) * 16 + cr] = acc[r];
    __syncthreads();
    if (t < 256) {
        float s = red[0][t] + red[1][t] + red[2][t] + red[3][t];
        part[((size_t)(bz * 8 + h) * 32 + sl) * 256 + t] = s;
    }
}

__global__ __launch_bounds__(256) void softmax_kernel(const float* __restrict__ part,
                                                      const float* __restrict__ nqsq,
                                                      const float* __restrict__ nksq,
                                                      const float* __restrict__ temp,
                                                      float* __restrict__ attn)
{
    int h = blockIdx.x, bz = blockIdx.y;
    int t = threadIdx.x;
    int c = t >> 4, d = t & 15;
    float g = 0.f;
    for (int sl = 0; sl < 32; ++sl) g += part[((size_t)(bz * 8 + h) * 32 + sl) * 256 + t];
    float nqv = fmaxf(sqrtf(nqsq[bz * C_ + h * 16 + c]), 1e-12f);
    float nkv = fmaxf(sqrtf(nksq[bz * C_ + h * 16 + d]), 1e-12f);
    g *= temp[h] / (nqv * nkv);
    float m = g;
#pragma unroll
    for (int off = 8; off; off >>= 1) m = fmaxf(m, __shfl_xor(m, off, 16));
    float e = __expf(g - m);
    float ssum = e;
#pragma unroll
    for (int off = 8; off; off >>= 1) ssum += __shfl_xor(ssum, off, 16);
    attn[(bz * 8 + h) * 256 + t] = e / ssum;
}

__global__ __launch_bounds__(256) void av_kernel(const float* __restrict__ attn,
                                                 const unsigned short* __restrict__ V, size_t sv,
                                                 unsigned short* __restrict__ Y, size_t sy)
{
    __shared__ __align__(16) float kv[16][260];
    __shared__ __align__(16) float at[16][16];
    int tile = blockIdx.x, h = blockIdx.y, bz = blockIdx.z;
    int n0 = tile * 256, t = threadIdx.x;
    const unsigned short* vb = V + (size_t)bz * sv + (size_t)(h * 16) * HW_;
    at[t >> 4][t & 15] = attn[(size_t)(bz * 8 + h) * 256 + (t & 15) * 16 + (t >> 4)];
#pragma unroll
    for (int i = 0; i < 4; ++i) {
        int e = t + i * 256;
        int d = e >> 6, nn4 = e & 63;
        ush4 v4 = *(const ush4*)(vb + (size_t)d * HW_ + n0 + nn4 * 4);
#pragma unroll
        for (int j = 0; j < 4; ++j) kv[d][nn4 * 4 + j] = bf2f((unsigned short)v4[j]);
    }
    __syncthreads();
    float acc[16];
#pragma unroll
    for (int cc = 0; cc < 16; ++cc) acc[cc] = 0.f;
#pragma unroll
    for (int d = 0; d < 16; ++d) {
        float kvv = kv[d][t];
        float4 a0 = *(const float4*)&at[d][0];
        float4 a1 = *(const float4*)&at[d][4];
        float4 a2 = *(const float4*)&at[d][8];
        float4 a3 = *(const float4*)&at[d][12];
        acc[0]  += a0.x * kvv; acc[1]  += a0.y * kvv; acc[2]  += a0.z * kvv; acc[3]  += a0.w * kvv;
        acc[4]  += a1.x * kvv; acc[5]  += a1.y * kvv; acc[6]  += a1.z * kvv; acc[7]  += a1.w * kvv;
        acc[8]  += a2.x * kvv; acc[9]  += a2.y * kvv; acc[10] += a2.z * kvv; acc[11] += a2.w * kvv;
        acc[12] += a3.x * kvv; acc[13] += a3.y * kvv; acc[14] += a3.z * kvv; acc[15] += a3.w * kvv;
    }
    unsigned short* yb = Y + (size_t)bz * sy + (size_t)(h * 16) * HW_ + n0 + t;
#pragma unroll
    for (int cc = 0; cc < 16; ++cc) yb[(size_t)cc * HW_] = f2bf(acc[cc]);
}

// ---------------------------------------------------------------- 256-pt radix-2 DIT FFT, 2 rows per 32-lane group
__device__ __forceinline__ void fft_stages2(float2* rowA, float2* rowB, const float2* tw, int lane)
{
#pragma unroll
    for (int s = 1; s <= 8; ++s) {
        const int half = 1 << (s - 1);
#pragma unroll
        for (int r = 0; r < 4; ++r) {
            int jb = lane + r * 32;
            int j = jb & (half - 1);
            int g = jb >> (s - 1);
            int i1 = (g << s) + j;
            float2 w = tw[j << (8 - s)];
            float2 u = rowA[i1];
            float2 q = rowA[i1 + half];
            float2 v = make_float2(q.x * w.x - q.y * w.y, q.x * w.y + q.y * w.x);
            rowA[i1]        = make_float2(u.x + v.x, u.y + v.y);
            rowA[i1 + half] = make_float2(u.x - v.x, u.y - v.y);
            float2 u2 = rowB[i1];
            float2 q2 = rowB[i1 + half];
            float2 v2 = make_float2(q2.x * w.x - q2.y * w.y, q2.x * w.y + q2.y * w.x);
            rowB[i1]        = make_float2(u2.x + v2.x, u2.y + v2.y);
            rowB[i1 + half] = make_float2(u2.x - v2.x, u2.y - v2.y);
        }
        __builtin_amdgcn_wave_barrier();
    }
    __syncthreads();
}

#define PI2_ 6.28318530717958647692f

// bf16 real rows -> transposed packed-bf16 spectrum T[c][k][h]; 16 rows/block
__global__ __launch_bounds__(256) void rfft_rowsT(const unsigned short* __restrict__ X, size_t sx,
                                                  unsigned* __restrict__ T, size_t st)
{
    __shared__ float2 sd[16][256];
    __shared__ float2 tw[128];
    int t = threadIdx.x;
    int bz = blockIdx.y;
    if (t < 128) { float sn, cs; __sincosf(-PI2_ * (float)t * (1.f / 256.f), &sn, &cs); tw[t] = make_float2(cs, sn); }
    size_t r0 = (size_t)blockIdx.x * 16;
    int c = (int)(r0 >> 8), h0 = (int)(r0 & 255);
    const unsigned short* Xb = X + (size_t)bz * sx;
    ush4 v4[4];
#pragma unroll
    for (int ii = 0; ii < 4; ++ii) {
        int e = t + ii * 256;
        int j = e >> 6, i4 = e & 63;
        v4[ii] = *(const ush4*)(Xb + (r0 + j) * 256 + i4 * 4);
    }
#pragma unroll
    for (int ii = 0; ii < 4; ++ii) {
        int e = t + ii * 256;
        int j = e >> 6, i4 = e & 63;
#pragma unroll
        for (int k2 = 0; k2 < 4; ++k2)
            sd[j][__brev((unsigned)(i4 * 4 + k2)) >> 24] = make_float2(bf2f((unsigned short)v4[ii][k2]), 0.f);
    }
    __syncthreads();
    fft_stages2(sd[t >> 5], sd[(t >> 5) + 8], tw, t & 31);
    unsigned* base = T + (size_t)bz * st + (size_t)c * PLANEF_;
    for (int e = t; e < 129 * 16; e += 256) {
        int j = e & 15, k = e >> 4;
        base[(size_t)k * 256 + h0 + j] = pack2bf(sd[j][k]);
    }
}

// forward complex FFT along h; 16 k-rows/block; uint4 I/O
__global__ __launch_bounds__(256) void cfftT_fwd(unsigned* __restrict__ T, size_t st)
{
    __shared__ float2 sd[16][256];
    __shared__ float2 tw[128];
    int t = threadIdx.x;
    int bz = blockIdx.z;
    if (t < 128) { float sn, cs; __sincosf(-PI2_ * (float)t * (1.f / 256.f), &sn, &cs); tw[t] = make_float2(cs, sn); }
    int k0 = blockIdx.x * 16;
    int c = blockIdx.y;
    unsigned* base = T + (size_t)bz * st + (size_t)c * PLANEF_;
    uint4v v4[4];
#pragma unroll
    for (int ii = 0; ii < 4; ++ii) {
        int e = t + ii * 256;
        int j = e >> 6, i4 = e & 63;
        int k = k0 + j;
        if (k < KF_) v4[ii] = *(const uint4v*)(base + (size_t)k * 256 + i4 * 4);
        else v4[ii] = (uint4v){0u, 0u, 0u, 0u};
    }
#pragma unroll
    for (int ii = 0; ii < 4; ++ii) {
        int e = t + ii * 256;
        int j = e >> 6, i4 = e & 63;
#pragma unroll
        for (int q = 0; q < 4; ++q)
            sd[j][__brev((unsigned)(i4 * 4 + q)) >> 24] = upk(v4[ii][q]);
    }
    __syncthreads();
    fft_stages2(sd[t >> 5], sd[(t >> 5) + 8], tw, t & 31);
#pragma unroll
    for (int ii = 0; ii < 4; ++ii) {
        int e = t + ii * 256;
        int j = e >> 6, i4 = e & 63;
        int k = k0 + j;
        if (k < KF_) {
            uint4v o;
#pragma unroll
            for (int q = 0; q < 4; ++q) o[q] = pack2bf(sd[j][i4 * 4 + q]);
            *(uint4v*)(base + (size_t)k * 256 + i4 * 4) = o;
        }
    }
}

// combine(amp,pha bf16) + inverse h-FFT; 16 k-rows/block
__global__ __launch_bounds__(256) void cifft_combine(const unsigned short* __restrict__ amp, size_t sa,
                                                     const unsigned short* __restrict__ pha, size_t sp,
                                                     unsigned* __restrict__ S, size_t ss)
{
    __shared__ float2 sd[16][256];
    __shared__ float2 tw[128];
    int t = threadIdx.x;
    int bz = blockIdx.z;
    if (t < 128) { float sn, cs; __sincosf(PI2_ * (float)t * (1.f / 256.f), &sn, &cs); tw[t] = make_float2(cs, sn); }
    int k0 = blockIdx.x * 16;
    int c = blockIdx.y;
    const unsigned short* ab = amp + (size_t)bz * sa + (size_t)c * PLANEF_;
    const unsigned short* pb = pha + (size_t)bz * sp + (size_t)c * PLANEF_;
    ush4 a4[4], p4[4];
#pragma unroll
    for (int ii = 0; ii < 4; ++ii) {
        int e = t + ii * 256;
        int j = e >> 6, i4 = e & 63;
        int k = k0 + j;
        if (k < KF_) {
            a4[ii] = *(const ush4*)(ab + (size_t)k * 256 + i4 * 4);
            p4[ii] = *(const ush4*)(pb + (size_t)k * 256 + i4 * 4);
        } else {
            a4[ii] = (ush4){0,0,0,0}; p4[ii] = (ush4){0,0,0,0};
        }
    }
#pragma unroll
    for (int ii = 0; ii < 4; ++ii) {
        int e = t + ii * 256;
        int j = e >> 6, i4 = e & 63;
        int k = k0 + j;
#pragma unroll
        for (int q = 0; q < 4; ++q) {
            float2 v = make_float2(0.f, 0.f);
            if (k < KF_) {
                float a = bf2f((unsigned short)a4[ii][q]);
                float p = bf2f((unsigned short)p4[ii][q]);
                float sn, cs;
                __sincosf(p, &sn, &cs);
                v = make_float2(a * cs + 2e-8f, a * sn + 1e-8f);
            }
            sd[j][__brev((unsigned)(i4 * 4 + q)) >> 24] = v;
        }
    }
    __syncthreads();
    fft_stages2(sd[t >> 5], sd[(t >> 5) + 8], tw, t & 31);
    unsigned* base = S + (size_t)bz * ss + (size_t)c * PLANEF_;
    for (int e = t; e < 4096; e += 256) {
        int j = e & 15, h = e >> 4;
        int k = k0 + j;
        if (k < KF_) {
            float2 o = sd[j][h];
            base[(size_t)h * KF_ + k] = pack2bf(make_float2(o.x * (1.f / 256.f), o.y * (1.f / 256.f)));
        }
    }
}

// row-major packed-bf16 spectrum -> 256 real (Hermitian) -> |.| -> bf16; 16 rows/block
__global__ __launch_bounds__(256) void irfft_rows16_abs(const unsigned* __restrict__ S, size_t ss,
                                                        unsigned short* __restrict__ Y, size_t sy)
{
    __shared__ float2 sd[16][256];
    __shared__ float2 tw[128];
    int t = threadIdx.x;
    int bz = blockIdx.y;
    if (t < 128) { float sn, cs; __sincosf(PI2_ * (float)t * (1.f / 256.f), &sn, &cs); tw[t] = make_float2(cs, sn); }
    size_t r0 = (size_t)blockIdx.x * 16;
    const unsigned* Sb = S + (size_t)bz * ss;
    for (int e = t; e < 4096; e += 256) {
        int j = e >> 8, i = e & 255;
        const unsigned* row = Sb + (r0 + j) * 129;
        float2 v;
        if (i < 129) v = upk(row[i]);
        else { float2 w2 = upk(row[256 - i]); v = make_float2(w2.x, -w2.y); }
        sd[j][__brev((unsigned)i) >> 24] = v;
    }
    __syncthreads();
    fft_stages2(sd[t >> 5], sd[(t >> 5) + 8], tw, t & 31);
    unsigned short* Yb = Y + (size_t)bz * sy;
#pragma unroll
    for (int ii = 0; ii < 2; ++ii) {
        int e = t + ii * 256;
        int j = e >> 5, i8 = e & 31;
        ush8 ov;
#pragma unroll
        for (int q = 0; q < 8; ++q) ov[q] = f2bf(fabsf(sd[j][i8 * 8 + q].x * (1.f / 256.f)));
        *(ush8*)(Yb + (r0 + j) * 256 + i8 * 8) = ov;
    }
}

// ---------------------------------------------------------------- host
extern "C" void kernel_launch(void* const* d_in, const int* in_sizes, int n_in,
                              void* d_out, int out_size, void* d_ws, size_t ws_size,
                              hipStream_t stream)
{
    (void)in_sizes; (void)n_in; (void)out_size;
    const float* ms    = (const float*)d_in[0];
    const float* pan   = (const float*)d_in[1];
    const float* ln1w  = (const float*)d_in[2];
    const float* ln1b  = (const float*)d_in[3];
    const float* ln2w  = (const float*)d_in[4];
    const float* ln2b  = (const float*)d_in[5];
    const float* qkvw  = (const float*)d_in[6];
    const float* dww   = (const float*)d_in[7];
    const float* temp  = (const float*)d_in[8];
    const float* projw = (const float*)d_in[9];
    const float* pre1w = (const float*)d_in[10];
    const float* pre1b = (const float*)d_in[11];
    const float* pre2w = (const float*)d_in[12];
    const float* pre2b = (const float*)d_in[13];
    const float* amp1w = (const float*)d_in[14];
    const float* amp1b = (const float*)d_in[15];
    const float* amp2w = (const float*)d_in[16];
    const float* amp2b = (const float*)d_in[17];
    const float* pha1w = (const float*)d_in[18];
    const float* pha1b = (const float*)d_in[19];
    const float* pha2w = (const float*)d_in[20];
    const float* pha2b = (const float*)d_in[21];
    const float* postw = (const float*)d_in[22];
    const float* postb = (const float*)d_in[23];
    const float* pinw  = (const float*)d_in[24];
    const float* poutw = (const float*)d_in[25];

    const size_t SLOT  = 8454144;
    const size_t CHWu  = 8388608;
    const size_t CPFu  = 4227072;
    const size_t SPECu = 4227072;
    const size_t PARAMU = 344064;
    const size_t PARAMF = 273792;

    auto need = [&](int nb, int nslot) -> size_t {
        return 2ull * (67108864ull + (size_t)nb * (size_t)nslot * SLOT + PARAMU) + 4ull * PARAMF + 64;
    };
    int NB; bool FUSED;
    if      (ws_size >= need(4, 5)) { NB = 4; FUSED = true;  }
    else if (ws_size >= need(4, 3)) { NB = 4; FUSED = false; }
    else if (ws_size >= need(2, 5)) { NB = 2; FUSED = true;  }
    else if (ws_size >= need(2, 3)) { NB = 2; FUSED = false; }
    else if (ws_size >= need(1, 5)) { NB = 1; FUSED = true;  }
    else                            { NB = 1; FUSED = false; }
    const int NSLOT = FUSED ? 5 : 3;

    unsigned short* F  = (unsigned short*)d_ws;
    unsigned short* XB = F + 33554432;
    unsigned short* U0 = XB + 33554432;
    unsigned short* U1 = U0 + (size_t)NB * SLOT;
    unsigned short* U2 = U1 + (size_t)NB * SLOT;
    unsigned short* U3 = U2 + (size_t)NB * SLOT;
    unsigned short* U4 = U3 + (size_t)NB * SLOT;
    unsigned short* parU = U0 + (size_t)NB * (size_t)NSLOT * SLOT;
    unsigned short* w_qkv   = parU;
    unsigned short* w_proj  = w_qkv  + 16384;
    unsigned short* w_pre1  = w_proj + 16384;
    unsigned short* w_pre2  = w_pre1 + 16384;
    unsigned short* w_post  = w_pre2 + 16384;
    unsigned short* w_amp1  = w_post + 16384;
    unsigned short* w_pha1  = w_amp1 + 32768;
    unsigned short* w_amp2  = w_pha1 + 32768;
    unsigned short* w_pha2  = w_amp2 + 16384;
    unsigned short* w_pin   = w_pha2 + 16384;
    unsigned short* w_pout2 = w_pin  + 131072;
    float* fpar   = (float*)(w_pout2 + 32768);
    float* ksumP  = fpar;
    float* nqsq   = ksumP + 128;
    float* nksq   = nqsq  + 512;
    float* attnP  = nksq  + 512;
    float* partP  = attnP + 8192;
    float* qkv_ws = partP + 262144;
    float* qkv_bb = qkv_ws + 128;
    float* pin_ws = qkv_bb + 128;
    float* pin_bb = pin_ws + 512;
    float* pinC   = pin_bb + 512;

    float* xout = (float*)d_out;

    auto CVT = [&](const float* src, unsigned short* dst, int n) {
        tobf16_kernel<<<(n + 255) / 256, 256, 0, stream>>>(src, dst, n);
    };
    foldln_kernel<<<128, 128, 0, stream>>>(qkvw, ln1w, ln1b, w_qkv, qkv_ws, qkv_bb, 128);
    foldln_kernel<<<512, 128, 0, stream>>>(pinw, ln2w, ln2b, w_pin, pin_ws, pin_bb, 256);
    CVT(projw, w_proj, 16384);
    CVT(pre1w, w_pre1, 16384); CVT(pre2w, w_pre2, 16384);
    CVT(postw, w_post, 16384);
    CVT(amp1w, w_amp1, 32768); CVT(pha1w, w_pha1, 32768);
    CVT(amp2w, w_amp2, 16384); CVT(pha2w, w_pha2, 16384);
    poutperm_kernel<<<128, 256, 0, stream>>>(poutw, w_pout2);
    pinc_kernel<<<1, 256, 0, stream>>>(pin_bb, pin_ws, (float4*)pinC);
    ksum_kernel<<<1, 128, 0, stream>>>(dww, ksumP);

    const size_t CHW = (size_t)C_ * HW_;
    const float* NUL = nullptr;

    for (int b0 = 0; b0 < B_; b0 += NB) {
        const float* msb  = ms  + (size_t)b0 * CHW;
        const float* panb = pan + (size_t)b0 * CHW;
        unsigned short* xbf  = XB + (size_t)b0 * CHWu;
        unsigned short* freb = F  + (size_t)b0 * CHWu;
        dim3 gz(512, 1, NB);
        dim3 gzf(258, 1, NB);

        zero2_kernel<<<(NB * 128 + 255) / 256, 256, 0, stream>>>(nqsq, nksq, NB * 128);

        if (FUSED) {
            mconv_dual<<<gz, 256, 0, stream>>>(
                msb, CHW, w_qkv, qkv_ws, qkv_bb, w_pre1, pre1b, U0, U1, SLOT);
            dwconv2<<<dim3(32, 128, NB), 256, 0, stream>>>(U0, SLOT, dww, ksumP, U2, SLOT, nqsq);
            mconv_dual<<<gz, 256, 0, stream>>>(
                panb, CHW, w_qkv, qkv_ws, qkv_bb, w_pre2, pre2b, U0, U3, SLOT);
            dwconv2<<<dim3(32, 128, NB), 256, 0, stream>>>(U0, SLOT, dww, ksumP, U4, SLOT, nksq);
            gram_mfma<<<dim3(32, 8, NB), 256, 0, stream>>>(U2, SLOT, U4, SLOT, partP);
            softmax_kernel<<<dim3(8, NB), 256, 0, stream>>>(partP, nqsq, nksq, temp, attnP);
            av_kernel<<<dim3(256, 8, NB), 256, 0, stream>>>(attnP, U4, SLOT, U0, SLOT);
            mconv2<1, 1, 0, false><<<gz, 256, 0, stream>>>(
                U0, SLOT, w_proj, 128, nullptr, msb, CHW, xbf, CHWu, HW_, 0, NUL, NUL);

            rfft_rowsT<<<dim3(2048, NB), 256, 0, stream>>>(U1, SLOT, (unsigned*)(void*)U0, SPECu);
            cfftT_fwd<<<dim3(9, 128, NB), 256, 0, stream>>>((unsigned*)(void*)U0, SPECu);
            rfft_rowsT<<<dim3(2048, NB), 256, 0, stream>>>(U3, SLOT, (unsigned*)(void*)U2, SPECu);
            cfftT_fwd<<<dim3(9, 128, NB), 256, 0, stream>>>((unsigned*)(void*)U2, SPECu);
            apconv2<<<gzf, 256, 0, stream>>>(
                (const unsigned*)(void*)U0, (const unsigned*)(void*)U2, SPECu,
                w_amp1, w_pha1, w_amp2, w_pha2, amp1b, pha1b, amp2b, pha2b,
                U1, U1 + CPFu, SLOT);
            cifft_combine<<<dim3(9, 128, NB), 256, 0, stream>>>(
                U1, SLOT, U1 + CPFu, SLOT, (unsigned*)(void*)U3, SPECu);
            irfft_rows16_abs<<<dim3(2048, NB), 256, 0, stream>>>((unsigned*)(void*)U3, SPECu, U0, SLOT);
            mconv2<1, 1, 0, false><<<gz, 256, 0, stream>>>(
                U0, SLOT, w_post, 128, postb, nullptr, 0, freb, CHWu, HW_, 0, NUL, NUL);
        } else {
            mconv2<0, 1, 0, true><<<gz, 256, 0, stream>>>(
                msb, CHW, w_qkv, 128, nullptr, nullptr, 0, U0, SLOT, HW_, 0, qkv_ws, qkv_bb);
            dwconv2<<<dim3(32, 128, NB), 256, 0, stream>>>(U0, SLOT, dww, ksumP, U1, SLOT, nqsq);
            mconv2<0, 1, 0, true><<<gz, 256, 0, stream>>>(
                panb, CHW, w_qkv, 128, nullptr, nullptr, 0, U0, SLOT, HW_, 0, qkv_ws, qkv_bb);
            dwconv2<<<dim3(32, 128, NB), 256, 0, stream>>>(U0, SLOT, dww, ksumP, U2, SLOT, nksq);
            gram_mfma<<<dim3(32, 8, NB), 256, 0, stream>>>(U1, SLOT, U2, SLOT, partP);
            softmax_kernel<<<dim3(8, NB), 256, 0, stream>>>(partP, nqsq, nksq, temp, attnP);
            av_kernel<<<dim3(256, 8, NB), 256, 0, stream>>>(attnP, U2, SLOT, U0, SLOT);
            mconv2<1, 1, 0, false><<<gz, 256, 0, stream>>>(
                U0, SLOT, w_proj, 128, nullptr, msb, CHW, xbf, CHWu, HW_, 0, NUL, NUL);

            mconv2<0, 1, 0, false><<<gz, 256, 0, stream>>>(
                msb, CHW, w_pre1, 128, pre1b, nullptr, 0, U0, SLOT, HW_, 1, NUL, NUL);
            rfft_rowsT<<<dim3(2048, NB), 256, 0, stream>>>(U0, SLOT, (unsigned*)(void*)U1, SPECu);
            cfftT_fwd<<<dim3(9, 128, NB), 256, 0, stream>>>((unsigned*)(void*)U1, SPECu);
            mconv2<0, 1, 0, false><<<gz, 256, 0, stream>>>(
                panb, CHW, w_pre2, 128, pre2b, nullptr, 0, U0, SLOT, HW_, 1, NUL, NUL);
            rfft_rowsT<<<dim3(2048, NB), 256, 0, stream>>>(U0, SLOT, (unsigned*)(void*)U2, SPECu);
            cfftT_fwd<<<dim3(9, 128, NB), 256, 0, stream>>>((unsigned*)(void*)U2, SPECu);
            apconv2<<<gzf, 256, 0, stream>>>(
                (const unsigned*)(void*)U1, (const unsigned*)(void*)U2, SPECu,
                w_amp1, w_pha1, w_amp2, w_pha2, amp1b, pha1b, amp2b, pha2b,
                U0, U0 + CPFu, SLOT);
            cifft_combine<<<dim3(9, 128, NB), 256, 0, stream>>>(
                U0, SLOT, U0 + CPFu, SLOT, (unsigned*)(void*)U2, SPECu);
            irfft_rows16_abs<<<dim3(2048, NB), 256, 0, stream>>>((unsigned*)(void*)U2, SPECu, U0, SLOT);
            mconv2<1, 1, 0, false><<<gz, 256, 0, stream>>>(
                U0, SLOT, w_post, 128, postb, nullptr, 0, freb, CHWu, HW_, 0, NUL, NUL);
        }
    }

    // ---- FFN (full batch, LN2 + gelu-gate fused, x bf16, nontemporal f32 out) ----
    ffn_mfma8<<<dim3(HW_ / 64, B_), 256, 0, stream>>>(XB, F, w_pin, w_pout2, (const float4*)pinC, xout);
}

// Round 16
// 1483.394 us; speedup vs baseline: 1.3705x; 1.0471x over previous
//
#include <hip/hip_runtime.h>
#include <math.h>

#define B_ 4
#define C_ 128
#define HW_ 65536
#define H__ 256
#define KF_ 129
#define PLANEF_ 33024

typedef __attribute__((ext_vector_type(8))) short short8v;
typedef __attribute__((ext_vector_type(4))) float f32x4;
typedef __attribute__((ext_vector_type(4))) unsigned short ush4;
typedef __attribute__((ext_vector_type(8))) unsigned short ush8;
typedef __attribute__((ext_vector_type(4))) unsigned uint4v;

__device__ __forceinline__ unsigned short f2bf(float f) {
    union { float f; unsigned u; } v; v.f = f;
    return (unsigned short)((v.u + 0x7FFFu + ((v.u >> 16) & 1u)) >> 16);
}
__device__ __forceinline__ float bf2f(unsigned short s) {
    union { unsigned u; float f; } v; v.u = (unsigned)s << 16;
    return v.f;
}
__device__ __forceinline__ unsigned pack2bf(float2 v) {
    return (unsigned)f2bf(v.x) | ((unsigned)f2bf(v.y) << 16);
}
__device__ __forceinline__ float2 upk(unsigned u) {
    return make_float2(bf2f((unsigned short)(u & 0xffff)), bf2f((unsigned short)(u >> 16)));
}
// fast gelu: A&S 7.1.26 erf (|err|<=1.5e-7) with __expf
__device__ __forceinline__ float geluf(float x) {
    float z = 0.70710678118654752f * fabsf(x);
    float t = __fdividef(1.f, fmaf(0.3275911f, z, 1.f));
    float p = fmaf(1.061405429f, t, -1.453152027f);
    p = fmaf(p, t, 1.421413741f);
    p = fmaf(p, t, -0.284496736f);
    p = fmaf(p, t, 0.254829592f);
    p = p * t;
    float erfv = 1.f - p * __expf(-z * z);
    float cdf = (x >= 0.f) ? fmaf(0.5f, erfv, 0.5f) : fmaf(-0.5f, erfv, 0.5f);
    return x * cdf;
}
// fast atan2, poly err ~1e-5 rad
__device__ __forceinline__ float fatan2(float y, float x) {
    float ax = fabsf(x), ay = fabsf(y);
    float mx = fmaxf(ax, ay), mn = fminf(ax, ay);
    float a = __fdividef(mn, fmaxf(mx, 1e-38f));
    float s = a * a;
    float r = fmaf(0.0208351f, s, -0.0851330f);
    r = fmaf(r, s, 0.1801410f);
    r = fmaf(r, s, -0.3302995f);
    r = fmaf(r, s, 0.9998660f);
    r = r * a;
    if (ay > ax) r = 1.57079632679489662f - r;
    if (x < 0.f) r = 3.14159265358979324f - r;
    return copysignf(r, y);
}
// LDS XOR swizzle on byte-offset within row
template<int W>
__device__ __forceinline__ char* swz_ptr(unsigned short (*xs)[W], int px, int cb) {
    return (char*)xs + px * (W * 2) + (cb ^ (((px >> 2) & 7) << 4));
}

// ---------------------------------------------------------------- prep
__global__ __launch_bounds__(256) void tobf16_kernel(const float* __restrict__ src,
                                                     unsigned short* __restrict__ dst, int n)
{
    int i = blockIdx.x * 256 + threadIdx.x;
    if (i < n) dst[i] = f2bf(src[i]);
}

__global__ __launch_bounds__(128) void foldln_kernel(const float* __restrict__ W,
                                                     const float* __restrict__ lnw,
                                                     const float* __restrict__ lnb,
                                                     unsigned short* __restrict__ Wb,
                                                     float* __restrict__ wsum, float* __restrict__ bsum,
                                                     int Cc)
{
    int o = blockIdx.x, t = threadIdx.x;
    float sw = 0.f, sb = 0.f;
    for (int c = t; c < Cc; c += 128) {
        float w = W[(size_t)o * Cc + c];
        float fw = w * lnw[c];
        unsigned short us = f2bf(fw);
        Wb[(size_t)o * Cc + c] = us;
        sw += bf2f(us);
        sb += w * lnb[c];
    }
    __shared__ float r1[128], r2[128];
    r1[t] = sw; r2[t] = sb; __syncthreads();
    for (int st = 64; st; st >>= 1) {
        if (t < st) { r1[t] += r1[t + st]; r2[t] += r2[t + st]; }
        __syncthreads();
    }
    if (!t) { wsum[o] = r1[0]; bsum[o] = r2[0]; }
}

__global__ __launch_bounds__(256) void poutperm_kernel(const float* __restrict__ src,
                                                       unsigned short* __restrict__ dst)
{
    int i = blockIdx.x * 256 + threadIdx.x;   // 32768
    int half = i >> 14, rem = i & 16383, o = rem >> 7, kp = rem & 127;
    int h = (kp >> 5) * 64 + half * 32 + (kp & 31);
    dst[i] = f2bf(src[o * 256 + h]);
}

__global__ void pinc_kernel(const float* __restrict__ bb, const float* __restrict__ ws,
                            float4* __restrict__ pinC)
{
    int i = threadIdx.x;
    if (i < 256) pinC[i] = make_float4(bb[i], ws[i], bb[i + 256], ws[i + 256]);
}

__global__ void ksum_kernel(const float* __restrict__ dw, float* __restrict__ ks)
{
    int c = threadIdx.x;
    if (c < C_) {
        float s = 0.f;
        for (int k = 0; k < 9; ++k) s += dw[c * 9 + k];
        ks[c] = s;
    }
}

__global__ __launch_bounds__(256) void zero2_kernel(float* __restrict__ a, float* __restrict__ b, int n)
{
    int i = blockIdx.x * 256 + threadIdx.x;
    if (i < n) { a[i] = 0.f; b[i] = 0.f; }
}

// ---------------------------------------------------------------- MFMA conv1x1 (CIN=128)
template<int INBF, int OUTBF, int PRO, bool LNF>
__global__ __launch_bounds__(256, 4) void mconv2(
    const void* __restrict__ Xv, size_t sx,
    const unsigned short* __restrict__ Wb, int wstride,
    const float* __restrict__ bias,
    const float* __restrict__ res, size_t sres,
    void* __restrict__ Yv, size_t sy, int plane, int flags,
    const float* __restrict__ wsum, const float* __restrict__ bsum)
{
    __shared__ unsigned short xs[128][136];
    __shared__ float2 lnred[LNF ? 8 : 1][LNF ? 128 : 1];
    __shared__ float2 lnmi[LNF ? 128 : 1];
    const int t = threadIdx.x;
    const int bz = blockIdx.z;
    const int p0 = blockIdx.x * 128;
    const int lane = t & 63;
    const int wr = t >> 7, wc = (t >> 6) & 1;
    const int lr = lane >> 4, lc = lane & 15;

    if constexpr (INBF == 0) {
        const float* Xb = (const float*)Xv + (size_t)bz * sx;
        const int px4 = t & 31;
        float s0 = 0.f, s1 = 0.f, s2v = 0.f, s3 = 0.f;
        float q0 = 0.f, q1 = 0.f, q2 = 0.f, q3 = 0.f;
#pragma unroll
        for (int g = 0; g < 2; ++g) {
            float4 st[8];
#pragma unroll
            for (int i = 0; i < 8; ++i) {
                int e = t + (g * 8 + i) * 256;
                int c = e >> 5;
                st[i] = *(const float4*)(Xb + (size_t)c * plane + p0 + px4 * 4);
            }
#pragma unroll
            for (int i = 0; i < 8; ++i) {
                int e = t + (g * 8 + i) * 256;
                int c = e >> 5;
                float a0 = st[i].x, a1 = st[i].y, a2 = st[i].z, a3 = st[i].w;
                if constexpr (PRO == 1) {
                    a0 = a0 > 0.f ? a0 : 0.1f * a0;
                    a1 = a1 > 0.f ? a1 : 0.1f * a1;
                    a2 = a2 > 0.f ? a2 : 0.1f * a2;
                    a3 = a3 > 0.f ? a3 : 0.1f * a3;
                }
                if constexpr (LNF) {
                    s0 += a0; q0 += a0 * a0;
                    s1 += a1; q1 += a1 * a1;
                    s2v += a2; q2 += a2 * a2;
                    s3 += a3; q3 += a3 * a3;
                }
                *(unsigned short*)swz_ptr(xs, px4 * 4 + 0, 2 * c) = f2bf(a0);
                *(unsigned short*)swz_ptr(xs, px4 * 4 + 1, 2 * c) = f2bf(a1);
                *(unsigned short*)swz_ptr(xs, px4 * 4 + 2, 2 * c) = f2bf(a2);
                *(unsigned short*)swz_ptr(xs, px4 * 4 + 3, 2 * c) = f2bf(a3);
            }
        }
        if constexpr (LNF) {
            lnred[t >> 5][px4 * 4 + 0] = make_float2(s0, q0);
            lnred[t >> 5][px4 * 4 + 1] = make_float2(s1, q1);
            lnred[t >> 5][px4 * 4 + 2] = make_float2(s2v, q2);
            lnred[t >> 5][px4 * 4 + 3] = make_float2(s3, q3);
        }
    } else {
        const unsigned short* Xb = (const unsigned short*)Xv + (size_t)bz * sx;
        ush8 st[8];
#pragma unroll
        for (int i = 0; i < 8; ++i) {
            int e = t + i * 256;
            int c = e >> 4, px8 = e & 15;
            st[i] = *(const ush8*)(Xb + (size_t)c * plane + p0 + px8 * 8);
        }
#pragma unroll
        for (int i = 0; i < 8; ++i) {
            int e = t + i * 256;
            int c = e >> 4, px8 = e & 15;
#pragma unroll
            for (int j = 0; j < 8; ++j) {
                unsigned short us = (unsigned short)st[i][j];
                if constexpr (PRO == 1) {
                    float f = bf2f(us);
                    f = f > 0.f ? f : 0.1f * f;
                    us = f2bf(f);
                }
                *(unsigned short*)swz_ptr(xs, px8 * 8 + j, 2 * c) = us;
            }
        }
    }
    __syncthreads();
    if constexpr (LNF) {
        if (t < 128) {
            float ss = 0.f, qq = 0.f;
#pragma unroll
            for (int j = 0; j < 8; ++j) { float2 a = lnred[j][t]; ss += a.x; qq += a.y; }
            float m = ss * (1.f / 128.f);
            float inv = rsqrtf(qq * (1.f / 128.f) - m * m + 1e-5f);
            lnmi[t] = make_float2(m, inv);
        }
        __syncthreads();
    }

    f32x4 acc[4][4];
#pragma unroll
    for (int mi = 0; mi < 4; ++mi)
#pragma unroll
        for (int ni = 0; ni < 4; ++ni) acc[mi][ni] = (f32x4){0.f, 0.f, 0.f, 0.f};

#pragma unroll
    for (int kk = 0; kk < 128; kk += 32) {
        short8v bfr[4];
#pragma unroll
        for (int ni = 0; ni < 4; ++ni)
            bfr[ni] = *(const short8v*)swz_ptr(xs, wc * 64 + ni * 16 + lc, 2 * (kk + lr * 8));
#pragma unroll
        for (int mi = 0; mi < 4; ++mi) {
            int row = wr * 64 + mi * 16 + lc;
            short8v afr = *(const short8v*)(Wb + (size_t)row * wstride + kk + lr * 8);
#pragma unroll
            for (int ni = 0; ni < 4; ++ni)
                acc[mi][ni] = __builtin_amdgcn_mfma_f32_16x16x32_bf16(afr, bfr[ni], acc[mi][ni], 0, 0, 0);
        }
    }

    float2 mrow[4];
    if constexpr (LNF) {
#pragma unroll
        for (int ni = 0; ni < 4; ++ni) mrow[ni] = lnmi[wc * 64 + ni * 16 + lc];
    }

#pragma unroll
    for (int mi = 0; mi < 4; ++mi) {
        int ob = wr * 64 + mi * 16 + lr * 4;
#pragma unroll
        for (int r = 0; r < 4; ++r) {
            int o = ob + r;
            float bv = 0.f, wso = 0.f;
            if constexpr (LNF) { bv = bsum[o]; wso = wsum[o]; }
            else { if (bias) bv = bias[o]; if (flags & 1) bv += 1e-8f; }
#pragma unroll
            for (int ni = 0; ni < 4; ++ni) {
                int px = wc * 64 + ni * 16 + lc;
                float v;
                if constexpr (LNF) {
                    float m = mrow[ni].x, inv = mrow[ni].y;
                    v = acc[mi][ni][r] * inv + bv - m * inv * wso;
                } else {
                    v = acc[mi][ni][r] + bv;
                }
                if (res) v += res[(size_t)bz * sres + (size_t)o * plane + p0 + px];
                if constexpr (OUTBF == 0) {
                    float* Y = (float*)Yv;
                    Y[(size_t)bz * sy + (size_t)o * plane + p0 + px] = v;
                } else {
                    unsigned short* Y = (unsigned short*)Yv;
                    Y[(size_t)bz * sy + (size_t)o * plane + p0 + px] = f2bf(v);
                }
            }
        }
    }
}

// ---------------------------------------------------------------- fused dual conv1x1: qkv (folded-LN) + pre (bias+1e-8)
__global__ __launch_bounds__(256, 3) void mconv_dual(
    const float* __restrict__ X, size_t sx,
    const unsigned short* __restrict__ Wq,
    const float* __restrict__ q_ws, const float* __restrict__ q_bb,
    const unsigned short* __restrict__ Wp,
    const float* __restrict__ pre_b,
    unsigned short* __restrict__ Y1, unsigned short* __restrict__ Y2, size_t sy)
{
    __shared__ unsigned short xs[128][136];
    __shared__ float2 lnred[8][128];
    __shared__ float2 lnmi[128];
    const int t = threadIdx.x;
    const int bz = blockIdx.z;
    const int p0 = blockIdx.x * 128;
    const int lane = t & 63;
    const int wr = t >> 7, wc = (t >> 6) & 1;
    const int lr = lane >> 4, lc = lane & 15;

    const float* Xb = X + (size_t)bz * sx;
    const int px4 = t & 31;
    float s0 = 0.f, s1 = 0.f, s2v = 0.f, s3 = 0.f;
    float q0 = 0.f, q1 = 0.f, q2 = 0.f, q3 = 0.f;
#pragma unroll
    for (int g = 0; g < 2; ++g) {
        float4 st[8];
#pragma unroll
        for (int i = 0; i < 8; ++i) {
            int e = t + (g * 8 + i) * 256;
            int c = e >> 5;
            st[i] = *(const float4*)(Xb + (size_t)c * HW_ + p0 + px4 * 4);
        }
#pragma unroll
        for (int i = 0; i < 8; ++i) {
            int e = t + (g * 8 + i) * 256;
            int c = e >> 5;
            float a0 = st[i].x, a1 = st[i].y, a2 = st[i].z, a3 = st[i].w;
            s0 += a0; q0 += a0 * a0;
            s1 += a1; q1 += a1 * a1;
            s2v += a2; q2 += a2 * a2;
            s3 += a3; q3 += a3 * a3;
            *(unsigned short*)swz_ptr(xs, px4 * 4 + 0, 2 * c) = f2bf(a0);
            *(unsigned short*)swz_ptr(xs, px4 * 4 + 1, 2 * c) = f2bf(a1);
            *(unsigned short*)swz_ptr(xs, px4 * 4 + 2, 2 * c) = f2bf(a2);
            *(unsigned short*)swz_ptr(xs, px4 * 4 + 3, 2 * c) = f2bf(a3);
        }
    }
    lnred[t >> 5][px4 * 4 + 0] = make_float2(s0, q0);
    lnred[t >> 5][px4 * 4 + 1] = make_float2(s1, q1);
    lnred[t >> 5][px4 * 4 + 2] = make_float2(s2v, q2);
    lnred[t >> 5][px4 * 4 + 3] = make_float2(s3, q3);
    __syncthreads();
    if (t < 128) {
        float ss = 0.f, qq = 0.f;
#pragma unroll
        for (int j = 0; j < 8; ++j) { float2 a = lnred[j][t]; ss += a.x; qq += a.y; }
        float m = ss * (1.f / 128.f);
        float inv = rsqrtf(qq * (1.f / 128.f) - m * m + 1e-5f);
        lnmi[t] = make_float2(m, inv);
    }
    __syncthreads();

    float2 mrow[4];
#pragma unroll
    for (int ni = 0; ni < 4; ++ni) mrow[ni] = lnmi[wc * 64 + ni * 16 + lc];

    {
        f32x4 acc[4][4];
#pragma unroll
        for (int mi = 0; mi < 4; ++mi)
#pragma unroll
            for (int ni = 0; ni < 4; ++ni) acc[mi][ni] = (f32x4){0.f, 0.f, 0.f, 0.f};
#pragma unroll
        for (int kk = 0; kk < 128; kk += 32) {
            short8v bfr[4];
#pragma unroll
            for (int ni = 0; ni < 4; ++ni)
                bfr[ni] = *(const short8v*)swz_ptr(xs, wc * 64 + ni * 16 + lc, 2 * (kk + lr * 8));
#pragma unroll
            for (int mi = 0; mi < 4; ++mi) {
                int row = wr * 64 + mi * 16 + lc;
                short8v afr = *(const short8v*)(Wq + (size_t)row * 128 + kk + lr * 8);
#pragma unroll
                for (int ni = 0; ni < 4; ++ni)
                    acc[mi][ni] = __builtin_amdgcn_mfma_f32_16x16x32_bf16(afr, bfr[ni], acc[mi][ni], 0, 0, 0);
            }
        }
#pragma unroll
        for (int mi = 0; mi < 4; ++mi)
#pragma unroll
            for (int r = 0; r < 4; ++r) {
                int o = wr * 64 + mi * 16 + lr * 4 + r;
                float bv = q_bb[o], wso = q_ws[o];
#pragma unroll
                for (int ni = 0; ni < 4; ++ni) {
                    int px = wc * 64 + ni * 16 + lc;
                    float m = mrow[ni].x, inv = mrow[ni].y;
                    float v = acc[mi][ni][r] * inv + bv - m * inv * wso;
                    Y1[(size_t)bz * sy + (size_t)o * HW_ + p0 + px] = f2bf(v);
                }
            }
    }

    {
        f32x4 acc[4][4];
#pragma unroll
        for (int mi = 0; mi < 4; ++mi)
#pragma unroll
            for (int ni = 0; ni < 4; ++ni) acc[mi][ni] = (f32x4){0.f, 0.f, 0.f, 0.f};
#pragma unroll
        for (int kk = 0; kk < 128; kk += 32) {
            short8v bfr[4];
#pragma unroll
            for (int ni = 0; ni < 4; ++ni)
                bfr[ni] = *(const short8v*)swz_ptr(xs, wc * 64 + ni * 16 + lc, 2 * (kk + lr * 8));
#pragma unroll
            for (int mi = 0; mi < 4; ++mi) {
                int row = wr * 64 + mi * 16 + lc;
                short8v afr = *(const short8v*)(Wp + (size_t)row * 128 + kk + lr * 8);
#pragma unroll
                for (int ni = 0; ni < 4; ++ni)
                    acc[mi][ni] = __builtin_amdgcn_mfma_f32_16x16x32_bf16(afr, bfr[ni], acc[mi][ni], 0, 0, 0);
            }
        }
#pragma unroll
        for (int mi = 0; mi < 4; ++mi)
#pragma unroll
            for (int r = 0; r < 4; ++r) {
                int o = wr * 64 + mi * 16 + lr * 4 + r;
                float bv = pre_b[o] + 1e-8f;
#pragma unroll
                for (int ni = 0; ni < 4; ++ni) {
                    int px = wc * 64 + ni * 16 + lc;
                    Y2[(size_t)bz * sy + (size_t)o * HW_ + p0 + px] = f2bf(acc[mi][ni][r] + bv);
                }
            }
    }
}

// ---------------------------------------------------------------- fused AV-mix + proj conv (replaces av_kernel + proj mconv2)
// Stage V tile -> in-place per-head 16x16 attention mix (each (px,head) chunk owned by one thread)
// -> 128x128 MFMA GEMM with w_proj -> + f32 ms residual -> bf16 x out.
__global__ __launch_bounds__(256, 3) void proj_av(
    const unsigned short* __restrict__ V, size_t sv,
    const float* __restrict__ attn,                 // [bz*8+h][256], A[c][d] at c*16+d
    const unsigned short* __restrict__ Wb,          // w_proj [128][128]
    const float* __restrict__ res, size_t sres,     // ms f32
    unsigned short* __restrict__ Y, size_t sy)
{
    __shared__ unsigned short xs[128][136];
    __shared__ float As[8][16][16];
    const int t = threadIdx.x;
    const int bz = blockIdx.z;
    const int p0 = blockIdx.x * 128;
    const int lane = t & 63;
    const int wr = t >> 7, wc = (t >> 6) & 1;
    const int lr = lane >> 4, lc = lane & 15;

    // ---- stage V (bf16) ----
    {
        const unsigned short* Xb = V + (size_t)bz * sv;
        ush8 st[8];
#pragma unroll
        for (int i = 0; i < 8; ++i) {
            int e = t + i * 256;
            int c = e >> 4, px8 = e & 15;
            st[i] = *(const ush8*)(Xb + (size_t)c * HW_ + p0 + px8 * 8);
        }
#pragma unroll
        for (int i = 0; i < 8; ++i) {
            int e = t + i * 256;
            int c = e >> 4, px8 = e & 15;
#pragma unroll
            for (int j = 0; j < 8; ++j)
                *(unsigned short*)swz_ptr(xs, px8 * 8 + j, 2 * c) = (unsigned short)st[i][j];
        }
    }
    // ---- load attention matrices ----
    for (int e = t; e < 2048; e += 256) {
        int h = e >> 8, cd = e & 255;
        As[h][cd >> 4][cd & 15] = attn[((size_t)(bz * 8 + h)) * 256 + cd];
    }
    __syncthreads();

    // ---- in-place per-(px,head) channel mix: xs[px][h*16+c] = sum_d A[c][d] * V[h*16+d] ----
#pragma unroll
    for (int it = 0; it < 4; ++it) {
        int task = t + it * 256;            // 1024 tasks = 128 px x 8 heads, each owned once
        int px = task & 127, h = task >> 7;
        char* sp0 = swz_ptr(xs, px, 32 * h);
        char* sp1 = swz_ptr(xs, px, 32 * h + 16);
        short8v v0 = *(short8v*)sp0;
        short8v v1 = *(short8v*)sp1;
        float vv[16];
#pragma unroll
        for (int d = 0; d < 8; ++d) {
            vv[d]     = bf2f((unsigned short)v0[d]);
            vv[8 + d] = bf2f((unsigned short)v1[d]);
        }
        short8v o0, o1;
#pragma unroll
        for (int c = 0; c < 8; ++c) {
            float a = 0.f, b2 = 0.f;
#pragma unroll
            for (int d = 0; d < 16; ++d) {
                a  = fmaf(As[h][c][d],     vv[d], a);
                b2 = fmaf(As[h][c + 8][d], vv[d], b2);
            }
            o0[c] = (short)f2bf(a);
            o1[c] = (short)f2bf(b2);
        }
        *(short8v*)sp0 = o0;
        *(short8v*)sp1 = o1;
    }
    __syncthreads();

    // ---- GEMM with w_proj + f32 residual -> bf16 ----
    f32x4 acc[4][4];
#pragma unroll
    for (int mi = 0; mi < 4; ++mi)
#pragma unroll
        for (int ni = 0; ni < 4; ++ni) acc[mi][ni] = (f32x4){0.f, 0.f, 0.f, 0.f};

#pragma unroll
    for (int kk = 0; kk < 128; kk += 32) {
        short8v bfr[4];
#pragma unroll
        for (int ni = 0; ni < 4; ++ni)
            bfr[ni] = *(const short8v*)swz_ptr(xs, wc * 64 + ni * 16 + lc, 2 * (kk + lr * 8));
#pragma unroll
        for (int mi = 0; mi < 4; ++mi) {
            int row = wr * 64 + mi * 16 + lc;
            short8v afr = *(const short8v*)(Wb + (size_t)row * 128 + kk + lr * 8);
#pragma unroll
            for (int ni = 0; ni < 4; ++ni)
                acc[mi][ni] = __builtin_amdgcn_mfma_f32_16x16x32_bf16(afr, bfr[ni], acc[mi][ni], 0, 0, 0);
        }
    }

#pragma unroll
    for (int mi = 0; mi < 4; ++mi)
#pragma unroll
        for (int r = 0; r < 4; ++r) {
            int o = wr * 64 + mi * 16 + lr * 4 + r;
#pragma unroll
            for (int ni = 0; ni < 4; ++ni) {
                int px = wc * 64 + ni * 16 + lc;
                float v = acc[mi][ni][r] + res[(size_t)bz * sres + (size_t)o * HW_ + p0 + px];
                Y[(size_t)bz * sy + (size_t)o * HW_ + p0 + px] = f2bf(v);
            }
        }
}

// ---------------------------------------------------------------- fused amp1+pha1+amp2+pha2 spectral block
__global__ __launch_bounds__(256, 2) void apconv2(
    const unsigned* __restrict__ T1, const unsigned* __restrict__ T2, size_t sT,
    const unsigned short* __restrict__ Wa1, const unsigned short* __restrict__ Wp1,
    const unsigned short* __restrict__ Wa2, const unsigned short* __restrict__ Wp2,
    const float* __restrict__ ba1, const float* __restrict__ bp1,
    const float* __restrict__ ba2, const float* __restrict__ bp2,
    unsigned short* __restrict__ AMP, unsigned short* __restrict__ PHA, size_t sO)
{
    __shared__ __align__(16) unsigned short buf[2][128][72];
    const int t = threadIdx.x;
    const int bz = blockIdx.z;
    const int p0 = blockIdx.x * 128;
    const int lane = t & 63;
    const int wr = t >> 7, wc = (t >> 6) & 1;
    const int lr = lane >> 4, lc = lane & 15;
    const int px2 = t & 63;

    typedef unsigned short (*row72)[72];
    typedef unsigned short (*row144)[144];
    row72 xa = (row72)buf[0];
    row72 xp = (row72)buf[1];
    row144 hb = (row144)&buf[0][0][0];

    f32x4 aa[4][4], ap[4][4];
#pragma unroll
    for (int mi = 0; mi < 4; ++mi)
#pragma unroll
        for (int ni = 0; ni < 4; ++ni) { aa[mi][ni] = (f32x4){0.f,0.f,0.f,0.f}; ap[mi][ni] = (f32x4){0.f,0.f,0.f,0.f}; }

    for (int ch = 0; ch < 256; ch += 64) {
        const unsigned* Ts = ((ch < 128) ? T1 : T2) + (size_t)bz * sT + (size_t)(ch & 127) * PLANEF_;
#pragma unroll
        for (int g = 0; g < 2; ++g) {
            uint2 st[8];
#pragma unroll
            for (int i = 0; i < 8; ++i) {
                int e = t + (g * 8 + i) * 256;
                int c = e >> 6;
                st[i] = *(const uint2*)(Ts + (size_t)c * PLANEF_ + p0 + px2 * 2);
            }
#pragma unroll
            for (int i = 0; i < 8; ++i) {
                int e = t + (g * 8 + i) * 256;
                int c = e >> 6;
                float2 z0 = upk(st[i].x), z1 = upk(st[i].y);
                float m0 = sqrtf(z0.x * z0.x + z0.y * z0.y);
                float m1 = sqrtf(z1.x * z1.x + z1.y * z1.y);
                float a0 = fatan2(z0.y, z0.x);
                float a1 = fatan2(z1.y, z1.x);
                *(unsigned short*)swz_ptr(xa, px2 * 2 + 0, 2 * c) = f2bf(m0);
                *(unsigned short*)swz_ptr(xa, px2 * 2 + 1, 2 * c) = f2bf(m1);
                *(unsigned short*)swz_ptr(xp, px2 * 2 + 0, 2 * c) = f2bf(a0);
                *(unsigned short*)swz_ptr(xp, px2 * 2 + 1, 2 * c) = f2bf(a1);
            }
        }
        __syncthreads();
#pragma unroll
        for (int kk = 0; kk < 64; kk += 32) {
            short8v bfa[4], bfp[4];
#pragma unroll
            for (int ni = 0; ni < 4; ++ni) {
                bfa[ni] = *(const short8v*)swz_ptr(xa, wc * 64 + ni * 16 + lc, 2 * (kk + lr * 8));
                bfp[ni] = *(const short8v*)swz_ptr(xp, wc * 64 + ni * 16 + lc, 2 * (kk + lr * 8));
            }
#pragma unroll
            for (int mi = 0; mi < 4; ++mi) {
                int row = wr * 64 + mi * 16 + lc;
                short8v afa = *(const short8v*)(Wa1 + (size_t)row * 256 + ch + kk + lr * 8);
                short8v afp = *(const short8v*)(Wp1 + (size_t)row * 256 + ch + kk + lr * 8);
#pragma unroll
                for (int ni = 0; ni < 4; ++ni) {
                    aa[mi][ni] = __builtin_amdgcn_mfma_f32_16x16x32_bf16(afa, bfa[ni], aa[mi][ni], 0, 0, 0);
                    ap[mi][ni] = __builtin_amdgcn_mfma_f32_16x16x32_bf16(afp, bfp[ni], ap[mi][ni], 0, 0, 0);
                }
            }
        }
        __syncthreads();
    }

    // ---- stage B (amp) ----
#pragma unroll
    for (int mi = 0; mi < 4; ++mi)
#pragma unroll
        for (int r = 0; r < 4; ++r) {
            int o = wr * 64 + mi * 16 + lr * 4 + r;
            float bva = ba1[o];
#pragma unroll
            for (int ni = 0; ni < 4; ++ni) {
                int px = wc * 64 + ni * 16 + lc;
                float v = aa[mi][ni][r] + bva;
                v = v > 0.f ? v : 0.1f * v;
                *(unsigned short*)swz_ptr(hb, px, 2 * o) = f2bf(v);
            }
        }
    __syncthreads();
    {
        f32x4 acc[4][4];
#pragma unroll
        for (int mi = 0; mi < 4; ++mi)
#pragma unroll
            for (int ni = 0; ni < 4; ++ni) acc[mi][ni] = (f32x4){0.f,0.f,0.f,0.f};
#pragma unroll
        for (int kk = 0; kk < 128; kk += 32) {
            short8v bfr[4];
#pragma unroll
            for (int ni = 0; ni < 4; ++ni)
                bfr[ni] = *(const short8v*)swz_ptr(hb, wc * 64 + ni * 16 + lc, 2 * (kk + lr * 8));
#pragma unroll
            for (int mi = 0; mi < 4; ++mi) {
                int row = wr * 64 + mi * 16 + lc;
                short8v afr = *(const short8v*)(Wa2 + (size_t)row * 128 + kk + lr * 8);
#pragma unroll
                for (int ni = 0; ni < 4; ++ni)
                    acc[mi][ni] = __builtin_amdgcn_mfma_f32_16x16x32_bf16(afr, bfr[ni], acc[mi][ni], 0, 0, 0);
            }
        }
#pragma unroll
        for (int mi = 0; mi < 4; ++mi)
#pragma unroll
            for (int r = 0; r < 4; ++r) {
                int o = wr * 64 + mi * 16 + lr * 4 + r;
                float bv = ba2[o];
#pragma unroll
                for (int ni = 0; ni < 4; ++ni) {
                    int px = wc * 64 + ni * 16 + lc;
                    AMP[(size_t)bz * sO + (size_t)o * PLANEF_ + p0 + px] = f2bf(acc[mi][ni][r] + bv);
                }
            }
    }
    __syncthreads();

    // ---- stage B (pha) ----
#pragma unroll
    for (int mi = 0; mi < 4; ++mi)
#pragma unroll
        for (int r = 0; r < 4; ++r) {
            int o = wr * 64 + mi * 16 + lr * 4 + r;
            float bvp = bp1[o];
#pragma unroll
            for (int ni = 0; ni < 4; ++ni) {
                int px = wc * 64 + ni * 16 + lc;
                float v = ap[mi][ni][r] + bvp;
                v = v > 0.f ? v : 0.1f * v;
                *(unsigned short*)swz_ptr(hb, px, 2 * o) = f2bf(v);
            }
        }
    __syncthreads();
    {
        f32x4 acc[4][4];
#pragma unroll
        for (int mi = 0; mi < 4; ++mi)
#pragma unroll
            for (int ni = 0; ni < 4; ++ni) acc[mi][ni] = (f32x4){0.f,0.f,0.f,0.f};
#pragma unroll
        for (int kk = 0; kk < 128; kk += 32) {
            short8v bfr[4];
#pragma unroll
            for (int ni = 0; ni < 4; ++ni)
                bfr[ni] = *(const short8v*)swz_ptr(hb, wc * 64 + ni * 16 + lc, 2 * (kk + lr * 8));
#pragma unroll
            for (int mi = 0; mi < 4; ++mi) {
                int row = wr * 64 + mi * 16 + lc;
                short8v afr = *(const short8v*)(Wp2 + (size_t)row * 128 + kk + lr * 8);
#pragma unroll
                for (int ni = 0; ni < 4; ++ni)
                    acc[mi][ni] = __builtin_amdgcn_mfma_f32_16x16x32_bf16(afr, bfr[ni], acc[mi][ni], 0, 0, 0);
            }
        }
#pragma unroll
        for (int mi = 0; mi < 4; ++mi)
#pragma unroll
            for (int r = 0; r < 4; ++r) {
                int o = wr * 64 + mi * 16 + lr * 4 + r;
                float bv = bp2[o];
#pragma unroll
                for (int ni = 0; ni < 4; ++ni) {
                    int px = wc * 64 + ni * 16 + lc;
                    PHA[(size_t)bz * sO + (size_t)o * PLANEF_ + p0 + px] = f2bf(acc[mi][ni][r] + bv);
                }
            }
    }
}

// ---------------------------------------------------------------- fused MFMA FFN (x bf16, fre bf16; residual from LDS; direct f32 stores)
__global__ __launch_bounds__(256, 3) void ffn_mfma8(
    const unsigned short* __restrict__ x, const unsigned short* __restrict__ fre,
    const unsigned short* __restrict__ pinb,
    const unsigned short* __restrict__ pout2,
    const float4* __restrict__ pinC,
    float* __restrict__ out)
{
    __shared__ unsigned short xs[64][264];
    __shared__ unsigned short hs[64][136];
    __shared__ float2 muinv[64];
    float2* sred = (float2*)&hs[0][0];
    const int b = blockIdx.y;
    const size_t p0 = (size_t)blockIdx.x * 64;
    const int t = threadIdx.x;
    const int wave = t >> 6, lane = t & 63;
    const int lr = lane >> 4, lc = lane & 15;
    const int px4 = t & 15;

    float s0 = 0.f, s1 = 0.f, s2v = 0.f, s3 = 0.f;
    float q0 = 0.f, q1 = 0.f, q2 = 0.f, q3 = 0.f;
    {
        ush4 stx[8], stf[8];
#pragma unroll
        for (int i = 0; i < 8; ++i) {
            int e = t + i * 256;
            int c = e >> 4;
            stx[i] = *(const ush4*)(x + (size_t)b * 8388608 + (size_t)c * HW_ + p0 + px4 * 4);
        }
#pragma unroll
        for (int i = 0; i < 8; ++i) {
            int e = t + i * 256;
            int c = e >> 4;
            stf[i] = *(const ush4*)(fre + (size_t)b * 8388608 + (size_t)c * HW_ + p0 + px4 * 4);
        }
#pragma unroll
        for (int i = 0; i < 8; ++i) {
            int e = t + i * 256;
            int c = e >> 4;
#pragma unroll
            for (int j = 0; j < 4; ++j) {
                unsigned short us = (unsigned short)stx[i][j];
                float a = bf2f(us);
                s0 += (j == 0) ? a : 0.f; s1 += (j == 1) ? a : 0.f;
                s2v += (j == 2) ? a : 0.f; s3 += (j == 3) ? a : 0.f;
                q0 += (j == 0) ? a * a : 0.f; q1 += (j == 1) ? a * a : 0.f;
                q2 += (j == 2) ? a * a : 0.f; q3 += (j == 3) ? a * a : 0.f;
                *(unsigned short*)swz_ptr(xs, px4 * 4 + j, 2 * c) = us;
            }
        }
#pragma unroll
        for (int i = 0; i < 8; ++i) {
            int e = t + i * 256;
            int c = e >> 4;
#pragma unroll
            for (int j = 0; j < 4; ++j) {
                unsigned short us = (unsigned short)stf[i][j];
                float a = bf2f(us);
                s0 += (j == 0) ? a : 0.f; s1 += (j == 1) ? a : 0.f;
                s2v += (j == 2) ? a : 0.f; s3 += (j == 3) ? a : 0.f;
                q0 += (j == 0) ? a * a : 0.f; q1 += (j == 1) ? a * a : 0.f;
                q2 += (j == 2) ? a * a : 0.f; q3 += (j == 3) ? a * a : 0.f;
                *(unsigned short*)swz_ptr(xs, px4 * 4 + j, 2 * (128 + c)) = us;
            }
        }
    }
    sred[(t >> 4) * 64 + px4 * 4 + 0] = make_float2(s0, q0);
    sred[(t >> 4) * 64 + px4 * 4 + 1] = make_float2(s1, q1);
    sred[(t >> 4) * 64 + px4 * 4 + 2] = make_float2(s2v, q2);
    sred[(t >> 4) * 64 + px4 * 4 + 3] = make_float2(s3, q3);
    __syncthreads();
    if (t < 64) {
        float ss = 0.f, qq = 0.f;
#pragma unroll
        for (int j = 0; j < 16; ++j) { float2 a = sred[j * 64 + t]; ss += a.x; qq += a.y; }
        float m = ss * (1.f / 256.f);
        float inv = rsqrtf(qq * (1.f / 256.f) - m * m + 1e-5f);
        muinv[t] = make_float2(m, inv);
    }
    __syncthreads();

    float2 mrow[4];
#pragma unroll
    for (int ni = 0; ni < 4; ++ni) mrow[ni] = muinv[ni * 16 + lc];

    f32x4 oc[2][4];
#pragma unroll
    for (int mi = 0; mi < 2; ++mi)
#pragma unroll
        for (int ni = 0; ni < 4; ++ni) oc[mi][ni] = (f32x4){0.f, 0.f, 0.f, 0.f};

#pragma unroll
    for (int half = 0; half < 2; ++half) {
        f32x4 a1[2][4], a2[2][4];
#pragma unroll
        for (int mi = 0; mi < 2; ++mi)
#pragma unroll
            for (int ni = 0; ni < 4; ++ni) { a1[mi][ni] = (f32x4){0.f,0.f,0.f,0.f}; a2[mi][ni] = (f32x4){0.f,0.f,0.f,0.f}; }

#pragma unroll
        for (int k0 = 0; k0 < 256; k0 += 32) {
            short8v bfr[4];
#pragma unroll
            for (int ni = 0; ni < 4; ++ni)
                bfr[ni] = *(const short8v*)swz_ptr(xs, ni * 16 + lc, 2 * (k0 + lr * 8));
#pragma unroll
            for (int mi = 0; mi < 2; ++mi) {
                int hrow = wave * 64 + half * 32 + mi * 16 + lc;
                short8v af1 = *(const short8v*)(pinb + (size_t)hrow * 256 + k0 + lr * 8);
                short8v af2 = *(const short8v*)(pinb + (size_t)(hrow + 256) * 256 + k0 + lr * 8);
#pragma unroll
                for (int ni = 0; ni < 4; ++ni) {
                    a1[mi][ni] = __builtin_amdgcn_mfma_f32_16x16x32_bf16(af1, bfr[ni], a1[mi][ni], 0, 0, 0);
                    a2[mi][ni] = __builtin_amdgcn_mfma_f32_16x16x32_bf16(af2, bfr[ni], a2[mi][ni], 0, 0, 0);
                }
            }
        }
        __syncthreads();
#pragma unroll
        for (int mi = 0; mi < 2; ++mi)
#pragma unroll
            for (int r = 0; r < 4; ++r) {
                int ho = wave * 64 + half * 32 + mi * 16 + lr * 4 + r;
                float4 bwc = pinC[ho];
                int kp = wave * 32 + mi * 16 + lr * 4 + r;
#pragma unroll
                for (int ni = 0; ni < 4; ++ni) {
                    float m = mrow[ni].x, inv = mrow[ni].y;
                    float v1 = a1[mi][ni][r] * inv + bwc.x - m * inv * bwc.y;
                    float v2 = a2[mi][ni][r] * inv + bwc.z - m * inv * bwc.w;
                    hs[ni * 16 + lc][kp] = f2bf(geluf(v1) * v2);
                }
            }
        __syncthreads();
#pragma unroll
        for (int k0 = 0; k0 < 128; k0 += 32) {
            short8v bfr2[4];
#pragma unroll
            for (int ni = 0; ni < 4; ++ni)
                bfr2[ni] = *(const short8v*)&hs[ni * 16 + lc][k0 + lr * 8];
#pragma unroll
            for (int mi = 0; mi < 2; ++mi) {
                int orow = wave * 32 + mi * 16 + lc;
                short8v af = *(const short8v*)(pout2 + half * 16384 + orow * 128 + k0 + lr * 8);
#pragma unroll
                for (int ni = 0; ni < 4; ++ni)
                    oc[mi][ni] = __builtin_amdgcn_mfma_f32_16x16x32_bf16(af, bfr2[ni], oc[mi][ni], 0, 0, 0);
            }
        }
    }

#pragma unroll
    for (int mi = 0; mi < 2; ++mi)
#pragma unroll
        for (int r = 0; r < 4; ++r) {
            int o = wave * 32 + mi * 16 + lr * 4 + r;
#pragma unroll
            for (int ni = 0; ni < 4; ++ni) {
                int px = ni * 16 + lc;
                float rx = bf2f(*(const unsigned short*)swz_ptr(xs, px, 2 * o));
                size_t yi = ((size_t)b * 128 + o) * HW_ + p0 + px;
                out[yi] = oc[mi][ni][r] + rx;
            }
        }
}

// ---------------------------------------------------------------- depthwise 3x3 cd-conv (bf16), 8 px/thread, fused ssq
__global__ __launch_bounds__(256) void dwconv2(const unsigned short* __restrict__ X, size_t sx,
                                               const float* __restrict__ w9,
                                               const float* __restrict__ ksum,
                                               unsigned short* __restrict__ Y, size_t sy,
                                               float* __restrict__ ssq)
{
    int bz = blockIdx.z;
    int c = blockIdx.y;
    int p8 = blockIdx.x * 256 + threadIdx.x;
    int p0 = p8 * 8;
    int i = p0 >> 8, j0 = p0 & 255;
    const unsigned short* xp = X + (size_t)bz * sx + (size_t)c * HW_;
    const float* wc = w9 + c * 9;
    float a[8] = {0.f,0.f,0.f,0.f,0.f,0.f,0.f,0.f};
    float ctr[8];
#pragma unroll
    for (int di = -1; di <= 1; ++di) {
        int ii = i + di;
        if (ii < 0 || ii > 255) continue;
        const unsigned short* row = xp + ii * 256;
        ush8 m8 = *(const ush8*)(row + j0);
        float lft = (j0 > 0) ? bf2f(row[j0 - 1]) : 0.f;
        float rgt = (j0 < 248) ? bf2f(row[j0 + 8]) : 0.f;
        float v[10];
        v[0] = lft;
#pragma unroll
        for (int k = 0; k < 8; ++k) v[k + 1] = bf2f((unsigned short)m8[k]);
        v[9] = rgt;
        if (di == 0) {
#pragma unroll
            for (int k = 0; k < 8; ++k) ctr[k] = v[k + 1];
        }
        float w0 = wc[(di + 1) * 3], w1 = wc[(di + 1) * 3 + 1], w2 = wc[(di + 1) * 3 + 2];
#pragma unroll
        for (int k = 0; k < 8; ++k) a[k] += w0 * v[k] + w1 * v[k + 1] + w2 * v[k + 2];
    }
    float km = 0.7f * ksum[c];
    ush8 ov;
    float q = 0.f;
#pragma unroll
    for (int k = 0; k < 8; ++k) {
        float o = a[k] - km * ctr[k];
        ov[k] = f2bf(o);
        q += o * o;
    }
    *(ush8*)(Y + (size_t)bz * sy + (size_t)c * HW_ + p0) = ov;

    __shared__ float red[256];
    red[threadIdx.x] = q; __syncthreads();
    for (int st = 128; st; st >>= 1) {
        if (threadIdx.x < st) red[threadIdx.x] += red[threadIdx.x + st];
        __syncthreads();
    }
    if (!threadIdx.x) atomicAdd(&ssq[bz * C_ + c], red[0]);
}

// ---------------------------------------------------------------- MFMA Gram: part[sl] = Q_h K_h^T over n-slice (direct global frags)
__global__ __launch_bounds__(256) void gram_mfma(const unsigned short* __restrict__ Q, size_t sq,
                                                 const unsigned short* __restrict__ K, size_t sk,
                                                 float* __restrict__ part)
{
    int sl = blockIdx.x, h = blockIdx.y, bz = blockIdx.z;
    const unsigned short* qb = Q + (size_t)bz * sq + (size_t)(h * 16) * HW_;
    const unsigned short* kb = K + (size_t)bz * sk + (size_t)(h * 16) * HW_;
    const int t = threadIdx.x;
    const int w = t >> 6, lane = t & 63;
    const int cr = lane & 15;
    const int kg = lane >> 4;

    f32x4 acc = (f32x4){0.f, 0.f, 0.f, 0.f};
    const int nbase0 = sl * 2048 + w * 512;
#pragma unroll 4
    for (int step = 0; step < 16; ++step) {
        int nb = nbase0 + step * 32 + kg * 8;
        short8v aq = *(const short8v*)(qb + (size_t)cr * HW_ + nb);
        short8v bk = *(const short8v*)(kb + (size_t)cr * HW_ + nb);
        acc = __builtin_amdgcn_mfma_f32_16x16x32_bf16(aq, bk, acc, 0, 0, 0);
    }

    __shared__ float red[4][256];
#pragma unroll
    for (int r = 0; r < 4; ++r)
        red[w][((lane >> 4) * 4 + r) * 16 + cr] = acc[r];
    __syncthreads();
    if (t < 256) {
        float s = red[0][t] + red[1][t] + red[2][t] + red[3][t];
        part[((size_t)(bz * 8 + h) * 32 + sl) * 256 + t] = s;
    }
}

__global__ __launch_bounds__(256) void softmax_kernel(const float* __restrict__ part,
                                                      const float* __restrict__ nqsq,
                                                      const float* __restrict__ nksq,
                                                      const float* __restrict__ temp,
                                                      float* __restrict__ attn)
{
    int h = blockIdx.x, bz = blockIdx.y;
    int t = threadIdx.x;
    int c = t >> 4, d = t & 15;
    float g = 0.f;
    for (int sl = 0; sl < 32; ++sl) g += part[((size_t)(bz * 8 + h) * 32 + sl) * 256 + t];
    float nqv = fmaxf(sqrtf(nqsq[bz * C_ + h * 16 + c]), 1e-12f);
    float nkv = fmaxf(sqrtf(nksq[bz * C_ + h * 16 + d]), 1e-12f);
    g *= temp[h] / (nqv * nkv);
    float m = g;
#pragma unroll
    for (int off = 8; off; off >>= 1) m = fmaxf(m, __shfl_xor(m, off, 16));
    float e = __expf(g - m);
    float ssum = e;
#pragma unroll
    for (int off = 8; off; off >>= 1) ssum += __shfl_xor(ssum, off, 16);
    attn[(bz * 8 + h) * 256 + t] = e / ssum;
}

// ---------------------------------------------------------------- 256-pt radix-2 DIT FFT, 2 rows per 32-lane group
__device__ __forceinline__ void fft_stages2(float2* rowA, float2* rowB, const float2* tw, int lane)
{
#pragma unroll
    for (int s = 1; s <= 8; ++s) {
        const int half = 1 << (s - 1);
#pragma unroll
        for (int r = 0; r < 4; ++r) {
            int jb = lane + r * 32;
            int j = jb & (half - 1);
            int g = jb >> (s - 1);
            int i1 = (g << s) + j;
            float2 w = tw[j << (8 - s)];
            float2 u = rowA[i1];
            float2 q = rowA[i1 + half];
            float2 v = make_float2(q.x * w.x - q.y * w.y, q.x * w.y + q.y * w.x);
            rowA[i1]        = make_float2(u.x + v.x, u.y + v.y);
            rowA[i1 + half] = make_float2(u.x - v.x, u.y - v.y);
            float2 u2 = rowB[i1];
            float2 q2 = rowB[i1 + half];
            float2 v2 = make_float2(q2.x * w.x - q2.y * w.y, q2.x * w.y + q2.y * w.x);
            rowB[i1]        = make_float2(u2.x + v2.x, u2.y + v2.y);
            rowB[i1 + half] = make_float2(u2.x - v2.x, u2.y - v2.y);
        }
        __builtin_amdgcn_wave_barrier();
    }
    __syncthreads();
}

#define PI2_ 6.28318530717958647692f

// bf16 real rows -> transposed packed-bf16 spectrum T[c][k][h]; 16 rows/block
__global__ __launch_bounds__(256) void rfft_rowsT(const unsigned short* __restrict__ X, size_t sx,
                                                  unsigned* __restrict__ T, size_t st)
{
    __shared__ float2 sd[16][256];
    __shared__ float2 tw[128];
    int t = threadIdx.x;
    int bz = blockIdx.y;
    if (t < 128) { float sn, cs; __sincosf(-PI2_ * (float)t * (1.f / 256.f), &sn, &cs); tw[t] = make_float2(cs, sn); }
    size_t r0 = (size_t)blockIdx.x * 16;
    int c = (int)(r0 >> 8), h0 = (int)(r0 & 255);
    const unsigned short* Xb = X + (size_t)bz * sx;
    ush4 v4[4];
#pragma unroll
    for (int ii = 0; ii < 4; ++ii) {
        int e = t + ii * 256;
        int j = e >> 6, i4 = e & 63;
        v4[ii] = *(const ush4*)(Xb + (r0 + j) * 256 + i4 * 4);
    }
#pragma unroll
    for (int ii = 0; ii < 4; ++ii) {
        int e = t + ii * 256;
        int j = e >> 6, i4 = e & 63;
#pragma unroll
        for (int k2 = 0; k2 < 4; ++k2)
            sd[j][__brev((unsigned)(i4 * 4 + k2)) >> 24] = make_float2(bf2f((unsigned short)v4[ii][k2]), 0.f);
    }
    __syncthreads();
    fft_stages2(sd[t >> 5], sd[(t >> 5) + 8], tw, t & 31);
    unsigned* base = T + (size_t)bz * st + (size_t)c * PLANEF_;
    for (int e = t; e < 129 * 16; e += 256) {
        int j = e & 15, k = e >> 4;
        base[(size_t)k * 256 + h0 + j] = pack2bf(sd[j][k]);
    }
}

// forward complex FFT along h; 16 k-rows/block; uint4 I/O
__global__ __launch_bounds__(256) void cfftT_fwd(unsigned* __restrict__ T, size_t st)
{
    __shared__ float2 sd[16][256];
    __shared__ float2 tw[128];
    int t = threadIdx.x;
    int bz = blockIdx.z;
    if (t < 128) { float sn, cs; __sincosf(-PI2_ * (float)t * (1.f / 256.f), &sn, &cs); tw[t] = make_float2(cs, sn); }
    int k0 = blockIdx.x * 16;
    int c = blockIdx.y;
    unsigned* base = T + (size_t)bz * st + (size_t)c * PLANEF_;
    uint4v v4[4];
#pragma unroll
    for (int ii = 0; ii < 4; ++ii) {
        int e = t + ii * 256;
        int j = e >> 6, i4 = e & 63;
        int k = k0 + j;
        if (k < KF_) v4[ii] = *(const uint4v*)(base + (size_t)k * 256 + i4 * 4);
        else v4[ii] = (uint4v){0u, 0u, 0u, 0u};
    }
#pragma unroll
    for (int ii = 0; ii < 4; ++ii) {
        int e = t + ii * 256;
        int j = e >> 6, i4 = e & 63;
#pragma unroll
        for (int q = 0; q < 4; ++q)
            sd[j][__brev((unsigned)(i4 * 4 + q)) >> 24] = upk(v4[ii][q]);
    }
    __syncthreads();
    fft_stages2(sd[t >> 5], sd[(t >> 5) + 8], tw, t & 31);
#pragma unroll
    for (int ii = 0; ii < 4; ++ii) {
        int e = t + ii * 256;
        int j = e >> 6, i4 = e & 63;
        int k = k0 + j;
        if (k < KF_) {
            uint4v o;
#pragma unroll
            for (int q = 0; q < 4; ++q) o[q] = pack2bf(sd[j][i4 * 4 + q]);
            *(uint4v*)(base + (size_t)k * 256 + i4 * 4) = o;
        }
    }
}

// combine(amp,pha bf16) + inverse h-FFT; 16 k-rows/block
__global__ __launch_bounds__(256) void cifft_combine(const unsigned short* __restrict__ amp, size_t sa,
                                                     const unsigned short* __restrict__ pha, size_t sp,
                                                     unsigned* __restrict__ S, size_t ss)
{
    __shared__ float2 sd[16][256];
    __shared__ float2 tw[128];
    int t = threadIdx.x;
    int bz = blockIdx.z;
    if (t < 128) { float sn, cs; __sincosf(PI2_ * (float)t * (1.f / 256.f), &sn, &cs); tw[t] = make_float2(cs, sn); }
    int k0 = blockIdx.x * 16;
    int c = blockIdx.y;
    const unsigned short* ab = amp + (size_t)bz * sa + (size_t)c * PLANEF_;
    const unsigned short* pb = pha + (size_t)bz * sp + (size_t)c * PLANEF_;
    ush4 a4[4], p4[4];
#pragma unroll
    for (int ii = 0; ii < 4; ++ii) {
        int e = t + ii * 256;
        int j = e >> 6, i4 = e & 63;
        int k = k0 + j;
        if (k < KF_) {
            a4[ii] = *(const ush4*)(ab + (size_t)k * 256 + i4 * 4);
            p4[ii] = *(const ush4*)(pb + (size_t)k * 256 + i4 * 4);
        } else {
            a4[ii] = (ush4){0,0,0,0}; p4[ii] = (ush4){0,0,0,0};
        }
    }
#pragma unroll
    for (int ii = 0; ii < 4; ++ii) {
        int e = t + ii * 256;
        int j = e >> 6, i4 = e & 63;
        int k = k0 + j;
#pragma unroll
        for (int q = 0; q < 4; ++q) {
            float2 v = make_float2(0.f, 0.f);
            if (k < KF_) {
                float a = bf2f((unsigned short)a4[ii][q]);
                float p = bf2f((unsigned short)p4[ii][q]);
                float sn, cs;
                __sincosf(p, &sn, &cs);
                v = make_float2(a * cs + 2e-8f, a * sn + 1e-8f);
            }
            sd[j][__brev((unsigned)(i4 * 4 + q)) >> 24] = v;
        }
    }
    __syncthreads();
    fft_stages2(sd[t >> 5], sd[(t >> 5) + 8], tw, t & 31);
    unsigned* base = S + (size_t)bz * ss + (size_t)c * PLANEF_;
    for (int e = t; e < 4096; e += 256) {
        int j = e & 15, h = e >> 4;
        int k = k0 + j;
        if (k < KF_) {
            float2 o = sd[j][h];
            base[(size_t)h * KF_ + k] = pack2bf(make_float2(o.x * (1.f / 256.f), o.y * (1.f / 256.f)));
        }
    }
}

// row-major packed-bf16 spectrum -> 256 real (Hermitian) -> |.| -> bf16; 16 rows/block
__global__ __launch_bounds__(256) void irfft_rows16_abs(const unsigned* __restrict__ S, size_t ss,
                                                        unsigned short* __restrict__ Y, size_t sy)
{
    __shared__ float2 sd[16][256];
    __shared__ float2 tw[128];
    int t = threadIdx.x;
    int bz = blockIdx.y;
    if (t < 128) { float sn, cs; __sincosf(PI2_ * (float)t * (1.f / 256.f), &sn, &cs); tw[t] = make_float2(cs, sn); }
    size_t r0 = (size_t)blockIdx.x * 16;
    const unsigned* Sb = S + (size_t)bz * ss;
    for (int e = t; e < 4096; e += 256) {
        int j = e >> 8, i = e & 255;
        const unsigned* row = Sb + (r0 + j) * 129;
        float2 v;
        if (i < 129) v = upk(row[i]);
        else { float2 w2 = upk(row[256 - i]); v = make_float2(w2.x, -w2.y); }
        sd[j][__brev((unsigned)i) >> 24] = v;
    }
    __syncthreads();
    fft_stages2(sd[t >> 5], sd[(t >> 5) + 8], tw, t & 31);
    unsigned short* Yb = Y + (size_t)bz * sy;
#pragma unroll
    for (int ii = 0; ii < 2; ++ii) {
        int e = t + ii * 256;
        int j = e >> 5, i8 = e & 31;
        ush8 ov;
#pragma unroll
        for (int q = 0; q < 8; ++q) ov[q] = f2bf(fabsf(sd[j][i8 * 8 + q].x * (1.f / 256.f)));
        *(ush8*)(Yb + (r0 + j) * 256 + i8 * 8) = ov;
    }
}

// ---------------------------------------------------------------- host
extern "C" void kernel_launch(void* const* d_in, const int* in_sizes, int n_in,
                              void* d_out, int out_size, void* d_ws, size_t ws_size,
                              hipStream_t stream)
{
    (void)in_sizes; (void)n_in; (void)out_size;
    const float* ms    = (const float*)d_in[0];
    const float* pan   = (const float*)d_in[1];
    const float* ln1w  = (const float*)d_in[2];
    const float* ln1b  = (const float*)d_in[3];
    const float* ln2w  = (const float*)d_in[4];
    const float* ln2b  = (const float*)d_in[5];
    const float* qkvw  = (const float*)d_in[6];
    const float* dww   = (const float*)d_in[7];
    const float* temp  = (const float*)d_in[8];
    const float* projw = (const float*)d_in[9];
    const float* pre1w = (const float*)d_in[10];
    const float* pre1b = (const float*)d_in[11];
    const float* pre2w = (const float*)d_in[12];
    const float* pre2b = (const float*)d_in[13];
    const float* amp1w = (const float*)d_in[14];
    const float* amp1b = (const float*)d_in[15];
    const float* amp2w = (const float*)d_in[16];
    const float* amp2b = (const float*)d_in[17];
    const float* pha1w = (const float*)d_in[18];
    const float* pha1b = (const float*)d_in[19];
    const float* pha2w = (const float*)d_in[20];
    const float* pha2b = (const float*)d_in[21];
    const float* postw = (const float*)d_in[22];
    const float* postb = (const float*)d_in[23];
    const float* pinw  = (const float*)d_in[24];
    const float* poutw = (const float*)d_in[25];

    const size_t SLOT  = 8454144;
    const size_t CHWu  = 8388608;
    const size_t CPFu  = 4227072;
    const size_t SPECu = 4227072;
    const size_t PARAMU = 344064;
    const size_t PARAMF = 273792;

    auto need = [&](int nb, int nslot) -> size_t {
        return 2ull * (67108864ull + (size_t)nb * (size_t)nslot * SLOT + PARAMU) + 4ull * PARAMF + 64;
    };
    int NB; bool FUSED;
    if      (ws_size >= need(4, 5)) { NB = 4; FUSED = true;  }
    else if (ws_size >= need(4, 3)) { NB = 4; FUSED = false; }
    else if (ws_size >= need(2, 5)) { NB = 2; FUSED = true;  }
    else if (ws_size >= need(2, 3)) { NB = 2; FUSED = false; }
    else if (ws_size >= need(1, 5)) { NB = 1; FUSED = true;  }
    else                            { NB = 1; FUSED = false; }
    const int NSLOT = FUSED ? 5 : 3;

    unsigned short* F  = (unsigned short*)d_ws;
    unsigned short* XB = F + 33554432;
    unsigned short* U0 = XB + 33554432;
    unsigned short* U1 = U0 + (size_t)NB * SLOT;
    unsigned short* U2 = U1 + (size_t)NB * SLOT;
    unsigned short* U3 = U2 + (size_t)NB * SLOT;
    unsigned short* U4 = U3 + (size_t)NB * SLOT;
    unsigned short* parU = U0 + (size_t)NB * (size_t)NSLOT * SLOT;
    unsigned short* w_qkv   = parU;
    unsigned short* w_proj  = w_qkv  + 16384;
    unsigned short* w_pre1  = w_proj + 16384;
    unsigned short* w_pre2  = w_pre1 + 16384;
    unsigned short* w_post  = w_pre2 + 16384;
    unsigned short* w_amp1  = w_post + 16384;
    unsigned short* w_pha1  = w_amp1 + 32768;
    unsigned short* w_amp2  = w_pha1 + 32768;
    unsigned short* w_pha2  = w_amp2 + 16384;
    unsigned short* w_pin   = w_pha2 + 16384;
    unsigned short* w_pout2 = w_pin  + 131072;
    float* fpar   = (float*)(w_pout2 + 32768);
    float* ksumP  = fpar;
    float* nqsq   = ksumP + 128;
    float* nksq   = nqsq  + 512;
    float* attnP  = nksq  + 512;
    float* partP  = attnP + 8192;
    float* qkv_ws = partP + 262144;
    float* qkv_bb = qkv_ws + 128;
    float* pin_ws = qkv_bb + 128;
    float* pin_bb = pin_ws + 512;
    float* pinC   = pin_bb + 512;

    float* xout = (float*)d_out;

    auto CVT = [&](const float* src, unsigned short* dst, int n) {
        tobf16_kernel<<<(n + 255) / 256, 256, 0, stream>>>(src, dst, n);
    };
    foldln_kernel<<<128, 128, 0, stream>>>(qkvw, ln1w, ln1b, w_qkv, qkv_ws, qkv_bb, 128);
    foldln_kernel<<<512, 128, 0, stream>>>(pinw, ln2w, ln2b, w_pin, pin_ws, pin_bb, 256);
    CVT(projw, w_proj, 16384);
    CVT(pre1w, w_pre1, 16384); CVT(pre2w, w_pre2, 16384);
    CVT(postw, w_post, 16384);
    CVT(amp1w, w_amp1, 32768); CVT(pha1w, w_pha1, 32768);
    CVT(amp2w, w_amp2, 16384); CVT(pha2w, w_pha2, 16384);
    poutperm_kernel<<<128, 256, 0, stream>>>(poutw, w_pout2);
    pinc_kernel<<<1, 256, 0, stream>>>(pin_bb, pin_ws, (float4*)pinC);
    ksum_kernel<<<1, 128, 0, stream>>>(dww, ksumP);

    const size_t CHW = (size_t)C_ * HW_;
    const float* NUL = nullptr;

    for (int b0 = 0; b0 < B_; b0 += NB) {
        const float* msb  = ms  + (size_t)b0 * CHW;
        const float* panb = pan + (size_t)b0 * CHW;
        unsigned short* xbf  = XB + (size_t)b0 * CHWu;
        unsigned short* freb = F  + (size_t)b0 * CHWu;
        dim3 gz(512, 1, NB);
        dim3 gzf(258, 1, NB);

        zero2_kernel<<<(NB * 128 + 255) / 256, 256, 0, stream>>>(nqsq, nksq, NB * 128);

        if (FUSED) {
            mconv_dual<<<gz, 256, 0, stream>>>(
                msb, CHW, w_qkv, qkv_ws, qkv_bb, w_pre1, pre1b, U0, U1, SLOT);
            dwconv2<<<dim3(32, 128, NB), 256, 0, stream>>>(U0, SLOT, dww, ksumP, U2, SLOT, nqsq);
            mconv_dual<<<gz, 256, 0, stream>>>(
                panb, CHW, w_qkv, qkv_ws, qkv_bb, w_pre2, pre2b, U0, U3, SLOT);
            dwconv2<<<dim3(32, 128, NB), 256, 0, stream>>>(U0, SLOT, dww, ksumP, U4, SLOT, nksq);
            gram_mfma<<<dim3(32, 8, NB), 256, 0, stream>>>(U2, SLOT, U4, SLOT, partP);
            softmax_kernel<<<dim3(8, NB), 256, 0, stream>>>(partP, nqsq, nksq, temp, attnP);
            proj_av<<<gz, 256, 0, stream>>>(U4, SLOT, attnP, w_proj, msb, CHW, xbf, CHWu);

            rfft_rowsT<<<dim3(2048, NB), 256, 0, stream>>>(U1, SLOT, (unsigned*)(void*)U0, SPECu);
            cfftT_fwd<<<dim3(9, 128, NB), 256, 0, stream>>>((unsigned*)(void*)U0, SPECu);
            rfft_rowsT<<<dim3(2048, NB), 256, 0, stream>>>(U3, SLOT, (unsigned*)(void*)U2, SPECu);
            cfftT_fwd<<<dim3(9, 128, NB), 256, 0, stream>>>((unsigned*)(void*)U2, SPECu);
            apconv2<<<gzf, 256, 0, stream>>>(
                (const unsigned*)(void*)U0, (const unsigned*)(void*)U2, SPECu,
                w_amp1, w_pha1, w_amp2, w_pha2, amp1b, pha1b, amp2b, pha2b,
                U1, U1 + CPFu, SLOT);
            cifft_combine<<<dim3(9, 128, NB), 256, 0, stream>>>(
                U1, SLOT, U1 + CPFu, SLOT, (unsigned*)(void*)U3, SPECu);
            irfft_rows16_abs<<<dim3(2048, NB), 256, 0, stream>>>((unsigned*)(void*)U3, SPECu, U0, SLOT);
            mconv2<1, 1, 0, false><<<gz, 256, 0, stream>>>(
                U0, SLOT, w_post, 128, postb, nullptr, 0, freb, CHWu, HW_, 0, NUL, NUL);
        } else {
            mconv2<0, 1, 0, true><<<gz, 256, 0, stream>>>(
                msb, CHW, w_qkv, 128, nullptr, nullptr, 0, U0, SLOT, HW_, 0, qkv_ws, qkv_bb);
            dwconv2<<<dim3(32, 128, NB), 256, 0, stream>>>(U0, SLOT, dww, ksumP, U1, SLOT, nqsq);
            mconv2<0, 1, 0, true><<<gz, 256, 0, stream>>>(
                panb, CHW, w_qkv, 128, nullptr, nullptr, 0, U0, SLOT, HW_, 0, qkv_ws, qkv_bb);
            dwconv2<<<dim3(32, 128, NB), 256, 0, stream>>>(U0, SLOT, dww, ksumP, U2, SLOT, nksq);
            gram_mfma<<<dim3(32, 8, NB), 256, 0, stream>>>(U1, SLOT, U2, SLOT, partP);
            softmax_kernel<<<dim3(8, NB), 256, 0, stream>>>(partP, nqsq, nksq, temp, attnP);
            proj_av<<<gz, 256, 0, stream>>>(U2, SLOT, attnP, w_proj, msb, CHW, xbf, CHWu);

            mconv2<0, 1, 0, false><<<gz, 256, 0, stream>>>(
                msb, CHW, w_pre1, 128, pre1b, nullptr, 0, U0, SLOT, HW_, 1, NUL, NUL);
            rfft_rowsT<<<dim3(2048, NB), 256, 0, stream>>>(U0, SLOT, (unsigned*)(void*)U1, SPECu);
            cfftT_fwd<<<dim3(9, 128, NB), 256, 0, stream>>>((unsigned*)(void*)U1, SPECu);
            mconv2<0, 1, 0, false><<<gz, 256, 0, stream>>>(
                panb, CHW, w_pre2, 128, pre2b, nullptr, 0, U0, SLOT, HW_, 1, NUL, NUL);
            rfft_rowsT<<<dim3(2048, NB), 256, 0, stream>>>(U0, SLOT, (unsigned*)(void*)U2, SPECu);
            cfftT_fwd<<<dim3(9, 128, NB), 256, 0, stream>>>((unsigned*)(void*)U2, SPECu);
            apconv2<<<gzf, 256, 0, stream>>>(
                (const unsigned*)(void*)U1, (const unsigned*)(void*)U2, SPECu,
                w_amp1, w_pha1, w_amp2, w_pha2, amp1b, pha1b, amp2b, pha2b,
                U0, U0 + CPFu, SLOT);
            cifft_combine<<<dim3(9, 128, NB), 256, 0, stream>>>(
                U0, SLOT, U0 + CPFu, SLOT, (unsigned*)(void*)U2, SPECu);
            irfft_rows16_abs<<<dim3(2048, NB), 256, 0, stream>>>((unsigned*)(void*)U2, SPECu, U0, SLOT);
            mconv2<1, 1, 0, false><<<gz, 256, 0, stream>>>(
                U0, SLOT, w_post, 128, postb, nullptr, 0, freb, CHWu, HW_, 0, NUL, NUL);
        }
    }

    // ---- FFN (full batch, LN2 + gelu-gate fused, x bf16, direct f32 out) ----
    ffn_mfma8<<<dim3(HW_ / 64, B_), 256, 0, stream>>>(XB, F, w_pin, w_pout2, (const float4*)pinC, xout);
}